// Round 6
// baseline (2526.869 us; speedup 1.0000x reference)
//
#include <hip/hip_runtime.h>
#include <cstdint>

#define NPTS 2048
#define BATCH 8
#define KNN 40

__device__ __forceinline__ float lrelu(float v){ return fmaxf(v, 0.2f*v); }
__device__ __forceinline__ bool better(float v1,int i1,float v2,int i2){
  return (v1>v2) || (v1==v2 && i1<i2);
}
__device__ __forceinline__ float4 ld4(const float* p){ return *(const float4*)p; }

// insert (d,m) into sorted-desc 8-list if it beats the tail; static CE chain.
#define INSERT8(v,id,d,m) \
  if (better(d, m, v[7], id[7])){ \
    v[7]=d; id[7]=m; \
    { if (better(v[7],id[7],v[6],id[6])){ float tv=v[6];int ti=id[6]; v[6]=v[7];id[6]=id[7]; v[7]=tv;id[7]=ti; } } \
    { if (better(v[6],id[6],v[5],id[5])){ float tv=v[5];int ti=id[5]; v[5]=v[6];id[5]=id[6]; v[6]=tv;id[6]=ti; } } \
    { if (better(v[5],id[5],v[4],id[4])){ float tv=v[4];int ti=id[4]; v[4]=v[5];id[4]=id[5]; v[5]=tv;id[5]=ti; } } \
    { if (better(v[4],id[4],v[3],id[3])){ float tv=v[3];int ti=id[3]; v[3]=v[4];id[3]=id[4]; v[4]=tv;id[4]=ti; } } \
    { if (better(v[3],id[3],v[2],id[2])){ float tv=v[2];int ti=id[2]; v[2]=v[3];id[2]=id[3]; v[3]=tv;id[3]=ti; } } \
    { if (better(v[2],id[2],v[1],id[1])){ float tv=v[1];int ti=id[1]; v[1]=v[2];id[1]=id[2]; v[2]=tv;id[2]=ti; } } \
    { if (better(v[1],id[1],v[0],id[0])){ float tv=v[0];int ti=id[0]; v[0]=v[1];id[0]=id[1]; v[1]=tv;id[1]=ti; } } \
  }

// ---------------- generic transpose: dst[c*R+r] = src[r*ld+off+c] ----------------
__global__ void transpose_kernel(const float* __restrict__ src, float* __restrict__ dst,
                                 int R, int C, int ld, int off){
  int i = blockIdx.x*256 + threadIdx.x;
  if (i < R*C){ int r = i / C, c = i % C; dst[c*R + r] = src[r*ld + off + c]; }
}

// ---------------- squared norms, rows layout (B,3,N) ----------------
template<int TAG>
__global__ void norms_rows_kernel(const float* __restrict__ x, float* __restrict__ xx, int N){
  int b = blockIdx.y; int n = blockIdx.x*256 + threadIdx.x;
  const float* xb = x + (size_t)b*3*N;
  float v0 = xb[n], v1 = xb[N+n], v2 = xb[2*N+n];
  xx[(size_t)b*N + n] = v0*v0 + v1*v1 + v2*v2;
}

// ---------------- squared norms, channel-last 64ch slice of (B,N,192) ----------------
template<int TAG>
__global__ void norms_cl_kernel(const float* __restrict__ f, int off, float* __restrict__ xx, int N){
  int b = blockIdx.y; int n = blockIdx.x*256 + threadIdx.x;
  const float4* p = (const float4*)(f + ((size_t)b*N + n)*192 + off);
  float s = 0.f;
#pragma unroll
  for (int q=0;q<16;q++){ float4 v = p[q]; s += v.x*v.x + v.y*v.y + v.z*v.z + v.w*v.w; }
  xx[(size_t)b*N + n] = s;
}

__device__ __forceinline__ void sort8(float (&v)[8], int (&id)[8]){
#define CE(a,bq) { if (better(v[bq],id[bq],v[a],id[a])){ float tv=v[a]; int ti=id[a]; v[a]=v[bq]; id[a]=id[bq]; v[bq]=tv; id[bq]=ti; } }
  CE(0,1) CE(2,3) CE(4,5) CE(6,7)
  CE(0,2) CE(1,3) CE(4,6) CE(5,7)
  CE(1,2) CE(5,6)
  CE(0,4) CE(1,5) CE(2,6) CE(3,7)
  CE(2,4) CE(3,5)
  CE(1,2) CE(3,4) CE(5,6)
#undef CE
}

// ---------------- knn 3-channel: 4 queries/block (1/wave), zero LDS, zero barriers ----------------
// Insertion top-8 during dist; 40-round butterfly extraction; rare refill recomputes.
template<int TAG>
__global__ __launch_bounds__(256) void knn3_kernel(
    const float* __restrict__ xrows, const float* __restrict__ xx,
    int* __restrict__ idxT, int N){
  const int b = blockIdx.y, tid = threadIdx.x;
  const int w = tid>>6, lane = tid&63;
  const int nq = blockIdx.x*4 + w;
  const float* xb = xrows + (size_t)b*3*N;
  const float* xxb = xx + (size_t)b*N;
  float c0 = xb[nq], c1 = xb[N+nq], c2 = xb[2*N+nq];
  float xxn = xxb[nq];
  float v[8]; int id[8];
#pragma unroll
  for (int j=0;j<8;j++){ v[j]=-__builtin_inff(); id[j]=0x7FFFFFFF; }
  for (int j=0;j<32;j++){
    int m = j*64 + lane;
    float s = c0*xb[m] + c1*xb[N+m] + c2*xb[2*N+m];
    float d = 2.f*s - xxn - xxb[m];
    INSERT8(v, id, d, m)
  }
  float lastv = 0.f; int lasti = 0;
  int win = 0;
  for (int r=0;r<KNN;r++){
    float bv = v[0]; int bi = id[0];
#pragma unroll
    for (int off=32; off; off>>=1){
      float ov = __shfl_xor(bv, off);
      int   oi = __shfl_xor(bi, off);
      if (better(ov, oi, bv, bi)){ bv = ov; bi = oi; }
    }
    if (lane == r) win = bi;
    if (id[0] == bi){
      lastv = v[0]; lasti = id[0];
#pragma unroll
      for (int j=0;j<7;j++){ v[j]=v[j+1]; id[j]=id[j+1]; }
      v[7] = -__builtin_inff(); id[7] = 0x7FFFFFFF;
      if (id[0] == 0x7FFFFFFF){   // rare refill: best strictly worse than last pop
        float nv = -__builtin_inff(); int ni = 0x7FFFFFFF;
        for (int j=0;j<32;j++){
          int m = j*64 + lane;
          float s = c0*xb[m] + c1*xb[N+m] + c2*xb[2*N+m];
          float dd = 2.f*s - xxn - xxb[m];
          if (better(lastv, lasti, dd, m) && better(dd, m, nv, ni)){ nv=dd; ni=m; }
        }
        v[0] = nv; id[0] = ni;
      }
    }
  }
  if (lane < KNN) idxT[((size_t)b*KNN + lane)*N + nq] = win;
}

// ---------------- knn 64-channel (channel-last), 4 waves x 2 queries/wave ----------------
// v7: DS-issue-bound fix. R5(v6) structure (32-cand tile, channel-half lane pairs,
// shfl_xor(32) combine, LDS strips, post-hoc top-8, pop extraction, rare LDS refill)
// but each wave serves TWO queries from the same ds_read stream:
//   - candidate ds_reads / staging writes / barriers PER QUERY halve (the measured
//     bottleneck: ~205us of b128 DS issue per dispatch at D=1).
//   - ctr regs: 2 queries x 8 float4 (channel half) = 64 VGPR.
//   - LDS = 8K cand + 4 waves x 2 strips x 8K = 72KB -> 2 blocks/CU (not exact fit).
// Distances bit-identical to v6 (same fmaf split/order). Extraction runs twice.
template<int TAG>
__global__ __launch_bounds__(256) void knn64_kernel(
    const float* __restrict__ featT, int featOff,
    const float* __restrict__ xx, int* __restrict__ idxT, int N){
  const int b = blockIdx.y, tid = threadIdx.x;
  const int w = tid>>6, lane = tid&63;
  __shared__ float cand[32*64];    // xor-swizzled [cand][ch] tile (8 KiB), block-shared
  __shared__ float dist[8*2048];   // 4 waves x 2 wave-private strips (64 KiB)
  const float* fb = featT + featOff;
  const float* xxb = xx + (size_t)b*N;
  const int nq0 = blockIdx.x*8 + w*2;       // this wave's query pair
  const int h = lane>>5;                    // channel half this lane covers
  float4 ctrA[8], ctrB[8];
  {
    const float4* cpA = (const float4*)(fb + ((size_t)b*N + nq0    )*192);
    const float4* cpB = (const float4*)(fb + ((size_t)b*N + nq0 + 1)*192);
#pragma unroll
    for (int q=0;q<8;q++){ ctrA[q] = cpA[h*8 + q]; ctrB[q] = cpB[h*8 + q]; }
  }
  float xxnA = xxb[nq0], xxnB = xxb[nq0+1];
  float* dw0 = &dist[(w*2  )*2048];
  float* dw1 = &dist[(w*2+1)*2048];
  float4 g[2];
#pragma unroll
  for (int r=0;r<2;r++){
    int k2 = tid + 256*r;
    int c = k2>>4, f = k2&15;
    g[r] = ld4(&fb[((size_t)b*N + c)*192 + 4*f]);
  }
  const int cc = lane&31, swz = cc&15, qb = h*8;
  for (int t=0;t<64;t++){
    __syncthreads();                 // prev compute done reading cand
#pragma unroll
    for (int r=0;r<2;r++){
      int k2 = tid + 256*r;
      int c = k2>>4, f = k2&15;
      *(float4*)&cand[(c<<6) + ((f ^ (c&15))<<2)] = g[r];
    }
    __syncthreads();
    if (t+1 < 64){                   // issue next tile's loads; latency overlaps compute
      int m0n = (t+1)*32;
#pragma unroll
      for (int r=0;r<2;r++){
        int k2 = tid + 256*r;
        int c = k2>>4, f = k2&15;
        g[r] = ld4(&fb[((size_t)b*N + m0n + c)*192 + 4*f]);
      }
    }
    float a0=0.f,a1=0.f,a2=0.f,a3=0.f;   // query A partials
    float b0=0.f,b1=0.f,b2=0.f,b3=0.f;   // query B partials
#pragma unroll
    for (int j=0;j<8;j++){
      float4 mv = *(const float4*)&cand[(cc<<6) + (((qb + j) ^ swz)<<2)];
      a0 = fmaf(ctrA[j].x, mv.x, a0);
      a1 = fmaf(ctrA[j].y, mv.y, a1);
      a2 = fmaf(ctrA[j].z, mv.z, a2);
      a3 = fmaf(ctrA[j].w, mv.w, a3);
      b0 = fmaf(ctrB[j].x, mv.x, b0);
      b1 = fmaf(ctrB[j].y, mv.y, b1);
      b2 = fmaf(ctrB[j].z, mv.z, b2);
      b3 = fmaf(ctrB[j].w, mv.w, b3);
    }
    float pA = (a0+a1)+(a2+a3);
    float pB = (b0+b1)+(b2+b3);
    float totA = pA + __shfl_xor(pA, 32);   // combine channel halves
    float totB = pB + __shfl_xor(pB, 32);
    if (h == (t&1)){                        // owner lane (m & 63 == lane) writes strip slots
      int m = t*32 + cc;
      float xxm = xxb[m];
      dw0[(t>>1)*64 + lane] = 2.f*totA - xxnA - xxm;
      dw1[(t>>1)*64 + lane] = 2.f*totB - xxnB - xxm;
    }
  }
  // ---- per query: per-lane exact top-8 + 40 extraction rounds (barrier-free) ----
  for (int qq=0; qq<2; qq++){
    float* dwq = (qq==0) ? dw0 : dw1;
    float v[8]; int id[8];
#pragma unroll
    for (int j=0;j<8;j++){ v[j]=dwq[j*64+lane]; id[j]=j*64+lane; }
    sort8(v, id);
#pragma unroll
    for (int gq=1; gq<4; gq++){
      float a[8]; int ai[8];
#pragma unroll
      for (int j=0;j<8;j++){ a[j]=dwq[(gq*8+j)*64+lane]; ai[j]=(gq*8+j)*64+lane; }
      sort8(a, ai);
      float m_[8]; int mi_[8];
#pragma unroll
      for (int k=0;k<8;k++){
        if (better(a[7-k], ai[7-k], v[k], id[k])){ m_[k]=a[7-k]; mi_[k]=ai[7-k]; }
        else                                     { m_[k]=v[k];   mi_[k]=id[k]; }
      }
#define CEB(x,y) { if (better(m_[y],mi_[y],m_[x],mi_[x])){ float tv=m_[x];int ti=mi_[x]; m_[x]=m_[y];mi_[x]=mi_[y]; m_[y]=tv;mi_[y]=ti; } }
      CEB(0,4) CEB(1,5) CEB(2,6) CEB(3,7)
      CEB(0,2) CEB(1,3) CEB(4,6) CEB(5,7)
      CEB(0,1) CEB(2,3) CEB(4,5) CEB(6,7)
#undef CEB
#pragma unroll
      for (int k=0;k<8;k++){ v[k]=m_[k]; id[k]=mi_[k]; }
    }
    float lastv = 0.f; int lasti = 0;
    int win = 0;
    for (int r=0;r<KNN;r++){
      float bv = v[0]; int bi = id[0];
#pragma unroll
      for (int off=32; off; off>>=1){
        float ov = __shfl_xor(bv, off);
        int   oi = __shfl_xor(bi, off);
        if (better(ov, oi, bv, bi)){ bv = ov; bi = oi; }
      }
      if (lane == r) win = bi;
      if (id[0] == bi){                // unique owner (indices unique)
        lastv = v[0]; lasti = id[0];
#pragma unroll
        for (int j=0;j<7;j++){ v[j]=v[j+1]; id[j]=id[j+1]; }
        v[7] = -__builtin_inff(); id[7] = 0x7FFFFFFF;
        if (id[0] == 0x7FFFFFFF){      // rare: lane contributed >8 of top-40 -> refill head
          float nv = -__builtin_inff(); int ni = 0x7FFFFFFF;
          for (int j=0;j<32;j++){
            float vv = dwq[j*64 + lane]; int m = j*64 + lane;
            if (better(lastv, lasti, vv, m) && better(vv, m, nv, ni)){ nv=vv; ni=m; }
          }
          v[0] = nv; id[0] = ni;
        }
      }
    }
    if (lane < KNN) idxT[((size_t)b*KNN + lane)*N + nq0 + qq] = win;
  }
}

// ==================== register-tiled edge kernels ====================

// ---- edgeA (t-path): 3ch -> 64 -> 128, max over k ----
// v2: 4 waves x 16 points; stage2 tiled as 4 panels o=p*32+oq*4 (conflict-free w2T reads).
__global__ __launch_bounds__(256) void edgeA_kernel(
    const float* __restrict__ x, const int* __restrict__ idxT,
    const float* __restrict__ w1, const float* __restrict__ w2,
    float* __restrict__ tT, int N){
  __shared__ float w1aT[3*64];
  __shared__ float wd3T[3*64];
  __shared__ float w2T[64*128];      // [c][o]; reused as merge buffer (4 x 16r x 128o)
  __shared__ float aT3[4][3*16];
  __shared__ float s1T[4][64*16];    // [c][r]
  const int tid = threadIdx.x, w = tid>>6, lane = tid&63;
  const int oq = lane&7, rg = lane>>3;
  const int o0 = oq*8, r0 = rg*2;
  const int b = blockIdx.y, n0 = blockIdx.x*16;
  for (int i=tid; i<192; i+=256){
    int o = i&63, c = i/64;
    float a = w1[o*6+c];
    w1aT[c*64+o] = a; wd3T[c*64+o] = w1[o*6+3+c] - a;
  }
  for (int i=tid; i<128*64; i+=256){
    int o = i>>6, c = i&63;
    w2T[c*128+o] = w2[o*64+c];
  }
  if (tid < 48){ int c = tid>>4, r = tid&15; aT3[0][c*16+r] = x[((size_t)b*3+c)*N + n0 + r]; }
  __syncthreads();
  float base[16];
#pragma unroll
  for (int i=0;i<16;i++) base[i]=0.f;
#pragma unroll
  for (int c=0;c<3;c++){
    float4 wA = ld4(&wd3T[c*64+o0]), wB = ld4(&wd3T[c*64+o0+4]);
    float2 av = *(const float2*)&aT3[0][c*16+r0];
    float wv[8] = {wA.x,wA.y,wA.z,wA.w,wB.x,wB.y,wB.z,wB.w};
    float rv[2] = {av.x,av.y};
#pragma unroll
    for (int oo=0;oo<8;oo++)
#pragma unroll
      for (int rr=0;rr<2;rr++) base[oo*2+rr] = fmaf(wv[oo], rv[rr], base[oo*2+rr]);
  }
  __syncthreads();   // all waves done reading aT3[0] before k-loop overwrites
  float mx[32];
#pragma unroll
  for (int i=0;i<32;i++) mx[i] = -__builtin_inff();
  for (int it=0; it<10; it++){
    int k = it*4 + w;
    int m = idxT[((size_t)b*KNN + k)*N + n0 + (lane&15)];
    if (lane < 48){ int c = lane>>4; aT3[w][c*16 + (lane&15)] = x[((size_t)b*3+c)*N + m]; }
    // stage1 (64 o x 16 r)
    float acc[16];
#pragma unroll
    for (int i=0;i<16;i++) acc[i] = base[i];
#pragma unroll
    for (int c=0;c<3;c++){
      float4 wA = ld4(&w1aT[c*64+o0]), wB = ld4(&w1aT[c*64+o0+4]);
      float2 av = *(const float2*)&aT3[w][c*16+r0];
      float wv[8] = {wA.x,wA.y,wA.z,wA.w,wB.x,wB.y,wB.z,wB.w};
      float rv[2] = {av.x,av.y};
#pragma unroll
      for (int oo=0;oo<8;oo++)
#pragma unroll
        for (int rr=0;rr<2;rr++) acc[oo*2+rr] = fmaf(wv[oo], rv[rr], acc[oo*2+rr]);
    }
#pragma unroll
    for (int oo=0;oo<8;oo++){
      float2 sv; sv.x = lrelu(acc[oo*2]); sv.y = lrelu(acc[oo*2+1]);
      *(float2*)&s1T[w][(o0+oo)*16 + r0] = sv;
    }
    // stage2 (128 o x 16 r): 4 panels, o = p*32 + oq*4 -> 32 banks, conflict-free
    float acc2[32];
#pragma unroll
    for (int i=0;i<32;i++) acc2[i]=0.f;
    for (int c=0;c<64;c++){
      float2 av = *(const float2*)&s1T[w][c*16 + r0];
#pragma unroll
      for (int p=0;p<4;p++){
        float4 wv = ld4(&w2T[c*128 + p*32 + oq*4]);
        acc2[p*8+0] = fmaf(wv.x, av.x, acc2[p*8+0]);
        acc2[p*8+1] = fmaf(wv.x, av.y, acc2[p*8+1]);
        acc2[p*8+2] = fmaf(wv.y, av.x, acc2[p*8+2]);
        acc2[p*8+3] = fmaf(wv.y, av.y, acc2[p*8+3]);
        acc2[p*8+4] = fmaf(wv.z, av.x, acc2[p*8+4]);
        acc2[p*8+5] = fmaf(wv.z, av.y, acc2[p*8+5]);
        acc2[p*8+6] = fmaf(wv.w, av.x, acc2[p*8+6]);
        acc2[p*8+7] = fmaf(wv.w, av.y, acc2[p*8+7]);
      }
    }
#pragma unroll
    for (int i=0;i<32;i++) mx[i] = fmaxf(mx[i], lrelu(acc2[i]));
  }
  __syncthreads();   // all waves done reading w2T -> reuse as merge buffer
#pragma unroll
  for (int rr=0;rr<2;rr++){
#pragma unroll
    for (int p=0;p<4;p++){
      float4 a = make_float4(mx[p*8+0+rr], mx[p*8+2+rr], mx[p*8+4+rr], mx[p*8+6+rr]);
      *(float4*)&w2T[w*2048 + (r0+rr)*128 + p*32 + oq*4] = a;
    }
  }
  __syncthreads();
  for (int i=tid; i<2048; i+=256){
    float vv = fmaxf(fmaxf(w2T[i], w2T[2048+i]), fmaxf(w2T[4096+i], w2T[6144+i]));
    int r = i>>7, o = i&127;
    tT[((size_t)b*N + n0 + r)*128 + o] = vv;
  }
}

// ---- edgeB: 3ch -> 64 -> 64, max over k ----
__global__ __launch_bounds__(128) void edgeB_kernel(
    const float* __restrict__ xp, const int* __restrict__ idxT,
    const float* __restrict__ w1, const float* __restrict__ w2,
    float* __restrict__ catT, int N){
  __shared__ float w1aT[3*64];
  __shared__ float wd3T[3*64];
  __shared__ float w2T[64*64];
  __shared__ float aT3[2][3*32];
  __shared__ float s1T[2][64*32];
  const int tid = threadIdx.x, w = tid>>6, lane = tid&63;
  const int oq = lane&7, rg = lane>>3;
  const int o0 = oq*8, r0 = rg*4;
  const int b = blockIdx.y, n0 = blockIdx.x*32;
  for (int i=tid; i<192; i+=128){
    int o = i&63, c = i>>6;
    float a = w1[o*6+c], bb = w1[o*6+3+c];
    w1aT[c*64+o] = a; wd3T[c*64+o] = bb - a;
  }
  for (int i=tid; i<64*64; i+=128){
    int o = i>>6, c = i&63;
    w2T[c*64+o] = w2[o*64+c];
  }
  if (tid < 32){
#pragma unroll
    for (int c=0;c<3;c++) aT3[0][c*32+tid] = xp[((size_t)b*3+c)*N + n0 + tid];
  }
  __syncthreads();
  float base[32];
#pragma unroll
  for (int i=0;i<32;i++) base[i]=0.f;
#pragma unroll
  for (int c=0;c<3;c++){
    float4 w0 = ld4(&wd3T[c*64+o0]), w1v = ld4(&wd3T[c*64+o0+4]);
    float4 av = ld4(&aT3[0][c*32+r0]);
    float wv[8] = {w0.x,w0.y,w0.z,w0.w,w1v.x,w1v.y,w1v.z,w1v.w};
    float rv[4] = {av.x,av.y,av.z,av.w};
#pragma unroll
    for (int oo=0;oo<8;oo++)
#pragma unroll
      for (int rr=0;rr<4;rr++) base[oo*4+rr] = fmaf(wv[oo], rv[rr], base[oo*4+rr]);
  }
  __syncthreads();
  float mx[32];
#pragma unroll
  for (int i=0;i<32;i++) mx[i] = -__builtin_inff();
  for (int it=0; it<20; it++){
    int k = it*2 + w;
    {
      int row = lane&31;
      int m = idxT[((size_t)b*KNN + k)*N + n0 + row];
      if (lane < 32){
#pragma unroll
        for (int c=0;c<3;c++) aT3[w][c*32+row] = xp[((size_t)b*3+c)*N + m];
      }
    }
    float acc[32];
#pragma unroll
    for (int i=0;i<32;i++) acc[i] = base[i];
#pragma unroll
    for (int c=0;c<3;c++){
      float4 w0 = ld4(&w1aT[c*64+o0]), w1v = ld4(&w1aT[c*64+o0+4]);
      float4 av = ld4(&aT3[w][c*32+r0]);
      float wv[8] = {w0.x,w0.y,w0.z,w0.w,w1v.x,w1v.y,w1v.z,w1v.w};
      float rv[4] = {av.x,av.y,av.z,av.w};
#pragma unroll
      for (int oo=0;oo<8;oo++)
#pragma unroll
        for (int rr=0;rr<4;rr++) acc[oo*4+rr] = fmaf(wv[oo], rv[rr], acc[oo*4+rr]);
    }
#pragma unroll
    for (int oo=0;oo<8;oo++){
      float4 sv = make_float4(lrelu(acc[oo*4+0]), lrelu(acc[oo*4+1]), lrelu(acc[oo*4+2]), lrelu(acc[oo*4+3]));
      *(float4*)&s1T[w][(o0+oo)*32 + r0] = sv;
    }
    float acc2[32];
#pragma unroll
    for (int i=0;i<32;i++) acc2[i]=0.f;
    for (int c=0;c<64;c++){
      float4 w0 = ld4(&w2T[c*64+o0]), w1v = ld4(&w2T[c*64+o0+4]);
      float4 av = ld4(&s1T[w][c*32+r0]);
      float wv[8] = {w0.x,w0.y,w0.z,w0.w,w1v.x,w1v.y,w1v.z,w1v.w};
      float rv[4] = {av.x,av.y,av.z,av.w};
#pragma unroll
      for (int oo=0;oo<8;oo++)
#pragma unroll
        for (int rr=0;rr<4;rr++) acc2[oo*4+rr] = fmaf(wv[oo], rv[rr], acc2[oo*4+rr]);
    }
#pragma unroll
    for (int i=0;i<32;i++) mx[i] = fmaxf(mx[i], lrelu(acc2[i]));
  }
  __syncthreads();
#pragma unroll
  for (int rr=0;rr<4;rr++){
    float4 a = make_float4(mx[0*4+rr], mx[1*4+rr], mx[2*4+rr], mx[3*4+rr]);
    float4 bq = make_float4(mx[4*4+rr], mx[5*4+rr], mx[6*4+rr], mx[7*4+rr]);
    *(float4*)&s1T[w][(r0+rr)*64 + o0] = a;
    *(float4*)&s1T[w][(r0+rr)*64 + o0 + 4] = bq;
  }
  __syncthreads();
  for (int i=tid; i<2048; i+=128){
    float v = fmaxf(s1T[0][i], s1T[1][i]);
    int r = i>>6, o = i&63;
    catT[((size_t)b*N + n0 + r)*192 + o] = v;
  }
}

// ---- edgeC: 64ch -> 64 -> 64, max over k ----
__global__ __launch_bounds__(128) void edgeC_kernel(
    const float* __restrict__ inT, int inOff, const int* __restrict__ idxT,
    const float* __restrict__ w1, const float* __restrict__ w2,
    float* __restrict__ catT, int outOff, int N){
  __shared__ float w1T[64*64];
  __shared__ float w2T[64*64];
  __shared__ float aT[2][64*32];
  __shared__ float s1T[2][64*32];
  const int tid = threadIdx.x, w = tid>>6, lane = tid&63;
  const int oq = lane&7, rg = lane>>3;
  const int o0 = oq*8, r0 = rg*4;
  const int b = blockIdx.y, n0 = blockIdx.x*32;
  for (int i=tid; i<64*64; i+=128){
    int o = i>>6, c = i&63;
    float a = w1[o*128+c], bb = w1[o*128+64+c];
    w1T[c*64+o] = a; w2T[c*64+o] = bb - a;
  }
  for (int i=tid; i<512; i+=128){
    int p = i>>4, cq = i&15;
    float4 v = ld4(&inT[((size_t)b*N + n0 + p)*192 + inOff + cq*4]);
    aT[0][(cq*4+0)*32+p] = v.x; aT[0][(cq*4+1)*32+p] = v.y;
    aT[0][(cq*4+2)*32+p] = v.z; aT[0][(cq*4+3)*32+p] = v.w;
  }
  __syncthreads();
  float base[32];
#pragma unroll
  for (int i=0;i<32;i++) base[i]=0.f;
  for (int c=0;c<64;c++){
    float4 w0 = ld4(&w2T[c*64+o0]), w1v = ld4(&w2T[c*64+o0+4]);
    float4 av = ld4(&aT[0][c*32+r0]);
    float wv[8] = {w0.x,w0.y,w0.z,w0.w,w1v.x,w1v.y,w1v.z,w1v.w};
    float rv[4] = {av.x,av.y,av.z,av.w};
#pragma unroll
    for (int oo=0;oo<8;oo++)
#pragma unroll
      for (int rr=0;rr<4;rr++) base[oo*4+rr] = fmaf(wv[oo], rv[rr], base[oo*4+rr]);
  }
  __syncthreads();
  for (int i=tid; i<64*64; i+=128){
    int o = i>>6, c = i&63;
    w2T[c*64+o] = w2[o*64+c];
  }
  __syncthreads();
  float mx[32];
#pragma unroll
  for (int i=0;i<32;i++) mx[i] = -__builtin_inff();
  const int row = lane&31, ch = lane>>5;
  for (int it=0; it<20; it++){
    int k = it*2 + w;
    {
      int m = idxT[((size_t)b*KNN + k)*N + n0 + row];
      const float* src = &inT[((size_t)b*N + m)*192 + inOff + ch*32];
      float4 g[8];
#pragma unroll
      for (int j=0;j<8;j++) g[j] = ld4(src + j*4);
#pragma unroll
      for (int j=0;j<8;j++){
        aT[w][(ch*32+j*4+0)*32 + row] = g[j].x;
        aT[w][(ch*32+j*4+1)*32 + row] = g[j].y;
        aT[w][(ch*32+j*4+2)*32 + row] = g[j].z;
        aT[w][(ch*32+j*4+3)*32 + row] = g[j].w;
      }
    }
    float acc[32];
#pragma unroll
    for (int i=0;i<32;i++) acc[i] = base[i];
    for (int c=0;c<64;c++){
      float4 w0 = ld4(&w1T[c*64+o0]), w1v = ld4(&w1T[c*64+o0+4]);
      float4 av = ld4(&aT[w][c*32+r0]);
      float wv[8] = {w0.x,w0.y,w0.z,w0.w,w1v.x,w1v.y,w1v.z,w1v.w};
      float rv[4] = {av.x,av.y,av.z,av.w};
#pragma unroll
      for (int oo=0;oo<8;oo++)
#pragma unroll
        for (int rr=0;rr<4;rr++) acc[oo*4+rr] = fmaf(wv[oo], rv[rr], acc[oo*4+rr]);
    }
#pragma unroll
    for (int oo=0;oo<8;oo++){
      float4 sv = make_float4(lrelu(acc[oo*4+0]), lrelu(acc[oo*4+1]), lrelu(acc[oo*4+2]), lrelu(acc[oo*4+3]));
      *(float4*)&s1T[w][(o0+oo)*32 + r0] = sv;
    }
    float acc2[32];
#pragma unroll
    for (int i=0;i<32;i++) acc2[i]=0.f;
    for (int c=0;c<64;c++){
      float4 w0 = ld4(&w2T[c*64+o0]), w1v = ld4(&w2T[c*64+o0+4]);
      float4 av = ld4(&s1T[w][c*32+r0]);
      float wv[8] = {w0.x,w0.y,w0.z,w0.w,w1v.x,w1v.y,w1v.z,w1v.w};
      float rv[4] = {av.x,av.y,av.z,av.w};
#pragma unroll
      for (int oo=0;oo<8;oo++)
#pragma unroll
        for (int rr=0;rr<4;rr++) acc2[oo*4+rr] = fmaf(wv[oo], rv[rr], acc2[oo*4+rr]);
    }
#pragma unroll
    for (int i=0;i<32;i++) mx[i] = fmaxf(mx[i], lrelu(acc2[i]));
  }
  __syncthreads();
#pragma unroll
  for (int rr=0;rr<4;rr++){
    float4 a = make_float4(mx[0*4+rr], mx[1*4+rr], mx[2*4+rr], mx[3*4+rr]);
    float4 bq = make_float4(mx[4*4+rr], mx[5*4+rr], mx[6*4+rr], mx[7*4+rr]);
    *(float4*)&s1T[w][(r0+rr)*64 + o0] = a;
    *(float4*)&s1T[w][(r0+rr)*64 + o0 + 4] = bq;
  }
  __syncthreads();
  for (int i=tid; i<2048; i+=128){
    float v = fmaxf(s1T[0][i], s1T[1][i]);
    int r = i>>6, o = i&63;
    catT[((size_t)b*N + n0 + r)*192 + outOff + o] = v;
  }
}

// ---- edgeD: 64ch -> 64 (single conv), max over k ----
__global__ __launch_bounds__(128) void edgeD_kernel(
    const float* __restrict__ inT, int inOff, const int* __restrict__ idxT,
    const float* __restrict__ w1, float* __restrict__ catT, int outOff, int N){
  __shared__ float w1T[64*64];
  __shared__ float wdT[64*64];
  __shared__ float aT[2][64*32];
  const int tid = threadIdx.x, w = tid>>6, lane = tid&63;
  const int oq = lane&7, rg = lane>>3;
  const int o0 = oq*8, r0 = rg*4;
  const int b = blockIdx.y, n0 = blockIdx.x*32;
  for (int i=tid; i<64*64; i+=128){
    int o = i>>6, c = i&63;
    float a = w1[o*128+c], bb = w1[o*128+64+c];
    w1T[c*64+o] = a; wdT[c*64+o] = bb - a;
  }
  for (int i=tid; i<512; i+=128){
    int p = i>>4, cq = i&15;
    float4 v = ld4(&inT[((size_t)b*N + n0 + p)*192 + inOff + cq*4]);
    aT[0][(cq*4+0)*32+p] = v.x; aT[0][(cq*4+1)*32+p] = v.y;
    aT[0][(cq*4+2)*32+p] = v.z; aT[0][(cq*4+3)*32+p] = v.w;
  }
  __syncthreads();
  float base[32];
#pragma unroll
  for (int i=0;i<32;i++) base[i]=0.f;
  for (int c=0;c<64;c++){
    float4 w0 = ld4(&wdT[c*64+o0]), w1v = ld4(&wdT[c*64+o0+4]);
    float4 av = ld4(&aT[0][c*32+r0]);
    float wv[8] = {w0.x,w0.y,w0.z,w0.w,w1v.x,w1v.y,w1v.z,w1v.w};
    float rv[4] = {av.x,av.y,av.z,av.w};
#pragma unroll
    for (int oo=0;oo<8;oo++)
#pragma unroll
      for (int rr=0;rr<4;rr++) base[oo*4+rr] = fmaf(wv[oo], rv[rr], base[oo*4+rr]);
  }
  __syncthreads();
  float mx[32];
#pragma unroll
  for (int i=0;i<32;i++) mx[i] = -__builtin_inff();
  const int row = lane&31, ch = lane>>5;
  for (int it=0; it<20; it++){
    int k = it*2 + w;
    {
      int m = idxT[((size_t)b*KNN + k)*N + n0 + row];
      const float* src = &inT[((size_t)b*N + m)*192 + inOff + ch*32];
      float4 g[8];
#pragma unroll
      for (int j=0;j<8;j++) g[j] = ld4(src + j*4);
#pragma unroll
      for (int j=0;j<8;j++){
        aT[w][(ch*32+j*4+0)*32 + row] = g[j].x;
        aT[w][(ch*32+j*4+1)*32 + row] = g[j].y;
        aT[w][(ch*32+j*4+2)*32 + row] = g[j].z;
        aT[w][(ch*32+j*4+3)*32 + row] = g[j].w;
      }
    }
    float acc[32];
#pragma unroll
    for (int i=0;i<32;i++) acc[i] = base[i];
    for (int c=0;c<64;c++){
      float4 w0 = ld4(&w1T[c*64+o0]), w1v = ld4(&w1T[c*64+o0+4]);
      float4 av = ld4(&aT[w][c*32+r0]);
      float wv[8] = {w0.x,w0.y,w0.z,w0.w,w1v.x,w1v.y,w1v.z,w1v.w};
      float rv[4] = {av.x,av.y,av.z,av.w};
#pragma unroll
      for (int oo=0;oo<8;oo++)
#pragma unroll
        for (int rr=0;rr<4;rr++) acc[oo*4+rr] = fmaf(wv[oo], rv[rr], acc[oo*4+rr]);
    }
#pragma unroll
    for (int i=0;i<32;i++) mx[i] = fmaxf(mx[i], lrelu(acc[i]));
  }
  __syncthreads();
#pragma unroll
  for (int rr=0;rr<4;rr++){
    float4 a = make_float4(mx[0*4+rr], mx[1*4+rr], mx[2*4+rr], mx[3*4+rr]);
    float4 bq = make_float4(mx[4*4+rr], mx[5*4+rr], mx[6*4+rr], mx[7*4+rr]);
    *(float4*)&wdT[w*2048 + (r0+rr)*64 + o0] = a;
    *(float4*)&wdT[w*2048 + (r0+rr)*64 + o0 + 4] = bq;
  }
  __syncthreads();
  for (int i=tid; i<2048; i+=128){
    float v = fmaxf(wdT[i], wdT[2048+i]);
    int r = i>>6, o = i&63;
    catT[((size_t)b*N + n0 + r)*192 + outOff + o] = v;
  }
}

// ---------------- conv1 (1024 outs) + lrelu + max -- register-tiled, weights in LDS ----------------
template<int CIN, int TAG>
__global__ __launch_bounds__(128) void convmax_kernel(
    const float* __restrict__ inT, const float* __restrict__ wT,
    float* __restrict__ partial, int N){
  __shared__ float wsh[CIN*64];
  __shared__ float ish[32*CIN];     // [c][32]
  const int tid = threadIdx.x, w = tid>>6, lane = tid&63;
  const int oq = lane&7, rg = lane>>3;
  const int o0 = oq*8, r0 = rg*4;
  const int b = blockIdx.z, oc = blockIdx.x, nt = blockIdx.y;
  for (int i=tid; i<CIN*64; i+=128){
    int c = i>>6, o = i&63;
    wsh[i] = wT[(size_t)c*1024 + oc*64 + o];
  }
  float mx[32];
#pragma unroll
  for (int i=0;i<32;i++) mx[i] = -__builtin_inff();
  const int nbase = nt*(N/8);
  for (int st=0; st<8; st++){
    __syncthreads();
    const float* src = inT + ((size_t)b*N + nbase + st*32)*CIN;
    for (int i=tid; i<32*(CIN/4); i+=128){
      int p = i/(CIN/4), cq = i%(CIN/4);
      float4 v = ld4(src + p*CIN + 4*cq);
      ish[(4*cq+0)*32+p]=v.x; ish[(4*cq+1)*32+p]=v.y;
      ish[(4*cq+2)*32+p]=v.z; ish[(4*cq+3)*32+p]=v.w;
    }
    __syncthreads();
    float acc[32];
#pragma unroll
    for (int i=0;i<32;i++) acc[i]=0.f;
    for (int c=0;c<CIN;c++){
      float4 w0 = ld4(&wsh[c*64+o0]), w1v = ld4(&wsh[c*64+o0+4]);
      float4 av = ld4(&ish[c*32+r0]);
      float wv[8] = {w0.x,w0.y,w0.z,w0.w,w1v.x,w1v.y,w1v.z,w1v.w};
      float rv[4] = {av.x,av.y,av.z,av.w};
#pragma unroll
      for (int oo=0;oo<8;oo++)
#pragma unroll
        for (int rr=0;rr<4;rr++) acc[oo*4+rr] = fmaf(wv[oo], rv[rr], acc[oo*4+rr]);
    }
#pragma unroll
    for (int i=0;i<32;i++) mx[i] = fmaxf(mx[i], lrelu(acc[i]));
  }
  float m8[8];
#pragma unroll
  for (int oo=0;oo<8;oo++)
    m8[oo] = fmaxf(fmaxf(mx[oo*4+0], mx[oo*4+1]), fmaxf(mx[oo*4+2], mx[oo*4+3]));
  __syncthreads();
  *(float4*)&ish[(w*8+rg)*64 + o0]     = make_float4(m8[0],m8[1],m8[2],m8[3]);
  *(float4*)&ish[(w*8+rg)*64 + o0 + 4] = make_float4(m8[4],m8[5],m8[6],m8[7]);
  __syncthreads();
  if (tid < 64){
    float v = -__builtin_inff();
#pragma unroll
    for (int g=0; g<16; g++) v = fmaxf(v, ish[g*64+tid]);
    partial[((size_t)b*8 + nt)*1024 + oc*64 + tid] = v;
  }
}

template<int TAG>
__global__ void reduce_max_kernel(const float* __restrict__ partial, float* __restrict__ out){
  int b = blockIdx.y; int o = blockIdx.x*256 + threadIdx.x;
  float v = -__builtin_inff();
  for (int s=0;s<8;s++) v = fmaxf(v, partial[((size_t)b*8 + s)*1024 + o]);
  out[(size_t)b*1024 + o] = v;
}

// ---------------- small FC ----------------
__global__ void fc_kernel(const float* __restrict__ in, const float* __restrict__ W,
                          const float* __restrict__ bias, float* __restrict__ out,
                          int CI, int O, int act){
  int b = blockIdx.x;
  __shared__ float insh[1024];
  for (int i=threadIdx.x;i<CI;i+=blockDim.x) insh[i]=in[(size_t)b*CI+i];
  __syncthreads();
  for (int o=threadIdx.x;o<O;o+=blockDim.x){
    float s = bias ? bias[o] : 0.f;
    for (int c=0;c<CI;c++) s = fmaf(W[(size_t)o*CI+c], insh[c], s);
    if (act) s = lrelu(s);
    out[(size_t)b*O+o]=s;
  }
}

// ---------------- x' = T^T x per batch ----------------
__global__ void transform_kernel(const float* __restrict__ x, const float* __restrict__ T9,
                                 float* __restrict__ xp, int N){
  int b = blockIdx.y; int n = blockIdx.x*256 + threadIdx.x;
  const float* t = T9 + (size_t)b*9;
  float x0=x[((size_t)b*3+0)*N+n], x1=x[((size_t)b*3+1)*N+n], x2=x[((size_t)b*3+2)*N+n];
#pragma unroll
  for (int i=0;i<3;i++)
    xp[((size_t)b*3+i)*N+n] = t[i]*x0 + t[3+i]*x1 + t[6+i]*x2;
}

// ---------------- bias1: n-invariant part of h1 ----------------
__global__ void bias1_kernel(const float* __restrict__ g, const float* __restrict__ lv,
                             const float* __restrict__ h1w, float* __restrict__ bias1){
  int b = blockIdx.x;
  __shared__ float insh[1088];
  for (int i=threadIdx.x;i<1088;i+=256) insh[i] = (i<1024)? g[(size_t)b*1024+i] : lv[(size_t)b*64 + (i-1024)];
  __syncthreads();
  int o = threadIdx.x;
  float s=0.f;
  for (int c=0;c<1088;c++) s = fmaf(h1w[(size_t)o*1280+c], insh[c], s);
  bias1[(size_t)b*256+o]=s;
}

// ---------------- head conv layers ----------------
template<int CI, int O, bool ACT>
__global__ __launch_bounds__(256) void conv1_kernel(
    const float* __restrict__ inT, const float* __restrict__ wT,
    const float* __restrict__ bias, float* __restrict__ outT, int N){
  const int b = blockIdx.y, n0 = blockIdx.x*32;
  __shared__ float insh[32*CI];
  const float* src = inT + ((size_t)b*N + n0)*CI;
  for (int i=threadIdx.x;i<32*CI;i+=256) insh[i] = src[i];
  __syncthreads();
  constexpr int NREP = 256/O;
  constexpr int NLOC = 32/NREP;
  const int o = threadIdx.x % O, rep = threadIdx.x / O;
  float acc[NLOC];
#pragma unroll
  for (int t=0;t<NLOC;t++) acc[t]=0.f;
  for (int c=0;c<CI;c++){
    float wv = wT[c*O + o];
#pragma unroll
    for (int t=0;t<NLOC;t++) acc[t] = fmaf(wv, insh[(t*NREP+rep)*CI + c], acc[t]);
  }
  float bv = bias ? bias[(size_t)b*O + o] : 0.f;
#pragma unroll
  for (int t=0;t<NLOC;t++){
    float s = acc[t] + bv;
    if (ACT) s = lrelu(s);
    outT[((size_t)b*N + n0 + t*NREP + rep)*O + o] = s;
  }
}

// ---------------- final layer: 128 -> 50, rows-layout output (B,50,N) ----------------
__global__ __launch_bounds__(256) void conv_out_kernel(
    const float* __restrict__ inT, const float* __restrict__ wT,
    float* __restrict__ out, int N){
  const int b = blockIdx.y, n0 = blockIdx.x*32;
  __shared__ float insh[32*129];
  const float* src = inT + ((size_t)b*N + n0)*128;
  for (int i=threadIdx.x;i<32*128;i+=256){ int nn=i>>7, c=i&127; insh[nn*129+c]=src[i]; }
  __syncthreads();
  const int nl = threadIdx.x & 31, og = threadIdx.x >> 5;
  float acc[7];
#pragma unroll
  for (int t=0;t<7;t++) acc[t]=0.f;
  for (int c=0;c<128;c++){
    float iv = insh[nl*129+c];
#pragma unroll
    for (int t=0;t<7;t++){
      int o = og + 8*t;
      float wv = (o<50)? wT[c*50+o] : 0.f;
      acc[t] = fmaf(wv, iv, acc[t]);
    }
  }
#pragma unroll
  for (int t=0;t<7;t++){
    int o = og + 8*t;
    if (o < 50) out[((size_t)b*50+o)*N + n0 + nl] = acc[t];
  }
}

extern "C" void kernel_launch(void* const* d_in, const int* in_sizes, int n_in,
                              void* d_out, int out_size, void* d_ws, size_t ws_size,
                              hipStream_t stream){
  const float* x    = (const float*)d_in[0];
  const float* l    = (const float*)d_in[1];
  const float* t_c1 = (const float*)d_in[2];
  const float* t_c2 = (const float*)d_in[3];
  const float* t_c3 = (const float*)d_in[4];
  const float* t_f1 = (const float*)d_in[5];
  const float* t_f2 = (const float*)d_in[6];
  const float* t_f3w= (const float*)d_in[7];
  const float* t_f3b= (const float*)d_in[8];
  const float* b1a  = (const float*)d_in[9];
  const float* b1b  = (const float*)d_in[10];
  const float* b2a  = (const float*)d_in[11];
  const float* b2b  = (const float*)d_in[12];
  const float* b3a  = (const float*)d_in[13];
  const float* m1   = (const float*)d_in[14];
  const float* m2   = (const float*)d_in[15];
  const float* h1   = (const float*)d_in[16];
  const float* h2   = (const float*)d_in[17];
  const float* h3   = (const float*)d_in[18];
  const float* h4   = (const float*)d_in[19];
  float* out = (float*)d_out;
  float* ws = (float*)d_ws;
  const int N = NPTS, B = BATCH;

  size_t off = 0;
  auto alloc = [&](size_t nf){ float* p = ws + off; off += nf; return p; };
  float* WT_TC3 = alloc((size_t)128*1024);
  float* WT_M1  = alloc((size_t)192*1024);
  float* WT_H1B = alloc((size_t)192*256);
  float* WT_H2  = alloc((size_t)256*256);
  float* WT_H3  = alloc((size_t)256*128);
  float* WT_H4  = alloc((size_t)128*64);
  int*   IDXT   = (int*)alloc((size_t)B*N*KNN);
  float* XX     = alloc((size_t)B*N);
  float* TT     = alloc((size_t)B*N*128);
  float* PARTIAL= alloc((size_t)B*8*1024);
  float* TG     = alloc((size_t)B*1024);
  float* T512   = alloc((size_t)B*512);
  float* T256   = alloc((size_t)B*256);
  float* T9     = alloc((size_t)B*16);
  float* XP     = alloc((size_t)B*3*N);
  float* CATT   = alloc((size_t)B*N*192);
  float* G      = alloc((size_t)B*1024);
  float* LV     = alloc((size_t)B*64);
  float* BIAS1  = alloc((size_t)B*256);
  float* H1T    = alloc((size_t)B*N*256);
  float* H2T    = alloc((size_t)B*N*256);
  float* H3T    = alloc((size_t)B*N*128);
  (void)ws_size; (void)in_sizes; (void)n_in; (void)out_size;

  dim3 blk(256);
  dim3 eblk(128);
  // weight transposes
  transpose_kernel<<<dim3((1024*128+255)/256), blk, 0, stream>>>(t_c3, WT_TC3, 1024,128,128,0);
  transpose_kernel<<<dim3((1024*192+255)/256), blk, 0, stream>>>(m1,  WT_M1, 1024,192,192,0);
  transpose_kernel<<<dim3((256*192+255)/256),  blk, 0, stream>>>(h1, WT_H1B, 256,192,1280,1088);
  transpose_kernel<<<dim3((256*256+255)/256),  blk, 0, stream>>>(h2, WT_H2, 256,256,256,0);
  transpose_kernel<<<dim3((128*256+255)/256),  blk, 0, stream>>>(h3, WT_H3, 128,256,256,0);
  transpose_kernel<<<dim3((50*128+255)/256),   blk, 0, stream>>>(h4, WT_H4, 50,128,128,0);

  // t-path
  norms_rows_kernel<0><<<dim3(N/256,B), blk, 0, stream>>>(x, XX, N);
  knn3_kernel<0><<<dim3(N/4,B), blk, 0, stream>>>(x, XX, IDXT, N);
  edgeA_kernel<<<dim3(N/16,B), blk, 0, stream>>>(x, IDXT, t_c1, t_c2, TT, N);
  convmax_kernel<128,0><<<dim3(16,8,B), eblk, 0, stream>>>(TT, WT_TC3, PARTIAL, N);
  reduce_max_kernel<0><<<dim3(4,B), blk, 0, stream>>>(PARTIAL, TG);
  fc_kernel<<<dim3(B), dim3(512), 0, stream>>>(TG, t_f1, nullptr, T512, 1024, 512, 1);
  fc_kernel<<<dim3(B), dim3(512), 0, stream>>>(T512, t_f2, nullptr, T256, 512, 256, 1);
  fc_kernel<<<dim3(B), dim3(512), 0, stream>>>(T256, t_f3w, t_f3b, T9, 256, 9, 0);
  transform_kernel<<<dim3(N/256,B), blk, 0, stream>>>(x, T9, XP, N);

  // edge block 1 (transformed points, 3ch)
  norms_rows_kernel<1><<<dim3(N/256,B), blk, 0, stream>>>(XP, XX, N);
  knn3_kernel<1><<<dim3(N/4,B), blk, 0, stream>>>(XP, XX, IDXT, N);
  edgeB_kernel<<<dim3(N/32,B), eblk, 0, stream>>>(XP, IDXT, b1a, b1b, CATT, N);

  // edge block 2 (x1 = CATT[...,0:64])
  norms_cl_kernel<0><<<dim3(N/256,B), blk, 0, stream>>>(CATT, 0, XX, N);
  knn64_kernel<0><<<dim3(N/8,B), blk, 0, stream>>>(CATT, 0, XX, IDXT, N);
  edgeC_kernel<<<dim3(N/32,B), eblk, 0, stream>>>(CATT, 0, IDXT, b2a, b2b, CATT, 64, N);

  // edge block 3 (x2 = CATT[...,64:128])
  norms_cl_kernel<1><<<dim3(N/256,B), blk, 0, stream>>>(CATT, 64, XX, N);
  knn64_kernel<1><<<dim3(N/8,B), blk, 0, stream>>>(CATT, 64, XX, IDXT, N);
  edgeD_kernel<<<dim3(N/32,B), eblk, 0, stream>>>(CATT, 64, IDXT, b3a, CATT, 128, N);

  // global feature + head
  convmax_kernel<192,1><<<dim3(16,8,B), eblk, 0, stream>>>(CATT, WT_M1, PARTIAL, N);
  reduce_max_kernel<1><<<dim3(4,B), blk, 0, stream>>>(PARTIAL, G);
  fc_kernel<<<dim3(B), dim3(512), 0, stream>>>(l, m2, nullptr, LV, 16, 64, 1);
  bias1_kernel<<<dim3(B), blk, 0, stream>>>(G, LV, h1, BIAS1);
  conv1_kernel<192,256,true><<<dim3(N/32,B), blk, 0, stream>>>(CATT, WT_H1B, BIAS1, H1T, N);
  conv1_kernel<256,256,true><<<dim3(N/32,B), blk, 0, stream>>>(H1T, WT_H2, nullptr, H2T, N);
  conv1_kernel<256,128,true><<<dim3(N/32,B), blk, 0, stream>>>(H2T, WT_H3, nullptr, H3T, N);
  conv_out_kernel<<<dim3(N/32,B), blk, 0, stream>>>(H3T, WT_H4, out, N);
}

// Round 7
// 2383.814 us; speedup vs baseline: 1.0600x; 1.0600x over previous
//
#include <hip/hip_runtime.h>
#include <cstdint>

#define NPTS 2048
#define BATCH 8
#define KNN 40

__device__ __forceinline__ float lrelu(float v){ return fmaxf(v, 0.2f*v); }
__device__ __forceinline__ bool better(float v1,int i1,float v2,int i2){
  return (v1>v2) || (v1==v2 && i1<i2);
}
__device__ __forceinline__ float4 ld4(const float* p){ return *(const float4*)p; }

// insert (d,m) into sorted-desc 8-list if it beats the tail; static CE chain.
#define INSERT8(v,id,d,m) \
  if (better(d, m, v[7], id[7])){ \
    v[7]=d; id[7]=m; \
    { if (better(v[7],id[7],v[6],id[6])){ float tv=v[6];int ti=id[6]; v[6]=v[7];id[6]=id[7]; v[7]=tv;id[7]=ti; } } \
    { if (better(v[6],id[6],v[5],id[5])){ float tv=v[5];int ti=id[5]; v[5]=v[6];id[5]=id[6]; v[6]=tv;id[6]=ti; } } \
    { if (better(v[5],id[5],v[4],id[4])){ float tv=v[4];int ti=id[4]; v[4]=v[5];id[4]=id[5]; v[5]=tv;id[5]=ti; } } \
    { if (better(v[4],id[4],v[3],id[3])){ float tv=v[3];int ti=id[3]; v[3]=v[4];id[3]=id[4]; v[4]=tv;id[4]=ti; } } \
    { if (better(v[3],id[3],v[2],id[2])){ float tv=v[2];int ti=id[2]; v[2]=v[3];id[2]=id[3]; v[3]=tv;id[3]=ti; } } \
    { if (better(v[2],id[2],v[1],id[1])){ float tv=v[1];int ti=id[1]; v[1]=v[2];id[1]=id[2]; v[2]=tv;id[2]=ti; } } \
    { if (better(v[1],id[1],v[0],id[0])){ float tv=v[0];int ti=id[0]; v[0]=v[1];id[0]=id[1]; v[1]=tv;id[1]=ti; } } \
  }

// ---------------- generic transpose: dst[c*R+r] = src[r*ld+off+c] ----------------
__global__ void transpose_kernel(const float* __restrict__ src, float* __restrict__ dst,
                                 int R, int C, int ld, int off){
  int i = blockIdx.x*256 + threadIdx.x;
  if (i < R*C){ int r = i / C, c = i % C; dst[c*R + r] = src[r*ld + off + c]; }
}

// ---------------- squared norms, rows layout (B,3,N) ----------------
template<int TAG>
__global__ void norms_rows_kernel(const float* __restrict__ x, float* __restrict__ xx, int N){
  int b = blockIdx.y; int n = blockIdx.x*256 + threadIdx.x;
  const float* xb = x + (size_t)b*3*N;
  float v0 = xb[n], v1 = xb[N+n], v2 = xb[2*N+n];
  xx[(size_t)b*N + n] = v0*v0 + v1*v1 + v2*v2;
}

// ---------------- squared norms, channel-last 64ch slice of (B,N,192) ----------------
template<int TAG>
__global__ void norms_cl_kernel(const float* __restrict__ f, int off, float* __restrict__ xx, int N){
  int b = blockIdx.y; int n = blockIdx.x*256 + threadIdx.x;
  const float4* p = (const float4*)(f + ((size_t)b*N + n)*192 + off);
  float s = 0.f;
#pragma unroll
  for (int q=0;q<16;q++){ float4 v = p[q]; s += v.x*v.x + v.y*v.y + v.z*v.z + v.w*v.w; }
  xx[(size_t)b*N + n] = s;
}

__device__ __forceinline__ void sort8(float (&v)[8], int (&id)[8]){
#define CE(a,bq) { if (better(v[bq],id[bq],v[a],id[a])){ float tv=v[a]; int ti=id[a]; v[a]=v[bq]; id[a]=id[bq]; v[bq]=tv; id[bq]=ti; } }
  CE(0,1) CE(2,3) CE(4,5) CE(6,7)
  CE(0,2) CE(1,3) CE(4,6) CE(5,7)
  CE(1,2) CE(5,6)
  CE(0,4) CE(1,5) CE(2,6) CE(3,7)
  CE(2,4) CE(3,5)
  CE(1,2) CE(3,4) CE(5,6)
#undef CE
}

// ---------------- knn 3-channel: 4 queries/block (1/wave), zero LDS, zero barriers ----------------
// Insertion top-8 during dist; 40-round butterfly extraction; rare refill recomputes.
template<int TAG>
__global__ __launch_bounds__(256) void knn3_kernel(
    const float* __restrict__ xrows, const float* __restrict__ xx,
    int* __restrict__ idxT, int N){
  const int b = blockIdx.y, tid = threadIdx.x;
  const int w = tid>>6, lane = tid&63;
  const int nq = blockIdx.x*4 + w;
  const float* xb = xrows + (size_t)b*3*N;
  const float* xxb = xx + (size_t)b*N;
  float c0 = xb[nq], c1 = xb[N+nq], c2 = xb[2*N+nq];
  float xxn = xxb[nq];
  float v[8]; int id[8];
#pragma unroll
  for (int j=0;j<8;j++){ v[j]=-__builtin_inff(); id[j]=0x7FFFFFFF; }
  for (int j=0;j<32;j++){
    int m = j*64 + lane;
    float s = c0*xb[m] + c1*xb[N+m] + c2*xb[2*N+m];
    float d = 2.f*s - xxn - xxb[m];
    INSERT8(v, id, d, m)
  }
  float lastv = 0.f; int lasti = 0;
  int win = 0;
  for (int r=0;r<KNN;r++){
    float bv = v[0]; int bi = id[0];
#pragma unroll
    for (int off=32; off; off>>=1){
      float ov = __shfl_xor(bv, off);
      int   oi = __shfl_xor(bi, off);
      if (better(ov, oi, bv, bi)){ bv = ov; bi = oi; }
    }
    if (lane == r) win = bi;
    if (id[0] == bi){
      lastv = v[0]; lasti = id[0];
#pragma unroll
      for (int j=0;j<7;j++){ v[j]=v[j+1]; id[j]=id[j+1]; }
      v[7] = -__builtin_inff(); id[7] = 0x7FFFFFFF;
      if (id[0] == 0x7FFFFFFF){   // rare refill: best strictly worse than last pop
        float nv = -__builtin_inff(); int ni = 0x7FFFFFFF;
        for (int j=0;j<32;j++){
          int m = j*64 + lane;
          float s = c0*xb[m] + c1*xb[N+m] + c2*xb[2*N+m];
          float dd = 2.f*s - xxn - xxb[m];
          if (better(lastv, lasti, dd, m) && better(dd, m, nv, ni)){ nv=dd; ni=m; }
        }
        v[0] = nv; id[0] = ni;
      }
    }
  }
  if (lane < KNN) idxT[((size_t)b*KNN + lane)*N + nq] = win;
}

// ---------------- knn 64-channel (channel-last), 4 queries/block ----------------
// v6 (R5 champion): R0 structure (LDS dist strips, tile prefetch, post-hoc top-8,
// pop extraction, rare LDS refill) but cand tile = 32 candidates (8 KiB):
//   LDS = 8K cand + 4x8K dist = 40960 B -> 4 blocks/CU = 16 waves/CU.
// Each candidate is computed by a lane PAIR (lane, lane^32) splitting channels
// 0-31 / 32-63; one shfl_xor(32) combines. Wave-count sweep (R4/R5/R6: 8w=449/379,
// 12w=324.7, 16w=322) shows this saturates the DS+VALU issue floor; do not trade
// residency for per-wave work here.
template<int TAG>
__global__ __launch_bounds__(256) void knn64_kernel(
    const float* __restrict__ featT, int featOff,
    const float* __restrict__ xx, int* __restrict__ idxT, int N){
  const int b = blockIdx.y, tid = threadIdx.x;
  const int w = tid>>6, lane = tid&63;
  __shared__ float cand[32*64];    // xor-swizzled [cand][ch] tile (8 KiB), block-shared
  __shared__ float dist[4*2048];   // wave-private strips (32 KiB)
  const float* fb = featT + featOff;
  const float* xxb = xx + (size_t)b*N;
  const int nq = blockIdx.x*4 + w;
  const int h = lane>>5;           // channel half this lane covers
  float4 ctr8[8];
  {
    const float4* cp = (const float4*)(fb + ((size_t)b*N + nq)*192);
#pragma unroll
    for (int q=0;q<8;q++) ctr8[q] = cp[h*8 + q];
  }
  float xxn = xxb[nq];
  float* dw = &dist[w*2048];
  float4 g[2];
#pragma unroll
  for (int r=0;r<2;r++){
    int k2 = tid + 256*r;
    int c = k2>>4, f = k2&15;
    g[r] = ld4(&fb[((size_t)b*N + c)*192 + 4*f]);
  }
  const int cc = lane&31, swz = cc&15, qb = h*8;
  for (int t=0;t<64;t++){
    __syncthreads();                 // prev compute done reading cand
#pragma unroll
    for (int r=0;r<2;r++){
      int k2 = tid + 256*r;
      int c = k2>>4, f = k2&15;
      *(float4*)&cand[(c<<6) + ((f ^ (c&15))<<2)] = g[r];
    }
    __syncthreads();
    if (t+1 < 64){                   // issue next tile's loads; latency overlaps compute
      int m0n = (t+1)*32;
#pragma unroll
      for (int r=0;r<2;r++){
        int k2 = tid + 256*r;
        int c = k2>>4, f = k2&15;
        g[r] = ld4(&fb[((size_t)b*N + m0n + c)*192 + 4*f]);
      }
    }
    float s0=0.f,s1=0.f,s2=0.f,s3=0.f;
#pragma unroll
    for (int j=0;j<8;j++){
      float4 mv = *(const float4*)&cand[(cc<<6) + (((qb + j) ^ swz)<<2)];
      s0 = fmaf(ctr8[j].x, mv.x, s0);
      s1 = fmaf(ctr8[j].y, mv.y, s1);
      s2 = fmaf(ctr8[j].z, mv.z, s2);
      s3 = fmaf(ctr8[j].w, mv.w, s3);
    }
    float p = (s0+s1)+(s2+s3);
    float tot = p + __shfl_xor(p, 32);    // combine channel halves (commutative -> both halves identical)
    if (h == (t&1)){                      // owner lane (m & 63 == lane) writes its strip slot
      int m = t*32 + cc;
      dw[(t>>1)*64 + lane] = 2.f*tot - xxn - xxb[m];
    }
  }
  // ---- per-lane exact top-8 of its 32 entries (sorted desc by (v desc, idx asc)) ----
  float v[8]; int id[8];
#pragma unroll
  for (int j=0;j<8;j++){ v[j]=dw[j*64+lane]; id[j]=j*64+lane; }
  sort8(v, id);
#pragma unroll
  for (int gq=1; gq<4; gq++){
    float a[8]; int ai[8];
#pragma unroll
    for (int j=0;j<8;j++){ a[j]=dw[(gq*8+j)*64+lane]; ai[j]=(gq*8+j)*64+lane; }
    sort8(a, ai);
    float m_[8]; int mi_[8];
#pragma unroll
    for (int k=0;k<8;k++){
      if (better(a[7-k], ai[7-k], v[k], id[k])){ m_[k]=a[7-k]; mi_[k]=ai[7-k]; }
      else                                     { m_[k]=v[k];   mi_[k]=id[k]; }
    }
#define CEB(x,y) { if (better(m_[y],mi_[y],m_[x],mi_[x])){ float tv=m_[x];int ti=mi_[x]; m_[x]=m_[y];mi_[x]=mi_[y]; m_[y]=tv;mi_[y]=ti; } }
    CEB(0,4) CEB(1,5) CEB(2,6) CEB(3,7)
    CEB(0,2) CEB(1,3) CEB(4,6) CEB(5,7)
    CEB(0,1) CEB(2,3) CEB(4,5) CEB(6,7)
#undef CEB
#pragma unroll
    for (int k=0;k<8;k++){ v[k]=m_[k]; id[k]=mi_[k]; }
  }
  // ---- 40 extraction rounds: butterfly + pop-shift; zero barriers, zero LDS steady state ----
  float lastv = 0.f; int lasti = 0;
  int win = 0;
  for (int r=0;r<KNN;r++){
    float bv = v[0]; int bi = id[0];
#pragma unroll
    for (int off=32; off; off>>=1){
      float ov = __shfl_xor(bv, off);
      int   oi = __shfl_xor(bi, off);
      if (better(ov, oi, bv, bi)){ bv = ov; bi = oi; }
    }
    if (lane == r) win = bi;
    if (id[0] == bi){                // unique owner (indices unique)
      lastv = v[0]; lasti = id[0];
#pragma unroll
      for (int j=0;j<7;j++){ v[j]=v[j+1]; id[j]=id[j+1]; }
      v[7] = -__builtin_inff(); id[7] = 0x7FFFFFFF;
      if (id[0] == 0x7FFFFFFF){      // rare: lane contributed >8 of top-40 -> refill head
        float nv = -__builtin_inff(); int ni = 0x7FFFFFFF;
        for (int j=0;j<32;j++){
          float vv = dw[j*64 + lane]; int m = j*64 + lane;
          if (better(lastv, lasti, vv, m) && better(vv, m, nv, ni)){ nv=vv; ni=m; }
        }
        v[0] = nv; id[0] = ni;
      }
    }
  }
  if (lane < KNN) idxT[((size_t)b*KNN + lane)*N + nq] = win;
}

// ==================== register-tiled edge kernels ====================

// ---- edgeA (t-path): 3ch -> 64 -> 128, max over k ----
// v2: 4 waves x 16 points; stage2 tiled as 4 panels o=p*32+oq*4 (conflict-free w2T reads).
__global__ __launch_bounds__(256) void edgeA_kernel(
    const float* __restrict__ x, const int* __restrict__ idxT,
    const float* __restrict__ w1, const float* __restrict__ w2,
    float* __restrict__ tT, int N){
  __shared__ float w1aT[3*64];
  __shared__ float wd3T[3*64];
  __shared__ float w2T[64*128];      // [c][o]; reused as merge buffer (4 x 16r x 128o)
  __shared__ float aT3[4][3*16];
  __shared__ float s1T[4][64*16];    // [c][r]
  const int tid = threadIdx.x, w = tid>>6, lane = tid&63;
  const int oq = lane&7, rg = lane>>3;
  const int o0 = oq*8, r0 = rg*2;
  const int b = blockIdx.y, n0 = blockIdx.x*16;
  for (int i=tid; i<192; i+=256){
    int o = i&63, c = i/64;
    float a = w1[o*6+c];
    w1aT[c*64+o] = a; wd3T[c*64+o] = w1[o*6+3+c] - a;
  }
  for (int i=tid; i<128*64; i+=256){
    int o = i>>6, c = i&63;
    w2T[c*128+o] = w2[o*64+c];
  }
  if (tid < 48){ int c = tid>>4, r = tid&15; aT3[0][c*16+r] = x[((size_t)b*3+c)*N + n0 + r]; }
  __syncthreads();
  float base[16];
#pragma unroll
  for (int i=0;i<16;i++) base[i]=0.f;
#pragma unroll
  for (int c=0;c<3;c++){
    float4 wA = ld4(&wd3T[c*64+o0]), wB = ld4(&wd3T[c*64+o0+4]);
    float2 av = *(const float2*)&aT3[0][c*16+r0];
    float wv[8] = {wA.x,wA.y,wA.z,wA.w,wB.x,wB.y,wB.z,wB.w};
    float rv[2] = {av.x,av.y};
#pragma unroll
    for (int oo=0;oo<8;oo++)
#pragma unroll
      for (int rr=0;rr<2;rr++) base[oo*2+rr] = fmaf(wv[oo], rv[rr], base[oo*2+rr]);
  }
  __syncthreads();   // all waves done reading aT3[0] before k-loop overwrites
  float mx[32];
#pragma unroll
  for (int i=0;i<32;i++) mx[i] = -__builtin_inff();
  for (int it=0; it<10; it++){
    int k = it*4 + w;
    int m = idxT[((size_t)b*KNN + k)*N + n0 + (lane&15)];
    if (lane < 48){ int c = lane>>4; aT3[w][c*16 + (lane&15)] = x[((size_t)b*3+c)*N + m]; }
    // stage1 (64 o x 16 r)
    float acc[16];
#pragma unroll
    for (int i=0;i<16;i++) acc[i] = base[i];
#pragma unroll
    for (int c=0;c<3;c++){
      float4 wA = ld4(&w1aT[c*64+o0]), wB = ld4(&w1aT[c*64+o0+4]);
      float2 av = *(const float2*)&aT3[w][c*16+r0];
      float wv[8] = {wA.x,wA.y,wA.z,wA.w,wB.x,wB.y,wB.z,wB.w};
      float rv[2] = {av.x,av.y};
#pragma unroll
      for (int oo=0;oo<8;oo++)
#pragma unroll
        for (int rr=0;rr<2;rr++) acc[oo*2+rr] = fmaf(wv[oo], rv[rr], acc[oo*2+rr]);
    }
#pragma unroll
    for (int oo=0;oo<8;oo++){
      float2 sv; sv.x = lrelu(acc[oo*2]); sv.y = lrelu(acc[oo*2+1]);
      *(float2*)&s1T[w][(o0+oo)*16 + r0] = sv;
    }
    // stage2 (128 o x 16 r): 4 panels, o = p*32 + oq*4 -> 32 banks, conflict-free
    float acc2[32];
#pragma unroll
    for (int i=0;i<32;i++) acc2[i]=0.f;
    for (int c=0;c<64;c++){
      float2 av = *(const float2*)&s1T[w][c*16 + r0];
#pragma unroll
      for (int p=0;p<4;p++){
        float4 wv = ld4(&w2T[c*128 + p*32 + oq*4]);
        acc2[p*8+0] = fmaf(wv.x, av.x, acc2[p*8+0]);
        acc2[p*8+1] = fmaf(wv.x, av.y, acc2[p*8+1]);
        acc2[p*8+2] = fmaf(wv.y, av.x, acc2[p*8+2]);
        acc2[p*8+3] = fmaf(wv.y, av.y, acc2[p*8+3]);
        acc2[p*8+4] = fmaf(wv.z, av.x, acc2[p*8+4]);
        acc2[p*8+5] = fmaf(wv.z, av.y, acc2[p*8+5]);
        acc2[p*8+6] = fmaf(wv.w, av.x, acc2[p*8+6]);
        acc2[p*8+7] = fmaf(wv.w, av.y, acc2[p*8+7]);
      }
    }
#pragma unroll
    for (int i=0;i<32;i++) mx[i] = fmaxf(mx[i], lrelu(acc2[i]));
  }
  __syncthreads();   // all waves done reading w2T -> reuse as merge buffer
#pragma unroll
  for (int rr=0;rr<2;rr++){
#pragma unroll
    for (int p=0;p<4;p++){
      float4 a = make_float4(mx[p*8+0+rr], mx[p*8+2+rr], mx[p*8+4+rr], mx[p*8+6+rr]);
      *(float4*)&w2T[w*2048 + (r0+rr)*128 + p*32 + oq*4] = a;
    }
  }
  __syncthreads();
  for (int i=tid; i<2048; i+=256){
    float vv = fmaxf(fmaxf(w2T[i], w2T[2048+i]), fmaxf(w2T[4096+i], w2T[6144+i]));
    int r = i>>7, o = i&127;
    tT[((size_t)b*N + n0 + r)*128 + o] = vv;
  }
}

// ---- edgeB: 3ch -> 64 -> 64, max over k ----
__global__ __launch_bounds__(128) void edgeB_kernel(
    const float* __restrict__ xp, const int* __restrict__ idxT,
    const float* __restrict__ w1, const float* __restrict__ w2,
    float* __restrict__ catT, int N){
  __shared__ float w1aT[3*64];
  __shared__ float wd3T[3*64];
  __shared__ float w2T[64*64];
  __shared__ float aT3[2][3*32];
  __shared__ float s1T[2][64*32];
  const int tid = threadIdx.x, w = tid>>6, lane = tid&63;
  const int oq = lane&7, rg = lane>>3;
  const int o0 = oq*8, r0 = rg*4;
  const int b = blockIdx.y, n0 = blockIdx.x*32;
  for (int i=tid; i<192; i+=128){
    int o = i&63, c = i>>6;
    float a = w1[o*6+c], bb = w1[o*6+3+c];
    w1aT[c*64+o] = a; wd3T[c*64+o] = bb - a;
  }
  for (int i=tid; i<64*64; i+=128){
    int o = i>>6, c = i&63;
    w2T[c*64+o] = w2[o*64+c];
  }
  if (tid < 32){
#pragma unroll
    for (int c=0;c<3;c++) aT3[0][c*32+tid] = xp[((size_t)b*3+c)*N + n0 + tid];
  }
  __syncthreads();
  float base[32];
#pragma unroll
  for (int i=0;i<32;i++) base[i]=0.f;
#pragma unroll
  for (int c=0;c<3;c++){
    float4 w0 = ld4(&wd3T[c*64+o0]), w1v = ld4(&wd3T[c*64+o0+4]);
    float4 av = ld4(&aT3[0][c*32+r0]);
    float wv[8] = {w0.x,w0.y,w0.z,w0.w,w1v.x,w1v.y,w1v.z,w1v.w};
    float rv[4] = {av.x,av.y,av.z,av.w};
#pragma unroll
    for (int oo=0;oo<8;oo++)
#pragma unroll
      for (int rr=0;rr<4;rr++) base[oo*4+rr] = fmaf(wv[oo], rv[rr], base[oo*4+rr]);
  }
  __syncthreads();
  float mx[32];
#pragma unroll
  for (int i=0;i<32;i++) mx[i] = -__builtin_inff();
  for (int it=0; it<20; it++){
    int k = it*2 + w;
    {
      int row = lane&31;
      int m = idxT[((size_t)b*KNN + k)*N + n0 + row];
      if (lane < 32){
#pragma unroll
        for (int c=0;c<3;c++) aT3[w][c*32+row] = xp[((size_t)b*3+c)*N + m];
      }
    }
    float acc[32];
#pragma unroll
    for (int i=0;i<32;i++) acc[i] = base[i];
#pragma unroll
    for (int c=0;c<3;c++){
      float4 w0 = ld4(&w1aT[c*64+o0]), w1v = ld4(&w1aT[c*64+o0+4]);
      float4 av = ld4(&aT3[w][c*32+r0]);
      float wv[8] = {w0.x,w0.y,w0.z,w0.w,w1v.x,w1v.y,w1v.z,w1v.w};
      float rv[4] = {av.x,av.y,av.z,av.w};
#pragma unroll
      for (int oo=0;oo<8;oo++)
#pragma unroll
        for (int rr=0;rr<4;rr++) acc[oo*4+rr] = fmaf(wv[oo], rv[rr], acc[oo*4+rr]);
    }
#pragma unroll
    for (int oo=0;oo<8;oo++){
      float4 sv = make_float4(lrelu(acc[oo*4+0]), lrelu(acc[oo*4+1]), lrelu(acc[oo*4+2]), lrelu(acc[oo*4+3]));
      *(float4*)&s1T[w][(o0+oo)*32 + r0] = sv;
    }
    float acc2[32];
#pragma unroll
    for (int i=0;i<32;i++) acc2[i]=0.f;
    for (int c=0;c<64;c++){
      float4 w0 = ld4(&w2T[c*64+o0]), w1v = ld4(&w2T[c*64+o0+4]);
      float4 av = ld4(&s1T[w][c*32+r0]);
      float wv[8] = {w0.x,w0.y,w0.z,w0.w,w1v.x,w1v.y,w1v.z,w1v.w};
      float rv[4] = {av.x,av.y,av.z,av.w};
#pragma unroll
      for (int oo=0;oo<8;oo++)
#pragma unroll
        for (int rr=0;rr<4;rr++) acc2[oo*4+rr] = fmaf(wv[oo], rv[rr], acc2[oo*4+rr]);
    }
#pragma unroll
    for (int i=0;i<32;i++) mx[i] = fmaxf(mx[i], lrelu(acc2[i]));
  }
  __syncthreads();
#pragma unroll
  for (int rr=0;rr<4;rr++){
    float4 a = make_float4(mx[0*4+rr], mx[1*4+rr], mx[2*4+rr], mx[3*4+rr]);
    float4 bq = make_float4(mx[4*4+rr], mx[5*4+rr], mx[6*4+rr], mx[7*4+rr]);
    *(float4*)&s1T[w][(r0+rr)*64 + o0] = a;
    *(float4*)&s1T[w][(r0+rr)*64 + o0 + 4] = bq;
  }
  __syncthreads();
  for (int i=tid; i<2048; i+=128){
    float v = fmaxf(s1T[0][i], s1T[1][i]);
    int r = i>>6, o = i&63;
    catT[((size_t)b*N + n0 + r)*192 + o] = v;
  }
}

// ---- edgeC: 64ch -> 64 -> 64, max over k ----
__global__ __launch_bounds__(128) void edgeC_kernel(
    const float* __restrict__ inT, int inOff, const int* __restrict__ idxT,
    const float* __restrict__ w1, const float* __restrict__ w2,
    float* __restrict__ catT, int outOff, int N){
  __shared__ float w1T[64*64];
  __shared__ float w2T[64*64];
  __shared__ float aT[2][64*32];
  __shared__ float s1T[2][64*32];
  const int tid = threadIdx.x, w = tid>>6, lane = tid&63;
  const int oq = lane&7, rg = lane>>3;
  const int o0 = oq*8, r0 = rg*4;
  const int b = blockIdx.y, n0 = blockIdx.x*32;
  for (int i=tid; i<64*64; i+=128){
    int o = i>>6, c = i&63;
    float a = w1[o*128+c], bb = w1[o*128+64+c];
    w1T[c*64+o] = a; w2T[c*64+o] = bb - a;
  }
  for (int i=tid; i<512; i+=128){
    int p = i>>4, cq = i&15;
    float4 v = ld4(&inT[((size_t)b*N + n0 + p)*192 + inOff + cq*4]);
    aT[0][(cq*4+0)*32+p] = v.x; aT[0][(cq*4+1)*32+p] = v.y;
    aT[0][(cq*4+2)*32+p] = v.z; aT[0][(cq*4+3)*32+p] = v.w;
  }
  __syncthreads();
  float base[32];
#pragma unroll
  for (int i=0;i<32;i++) base[i]=0.f;
  for (int c=0;c<64;c++){
    float4 w0 = ld4(&w2T[c*64+o0]), w1v = ld4(&w2T[c*64+o0+4]);
    float4 av = ld4(&aT[0][c*32+r0]);
    float wv[8] = {w0.x,w0.y,w0.z,w0.w,w1v.x,w1v.y,w1v.z,w1v.w};
    float rv[4] = {av.x,av.y,av.z,av.w};
#pragma unroll
    for (int oo=0;oo<8;oo++)
#pragma unroll
      for (int rr=0;rr<4;rr++) base[oo*4+rr] = fmaf(wv[oo], rv[rr], base[oo*4+rr]);
  }
  __syncthreads();
  for (int i=tid; i<64*64; i+=128){
    int o = i>>6, c = i&63;
    w2T[c*64+o] = w2[o*64+c];
  }
  __syncthreads();
  float mx[32];
#pragma unroll
  for (int i=0;i<32;i++) mx[i] = -__builtin_inff();
  const int row = lane&31, ch = lane>>5;
  for (int it=0; it<20; it++){
    int k = it*2 + w;
    {
      int m = idxT[((size_t)b*KNN + k)*N + n0 + row];
      const float* src = &inT[((size_t)b*N + m)*192 + inOff + ch*32];
      float4 g[8];
#pragma unroll
      for (int j=0;j<8;j++) g[j] = ld4(src + j*4);
#pragma unroll
      for (int j=0;j<8;j++){
        aT[w][(ch*32+j*4+0)*32 + row] = g[j].x;
        aT[w][(ch*32+j*4+1)*32 + row] = g[j].y;
        aT[w][(ch*32+j*4+2)*32 + row] = g[j].z;
        aT[w][(ch*32+j*4+3)*32 + row] = g[j].w;
      }
    }
    float acc[32];
#pragma unroll
    for (int i=0;i<32;i++) acc[i] = base[i];
    for (int c=0;c<64;c++){
      float4 w0 = ld4(&w1T[c*64+o0]), w1v = ld4(&w1T[c*64+o0+4]);
      float4 av = ld4(&aT[w][c*32+r0]);
      float wv[8] = {w0.x,w0.y,w0.z,w0.w,w1v.x,w1v.y,w1v.z,w1v.w};
      float rv[4] = {av.x,av.y,av.z,av.w};
#pragma unroll
      for (int oo=0;oo<8;oo++)
#pragma unroll
        for (int rr=0;rr<4;rr++) acc[oo*4+rr] = fmaf(wv[oo], rv[rr], acc[oo*4+rr]);
    }
#pragma unroll
    for (int oo=0;oo<8;oo++){
      float4 sv = make_float4(lrelu(acc[oo*4+0]), lrelu(acc[oo*4+1]), lrelu(acc[oo*4+2]), lrelu(acc[oo*4+3]));
      *(float4*)&s1T[w][(o0+oo)*32 + r0] = sv;
    }
    float acc2[32];
#pragma unroll
    for (int i=0;i<32;i++) acc2[i]=0.f;
    for (int c=0;c<64;c++){
      float4 w0 = ld4(&w2T[c*64+o0]), w1v = ld4(&w2T[c*64+o0+4]);
      float4 av = ld4(&s1T[w][c*32+r0]);
      float wv[8] = {w0.x,w0.y,w0.z,w0.w,w1v.x,w1v.y,w1v.z,w1v.w};
      float rv[4] = {av.x,av.y,av.z,av.w};
#pragma unroll
      for (int oo=0;oo<8;oo++)
#pragma unroll
        for (int rr=0;rr<4;rr++) acc2[oo*4+rr] = fmaf(wv[oo], rv[rr], acc2[oo*4+rr]);
    }
#pragma unroll
    for (int i=0;i<32;i++) mx[i] = fmaxf(mx[i], lrelu(acc2[i]));
  }
  __syncthreads();
#pragma unroll
  for (int rr=0;rr<4;rr++){
    float4 a = make_float4(mx[0*4+rr], mx[1*4+rr], mx[2*4+rr], mx[3*4+rr]);
    float4 bq = make_float4(mx[4*4+rr], mx[5*4+rr], mx[6*4+rr], mx[7*4+rr]);
    *(float4*)&s1T[w][(r0+rr)*64 + o0] = a;
    *(float4*)&s1T[w][(r0+rr)*64 + o0 + 4] = bq;
  }
  __syncthreads();
  for (int i=tid; i<2048; i+=128){
    float v = fmaxf(s1T[0][i], s1T[1][i]);
    int r = i>>6, o = i&63;
    catT[((size_t)b*N + n0 + r)*192 + outOff + o] = v;
  }
}

// ---- edgeD: 64ch -> 64 (single conv), max over k ----
__global__ __launch_bounds__(128) void edgeD_kernel(
    const float* __restrict__ inT, int inOff, const int* __restrict__ idxT,
    const float* __restrict__ w1, float* __restrict__ catT, int outOff, int N){
  __shared__ float w1T[64*64];
  __shared__ float wdT[64*64];
  __shared__ float aT[2][64*32];
  const int tid = threadIdx.x, w = tid>>6, lane = tid&63;
  const int oq = lane&7, rg = lane>>3;
  const int o0 = oq*8, r0 = rg*4;
  const int b = blockIdx.y, n0 = blockIdx.x*32;
  for (int i=tid; i<64*64; i+=128){
    int o = i>>6, c = i&63;
    float a = w1[o*128+c], bb = w1[o*128+64+c];
    w1T[c*64+o] = a; wdT[c*64+o] = bb - a;
  }
  for (int i=tid; i<512; i+=128){
    int p = i>>4, cq = i&15;
    float4 v = ld4(&inT[((size_t)b*N + n0 + p)*192 + inOff + cq*4]);
    aT[0][(cq*4+0)*32+p] = v.x; aT[0][(cq*4+1)*32+p] = v.y;
    aT[0][(cq*4+2)*32+p] = v.z; aT[0][(cq*4+3)*32+p] = v.w;
  }
  __syncthreads();
  float base[32];
#pragma unroll
  for (int i=0;i<32;i++) base[i]=0.f;
  for (int c=0;c<64;c++){
    float4 w0 = ld4(&wdT[c*64+o0]), w1v = ld4(&wdT[c*64+o0+4]);
    float4 av = ld4(&aT[0][c*32+r0]);
    float wv[8] = {w0.x,w0.y,w0.z,w0.w,w1v.x,w1v.y,w1v.z,w1v.w};
    float rv[4] = {av.x,av.y,av.z,av.w};
#pragma unroll
    for (int oo=0;oo<8;oo++)
#pragma unroll
      for (int rr=0;rr<4;rr++) base[oo*4+rr] = fmaf(wv[oo], rv[rr], base[oo*4+rr]);
  }
  __syncthreads();
  float mx[32];
#pragma unroll
  for (int i=0;i<32;i++) mx[i] = -__builtin_inff();
  const int row = lane&31, ch = lane>>5;
  for (int it=0; it<20; it++){
    int k = it*2 + w;
    {
      int m = idxT[((size_t)b*KNN + k)*N + n0 + row];
      const float* src = &inT[((size_t)b*N + m)*192 + inOff + ch*32];
      float4 g[8];
#pragma unroll
      for (int j=0;j<8;j++) g[j] = ld4(src + j*4);
#pragma unroll
      for (int j=0;j<8;j++){
        aT[w][(ch*32+j*4+0)*32 + row] = g[j].x;
        aT[w][(ch*32+j*4+1)*32 + row] = g[j].y;
        aT[w][(ch*32+j*4+2)*32 + row] = g[j].z;
        aT[w][(ch*32+j*4+3)*32 + row] = g[j].w;
      }
    }
    float acc[32];
#pragma unroll
    for (int i=0;i<32;i++) acc[i] = base[i];
    for (int c=0;c<64;c++){
      float4 w0 = ld4(&w1T[c*64+o0]), w1v = ld4(&w1T[c*64+o0+4]);
      float4 av = ld4(&aT[w][c*32+r0]);
      float wv[8] = {w0.x,w0.y,w0.z,w0.w,w1v.x,w1v.y,w1v.z,w1v.w};
      float rv[4] = {av.x,av.y,av.z,av.w};
#pragma unroll
      for (int oo=0;oo<8;oo++)
#pragma unroll
        for (int rr=0;rr<4;rr++) acc[oo*4+rr] = fmaf(wv[oo], rv[rr], acc[oo*4+rr]);
    }
#pragma unroll
    for (int i=0;i<32;i++) mx[i] = fmaxf(mx[i], lrelu(acc[i]));
  }
  __syncthreads();
#pragma unroll
  for (int rr=0;rr<4;rr++){
    float4 a = make_float4(mx[0*4+rr], mx[1*4+rr], mx[2*4+rr], mx[3*4+rr]);
    float4 bq = make_float4(mx[4*4+rr], mx[5*4+rr], mx[6*4+rr], mx[7*4+rr]);
    *(float4*)&wdT[w*2048 + (r0+rr)*64 + o0] = a;
    *(float4*)&wdT[w*2048 + (r0+rr)*64 + o0 + 4] = bq;
  }
  __syncthreads();
  for (int i=tid; i<2048; i+=128){
    float v = fmaxf(wdT[i], wdT[2048+i]);
    int r = i>>6, o = i&63;
    catT[((size_t)b*N + n0 + r)*192 + outOff + o] = v;
  }
}

// ---------------- conv1 (1024 outs) + lrelu + max -- register-tiled, weights in LDS ----------------
// v2: ish staging XOR-swizzled. Old layout [c][32] stored column p from 32 lanes
// sharing one p -> bank = p -> 32-way conflict (3.25e7 SQ_LDS_BANK_CONFLICT, R6).
// New mapping: offset(c,p) = c*32 + (((p>>2) ^ ((c>>2)&7))<<2) + (p&3).
// Store spreads over 16 banks (4-way); compute read ld4 at col group (rg ^ ((c>>2)&7))
// stays 16B-aligned and conflict-free (XOR by per-c constant is a bijection on rg).
template<int CIN, int TAG>
__global__ __launch_bounds__(128) void convmax_kernel(
    const float* __restrict__ inT, const float* __restrict__ wT,
    float* __restrict__ partial, int N){
  __shared__ float wsh[CIN*64];
  __shared__ float ish[32*CIN];     // [c][32], XOR-swizzled 4-col groups
  const int tid = threadIdx.x, w = tid>>6, lane = tid&63;
  const int oq = lane&7, rg = lane>>3;
  const int o0 = oq*8;
  const int b = blockIdx.z, oc = blockIdx.x, nt = blockIdx.y;
  for (int i=tid; i<CIN*64; i+=128){
    int c = i>>6, o = i&63;
    wsh[i] = wT[(size_t)c*1024 + oc*64 + o];
  }
  float mx[32];
#pragma unroll
  for (int i=0;i<32;i++) mx[i] = -__builtin_inff();
  const int nbase = nt*(N/8);
  for (int st=0; st<8; st++){
    __syncthreads();
    const float* src = inT + ((size_t)b*N + nbase + st*32)*CIN;
    for (int i=tid; i<32*(CIN/4); i+=128){
      int p = i/(CIN/4), cq = i%(CIN/4);
      float4 v = ld4(src + p*CIN + 4*cq);
      int base = (((p>>2) ^ (cq&7))<<2) + (p&3);
      ish[(4*cq+0)*32 + base] = v.x;
      ish[(4*cq+1)*32 + base] = v.y;
      ish[(4*cq+2)*32 + base] = v.z;
      ish[(4*cq+3)*32 + base] = v.w;
    }
    __syncthreads();
    float acc[32];
#pragma unroll
    for (int i=0;i<32;i++) acc[i]=0.f;
    for (int c=0;c<CIN;c++){
      float4 w0 = ld4(&wsh[c*64+o0]), w1v = ld4(&wsh[c*64+o0+4]);
      float4 av = ld4(&ish[c*32 + ((rg ^ ((c>>2)&7))<<2)]);
      float wv[8] = {w0.x,w0.y,w0.z,w0.w,w1v.x,w1v.y,w1v.z,w1v.w};
      float rv[4] = {av.x,av.y,av.z,av.w};
#pragma unroll
      for (int oo=0;oo<8;oo++)
#pragma unroll
        for (int rr=0;rr<4;rr++) acc[oo*4+rr] = fmaf(wv[oo], rv[rr], acc[oo*4+rr]);
    }
#pragma unroll
    for (int i=0;i<32;i++) mx[i] = fmaxf(mx[i], lrelu(acc[i]));
  }
  float m8[8];
#pragma unroll
  for (int oo=0;oo<8;oo++)
    m8[oo] = fmaxf(fmaxf(mx[oo*4+0], mx[oo*4+1]), fmaxf(mx[oo*4+2], mx[oo*4+3]));
  __syncthreads();
  *(float4*)&ish[(w*8+rg)*64 + o0]     = make_float4(m8[0],m8[1],m8[2],m8[3]);
  *(float4*)&ish[(w*8+rg)*64 + o0 + 4] = make_float4(m8[4],m8[5],m8[6],m8[7]);
  __syncthreads();
  if (tid < 64){
    float v = -__builtin_inff();
#pragma unroll
    for (int g=0; g<16; g++) v = fmaxf(v, ish[g*64+tid]);
    partial[((size_t)b*8 + nt)*1024 + oc*64 + tid] = v;
  }
}

template<int TAG>
__global__ void reduce_max_kernel(const float* __restrict__ partial, float* __restrict__ out){
  int b = blockIdx.y; int o = blockIdx.x*256 + threadIdx.x;
  float v = -__builtin_inff();
  for (int s=0;s<8;s++) v = fmaxf(v, partial[((size_t)b*8 + s)*1024 + o]);
  out[(size_t)b*1024 + o] = v;
}

// ---------------- small FC ----------------
__global__ void fc_kernel(const float* __restrict__ in, const float* __restrict__ W,
                          const float* __restrict__ bias, float* __restrict__ out,
                          int CI, int O, int act){
  int b = blockIdx.x;
  __shared__ float insh[1024];
  for (int i=threadIdx.x;i<CI;i+=blockDim.x) insh[i]=in[(size_t)b*CI+i];
  __syncthreads();
  for (int o=threadIdx.x;o<O;o+=blockDim.x){
    float s = bias ? bias[o] : 0.f;
    for (int c=0;c<CI;c++) s = fmaf(W[(size_t)o*CI+c], insh[c], s);
    if (act) s = lrelu(s);
    out[(size_t)b*O+o]=s;
  }
}

// ---------------- x' = T^T x per batch ----------------
__global__ void transform_kernel(const float* __restrict__ x, const float* __restrict__ T9,
                                 float* __restrict__ xp, int N){
  int b = blockIdx.y; int n = blockIdx.x*256 + threadIdx.x;
  const float* t = T9 + (size_t)b*9;
  float x0=x[((size_t)b*3+0)*N+n], x1=x[((size_t)b*3+1)*N+n], x2=x[((size_t)b*3+2)*N+n];
#pragma unroll
  for (int i=0;i<3;i++)
    xp[((size_t)b*3+i)*N+n] = t[i]*x0 + t[3+i]*x1 + t[6+i]*x2;
}

// ---------------- bias1: n-invariant part of h1 ----------------
__global__ void bias1_kernel(const float* __restrict__ g, const float* __restrict__ lv,
                             const float* __restrict__ h1w, float* __restrict__ bias1){
  int b = blockIdx.x;
  __shared__ float insh[1088];
  for (int i=threadIdx.x;i<1088;i+=256) insh[i] = (i<1024)? g[(size_t)b*1024+i] : lv[(size_t)b*64 + (i-1024)];
  __syncthreads();
  int o = threadIdx.x;
  float s=0.f;
  for (int c=0;c<1088;c++) s = fmaf(h1w[(size_t)o*1280+c], insh[c], s);
  bias1[(size_t)b*256+o]=s;
}

// ---------------- head conv layers ----------------
template<int CI, int O, bool ACT>
__global__ __launch_bounds__(256) void conv1_kernel(
    const float* __restrict__ inT, const float* __restrict__ wT,
    const float* __restrict__ bias, float* __restrict__ outT, int N){
  const int b = blockIdx.y, n0 = blockIdx.x*32;
  __shared__ float insh[32*CI];
  const float* src = inT + ((size_t)b*N + n0)*CI;
  for (int i=threadIdx.x;i<32*CI;i+=256) insh[i] = src[i];
  __syncthreads();
  constexpr int NREP = 256/O;
  constexpr int NLOC = 32/NREP;
  const int o = threadIdx.x % O, rep = threadIdx.x / O;
  float acc[NLOC];
#pragma unroll
  for (int t=0;t<NLOC;t++) acc[t]=0.f;
  for (int c=0;c<CI;c++){
    float wv = wT[c*O + o];
#pragma unroll
    for (int t=0;t<NLOC;t++) acc[t] = fmaf(wv, insh[(t*NREP+rep)*CI + c], acc[t]);
  }
  float bv = bias ? bias[(size_t)b*O + o] : 0.f;
#pragma unroll
  for (int t=0;t<NLOC;t++){
    float s = acc[t] + bv;
    if (ACT) s = lrelu(s);
    outT[((size_t)b*N + n0 + t*NREP + rep)*O + o] = s;
  }
}

// ---------------- final layer: 128 -> 50, rows-layout output (B,50,N) ----------------
__global__ __launch_bounds__(256) void conv_out_kernel(
    const float* __restrict__ inT, const float* __restrict__ wT,
    float* __restrict__ out, int N){
  const int b = blockIdx.y, n0 = blockIdx.x*32;
  __shared__ float insh[32*129];
  const float* src = inT + ((size_t)b*N + n0)*128;
  for (int i=threadIdx.x;i<32*128;i+=256){ int nn=i>>7, c=i&127; insh[nn*129+c]=src[i]; }
  __syncthreads();
  const int nl = threadIdx.x & 31, og = threadIdx.x >> 5;
  float acc[7];
#pragma unroll
  for (int t=0;t<7;t++) acc[t]=0.f;
  for (int c=0;c<128;c++){
    float iv = insh[nl*129+c];
#pragma unroll
    for (int t=0;t<7;t++){
      int o = og + 8*t;
      float wv = (o<50)? wT[c*50+o] : 0.f;
      acc[t] = fmaf(wv, iv, acc[t]);
    }
  }
#pragma unroll
  for (int t=0;t<7;t++){
    int o = og + 8*t;
    if (o < 50) out[((size_t)b*50+o)*N + n0 + nl] = acc[t];
  }
}

extern "C" void kernel_launch(void* const* d_in, const int* in_sizes, int n_in,
                              void* d_out, int out_size, void* d_ws, size_t ws_size,
                              hipStream_t stream){
  const float* x    = (const float*)d_in[0];
  const float* l    = (const float*)d_in[1];
  const float* t_c1 = (const float*)d_in[2];
  const float* t_c2 = (const float*)d_in[3];
  const float* t_c3 = (const float*)d_in[4];
  const float* t_f1 = (const float*)d_in[5];
  const float* t_f2 = (const float*)d_in[6];
  const float* t_f3w= (const float*)d_in[7];
  const float* t_f3b= (const float*)d_in[8];
  const float* b1a  = (const float*)d_in[9];
  const float* b1b  = (const float*)d_in[10];
  const float* b2a  = (const float*)d_in[11];
  const float* b2b  = (const float*)d_in[12];
  const float* b3a  = (const float*)d_in[13];
  const float* m1   = (const float*)d_in[14];
  const float* m2   = (const float*)d_in[15];
  const float* h1   = (const float*)d_in[16];
  const float* h2   = (const float*)d_in[17];
  const float* h3   = (const float*)d_in[18];
  const float* h4   = (const float*)d_in[19];
  float* out = (float*)d_out;
  float* ws = (float*)d_ws;
  const int N = NPTS, B = BATCH;

  size_t off = 0;
  auto alloc = [&](size_t nf){ float* p = ws + off; off += nf; return p; };
  float* WT_TC3 = alloc((size_t)128*1024);
  float* WT_M1  = alloc((size_t)192*1024);
  float* WT_H1B = alloc((size_t)192*256);
  float* WT_H2  = alloc((size_t)256*256);
  float* WT_H3  = alloc((size_t)256*128);
  float* WT_H4  = alloc((size_t)128*64);
  int*   IDXT   = (int*)alloc((size_t)B*N*KNN);
  float* XX     = alloc((size_t)B*N);
  float* TT     = alloc((size_t)B*N*128);
  float* PARTIAL= alloc((size_t)B*8*1024);
  float* TG     = alloc((size_t)B*1024);
  float* T512   = alloc((size_t)B*512);
  float* T256   = alloc((size_t)B*256);
  float* T9     = alloc((size_t)B*16);
  float* XP     = alloc((size_t)B*3*N);
  float* CATT   = alloc((size_t)B*N*192);
  float* G      = alloc((size_t)B*1024);
  float* LV     = alloc((size_t)B*64);
  float* BIAS1  = alloc((size_t)B*256);
  float* H1T    = alloc((size_t)B*N*256);
  float* H2T    = alloc((size_t)B*N*256);
  float* H3T    = alloc((size_t)B*N*128);
  (void)ws_size; (void)in_sizes; (void)n_in; (void)out_size;

  dim3 blk(256);
  dim3 eblk(128);
  // weight transposes
  transpose_kernel<<<dim3((1024*128+255)/256), blk, 0, stream>>>(t_c3, WT_TC3, 1024,128,128,0);
  transpose_kernel<<<dim3((1024*192+255)/256), blk, 0, stream>>>(m1,  WT_M1, 1024,192,192,0);
  transpose_kernel<<<dim3((256*192+255)/256),  blk, 0, stream>>>(h1, WT_H1B, 256,192,1280,1088);
  transpose_kernel<<<dim3((256*256+255)/256),  blk, 0, stream>>>(h2, WT_H2, 256,256,256,0);
  transpose_kernel<<<dim3((128*256+255)/256),  blk, 0, stream>>>(h3, WT_H3, 128,256,256,0);
  transpose_kernel<<<dim3((50*128+255)/256),   blk, 0, stream>>>(h4, WT_H4, 50,128,128,0);

  // t-path
  norms_rows_kernel<0><<<dim3(N/256,B), blk, 0, stream>>>(x, XX, N);
  knn3_kernel<0><<<dim3(N/4,B), blk, 0, stream>>>(x, XX, IDXT, N);
  edgeA_kernel<<<dim3(N/16,B), blk, 0, stream>>>(x, IDXT, t_c1, t_c2, TT, N);
  convmax_kernel<128,0><<<dim3(16,8,B), eblk, 0, stream>>>(TT, WT_TC3, PARTIAL, N);
  reduce_max_kernel<0><<<dim3(4,B), blk, 0, stream>>>(PARTIAL, TG);
  fc_kernel<<<dim3(B), dim3(512), 0, stream>>>(TG, t_f1, nullptr, T512, 1024, 512, 1);
  fc_kernel<<<dim3(B), dim3(512), 0, stream>>>(T512, t_f2, nullptr, T256, 512, 256, 1);
  fc_kernel<<<dim3(B), dim3(512), 0, stream>>>(T256, t_f3w, t_f3b, T9, 256, 9, 0);
  transform_kernel<<<dim3(N/256,B), blk, 0, stream>>>(x, T9, XP, N);

  // edge block 1 (transformed points, 3ch)
  norms_rows_kernel<1><<<dim3(N/256,B), blk, 0, stream>>>(XP, XX, N);
  knn3_kernel<1><<<dim3(N/4,B), blk, 0, stream>>>(XP, XX, IDXT, N);
  edgeB_kernel<<<dim3(N/32,B), eblk, 0, stream>>>(XP, IDXT, b1a, b1b, CATT, N);

  // edge block 2 (x1 = CATT[...,0:64])
  norms_cl_kernel<0><<<dim3(N/256,B), blk, 0, stream>>>(CATT, 0, XX, N);
  knn64_kernel<0><<<dim3(N/4,B), blk, 0, stream>>>(CATT, 0, XX, IDXT, N);
  edgeC_kernel<<<dim3(N/32,B), eblk, 0, stream>>>(CATT, 0, IDXT, b2a, b2b, CATT, 64, N);

  // edge block 3 (x2 = CATT[...,64:128])
  norms_cl_kernel<1><<<dim3(N/256,B), blk, 0, stream>>>(CATT, 64, XX, N);
  knn64_kernel<1><<<dim3(N/4,B), blk, 0, stream>>>(CATT, 64, XX, IDXT, N);
  edgeD_kernel<<<dim3(N/32,B), eblk, 0, stream>>>(CATT, 64, IDXT, b3a, CATT, 128, N);

  // global feature + head
  convmax_kernel<192,1><<<dim3(16,8,B), eblk, 0, stream>>>(CATT, WT_M1, PARTIAL, N);
  reduce_max_kernel<1><<<dim3(4,B), blk, 0, stream>>>(PARTIAL, G);
  fc_kernel<<<dim3(B), dim3(512), 0, stream>>>(l, m2, nullptr, LV, 16, 64, 1);
  bias1_kernel<<<dim3(B), blk, 0, stream>>>(G, LV, h1, BIAS1);
  conv1_kernel<192,256,true><<<dim3(N/32,B), blk, 0, stream>>>(CATT, WT_H1B, BIAS1, H1T, N);
  conv1_kernel<256,256,true><<<dim3(N/32,B), blk, 0, stream>>>(H1T, WT_H2, nullptr, H2T, N);
  conv1_kernel<256,128,true><<<dim3(N/32,B), blk, 0, stream>>>(H2T, WT_H3, nullptr, H3T, N);
  conv_out_kernel<<<dim3(N/32,B), blk, 0, stream>>>(H3T, WT_H4, out, N);
}

// Round 8
// 2326.422 us; speedup vs baseline: 1.0862x; 1.0247x over previous
//
#include <hip/hip_runtime.h>
#include <cstdint>

#define NPTS 2048
#define BATCH 8
#define KNN 40

__device__ __forceinline__ float lrelu(float v){ return fmaxf(v, 0.2f*v); }
__device__ __forceinline__ bool better(float v1,int i1,float v2,int i2){
  return (v1>v2) || (v1==v2 && i1<i2);
}
__device__ __forceinline__ float4 ld4(const float* p){ return *(const float4*)p; }

// insert (d,m) into sorted-desc 8-list if it beats the tail; static CE chain.
#define INSERT8(v,id,d,m) \
  if (better(d, m, v[7], id[7])){ \
    v[7]=d; id[7]=m; \
    { if (better(v[7],id[7],v[6],id[6])){ float tv=v[6];int ti=id[6]; v[6]=v[7];id[6]=id[7]; v[7]=tv;id[7]=ti; } } \
    { if (better(v[6],id[6],v[5],id[5])){ float tv=v[5];int ti=id[5]; v[5]=v[6];id[5]=id[6]; v[6]=tv;id[6]=ti; } } \
    { if (better(v[5],id[5],v[4],id[4])){ float tv=v[4];int ti=id[4]; v[4]=v[5];id[4]=id[5]; v[5]=tv;id[5]=ti; } } \
    { if (better(v[4],id[4],v[3],id[3])){ float tv=v[3];int ti=id[3]; v[3]=v[4];id[3]=id[4]; v[4]=tv;id[4]=ti; } } \
    { if (better(v[3],id[3],v[2],id[2])){ float tv=v[2];int ti=id[2]; v[2]=v[3];id[2]=id[3]; v[3]=tv;id[3]=ti; } } \
    { if (better(v[2],id[2],v[1],id[1])){ float tv=v[1];int ti=id[1]; v[1]=v[2];id[1]=id[2]; v[2]=tv;id[2]=ti; } } \
    { if (better(v[1],id[1],v[0],id[0])){ float tv=v[0];int ti=id[0]; v[0]=v[1];id[0]=id[1]; v[1]=tv;id[1]=ti; } } \
  }

// ---------------- generic transpose: dst[c*R+r] = src[r*ld+off+c] ----------------
__global__ void transpose_kernel(const float* __restrict__ src, float* __restrict__ dst,
                                 int R, int C, int ld, int off){
  int i = blockIdx.x*256 + threadIdx.x;
  if (i < R*C){ int r = i / C, c = i % C; dst[c*R + r] = src[r*ld + off + c]; }
}

// ---------------- squared norms, rows layout (B,3,N) ----------------
template<int TAG>
__global__ void norms_rows_kernel(const float* __restrict__ x, float* __restrict__ xx, int N){
  int b = blockIdx.y; int n = blockIdx.x*256 + threadIdx.x;
  const float* xb = x + (size_t)b*3*N;
  float v0 = xb[n], v1 = xb[N+n], v2 = xb[2*N+n];
  xx[(size_t)b*N + n] = v0*v0 + v1*v1 + v2*v2;
}

// ---------------- squared norms, channel-last 64ch slice of (B,N,192) ----------------
template<int TAG>
__global__ void norms_cl_kernel(const float* __restrict__ f, int off, float* __restrict__ xx, int N){
  int b = blockIdx.y; int n = blockIdx.x*256 + threadIdx.x;
  const float4* p = (const float4*)(f + ((size_t)b*N + n)*192 + off);
  float s = 0.f;
#pragma unroll
  for (int q=0;q<16;q++){ float4 v = p[q]; s += v.x*v.x + v.y*v.y + v.z*v.z + v.w*v.w; }
  xx[(size_t)b*N + n] = s;
}

__device__ __forceinline__ void sort8(float (&v)[8], int (&id)[8]){
#define CE(a,bq) { if (better(v[bq],id[bq],v[a],id[a])){ float tv=v[a]; int ti=id[a]; v[a]=v[bq]; id[a]=id[bq]; v[bq]=tv; id[bq]=ti; } }
  CE(0,1) CE(2,3) CE(4,5) CE(6,7)
  CE(0,2) CE(1,3) CE(4,6) CE(5,7)
  CE(1,2) CE(5,6)
  CE(0,4) CE(1,5) CE(2,6) CE(3,7)
  CE(2,4) CE(3,5)
  CE(1,2) CE(3,4) CE(5,6)
#undef CE
}

// ---------------- knn 3-channel: 4 queries/block (1/wave), zero LDS, zero barriers ----------------
template<int TAG>
__global__ __launch_bounds__(256) void knn3_kernel(
    const float* __restrict__ xrows, const float* __restrict__ xx,
    int* __restrict__ idxT, int N){
  const int b = blockIdx.y, tid = threadIdx.x;
  const int w = tid>>6, lane = tid&63;
  const int nq = blockIdx.x*4 + w;
  const float* xb = xrows + (size_t)b*3*N;
  const float* xxb = xx + (size_t)b*N;
  float c0 = xb[nq], c1 = xb[N+nq], c2 = xb[2*N+nq];
  float xxn = xxb[nq];
  float v[8]; int id[8];
#pragma unroll
  for (int j=0;j<8;j++){ v[j]=-__builtin_inff(); id[j]=0x7FFFFFFF; }
  for (int j=0;j<32;j++){
    int m = j*64 + lane;
    float s = c0*xb[m] + c1*xb[N+m] + c2*xb[2*N+m];
    float d = 2.f*s - xxn - xxb[m];
    INSERT8(v, id, d, m)
  }
  float lastv = 0.f; int lasti = 0;
  int win = 0;
  for (int r=0;r<KNN;r++){
    float bv = v[0]; int bi = id[0];
#pragma unroll
    for (int off=32; off; off>>=1){
      float ov = __shfl_xor(bv, off);
      int   oi = __shfl_xor(bi, off);
      if (better(ov, oi, bv, bi)){ bv = ov; bi = oi; }
    }
    if (lane == r) win = bi;
    if (id[0] == bi){
      lastv = v[0]; lasti = id[0];
#pragma unroll
      for (int j=0;j<7;j++){ v[j]=v[j+1]; id[j]=id[j+1]; }
      v[7] = -__builtin_inff(); id[7] = 0x7FFFFFFF;
      if (id[0] == 0x7FFFFFFF){   // rare refill: best strictly worse than last pop
        float nv = -__builtin_inff(); int ni = 0x7FFFFFFF;
        for (int j=0;j<32;j++){
          int m = j*64 + lane;
          float s = c0*xb[m] + c1*xb[N+m] + c2*xb[2*N+m];
          float dd = 2.f*s - xxn - xxb[m];
          if (better(lastv, lasti, dd, m) && better(dd, m, nv, ni)){ nv=dd; ni=m; }
        }
        v[0] = nv; id[0] = ni;
      }
    }
  }
  if (lane < KNN) idxT[((size_t)b*KNN + lane)*N + nq] = win;
}

// ---------------- knn 64-channel (channel-last), 4 queries/block ----------------
// v6 (R5 champion): 32-cand tile (8 KiB) + 4x8K strips = 40960 B -> 16 waves/CU.
// Wave-count sweep (8w=449/379, 12w=324.7, 16w=322) shows DS+VALU issue floor reached.
template<int TAG>
__global__ __launch_bounds__(256) void knn64_kernel(
    const float* __restrict__ featT, int featOff,
    const float* __restrict__ xx, int* __restrict__ idxT, int N){
  const int b = blockIdx.y, tid = threadIdx.x;
  const int w = tid>>6, lane = tid&63;
  __shared__ float cand[32*64];    // xor-swizzled [cand][ch] tile (8 KiB), block-shared
  __shared__ float dist[4*2048];   // wave-private strips (32 KiB)
  const float* fb = featT + featOff;
  const float* xxb = xx + (size_t)b*N;
  const int nq = blockIdx.x*4 + w;
  const int h = lane>>5;           // channel half this lane covers
  float4 ctr8[8];
  {
    const float4* cp = (const float4*)(fb + ((size_t)b*N + nq)*192);
#pragma unroll
    for (int q=0;q<8;q++) ctr8[q] = cp[h*8 + q];
  }
  float xxn = xxb[nq];
  float* dw = &dist[w*2048];
  float4 g[2];
#pragma unroll
  for (int r=0;r<2;r++){
    int k2 = tid + 256*r;
    int c = k2>>4, f = k2&15;
    g[r] = ld4(&fb[((size_t)b*N + c)*192 + 4*f]);
  }
  const int cc = lane&31, swz = cc&15, qb = h*8;
  for (int t=0;t<64;t++){
    __syncthreads();                 // prev compute done reading cand
#pragma unroll
    for (int r=0;r<2;r++){
      int k2 = tid + 256*r;
      int c = k2>>4, f = k2&15;
      *(float4*)&cand[(c<<6) + ((f ^ (c&15))<<2)] = g[r];
    }
    __syncthreads();
    if (t+1 < 64){                   // issue next tile's loads; latency overlaps compute
      int m0n = (t+1)*32;
#pragma unroll
      for (int r=0;r<2;r++){
        int k2 = tid + 256*r;
        int c = k2>>4, f = k2&15;
        g[r] = ld4(&fb[((size_t)b*N + m0n + c)*192 + 4*f]);
      }
    }
    float s0=0.f,s1=0.f,s2=0.f,s3=0.f;
#pragma unroll
    for (int j=0;j<8;j++){
      float4 mv = *(const float4*)&cand[(cc<<6) + (((qb + j) ^ swz)<<2)];
      s0 = fmaf(ctr8[j].x, mv.x, s0);
      s1 = fmaf(ctr8[j].y, mv.y, s1);
      s2 = fmaf(ctr8[j].z, mv.z, s2);
      s3 = fmaf(ctr8[j].w, mv.w, s3);
    }
    float p = (s0+s1)+(s2+s3);
    float tot = p + __shfl_xor(p, 32);    // combine channel halves (commutative -> both halves identical)
    if (h == (t&1)){                      // owner lane (m & 63 == lane) writes its strip slot
      int m = t*32 + cc;
      dw[(t>>1)*64 + lane] = 2.f*tot - xxn - xxb[m];
    }
  }
  // ---- per-lane exact top-8 of its 32 entries (sorted desc by (v desc, idx asc)) ----
  float v[8]; int id[8];
#pragma unroll
  for (int j=0;j<8;j++){ v[j]=dw[j*64+lane]; id[j]=j*64+lane; }
  sort8(v, id);
#pragma unroll
  for (int gq=1; gq<4; gq++){
    float a[8]; int ai[8];
#pragma unroll
    for (int j=0;j<8;j++){ a[j]=dw[(gq*8+j)*64+lane]; ai[j]=(gq*8+j)*64+lane; }
    sort8(a, ai);
    float m_[8]; int mi_[8];
#pragma unroll
    for (int k=0;k<8;k++){
      if (better(a[7-k], ai[7-k], v[k], id[k])){ m_[k]=a[7-k]; mi_[k]=ai[7-k]; }
      else                                     { m_[k]=v[k];   mi_[k]=id[k]; }
    }
#define CEB(x,y) { if (better(m_[y],mi_[y],m_[x],mi_[x])){ float tv=m_[x];int ti=mi_[x]; m_[x]=m_[y];mi_[x]=mi_[y]; m_[y]=tv;mi_[y]=ti; } }
    CEB(0,4) CEB(1,5) CEB(2,6) CEB(3,7)
    CEB(0,2) CEB(1,3) CEB(4,6) CEB(5,7)
    CEB(0,1) CEB(2,3) CEB(4,5) CEB(6,7)
#undef CEB
#pragma unroll
    for (int k=0;k<8;k++){ v[k]=m_[k]; id[k]=mi_[k]; }
  }
  // ---- 40 extraction rounds: butterfly + pop-shift; zero barriers, zero LDS steady state ----
  float lastv = 0.f; int lasti = 0;
  int win = 0;
  for (int r=0;r<KNN;r++){
    float bv = v[0]; int bi = id[0];
#pragma unroll
    for (int off=32; off; off>>=1){
      float ov = __shfl_xor(bv, off);
      int   oi = __shfl_xor(bi, off);
      if (better(ov, oi, bv, bi)){ bv = ov; bi = oi; }
    }
    if (lane == r) win = bi;
    if (id[0] == bi){                // unique owner (indices unique)
      lastv = v[0]; lasti = id[0];
#pragma unroll
      for (int j=0;j<7;j++){ v[j]=v[j+1]; id[j]=id[j+1]; }
      v[7] = -__builtin_inff(); id[7] = 0x7FFFFFFF;
      if (id[0] == 0x7FFFFFFF){      // rare: lane contributed >8 of top-40 -> refill head
        float nv = -__builtin_inff(); int ni = 0x7FFFFFFF;
        for (int j=0;j<32;j++){
          float vv = dw[j*64 + lane]; int m = j*64 + lane;
          if (better(lastv, lasti, vv, m) && better(vv, m, nv, ni)){ nv=vv; ni=m; }
        }
        v[0] = nv; id[0] = ni;
      }
    }
  }
  if (lane < KNN) idxT[((size_t)b*KNN + lane)*N + nq] = win;
}

// ==================== register-tiled edge kernels ====================

// ---- edgeA (t-path): 3ch -> 64 -> 128, max over k ----
__global__ __launch_bounds__(256) void edgeA_kernel(
    const float* __restrict__ x, const int* __restrict__ idxT,
    const float* __restrict__ w1, const float* __restrict__ w2,
    float* __restrict__ tT, int N){
  __shared__ float w1aT[3*64];
  __shared__ float wd3T[3*64];
  __shared__ float w2T[64*128];      // [c][o]; reused as merge buffer (4 x 16r x 128o)
  __shared__ float aT3[4][3*16];
  __shared__ float s1T[4][64*16];    // [c][r]
  const int tid = threadIdx.x, w = tid>>6, lane = tid&63;
  const int oq = lane&7, rg = lane>>3;
  const int o0 = oq*8, r0 = rg*2;
  const int b = blockIdx.y, n0 = blockIdx.x*16;
  for (int i=tid; i<192; i+=256){
    int o = i&63, c = i/64;
    float a = w1[o*6+c];
    w1aT[c*64+o] = a; wd3T[c*64+o] = w1[o*6+3+c] - a;
  }
  for (int i=tid; i<128*64; i+=256){
    int o = i>>6, c = i&63;
    w2T[c*128+o] = w2[o*64+c];
  }
  if (tid < 48){ int c = tid>>4, r = tid&15; aT3[0][c*16+r] = x[((size_t)b*3+c)*N + n0 + r]; }
  __syncthreads();
  float base[16];
#pragma unroll
  for (int i=0;i<16;i++) base[i]=0.f;
#pragma unroll
  for (int c=0;c<3;c++){
    float4 wA = ld4(&wd3T[c*64+o0]), wB = ld4(&wd3T[c*64+o0+4]);
    float2 av = *(const float2*)&aT3[0][c*16+r0];
    float wv[8] = {wA.x,wA.y,wA.z,wA.w,wB.x,wB.y,wB.z,wB.w};
    float rv[2] = {av.x,av.y};
#pragma unroll
    for (int oo=0;oo<8;oo++)
#pragma unroll
      for (int rr=0;rr<2;rr++) base[oo*2+rr] = fmaf(wv[oo], rv[rr], base[oo*2+rr]);
  }
  __syncthreads();   // all waves done reading aT3[0] before k-loop overwrites
  float mx[32];
#pragma unroll
  for (int i=0;i<32;i++) mx[i] = -__builtin_inff();
  for (int it=0; it<10; it++){
    int k = it*4 + w;
    int m = idxT[((size_t)b*KNN + k)*N + n0 + (lane&15)];
    if (lane < 48){ int c = lane>>4; aT3[w][c*16 + (lane&15)] = x[((size_t)b*3+c)*N + m]; }
    // stage1 (64 o x 16 r)
    float acc[16];
#pragma unroll
    for (int i=0;i<16;i++) acc[i] = base[i];
#pragma unroll
    for (int c=0;c<3;c++){
      float4 wA = ld4(&w1aT[c*64+o0]), wB = ld4(&w1aT[c*64+o0+4]);
      float2 av = *(const float2*)&aT3[w][c*16+r0];
      float wv[8] = {wA.x,wA.y,wA.z,wA.w,wB.x,wB.y,wB.z,wB.w};
      float rv[2] = {av.x,av.y};
#pragma unroll
      for (int oo=0;oo<8;oo++)
#pragma unroll
        for (int rr=0;rr<2;rr++) acc[oo*2+rr] = fmaf(wv[oo], rv[rr], acc[oo*2+rr]);
    }
#pragma unroll
    for (int oo=0;oo<8;oo++){
      float2 sv; sv.x = lrelu(acc[oo*2]); sv.y = lrelu(acc[oo*2+1]);
      *(float2*)&s1T[w][(o0+oo)*16 + r0] = sv;
    }
    // stage2 (128 o x 16 r): 4 panels, o = p*32 + oq*4 -> 32 banks, conflict-free
    float acc2[32];
#pragma unroll
    for (int i=0;i<32;i++) acc2[i]=0.f;
    for (int c=0;c<64;c++){
      float2 av = *(const float2*)&s1T[w][c*16 + r0];
#pragma unroll
      for (int p=0;p<4;p++){
        float4 wv = ld4(&w2T[c*128 + p*32 + oq*4]);
        acc2[p*8+0] = fmaf(wv.x, av.x, acc2[p*8+0]);
        acc2[p*8+1] = fmaf(wv.x, av.y, acc2[p*8+1]);
        acc2[p*8+2] = fmaf(wv.y, av.x, acc2[p*8+2]);
        acc2[p*8+3] = fmaf(wv.y, av.y, acc2[p*8+3]);
        acc2[p*8+4] = fmaf(wv.z, av.x, acc2[p*8+4]);
        acc2[p*8+5] = fmaf(wv.z, av.y, acc2[p*8+5]);
        acc2[p*8+6] = fmaf(wv.w, av.x, acc2[p*8+6]);
        acc2[p*8+7] = fmaf(wv.w, av.y, acc2[p*8+7]);
      }
    }
#pragma unroll
    for (int i=0;i<32;i++) mx[i] = fmaxf(mx[i], lrelu(acc2[i]));
  }
  __syncthreads();   // all waves done reading w2T -> reuse as merge buffer
#pragma unroll
  for (int rr=0;rr<2;rr++){
#pragma unroll
    for (int p=0;p<4;p++){
      float4 a = make_float4(mx[p*8+0+rr], mx[p*8+2+rr], mx[p*8+4+rr], mx[p*8+6+rr]);
      *(float4*)&w2T[w*2048 + (r0+rr)*128 + p*32 + oq*4] = a;
    }
  }
  __syncthreads();
  for (int i=tid; i<2048; i+=256){
    float vv = fmaxf(fmaxf(w2T[i], w2T[2048+i]), fmaxf(w2T[4096+i], w2T[6144+i]));
    int r = i>>7, o = i&127;
    tT[((size_t)b*N + n0 + r)*128 + o] = vv;
  }
}

// ---- edgeB: 3ch -> 64 -> 64, max over k ----
__global__ __launch_bounds__(128) void edgeB_kernel(
    const float* __restrict__ xp, const int* __restrict__ idxT,
    const float* __restrict__ w1, const float* __restrict__ w2,
    float* __restrict__ catT, int N){
  __shared__ float w1aT[3*64];
  __shared__ float wd3T[3*64];
  __shared__ float w2T[64*64];
  __shared__ float aT3[2][3*32];
  __shared__ float s1T[2][64*32];
  const int tid = threadIdx.x, w = tid>>6, lane = tid&63;
  const int oq = lane&7, rg = lane>>3;
  const int o0 = oq*8, r0 = rg*4;
  const int b = blockIdx.y, n0 = blockIdx.x*32;
  for (int i=tid; i<192; i+=128){
    int o = i&63, c = i>>6;
    float a = w1[o*6+c], bb = w1[o*6+3+c];
    w1aT[c*64+o] = a; wd3T[c*64+o] = bb - a;
  }
  for (int i=tid; i<64*64; i+=128){
    int o = i>>6, c = i&63;
    w2T[c*64+o] = w2[o*64+c];
  }
  if (tid < 32){
#pragma unroll
    for (int c=0;c<3;c++) aT3[0][c*32+tid] = xp[((size_t)b*3+c)*N + n0 + tid];
  }
  __syncthreads();
  float base[32];
#pragma unroll
  for (int i=0;i<32;i++) base[i]=0.f;
#pragma unroll
  for (int c=0;c<3;c++){
    float4 w0 = ld4(&wd3T[c*64+o0]), w1v = ld4(&wd3T[c*64+o0+4]);
    float4 av = ld4(&aT3[0][c*32+r0]);
    float wv[8] = {w0.x,w0.y,w0.z,w0.w,w1v.x,w1v.y,w1v.z,w1v.w};
    float rv[4] = {av.x,av.y,av.z,av.w};
#pragma unroll
    for (int oo=0;oo<8;oo++)
#pragma unroll
      for (int rr=0;rr<4;rr++) base[oo*4+rr] = fmaf(wv[oo], rv[rr], base[oo*4+rr]);
  }
  __syncthreads();
  float mx[32];
#pragma unroll
  for (int i=0;i<32;i++) mx[i] = -__builtin_inff();
  for (int it=0; it<20; it++){
    int k = it*2 + w;
    {
      int row = lane&31;
      int m = idxT[((size_t)b*KNN + k)*N + n0 + row];
      if (lane < 32){
#pragma unroll
        for (int c=0;c<3;c++) aT3[w][c*32+row] = xp[((size_t)b*3+c)*N + m];
      }
    }
    float acc[32];
#pragma unroll
    for (int i=0;i<32;i++) acc[i] = base[i];
#pragma unroll
    for (int c=0;c<3;c++){
      float4 w0 = ld4(&w1aT[c*64+o0]), w1v = ld4(&w1aT[c*64+o0+4]);
      float4 av = ld4(&aT3[w][c*32+r0]);
      float wv[8] = {w0.x,w0.y,w0.z,w0.w,w1v.x,w1v.y,w1v.z,w1v.w};
      float rv[4] = {av.x,av.y,av.z,av.w};
#pragma unroll
      for (int oo=0;oo<8;oo++)
#pragma unroll
        for (int rr=0;rr<4;rr++) acc[oo*4+rr] = fmaf(wv[oo], rv[rr], acc[oo*4+rr]);
    }
#pragma unroll
    for (int oo=0;oo<8;oo++){
      float4 sv = make_float4(lrelu(acc[oo*4+0]), lrelu(acc[oo*4+1]), lrelu(acc[oo*4+2]), lrelu(acc[oo*4+3]));
      *(float4*)&s1T[w][(o0+oo)*32 + r0] = sv;
    }
    float acc2[32];
#pragma unroll
    for (int i=0;i<32;i++) acc2[i]=0.f;
    for (int c=0;c<64;c++){
      float4 w0 = ld4(&w2T[c*64+o0]), w1v = ld4(&w2T[c*64+o0+4]);
      float4 av = ld4(&s1T[w][c*32+r0]);
      float wv[8] = {w0.x,w0.y,w0.z,w0.w,w1v.x,w1v.y,w1v.z,w1v.w};
      float rv[4] = {av.x,av.y,av.z,av.w};
#pragma unroll
      for (int oo=0;oo<8;oo++)
#pragma unroll
        for (int rr=0;rr<4;rr++) acc2[oo*4+rr] = fmaf(wv[oo], rv[rr], acc2[oo*4+rr]);
    }
#pragma unroll
    for (int i=0;i<32;i++) mx[i] = fmaxf(mx[i], lrelu(acc2[i]));
  }
  __syncthreads();
#pragma unroll
  for (int rr=0;rr<4;rr++){
    float4 a = make_float4(mx[0*4+rr], mx[1*4+rr], mx[2*4+rr], mx[3*4+rr]);
    float4 bq = make_float4(mx[4*4+rr], mx[5*4+rr], mx[6*4+rr], mx[7*4+rr]);
    *(float4*)&s1T[w][(r0+rr)*64 + o0] = a;
    *(float4*)&s1T[w][(r0+rr)*64 + o0 + 4] = bq;
  }
  __syncthreads();
  for (int i=tid; i<2048; i+=128){
    float v = fmaxf(s1T[0][i], s1T[1][i]);
    int r = i>>6, o = i&63;
    catT[((size_t)b*N + n0 + r)*192 + o] = v;
  }
}

// ---- edgeC: 64ch -> 64 -> 64, max over k ----
__global__ __launch_bounds__(128) void edgeC_kernel(
    const float* __restrict__ inT, int inOff, const int* __restrict__ idxT,
    const float* __restrict__ w1, const float* __restrict__ w2,
    float* __restrict__ catT, int outOff, int N){
  __shared__ float w1T[64*64];
  __shared__ float w2T[64*64];
  __shared__ float aT[2][64*32];
  __shared__ float s1T[2][64*32];
  const int tid = threadIdx.x, w = tid>>6, lane = tid&63;
  const int oq = lane&7, rg = lane>>3;
  const int o0 = oq*8, r0 = rg*4;
  const int b = blockIdx.y, n0 = blockIdx.x*32;
  for (int i=tid; i<64*64; i+=128){
    int o = i>>6, c = i&63;
    float a = w1[o*128+c], bb = w1[o*128+64+c];
    w1T[c*64+o] = a; w2T[c*64+o] = bb - a;
  }
  for (int i=tid; i<512; i+=128){
    int p = i>>4, cq = i&15;
    float4 v = ld4(&inT[((size_t)b*N + n0 + p)*192 + inOff + cq*4]);
    aT[0][(cq*4+0)*32+p] = v.x; aT[0][(cq*4+1)*32+p] = v.y;
    aT[0][(cq*4+2)*32+p] = v.z; aT[0][(cq*4+3)*32+p] = v.w;
  }
  __syncthreads();
  float base[32];
#pragma unroll
  for (int i=0;i<32;i++) base[i]=0.f;
  for (int c=0;c<64;c++){
    float4 w0 = ld4(&w2T[c*64+o0]), w1v = ld4(&w2T[c*64+o0+4]);
    float4 av = ld4(&aT[0][c*32+r0]);
    float wv[8] = {w0.x,w0.y,w0.z,w0.w,w1v.x,w1v.y,w1v.z,w1v.w};
    float rv[4] = {av.x,av.y,av.z,av.w};
#pragma unroll
    for (int oo=0;oo<8;oo++)
#pragma unroll
      for (int rr=0;rr<4;rr++) base[oo*4+rr] = fmaf(wv[oo], rv[rr], base[oo*4+rr]);
  }
  __syncthreads();
  for (int i=tid; i<64*64; i+=128){
    int o = i>>6, c = i&63;
    w2T[c*64+o] = w2[o*64+c];
  }
  __syncthreads();
  float mx[32];
#pragma unroll
  for (int i=0;i<32;i++) mx[i] = -__builtin_inff();
  const int row = lane&31, ch = lane>>5;
  for (int it=0; it<20; it++){
    int k = it*2 + w;
    {
      int m = idxT[((size_t)b*KNN + k)*N + n0 + row];
      const float* src = &inT[((size_t)b*N + m)*192 + inOff + ch*32];
      float4 g[8];
#pragma unroll
      for (int j=0;j<8;j++) g[j] = ld4(src + j*4);
#pragma unroll
      for (int j=0;j<8;j++){
        aT[w][(ch*32+j*4+0)*32 + row] = g[j].x;
        aT[w][(ch*32+j*4+1)*32 + row] = g[j].y;
        aT[w][(ch*32+j*4+2)*32 + row] = g[j].z;
        aT[w][(ch*32+j*4+3)*32 + row] = g[j].w;
      }
    }
    float acc[32];
#pragma unroll
    for (int i=0;i<32;i++) acc[i] = base[i];
    for (int c=0;c<64;c++){
      float4 w0 = ld4(&w1T[c*64+o0]), w1v = ld4(&w1T[c*64+o0+4]);
      float4 av = ld4(&aT[w][c*32+r0]);
      float wv[8] = {w0.x,w0.y,w0.z,w0.w,w1v.x,w1v.y,w1v.z,w1v.w};
      float rv[4] = {av.x,av.y,av.z,av.w};
#pragma unroll
      for (int oo=0;oo<8;oo++)
#pragma unroll
        for (int rr=0;rr<4;rr++) acc[oo*4+rr] = fmaf(wv[oo], rv[rr], acc[oo*4+rr]);
    }
#pragma unroll
    for (int oo=0;oo<8;oo++){
      float4 sv = make_float4(lrelu(acc[oo*4+0]), lrelu(acc[oo*4+1]), lrelu(acc[oo*4+2]), lrelu(acc[oo*4+3]));
      *(float4*)&s1T[w][(o0+oo)*32 + r0] = sv;
    }
    float acc2[32];
#pragma unroll
    for (int i=0;i<32;i++) acc2[i]=0.f;
    for (int c=0;c<64;c++){
      float4 w0 = ld4(&w2T[c*64+o0]), w1v = ld4(&w2T[c*64+o0+4]);
      float4 av = ld4(&s1T[w][c*32+r0]);
      float wv[8] = {w0.x,w0.y,w0.z,w0.w,w1v.x,w1v.y,w1v.z,w1v.w};
      float rv[4] = {av.x,av.y,av.z,av.w};
#pragma unroll
      for (int oo=0;oo<8;oo++)
#pragma unroll
        for (int rr=0;rr<4;rr++) acc2[oo*4+rr] = fmaf(wv[oo], rv[rr], acc2[oo*4+rr]);
    }
#pragma unroll
    for (int i=0;i<32;i++) mx[i] = fmaxf(mx[i], lrelu(acc2[i]));
  }
  __syncthreads();
#pragma unroll
  for (int rr=0;rr<4;rr++){
    float4 a = make_float4(mx[0*4+rr], mx[1*4+rr], mx[2*4+rr], mx[3*4+rr]);
    float4 bq = make_float4(mx[4*4+rr], mx[5*4+rr], mx[6*4+rr], mx[7*4+rr]);
    *(float4*)&s1T[w][(r0+rr)*64 + o0] = a;
    *(float4*)&s1T[w][(r0+rr)*64 + o0 + 4] = bq;
  }
  __syncthreads();
  for (int i=tid; i<2048; i+=128){
    float v = fmaxf(s1T[0][i], s1T[1][i]);
    int r = i>>6, o = i&63;
    catT[((size_t)b*N + n0 + r)*192 + outOff + o] = v;
  }
}

// ---- edgeD: 64ch -> 64 (single conv), max over k ----
__global__ __launch_bounds__(128) void edgeD_kernel(
    const float* __restrict__ inT, int inOff, const int* __restrict__ idxT,
    const float* __restrict__ w1, float* __restrict__ catT, int outOff, int N){
  __shared__ float w1T[64*64];
  __shared__ float wdT[64*64];
  __shared__ float aT[2][64*32];
  const int tid = threadIdx.x, w = tid>>6, lane = tid&63;
  const int oq = lane&7, rg = lane>>3;
  const int o0 = oq*8, r0 = rg*4;
  const int b = blockIdx.y, n0 = blockIdx.x*32;
  for (int i=tid; i<64*64; i+=128){
    int o = i>>6, c = i&63;
    float a = w1[o*128+c], bb = w1[o*128+64+c];
    w1T[c*64+o] = a; wdT[c*64+o] = bb - a;
  }
  for (int i=tid; i<512; i+=128){
    int p = i>>4, cq = i&15;
    float4 v = ld4(&inT[((size_t)b*N + n0 + p)*192 + inOff + cq*4]);
    aT[0][(cq*4+0)*32+p] = v.x; aT[0][(cq*4+1)*32+p] = v.y;
    aT[0][(cq*4+2)*32+p] = v.z; aT[0][(cq*4+3)*32+p] = v.w;
  }
  __syncthreads();
  float base[32];
#pragma unroll
  for (int i=0;i<32;i++) base[i]=0.f;
  for (int c=0;c<64;c++){
    float4 w0 = ld4(&wdT[c*64+o0]), w1v = ld4(&wdT[c*64+o0+4]);
    float4 av = ld4(&aT[0][c*32+r0]);
    float wv[8] = {w0.x,w0.y,w0.z,w0.w,w1v.x,w1v.y,w1v.z,w1v.w};
    float rv[4] = {av.x,av.y,av.z,av.w};
#pragma unroll
    for (int oo=0;oo<8;oo++)
#pragma unroll
      for (int rr=0;rr<4;rr++) base[oo*4+rr] = fmaf(wv[oo], rv[rr], base[oo*4+rr]);
  }
  __syncthreads();
  float mx[32];
#pragma unroll
  for (int i=0;i<32;i++) mx[i] = -__builtin_inff();
  const int row = lane&31, ch = lane>>5;
  for (int it=0; it<20; it++){
    int k = it*2 + w;
    {
      int m = idxT[((size_t)b*KNN + k)*N + n0 + row];
      const float* src = &inT[((size_t)b*N + m)*192 + inOff + ch*32];
      float4 g[8];
#pragma unroll
      for (int j=0;j<8;j++) g[j] = ld4(src + j*4);
#pragma unroll
      for (int j=0;j<8;j++){
        aT[w][(ch*32+j*4+0)*32 + row] = g[j].x;
        aT[w][(ch*32+j*4+1)*32 + row] = g[j].y;
        aT[w][(ch*32+j*4+2)*32 + row] = g[j].z;
        aT[w][(ch*32+j*4+3)*32 + row] = g[j].w;
      }
    }
    float acc[32];
#pragma unroll
    for (int i=0;i<32;i++) acc[i] = base[i];
    for (int c=0;c<64;c++){
      float4 w0 = ld4(&w1T[c*64+o0]), w1v = ld4(&w1T[c*64+o0+4]);
      float4 av = ld4(&aT[w][c*32+r0]);
      float wv[8] = {w0.x,w0.y,w0.z,w0.w,w1v.x,w1v.y,w1v.z,w1v.w};
      float rv[4] = {av.x,av.y,av.z,av.w};
#pragma unroll
      for (int oo=0;oo<8;oo++)
#pragma unroll
        for (int rr=0;rr<4;rr++) acc[oo*4+rr] = fmaf(wv[oo], rv[rr], acc[oo*4+rr]);
    }
#pragma unroll
    for (int i=0;i<32;i++) mx[i] = fmaxf(mx[i], lrelu(acc[i]));
  }
  __syncthreads();
#pragma unroll
  for (int rr=0;rr<4;rr++){
    float4 a = make_float4(mx[0*4+rr], mx[1*4+rr], mx[2*4+rr], mx[3*4+rr]);
    float4 bq = make_float4(mx[4*4+rr], mx[5*4+rr], mx[6*4+rr], mx[7*4+rr]);
    *(float4*)&wdT[w*2048 + (r0+rr)*64 + o0] = a;
    *(float4*)&wdT[w*2048 + (r0+rr)*64 + o0 + 4] = bq;
  }
  __syncthreads();
  for (int i=tid; i<2048; i+=128){
    float v = fmaxf(wdT[i], wdT[2048+i]);
    int r = i>>6, o = i&63;
    catT[((size_t)b*N + n0 + r)*192 + outOff + o] = v;
  }
}

// ---------------- conv1 (1024 outs) + lrelu + max -- register-tiled, weights in LDS ----------------
// v3: DEDUP. R7 version had both waves computing the identical 64o x 32r tile
// (w unused in the main loop -> 2x duplicated FMA and DS issue). Now the st-loop
// is split between waves (st = it*2 + w), each wave staging its own ish buffer.
// Steady state is barrier-free (waves touch disjoint LDS; wsh read-only after
// one barrier). Same c-order per (o,row) -> bit-exact output.
template<int CIN, int TAG>
__global__ __launch_bounds__(128) void convmax_kernel(
    const float* __restrict__ inT, const float* __restrict__ wT,
    float* __restrict__ partial, int N){
  __shared__ float wsh[CIN*64];
  __shared__ float ish[2][32*CIN];  // per-wave staging, XOR-swizzled 4-col groups
  const int tid = threadIdx.x, w = tid>>6, lane = tid&63;
  const int oq = lane&7, rg = lane>>3;
  const int o0 = oq*8, r0 = rg*4;
  const int b = blockIdx.z, oc = blockIdx.x, nt = blockIdx.y;
  for (int i=tid; i<CIN*64; i+=128){
    int c = i>>6, o = i&63;
    wsh[i] = wT[(size_t)c*1024 + oc*64 + o];
  }
  __syncthreads();                  // wsh ready; ish is wave-private afterwards
  float mx[32];
#pragma unroll
  for (int i=0;i<32;i++) mx[i] = -__builtin_inff();
  const int nbase = nt*(N/8);
  float* mish = ish[w];
  for (int it=0; it<4; it++){
    const int st = it*2 + w;        // wave w handles tiles {w, w+2, w+4, w+6}
    const float* src = inT + ((size_t)b*N + nbase + st*32)*CIN;
    for (int i=lane; i<32*(CIN/4); i+=64){
      int p = i/(CIN/4), cq = i%(CIN/4);
      float4 v = ld4(src + p*CIN + 4*cq);
      int base = (((p>>2) ^ (cq&7))<<2) + (p&3);
      mish[(4*cq+0)*32 + base] = v.x;
      mish[(4*cq+1)*32 + base] = v.y;
      mish[(4*cq+2)*32 + base] = v.z;
      mish[(4*cq+3)*32 + base] = v.w;
    }
    // wave-local write->read ordering via lgkmcnt (in-order DS per wave); no barrier
    float acc[32];
#pragma unroll
    for (int i=0;i<32;i++) acc[i]=0.f;
    for (int c=0;c<CIN;c++){
      float4 w0 = ld4(&wsh[c*64+o0]), w1v = ld4(&wsh[c*64+o0+4]);
      float4 av = ld4(&mish[c*32 + ((rg ^ ((c>>2)&7))<<2)]);
      float wv[8] = {w0.x,w0.y,w0.z,w0.w,w1v.x,w1v.y,w1v.z,w1v.w};
      float rv[4] = {av.x,av.y,av.z,av.w};
#pragma unroll
      for (int oo=0;oo<8;oo++)
#pragma unroll
        for (int rr=0;rr<4;rr++) acc[oo*4+rr] = fmaf(wv[oo], rv[rr], acc[oo*4+rr]);
    }
#pragma unroll
    for (int i=0;i<32;i++) mx[i] = fmaxf(mx[i], lrelu(acc[i]));
  }
  float m8[8];
#pragma unroll
  for (int oo=0;oo<8;oo++)
    m8[oo] = fmaxf(fmaxf(mx[oo*4+0], mx[oo*4+1]), fmaxf(mx[oo*4+2], mx[oo*4+3]));
  __syncthreads();                  // both waves done with their ish -> reuse ish[0] as merge buffer
  float* mb = ish[0];
  *(float4*)&mb[(w*8+rg)*64 + o0]     = make_float4(m8[0],m8[1],m8[2],m8[3]);
  *(float4*)&mb[(w*8+rg)*64 + o0 + 4] = make_float4(m8[4],m8[5],m8[6],m8[7]);
  __syncthreads();
  if (tid < 64){
    float v = -__builtin_inff();
#pragma unroll
    for (int g=0; g<16; g++) v = fmaxf(v, mb[g*64+tid]);
    partial[((size_t)b*8 + nt)*1024 + oc*64 + tid] = v;
  }
}

template<int TAG>
__global__ void reduce_max_kernel(const float* __restrict__ partial, float* __restrict__ out){
  int b = blockIdx.y; int o = blockIdx.x*256 + threadIdx.x;
  float v = -__builtin_inff();
  for (int s=0;s<8;s++) v = fmaxf(v, partial[((size_t)b*8 + s)*1024 + o]);
  out[(size_t)b*1024 + o] = v;
}

// ---------------- small FC ----------------
__global__ void fc_kernel(const float* __restrict__ in, const float* __restrict__ W,
                          const float* __restrict__ bias, float* __restrict__ out,
                          int CI, int O, int act){
  int b = blockIdx.x;
  __shared__ float insh[1024];
  for (int i=threadIdx.x;i<CI;i+=blockDim.x) insh[i]=in[(size_t)b*CI+i];
  __syncthreads();
  for (int o=threadIdx.x;o<O;o+=blockDim.x){
    float s = bias ? bias[o] : 0.f;
    for (int c=0;c<CI;c++) s = fmaf(W[(size_t)o*CI+c], insh[c], s);
    if (act) s = lrelu(s);
    out[(size_t)b*O+o]=s;
  }
}

// ---------------- x' = T^T x per batch ----------------
__global__ void transform_kernel(const float* __restrict__ x, const float* __restrict__ T9,
                                 float* __restrict__ xp, int N){
  int b = blockIdx.y; int n = blockIdx.x*256 + threadIdx.x;
  const float* t = T9 + (size_t)b*9;
  float x0=x[((size_t)b*3+0)*N+n], x1=x[((size_t)b*3+1)*N+n], x2=x[((size_t)b*3+2)*N+n];
#pragma unroll
  for (int i=0;i<3;i++)
    xp[((size_t)b*3+i)*N+n] = t[i]*x0 + t[3+i]*x1 + t[6+i]*x2;
}

// ---------------- bias1: n-invariant part of h1 ----------------
__global__ void bias1_kernel(const float* __restrict__ g, const float* __restrict__ lv,
                             const float* __restrict__ h1w, float* __restrict__ bias1){
  int b = blockIdx.x;
  __shared__ float insh[1088];
  for (int i=threadIdx.x;i<1088;i+=256) insh[i] = (i<1024)? g[(size_t)b*1024+i] : lv[(size_t)b*64 + (i-1024)];
  __syncthreads();
  int o = threadIdx.x;
  float s=0.f;
  for (int c=0;c<1088;c++) s = fmaf(h1w[(size_t)o*1280+c], insh[c], s);
  bias1[(size_t)b*256+o]=s;
}

// ---------------- head conv layers -- register-tiled (convmax pattern) ----------------
// v2: replaces the broadcast-read version (32 ds_read_b32 per thread per c ->
// ~16.8M ds_read per dispatch, DS-issue-bound). Now 8o x 2r per thread, 64-output
// chunks via blockIdx.z, weights staged [c][64] in LDS, inputs [c][32] XOR-swizzled,
// c-chunked (128/96) so LDS = 48/36 KB -> 3-4 blocks/CU. Same c accumulation
// order -> bit-exact vs previous version.
template<int CI, int O, bool ACT>
__global__ __launch_bounds__(128) void conv1_kernel(
    const float* __restrict__ inT, const float* __restrict__ wT,
    const float* __restrict__ bias, float* __restrict__ outT, int N){
  constexpr int CCH = (CI % 128 == 0) ? 128 : 96;   // 256->128, 192->96
  constexpr int NCH = CI / CCH;
  __shared__ float wsh[CCH*64];
  __shared__ float ish[32*CCH];     // [c][32], XOR-swizzled 4-col groups
  const int tid = threadIdx.x, w = tid>>6, lane = tid&63;
  const int oq = lane&7, rg = lane>>3;
  const int o0 = oq*8, r0 = w*16 + rg*2;   // rows split across waves (dedup)
  const int b = blockIdx.y, n0 = blockIdx.x*32, oc = blockIdx.z;
  const float* src = inT + ((size_t)b*N + n0)*CI;
  float acc[16];
#pragma unroll
  for (int i=0;i<16;i++) acc[i]=0.f;
  for (int ch=0; ch<NCH; ch++){
    const int cc0 = ch*CCH;
    if (ch) __syncthreads();        // prev chunk's compute done before restage
    for (int i=tid; i<CCH*64; i+=128){
      int c = i>>6, od = i&63;
      wsh[i] = wT[(size_t)(cc0+c)*O + oc*64 + od];
    }
    for (int i=tid; i<32*(CCH/4); i+=128){
      int p = i/(CCH/4), cq = i%(CCH/4);
      float4 v = ld4(src + p*CI + cc0 + 4*cq);
      int base = (((p>>2) ^ (cq&7))<<2) + (p&3);
      ish[(4*cq+0)*32 + base] = v.x;
      ish[(4*cq+1)*32 + base] = v.y;
      ish[(4*cq+2)*32 + base] = v.z;
      ish[(4*cq+3)*32 + base] = v.w;
    }
    __syncthreads();
    for (int c=0;c<CCH;c++){
      float4 w0 = ld4(&wsh[c*64+o0]), w1v = ld4(&wsh[c*64+o0+4]);
      float2 av = *(const float2*)&ish[c*32 + ((((r0>>2) ^ ((c>>2)&7))<<2) + (r0&3))];
      float wv[8] = {w0.x,w0.y,w0.z,w0.w,w1v.x,w1v.y,w1v.z,w1v.w};
      float rv[2] = {av.x,av.y};
#pragma unroll
      for (int oo=0;oo<8;oo++)
#pragma unroll
        for (int rr=0;rr<2;rr++) acc[oo*2+rr] = fmaf(wv[oo], rv[rr], acc[oo*2+rr]);
    }
  }
  float bv[8];
  if (bias){
    float4 b0 = ld4(&bias[(size_t)b*O + oc*64 + o0]);
    float4 b1 = ld4(&bias[(size_t)b*O + oc*64 + o0 + 4]);
    bv[0]=b0.x; bv[1]=b0.y; bv[2]=b0.z; bv[3]=b0.w;
    bv[4]=b1.x; bv[5]=b1.y; bv[6]=b1.z; bv[7]=b1.w;
  } else {
#pragma unroll
    for (int i=0;i<8;i++) bv[i]=0.f;
  }
#pragma unroll
  for (int rr=0;rr<2;rr++){
    float oa[8];
#pragma unroll
    for (int oo=0;oo<8;oo++){
      float s = acc[oo*2+rr] + bv[oo];
      oa[oo] = ACT ? lrelu(s) : s;
    }
    float* dst = &outT[((size_t)b*N + n0 + r0 + rr)*O + oc*64 + o0];
    *(float4*)dst     = make_float4(oa[0],oa[1],oa[2],oa[3]);
    *(float4*)(dst+4) = make_float4(oa[4],oa[5],oa[6],oa[7]);
  }
}

// ---------------- final layer: 128 -> 50, rows-layout output (B,50,N) ----------------
__global__ __launch_bounds__(256) void conv_out_kernel(
    const float* __restrict__ inT, const float* __restrict__ wT,
    float* __restrict__ out, int N){
  const int b = blockIdx.y, n0 = blockIdx.x*32;
  __shared__ float insh[32*129];
  const float* src = inT + ((size_t)b*N + n0)*128;
  for (int i=threadIdx.x;i<32*128;i+=256){ int nn=i>>7, c=i&127; insh[nn*129+c]=src[i]; }
  __syncthreads();
  const int nl = threadIdx.x & 31, og = threadIdx.x >> 5;
  float acc[7];
#pragma unroll
  for (int t=0;t<7;t++) acc[t]=0.f;
  for (int c=0;c<128;c++){
    float iv = insh[nl*129+c];
#pragma unroll
    for (int t=0;t<7;t++){
      int o = og + 8*t;
      float wv = (o<50)? wT[c*50+o] : 0.f;
      acc[t] = fmaf(wv, iv, acc[t]);
    }
  }
#pragma unroll
  for (int t=0;t<7;t++){
    int o = og + 8*t;
    if (o < 50) out[((size_t)b*50+o)*N + n0 + nl] = acc[t];
  }
}

extern "C" void kernel_launch(void* const* d_in, const int* in_sizes, int n_in,
                              void* d_out, int out_size, void* d_ws, size_t ws_size,
                              hipStream_t stream){
  const float* x    = (const float*)d_in[0];
  const float* l    = (const float*)d_in[1];
  const float* t_c1 = (const float*)d_in[2];
  const float* t_c2 = (const float*)d_in[3];
  const float* t_c3 = (const float*)d_in[4];
  const float* t_f1 = (const float*)d_in[5];
  const float* t_f2 = (const float*)d_in[6];
  const float* t_f3w= (const float*)d_in[7];
  const float* t_f3b= (const float*)d_in[8];
  const float* b1a  = (const float*)d_in[9];
  const float* b1b  = (const float*)d_in[10];
  const float* b2a  = (const float*)d_in[11];
  const float* b2b  = (const float*)d_in[12];
  const float* b3a  = (const float*)d_in[13];
  const float* m1   = (const float*)d_in[14];
  const float* m2   = (const float*)d_in[15];
  const float* h1   = (const float*)d_in[16];
  const float* h2   = (const float*)d_in[17];
  const float* h3   = (const float*)d_in[18];
  const float* h4   = (const float*)d_in[19];
  float* out = (float*)d_out;
  float* ws = (float*)d_ws;
  const int N = NPTS, B = BATCH;

  size_t off = 0;
  auto alloc = [&](size_t nf){ float* p = ws + off; off += nf; return p; };
  float* WT_TC3 = alloc((size_t)128*1024);
  float* WT_M1  = alloc((size_t)192*1024);
  float* WT_H1B = alloc((size_t)192*256);
  float* WT_H2  = alloc((size_t)256*256);
  float* WT_H3  = alloc((size_t)256*128);
  float* WT_H4  = alloc((size_t)128*64);
  int*   IDXT   = (int*)alloc((size_t)B*N*KNN);
  float* XX     = alloc((size_t)B*N);
  float* TT     = alloc((size_t)B*N*128);
  float* PARTIAL= alloc((size_t)B*8*1024);
  float* TG     = alloc((size_t)B*1024);
  float* T512   = alloc((size_t)B*512);
  float* T256   = alloc((size_t)B*256);
  float* T9     = alloc((size_t)B*16);
  float* XP     = alloc((size_t)B*3*N);
  float* CATT   = alloc((size_t)B*N*192);
  float* G      = alloc((size_t)B*1024);
  float* LV     = alloc((size_t)B*64);
  float* BIAS1  = alloc((size_t)B*256);
  float* H1T    = alloc((size_t)B*N*256);
  float* H2T    = alloc((size_t)B*N*256);
  float* H3T    = alloc((size_t)B*N*128);
  (void)ws_size; (void)in_sizes; (void)n_in; (void)out_size;

  dim3 blk(256);
  dim3 eblk(128);
  // weight transposes
  transpose_kernel<<<dim3((1024*128+255)/256), blk, 0, stream>>>(t_c3, WT_TC3, 1024,128,128,0);
  transpose_kernel<<<dim3((1024*192+255)/256), blk, 0, stream>>>(m1,  WT_M1, 1024,192,192,0);
  transpose_kernel<<<dim3((256*192+255)/256),  blk, 0, stream>>>(h1, WT_H1B, 256,192,1280,1088);
  transpose_kernel<<<dim3((256*256+255)/256),  blk, 0, stream>>>(h2, WT_H2, 256,256,256,0);
  transpose_kernel<<<dim3((128*256+255)/256),  blk, 0, stream>>>(h3, WT_H3, 128,256,256,0);
  transpose_kernel<<<dim3((50*128+255)/256),   blk, 0, stream>>>(h4, WT_H4, 50,128,128,0);

  // t-path
  norms_rows_kernel<0><<<dim3(N/256,B), blk, 0, stream>>>(x, XX, N);
  knn3_kernel<0><<<dim3(N/4,B), blk, 0, stream>>>(x, XX, IDXT, N);
  edgeA_kernel<<<dim3(N/16,B), blk, 0, stream>>>(x, IDXT, t_c1, t_c2, TT, N);
  convmax_kernel<128,0><<<dim3(16,8,B), eblk, 0, stream>>>(TT, WT_TC3, PARTIAL, N);
  reduce_max_kernel<0><<<dim3(4,B), blk, 0, stream>>>(PARTIAL, TG);
  fc_kernel<<<dim3(B), dim3(512), 0, stream>>>(TG, t_f1, nullptr, T512, 1024, 512, 1);
  fc_kernel<<<dim3(B), dim3(512), 0, stream>>>(T512, t_f2, nullptr, T256, 512, 256, 1);
  fc_kernel<<<dim3(B), dim3(512), 0, stream>>>(T256, t_f3w, t_f3b, T9, 256, 9, 0);
  transform_kernel<<<dim3(N/256,B), blk, 0, stream>>>(x, T9, XP, N);

  // edge block 1 (transformed points, 3ch)
  norms_rows_kernel<1><<<dim3(N/256,B), blk, 0, stream>>>(XP, XX, N);
  knn3_kernel<1><<<dim3(N/4,B), blk, 0, stream>>>(XP, XX, IDXT, N);
  edgeB_kernel<<<dim3(N/32,B), eblk, 0, stream>>>(XP, IDXT, b1a, b1b, CATT, N);

  // edge block 2 (x1 = CATT[...,0:64])
  norms_cl_kernel<0><<<dim3(N/256,B), blk, 0, stream>>>(CATT, 0, XX, N);
  knn64_kernel<0><<<dim3(N/4,B), blk, 0, stream>>>(CATT, 0, XX, IDXT, N);
  edgeC_kernel<<<dim3(N/32,B), eblk, 0, stream>>>(CATT, 0, IDXT, b2a, b2b, CATT, 64, N);

  // edge block 3 (x2 = CATT[...,64:128])
  norms_cl_kernel<1><<<dim3(N/256,B), blk, 0, stream>>>(CATT, 64, XX, N);
  knn64_kernel<1><<<dim3(N/4,B), blk, 0, stream>>>(CATT, 64, XX, IDXT, N);
  edgeD_kernel<<<dim3(N/32,B), eblk, 0, stream>>>(CATT, 64, IDXT, b3a, CATT, 128, N);

  // global feature + head
  convmax_kernel<192,1><<<dim3(16,8,B), eblk, 0, stream>>>(CATT, WT_M1, PARTIAL, N);
  reduce_max_kernel<1><<<dim3(4,B), blk, 0, stream>>>(PARTIAL, G);
  fc_kernel<<<dim3(B), dim3(512), 0, stream>>>(l, m2, nullptr, LV, 16, 64, 1);
  bias1_kernel<<<dim3(B), blk, 0, stream>>>(G, LV, h1, BIAS1);
  conv1_kernel<192,256,true><<<dim3(N/32,B,4), eblk, 0, stream>>>(CATT, WT_H1B, BIAS1, H1T, N);
  conv1_kernel<256,256,true><<<dim3(N/32,B,4), eblk, 0, stream>>>(H1T, WT_H2, nullptr, H2T, N);
  conv1_kernel<256,128,true><<<dim3(N/32,B,2), eblk, 0, stream>>>(H2T, WT_H3, nullptr, H3T, N);
  conv_out_kernel<<<dim3(N/32,B), blk, 0, stream>>>(H3T, WT_H4, out, N);
}

// Round 10
// 2296.942 us; speedup vs baseline: 1.1001x; 1.0128x over previous
//
#include <hip/hip_runtime.h>
#include <cstdint>

#define NPTS 2048
#define BATCH 8
#define KNN 40

__device__ __forceinline__ float lrelu(float v){ return fmaxf(v, 0.2f*v); }
__device__ __forceinline__ bool better(float v1,int i1,float v2,int i2){
  return (v1>v2) || (v1==v2 && i1<i2);
}
__device__ __forceinline__ float4 ld4(const float* p){ return *(const float4*)p; }

// insert (d,m) into sorted-desc 8-list if it beats the tail; static CE chain.
#define INSERT8(v,id,d,m) \
  if (better(d, m, v[7], id[7])){ \
    v[7]=d; id[7]=m; \
    { if (better(v[7],id[7],v[6],id[6])){ float tv=v[6];int ti=id[6]; v[6]=v[7];id[6]=id[7]; v[7]=tv;id[7]=ti; } } \
    { if (better(v[6],id[6],v[5],id[5])){ float tv=v[5];int ti=id[5]; v[5]=v[6];id[5]=id[6]; v[6]=tv;id[6]=ti; } } \
    { if (better(v[5],id[5],v[4],id[4])){ float tv=v[4];int ti=id[4]; v[4]=v[5];id[4]=id[5]; v[5]=tv;id[5]=ti; } } \
    { if (better(v[4],id[4],v[3],id[3])){ float tv=v[3];int ti=id[3]; v[3]=v[4];id[3]=id[4]; v[4]=tv;id[4]=ti; } } \
    { if (better(v[3],id[3],v[2],id[2])){ float tv=v[2];int ti=id[2]; v[2]=v[3];id[2]=id[3]; v[3]=tv;id[3]=ti; } } \
    { if (better(v[2],id[2],v[1],id[1])){ float tv=v[1];int ti=id[1]; v[1]=v[2];id[1]=id[2]; v[2]=tv;id[2]=ti; } } \
    { if (better(v[1],id[1],v[0],id[0])){ float tv=v[0];int ti=id[0]; v[0]=v[1];id[0]=id[1]; v[1]=tv;id[1]=ti; } } \
  }

// ---------------- fused weight transposes (6 jobs, 1 launch) ----------------
// dst[c*R+r] = src[r*ld+off+c]; params per job (blockIdx.y).
__global__ void transpose6_kernel(
    const float* __restrict__ s0, float* __restrict__ d0,
    const float* __restrict__ s1, float* __restrict__ d1,
    const float* __restrict__ s2, float* __restrict__ d2,
    const float* __restrict__ s3, float* __restrict__ d3,
    const float* __restrict__ s4, float* __restrict__ d4,
    const float* __restrict__ s5, float* __restrict__ d5){
  int i = blockIdx.x*256 + threadIdx.x;
  const float* src; float* dst; int R,C,ld,off;
  switch (blockIdx.y){
    case 0:  src=s0; dst=d0; R=1024; C=128; ld=128;  off=0;    break;
    case 1:  src=s1; dst=d1; R=1024; C=192; ld=192;  off=0;    break;
    case 2:  src=s2; dst=d2; R=256;  C=192; ld=1280; off=1088; break;
    case 3:  src=s3; dst=d3; R=256;  C=256; ld=256;  off=0;    break;
    case 4:  src=s4; dst=d4; R=128;  C=256; ld=256;  off=0;    break;
    default: src=s5; dst=d5; R=50;   C=128; ld=128;  off=0;    break;
  }
  if (i < R*C){ int r = i / C, c = i % C; dst[c*R + r] = src[r*ld + off + c]; }
}

// ---------------- squared norms, rows layout (B,3,N) ----------------
template<int TAG>
__global__ void norms_rows_kernel(const float* __restrict__ x, float* __restrict__ xx, int N){
  int b = blockIdx.y; int n = blockIdx.x*256 + threadIdx.x;
  const float* xb = x + (size_t)b*3*N;
  float v0 = xb[n], v1 = xb[N+n], v2 = xb[2*N+n];
  xx[(size_t)b*N + n] = v0*v0 + v1*v1 + v2*v2;
}

// ---------------- squared norms, channel-last 64ch slice of (B,N,192) ----------------
template<int TAG>
__global__ void norms_cl_kernel(const float* __restrict__ f, int off, float* __restrict__ xx, int N){
  int b = blockIdx.y; int n = blockIdx.x*256 + threadIdx.x;
  const float4* p = (const float4*)(f + ((size_t)b*N + n)*192 + off);
  float s = 0.f;
#pragma unroll
  for (int q=0;q<16;q++){ float4 v = p[q]; s += v.x*v.x + v.y*v.y + v.z*v.z + v.w*v.w; }
  xx[(size_t)b*N + n] = s;
}

__device__ __forceinline__ void sort8(float (&v)[8], int (&id)[8]){
#define CE(a,bq) { if (better(v[bq],id[bq],v[a],id[a])){ float tv=v[a]; int ti=id[a]; v[a]=v[bq]; id[a]=id[bq]; v[bq]=tv; id[bq]=ti; } }
  CE(0,1) CE(2,3) CE(4,5) CE(6,7)
  CE(0,2) CE(1,3) CE(4,6) CE(5,7)
  CE(1,2) CE(5,6)
  CE(0,4) CE(1,5) CE(2,6) CE(3,7)
  CE(2,4) CE(3,5)
  CE(1,2) CE(3,4) CE(5,6)
#undef CE
}

// ---------------- knn 3-channel: 4 queries/block (1/wave), zero LDS, zero barriers ----------------
template<int TAG>
__global__ __launch_bounds__(256) void knn3_kernel(
    const float* __restrict__ xrows, const float* __restrict__ xx,
    int* __restrict__ idxT, int N){
  const int b = blockIdx.y, tid = threadIdx.x;
  const int w = tid>>6, lane = tid&63;
  const int nq = blockIdx.x*4 + w;
  const float* xb = xrows + (size_t)b*3*N;
  const float* xxb = xx + (size_t)b*N;
  float c0 = xb[nq], c1 = xb[N+nq], c2 = xb[2*N+nq];
  float xxn = xxb[nq];
  float v[8]; int id[8];
#pragma unroll
  for (int j=0;j<8;j++){ v[j]=-__builtin_inff(); id[j]=0x7FFFFFFF; }
  for (int j=0;j<32;j++){
    int m = j*64 + lane;
    float s = c0*xb[m] + c1*xb[N+m] + c2*xb[2*N+m];
    float d = 2.f*s - xxn - xxb[m];
    INSERT8(v, id, d, m)
  }
  float lastv = 0.f; int lasti = 0;
  int win = 0;
  for (int r=0;r<KNN;r++){
    float bv = v[0]; int bi = id[0];
#pragma unroll
    for (int off=32; off; off>>=1){
      float ov = __shfl_xor(bv, off);
      int   oi = __shfl_xor(bi, off);
      if (better(ov, oi, bv, bi)){ bv = ov; bi = oi; }
    }
    if (lane == r) win = bi;
    if (id[0] == bi){
      lastv = v[0]; lasti = id[0];
#pragma unroll
      for (int j=0;j<7;j++){ v[j]=v[j+1]; id[j]=id[j+1]; }
      v[7] = -__builtin_inff(); id[7] = 0x7FFFFFFF;
      if (id[0] == 0x7FFFFFFF){   // rare refill: best strictly worse than last pop
        float nv = -__builtin_inff(); int ni = 0x7FFFFFFF;
        for (int j=0;j<32;j++){
          int m = j*64 + lane;
          float s = c0*xb[m] + c1*xb[N+m] + c2*xb[2*N+m];
          float dd = 2.f*s - xxn - xxb[m];
          if (better(lastv, lasti, dd, m) && better(dd, m, nv, ni)){ nv=dd; ni=m; }
        }
        v[0] = nv; id[0] = ni;
      }
    }
  }
  if (lane < KNN) idxT[((size_t)b*KNN + lane)*N + nq] = win;
}

// ---------------- knn 64-channel (channel-last), 4 queries/block ----------------
// v6 (R5 champion): 32-cand tile (8 KiB) + 4x8K strips = 40960 B -> 16 waves/CU.
// Wave-count sweep (8w=449/379, 12w=324.7, 16w=322) shows DS+VALU issue floor reached.
template<int TAG>
__global__ __launch_bounds__(256) void knn64_kernel(
    const float* __restrict__ featT, int featOff,
    const float* __restrict__ xx, int* __restrict__ idxT, int N){
  const int b = blockIdx.y, tid = threadIdx.x;
  const int w = tid>>6, lane = tid&63;
  __shared__ float cand[32*64];    // xor-swizzled [cand][ch] tile (8 KiB), block-shared
  __shared__ float dist[4*2048];   // wave-private strips (32 KiB)
  const float* fb = featT + featOff;
  const float* xxb = xx + (size_t)b*N;
  const int nq = blockIdx.x*4 + w;
  const int h = lane>>5;           // channel half this lane covers
  float4 ctr8[8];
  {
    const float4* cp = (const float4*)(fb + ((size_t)b*N + nq)*192);
#pragma unroll
    for (int q=0;q<8;q++) ctr8[q] = cp[h*8 + q];
  }
  float xxn = xxb[nq];
  float* dw = &dist[w*2048];
  float4 g[2];
#pragma unroll
  for (int r=0;r<2;r++){
    int k2 = tid + 256*r;
    int c = k2>>4, f = k2&15;
    g[r] = ld4(&fb[((size_t)b*N + c)*192 + 4*f]);
  }
  const int cc = lane&31, swz = cc&15, qb = h*8;
  for (int t=0;t<64;t++){
    __syncthreads();                 // prev compute done reading cand
#pragma unroll
    for (int r=0;r<2;r++){
      int k2 = tid + 256*r;
      int c = k2>>4, f = k2&15;
      *(float4*)&cand[(c<<6) + ((f ^ (c&15))<<2)] = g[r];
    }
    __syncthreads();
    if (t+1 < 64){                   // issue next tile's loads; latency overlaps compute
      int m0n = (t+1)*32;
#pragma unroll
      for (int r=0;r<2;r++){
        int k2 = tid + 256*r;
        int c = k2>>4, f = k2&15;
        g[r] = ld4(&fb[((size_t)b*N + m0n + c)*192 + 4*f]);
      }
    }
    float s0=0.f,s1=0.f,s2=0.f,s3=0.f;
#pragma unroll
    for (int j=0;j<8;j++){
      float4 mv = *(const float4*)&cand[(cc<<6) + (((qb + j) ^ swz)<<2)];
      s0 = fmaf(ctr8[j].x, mv.x, s0);
      s1 = fmaf(ctr8[j].y, mv.y, s1);
      s2 = fmaf(ctr8[j].z, mv.z, s2);
      s3 = fmaf(ctr8[j].w, mv.w, s3);
    }
    float p = (s0+s1)+(s2+s3);
    float tot = p + __shfl_xor(p, 32);    // combine channel halves (commutative -> both halves identical)
    if (h == (t&1)){                      // owner lane (m & 63 == lane) writes its strip slot
      int m = t*32 + cc;
      dw[(t>>1)*64 + lane] = 2.f*tot - xxn - xxb[m];
    }
  }
  // ---- per-lane exact top-8 of its 32 entries (sorted desc by (v desc, idx asc)) ----
  float v[8]; int id[8];
#pragma unroll
  for (int j=0;j<8;j++){ v[j]=dw[j*64+lane]; id[j]=j*64+lane; }
  sort8(v, id);
#pragma unroll
  for (int gq=1; gq<4; gq++){
    float a[8]; int ai[8];
#pragma unroll
    for (int j=0;j<8;j++){ a[j]=dw[(gq*8+j)*64+lane]; ai[j]=(gq*8+j)*64+lane; }
    sort8(a, ai);
    float m_[8]; int mi_[8];
#pragma unroll
    for (int k=0;k<8;k++){
      if (better(a[7-k], ai[7-k], v[k], id[k])){ m_[k]=a[7-k]; mi_[k]=ai[7-k]; }
      else                                     { m_[k]=v[k];   mi_[k]=id[k]; }
    }
#define CEB(x,y) { if (better(m_[y],mi_[y],m_[x],mi_[x])){ float tv=m_[x];int ti=mi_[x]; m_[x]=m_[y];mi_[x]=mi_[y]; m_[y]=tv;mi_[y]=ti; } }
    CEB(0,4) CEB(1,5) CEB(2,6) CEB(3,7)
    CEB(0,2) CEB(1,3) CEB(4,6) CEB(5,7)
    CEB(0,1) CEB(2,3) CEB(4,5) CEB(6,7)
#undef CEB
#pragma unroll
    for (int k=0;k<8;k++){ v[k]=m_[k]; id[k]=mi_[k]; }
  }
  // ---- 40 extraction rounds: butterfly + pop-shift; zero barriers, zero LDS steady state ----
  float lastv = 0.f; int lasti = 0;
  int win = 0;
  for (int r=0;r<KNN;r++){
    float bv = v[0]; int bi = id[0];
#pragma unroll
    for (int off=32; off; off>>=1){
      float ov = __shfl_xor(bv, off);
      int   oi = __shfl_xor(bi, off);
      if (better(ov, oi, bv, bi)){ bv = ov; bi = oi; }
    }
    if (lane == r) win = bi;
    if (id[0] == bi){                // unique owner (indices unique)
      lastv = v[0]; lasti = id[0];
#pragma unroll
      for (int j=0;j<7;j++){ v[j]=v[j+1]; id[j]=id[j+1]; }
      v[7] = -__builtin_inff(); id[7] = 0x7FFFFFFF;
      if (id[0] == 0x7FFFFFFF){      // rare: lane contributed >8 of top-40 -> refill head
        float nv = -__builtin_inff(); int ni = 0x7FFFFFFF;
        for (int j=0;j<32;j++){
          float vv = dw[j*64 + lane]; int m = j*64 + lane;
          if (better(lastv, lasti, vv, m) && better(vv, m, nv, ni)){ nv=vv; ni=m; }
        }
        v[0] = nv; id[0] = ni;
      }
    }
  }
  if (lane < KNN) idxT[((size_t)b*KNN + lane)*N + nq] = win;
}

// ==================== register-tiled edge kernels ====================

// ---- edgeA (t-path): 3ch -> 64 -> 128, max over k ----
__global__ __launch_bounds__(256) void edgeA_kernel(
    const float* __restrict__ x, const int* __restrict__ idxT,
    const float* __restrict__ w1, const float* __restrict__ w2,
    float* __restrict__ tT, int N){
  __shared__ float w1aT[3*64];
  __shared__ float wd3T[3*64];
  __shared__ float w2T[64*128];      // [c][o]; reused as merge buffer (4 x 16r x 128o)
  __shared__ float aT3[4][3*16];
  __shared__ float s1T[4][64*16];    // [c][r]
  const int tid = threadIdx.x, w = tid>>6, lane = tid&63;
  const int oq = lane&7, rg = lane>>3;
  const int o0 = oq*8, r0 = rg*2;
  const int b = blockIdx.y, n0 = blockIdx.x*16;
  for (int i=tid; i<192; i+=256){
    int o = i&63, c = i/64;
    float a = w1[o*6+c];
    w1aT[c*64+o] = a; wd3T[c*64+o] = w1[o*6+3+c] - a;
  }
  for (int i=tid; i<128*64; i+=256){
    int o = i>>6, c = i&63;
    w2T[c*128+o] = w2[o*64+c];
  }
  if (tid < 48){ int c = tid>>4, r = tid&15; aT3[0][c*16+r] = x[((size_t)b*3+c)*N + n0 + r]; }
  __syncthreads();
  float base[16];
#pragma unroll
  for (int i=0;i<16;i++) base[i]=0.f;
#pragma unroll
  for (int c=0;c<3;c++){
    float4 wA = ld4(&wd3T[c*64+o0]), wB = ld4(&wd3T[c*64+o0+4]);
    float2 av = *(const float2*)&aT3[0][c*16+r0];
    float wv[8] = {wA.x,wA.y,wA.z,wA.w,wB.x,wB.y,wB.z,wB.w};
    float rv[2] = {av.x,av.y};
#pragma unroll
    for (int oo=0;oo<8;oo++)
#pragma unroll
      for (int rr=0;rr<2;rr++) base[oo*2+rr] = fmaf(wv[oo], rv[rr], base[oo*2+rr]);
  }
  __syncthreads();   // all waves done reading aT3[0] before k-loop overwrites
  float mx[32];
#pragma unroll
  for (int i=0;i<32;i++) mx[i] = -__builtin_inff();
  for (int it=0; it<10; it++){
    int k = it*4 + w;
    int m = idxT[((size_t)b*KNN + k)*N + n0 + (lane&15)];
    if (lane < 48){ int c = lane>>4; aT3[w][c*16 + (lane&15)] = x[((size_t)b*3+c)*N + m]; }
    // stage1 (64 o x 16 r)
    float acc[16];
#pragma unroll
    for (int i=0;i<16;i++) acc[i] = base[i];
#pragma unroll
    for (int c=0;c<3;c++){
      float4 wA = ld4(&w1aT[c*64+o0]), wB = ld4(&w1aT[c*64+o0+4]);
      float2 av = *(const float2*)&aT3[w][c*16+r0];
      float wv[8] = {wA.x,wA.y,wA.z,wA.w,wB.x,wB.y,wB.z,wB.w};
      float rv[2] = {av.x,av.y};
#pragma unroll
      for (int oo=0;oo<8;oo++)
#pragma unroll
        for (int rr=0;rr<2;rr++) acc[oo*2+rr] = fmaf(wv[oo], rv[rr], acc[oo*2+rr]);
    }
#pragma unroll
    for (int oo=0;oo<8;oo++){
      float2 sv; sv.x = lrelu(acc[oo*2]); sv.y = lrelu(acc[oo*2+1]);
      *(float2*)&s1T[w][(o0+oo)*16 + r0] = sv;
    }
    // stage2 (128 o x 16 r): 4 panels, o = p*32 + oq*4 -> 32 banks, conflict-free
    float acc2[32];
#pragma unroll
    for (int i=0;i<32;i++) acc2[i]=0.f;
    for (int c=0;c<64;c++){
      float2 av = *(const float2*)&s1T[w][c*16 + r0];
#pragma unroll
      for (int p=0;p<4;p++){
        float4 wv = ld4(&w2T[c*128 + p*32 + oq*4]);
        acc2[p*8+0] = fmaf(wv.x, av.x, acc2[p*8+0]);
        acc2[p*8+1] = fmaf(wv.x, av.y, acc2[p*8+1]);
        acc2[p*8+2] = fmaf(wv.y, av.x, acc2[p*8+2]);
        acc2[p*8+3] = fmaf(wv.y, av.y, acc2[p*8+3]);
        acc2[p*8+4] = fmaf(wv.z, av.x, acc2[p*8+4]);
        acc2[p*8+5] = fmaf(wv.z, av.y, acc2[p*8+5]);
        acc2[p*8+6] = fmaf(wv.w, av.x, acc2[p*8+6]);
        acc2[p*8+7] = fmaf(wv.w, av.y, acc2[p*8+7]);
      }
    }
#pragma unroll
    for (int i=0;i<32;i++) mx[i] = fmaxf(mx[i], lrelu(acc2[i]));
  }
  __syncthreads();   // all waves done reading w2T -> reuse as merge buffer
#pragma unroll
  for (int rr=0;rr<2;rr++){
#pragma unroll
    for (int p=0;p<4;p++){
      float4 a = make_float4(mx[p*8+0+rr], mx[p*8+2+rr], mx[p*8+4+rr], mx[p*8+6+rr]);
      *(float4*)&w2T[w*2048 + (r0+rr)*128 + p*32 + oq*4] = a;
    }
  }
  __syncthreads();
  for (int i=tid; i<2048; i+=256){
    float vv = fmaxf(fmaxf(w2T[i], w2T[2048+i]), fmaxf(w2T[4096+i], w2T[6144+i]));
    int r = i>>7, o = i&127;
    tT[((size_t)b*N + n0 + r)*128 + o] = vv;
  }
}

// ---- edgeB: 3ch -> 64 -> 64, max over k ----
// v2: gather software-pipelined (idx+3 floats prefetched during compute).
__global__ __launch_bounds__(128) void edgeB_kernel(
    const float* __restrict__ xp, const int* __restrict__ idxT,
    const float* __restrict__ w1, const float* __restrict__ w2,
    float* __restrict__ catT, int N){
  __shared__ float w1aT[3*64];
  __shared__ float wd3T[3*64];
  __shared__ float w2T[64*64];
  __shared__ float aT3[2][3*32];
  __shared__ float s1T[2][64*32];
  const int tid = threadIdx.x, w = tid>>6, lane = tid&63;
  const int oq = lane&7, rg = lane>>3;
  const int o0 = oq*8, r0 = rg*4;
  const int b = blockIdx.y, n0 = blockIdx.x*32;
  for (int i=tid; i<192; i+=128){
    int o = i&63, c = i>>6;
    float a = w1[o*6+c], bb = w1[o*6+3+c];
    w1aT[c*64+o] = a; wd3T[c*64+o] = bb - a;
  }
  for (int i=tid; i<64*64; i+=128){
    int o = i>>6, c = i&63;
    w2T[c*64+o] = w2[o*64+c];
  }
  if (tid < 32){
#pragma unroll
    for (int c=0;c<3;c++) aT3[0][c*32+tid] = xp[((size_t)b*3+c)*N + n0 + tid];
  }
  __syncthreads();
  float base[32];
#pragma unroll
  for (int i=0;i<32;i++) base[i]=0.f;
#pragma unroll
  for (int c=0;c<3;c++){
    float4 w0 = ld4(&wd3T[c*64+o0]), w1v = ld4(&wd3T[c*64+o0+4]);
    float4 av = ld4(&aT3[0][c*32+r0]);
    float wv[8] = {w0.x,w0.y,w0.z,w0.w,w1v.x,w1v.y,w1v.z,w1v.w};
    float rv[4] = {av.x,av.y,av.z,av.w};
#pragma unroll
    for (int oo=0;oo<8;oo++)
#pragma unroll
      for (int rr=0;rr<4;rr++) base[oo*4+rr] = fmaf(wv[oo], rv[rr], base[oo*4+rr]);
  }
  __syncthreads();
  float mx[32];
#pragma unroll
  for (int i=0;i<32;i++) mx[i] = -__builtin_inff();
  const int row = lane&31;
  float g0=0.f, g1=0.f, g2=0.f;
  {
    int m = idxT[((size_t)b*KNN + w)*N + n0 + row];
    if (lane < 32){
      g0 = xp[((size_t)b*3+0)*N + m];
      g1 = xp[((size_t)b*3+1)*N + m];
      g2 = xp[((size_t)b*3+2)*N + m];
    }
  }
  for (int it=0; it<20; it++){
    if (lane < 32){
      aT3[w][0*32+row] = g0;
      aT3[w][1*32+row] = g1;
      aT3[w][2*32+row] = g2;
    }
    if (it+1 < 20){                  // prefetch next gather; latency hides under compute
      int m = idxT[((size_t)b*KNN + (it+1)*2 + w)*N + n0 + row];
      if (lane < 32){
        g0 = xp[((size_t)b*3+0)*N + m];
        g1 = xp[((size_t)b*3+1)*N + m];
        g2 = xp[((size_t)b*3+2)*N + m];
      }
    }
    float acc[32];
#pragma unroll
    for (int i=0;i<32;i++) acc[i] = base[i];
#pragma unroll
    for (int c=0;c<3;c++){
      float4 w0 = ld4(&w1aT[c*64+o0]), w1v = ld4(&w1aT[c*64+o0+4]);
      float4 av = ld4(&aT3[w][c*32+r0]);
      float wv[8] = {w0.x,w0.y,w0.z,w0.w,w1v.x,w1v.y,w1v.z,w1v.w};
      float rv[4] = {av.x,av.y,av.z,av.w};
#pragma unroll
      for (int oo=0;oo<8;oo++)
#pragma unroll
        for (int rr=0;rr<4;rr++) acc[oo*4+rr] = fmaf(wv[oo], rv[rr], acc[oo*4+rr]);
    }
#pragma unroll
    for (int oo=0;oo<8;oo++){
      float4 sv = make_float4(lrelu(acc[oo*4+0]), lrelu(acc[oo*4+1]), lrelu(acc[oo*4+2]), lrelu(acc[oo*4+3]));
      *(float4*)&s1T[w][(o0+oo)*32 + r0] = sv;
    }
    float acc2[32];
#pragma unroll
    for (int i=0;i<32;i++) acc2[i]=0.f;
    for (int c=0;c<64;c++){
      float4 w0 = ld4(&w2T[c*64+o0]), w1v = ld4(&w2T[c*64+o0+4]);
      float4 av = ld4(&s1T[w][c*32+r0]);
      float wv[8] = {w0.x,w0.y,w0.z,w0.w,w1v.x,w1v.y,w1v.z,w1v.w};
      float rv[4] = {av.x,av.y,av.z,av.w};
#pragma unroll
      for (int oo=0;oo<8;oo++)
#pragma unroll
        for (int rr=0;rr<4;rr++) acc2[oo*4+rr] = fmaf(wv[oo], rv[rr], acc2[oo*4+rr]);
    }
#pragma unroll
    for (int i=0;i<32;i++) mx[i] = fmaxf(mx[i], lrelu(acc2[i]));
  }
  __syncthreads();
#pragma unroll
  for (int rr=0;rr<4;rr++){
    float4 a = make_float4(mx[0*4+rr], mx[1*4+rr], mx[2*4+rr], mx[3*4+rr]);
    float4 bq = make_float4(mx[4*4+rr], mx[5*4+rr], mx[6*4+rr], mx[7*4+rr]);
    *(float4*)&s1T[w][(r0+rr)*64 + o0] = a;
    *(float4*)&s1T[w][(r0+rr)*64 + o0 + 4] = bq;
  }
  __syncthreads();
  for (int i=tid; i<2048; i+=128){
    float v = fmaxf(s1T[0][i], s1T[1][i]);
    int r = i>>6, o = i&63;
    catT[((size_t)b*N + n0 + r)*192 + o] = v;
  }
}

// ---- edgeC: 64ch -> 64 -> 64, max over k ----
// v2: gather software-pipelined (idx + 8 float4 prefetched during compute).
__global__ __launch_bounds__(128) void edgeC_kernel(
    const float* __restrict__ inT, int inOff, const int* __restrict__ idxT,
    const float* __restrict__ w1, const float* __restrict__ w2,
    float* __restrict__ catT, int outOff, int N){
  __shared__ float w1T[64*64];
  __shared__ float w2T[64*64];
  __shared__ float aT[2][64*32];
  __shared__ float s1T[2][64*32];
  const int tid = threadIdx.x, w = tid>>6, lane = tid&63;
  const int oq = lane&7, rg = lane>>3;
  const int o0 = oq*8, r0 = rg*4;
  const int b = blockIdx.y, n0 = blockIdx.x*32;
  for (int i=tid; i<64*64; i+=128){
    int o = i>>6, c = i&63;
    float a = w1[o*128+c], bb = w1[o*128+64+c];
    w1T[c*64+o] = a; w2T[c*64+o] = bb - a;
  }
  for (int i=tid; i<512; i+=128){
    int p = i>>4, cq = i&15;
    float4 v = ld4(&inT[((size_t)b*N + n0 + p)*192 + inOff + cq*4]);
    aT[0][(cq*4+0)*32+p] = v.x; aT[0][(cq*4+1)*32+p] = v.y;
    aT[0][(cq*4+2)*32+p] = v.z; aT[0][(cq*4+3)*32+p] = v.w;
  }
  __syncthreads();
  float base[32];
#pragma unroll
  for (int i=0;i<32;i++) base[i]=0.f;
  for (int c=0;c<64;c++){
    float4 w0 = ld4(&w2T[c*64+o0]), w1v = ld4(&w2T[c*64+o0+4]);
    float4 av = ld4(&aT[0][c*32+r0]);
    float wv[8] = {w0.x,w0.y,w0.z,w0.w,w1v.x,w1v.y,w1v.z,w1v.w};
    float rv[4] = {av.x,av.y,av.z,av.w};
#pragma unroll
    for (int oo=0;oo<8;oo++)
#pragma unroll
      for (int rr=0;rr<4;rr++) base[oo*4+rr] = fmaf(wv[oo], rv[rr], base[oo*4+rr]);
  }
  __syncthreads();
  for (int i=tid; i<64*64; i+=128){
    int o = i>>6, c = i&63;
    w2T[c*64+o] = w2[o*64+c];
  }
  __syncthreads();
  float mx[32];
#pragma unroll
  for (int i=0;i<32;i++) mx[i] = -__builtin_inff();
  const int row = lane&31, ch = lane>>5;
  float4 g[8];
  {
    int m = idxT[((size_t)b*KNN + w)*N + n0 + row];
    const float* src = &inT[((size_t)b*N + m)*192 + inOff + ch*32];
#pragma unroll
    for (int j=0;j<8;j++) g[j] = ld4(src + j*4);
  }
  for (int it=0; it<20; it++){
#pragma unroll
    for (int j=0;j<8;j++){
      aT[w][(ch*32+j*4+0)*32 + row] = g[j].x;
      aT[w][(ch*32+j*4+1)*32 + row] = g[j].y;
      aT[w][(ch*32+j*4+2)*32 + row] = g[j].z;
      aT[w][(ch*32+j*4+3)*32 + row] = g[j].w;
    }
    if (it+1 < 20){                 // prefetch next gather; latency hides under compute
      int m = idxT[((size_t)b*KNN + (it+1)*2 + w)*N + n0 + row];
      const float* src = &inT[((size_t)b*N + m)*192 + inOff + ch*32];
#pragma unroll
      for (int j=0;j<8;j++) g[j] = ld4(src + j*4);
    }
    float acc[32];
#pragma unroll
    for (int i=0;i<32;i++) acc[i] = base[i];
    for (int c=0;c<64;c++){
      float4 w0 = ld4(&w1T[c*64+o0]), w1v = ld4(&w1T[c*64+o0+4]);
      float4 av = ld4(&aT[w][c*32+r0]);
      float wv[8] = {w0.x,w0.y,w0.z,w0.w,w1v.x,w1v.y,w1v.z,w1v.w};
      float rv[4] = {av.x,av.y,av.z,av.w};
#pragma unroll
      for (int oo=0;oo<8;oo++)
#pragma unroll
        for (int rr=0;rr<4;rr++) acc[oo*4+rr] = fmaf(wv[oo], rv[rr], acc[oo*4+rr]);
    }
#pragma unroll
    for (int oo=0;oo<8;oo++){
      float4 sv = make_float4(lrelu(acc[oo*4+0]), lrelu(acc[oo*4+1]), lrelu(acc[oo*4+2]), lrelu(acc[oo*4+3]));
      *(float4*)&s1T[w][(o0+oo)*32 + r0] = sv;
    }
    float acc2[32];
#pragma unroll
    for (int i=0;i<32;i++) acc2[i]=0.f;
    for (int c=0;c<64;c++){
      float4 w0 = ld4(&w2T[c*64+o0]), w1v = ld4(&w2T[c*64+o0+4]);
      float4 av = ld4(&s1T[w][c*32+r0]);
      float wv[8] = {w0.x,w0.y,w0.z,w0.w,w1v.x,w1v.y,w1v.z,w1v.w};
      float rv[4] = {av.x,av.y,av.z,av.w};
#pragma unroll
      for (int oo=0;oo<8;oo++)
#pragma unroll
        for (int rr=0;rr<4;rr++) acc2[oo*4+rr] = fmaf(wv[oo], rv[rr], acc2[oo*4+rr]);
    }
#pragma unroll
    for (int i=0;i<32;i++) mx[i] = fmaxf(mx[i], lrelu(acc2[i]));
  }
  __syncthreads();
#pragma unroll
  for (int rr=0;rr<4;rr++){
    float4 a = make_float4(mx[0*4+rr], mx[1*4+rr], mx[2*4+rr], mx[3*4+rr]);
    float4 bq = make_float4(mx[4*4+rr], mx[5*4+rr], mx[6*4+rr], mx[7*4+rr]);
    *(float4*)&s1T[w][(r0+rr)*64 + o0] = a;
    *(float4*)&s1T[w][(r0+rr)*64 + o0 + 4] = bq;
  }
  __syncthreads();
  for (int i=tid; i<2048; i+=128){
    float v = fmaxf(s1T[0][i], s1T[1][i]);
    int r = i>>6, o = i&63;
    catT[((size_t)b*N + n0 + r)*192 + outOff + o] = v;
  }
}

// ---- edgeD: 64ch -> 64 (single conv), max over k ----
// v2: gather software-pipelined.
__global__ __launch_bounds__(128) void edgeD_kernel(
    const float* __restrict__ inT, int inOff, const int* __restrict__ idxT,
    const float* __restrict__ w1, float* __restrict__ catT, int outOff, int N){
  __shared__ float w1T[64*64];
  __shared__ float wdT[64*64];
  __shared__ float aT[2][64*32];
  const int tid = threadIdx.x, w = tid>>6, lane = tid&63;
  const int oq = lane&7, rg = lane>>3;
  const int o0 = oq*8, r0 = rg*4;
  const int b = blockIdx.y, n0 = blockIdx.x*32;
  for (int i=tid; i<64*64; i+=128){
    int o = i>>6, c = i&63;
    float a = w1[o*128+c], bb = w1[o*128+64+c];
    w1T[c*64+o] = a; wdT[c*64+o] = bb - a;
  }
  for (int i=tid; i<512; i+=128){
    int p = i>>4, cq = i&15;
    float4 v = ld4(&inT[((size_t)b*N + n0 + p)*192 + inOff + cq*4]);
    aT[0][(cq*4+0)*32+p] = v.x; aT[0][(cq*4+1)*32+p] = v.y;
    aT[0][(cq*4+2)*32+p] = v.z; aT[0][(cq*4+3)*32+p] = v.w;
  }
  __syncthreads();
  float base[32];
#pragma unroll
  for (int i=0;i<32;i++) base[i]=0.f;
  for (int c=0;c<64;c++){
    float4 w0 = ld4(&wdT[c*64+o0]), w1v = ld4(&wdT[c*64+o0+4]);
    float4 av = ld4(&aT[0][c*32+r0]);
    float wv[8] = {w0.x,w0.y,w0.z,w0.w,w1v.x,w1v.y,w1v.z,w1v.w};
    float rv[4] = {av.x,av.y,av.z,av.w};
#pragma unroll
    for (int oo=0;oo<8;oo++)
#pragma unroll
      for (int rr=0;rr<4;rr++) base[oo*4+rr] = fmaf(wv[oo], rv[rr], base[oo*4+rr]);
  }
  __syncthreads();
  float mx[32];
#pragma unroll
  for (int i=0;i<32;i++) mx[i] = -__builtin_inff();
  const int row = lane&31, ch = lane>>5;
  float4 g[8];
  {
    int m = idxT[((size_t)b*KNN + w)*N + n0 + row];
    const float* src = &inT[((size_t)b*N + m)*192 + inOff + ch*32];
#pragma unroll
    for (int j=0;j<8;j++) g[j] = ld4(src + j*4);
  }
  for (int it=0; it<20; it++){
#pragma unroll
    for (int j=0;j<8;j++){
      aT[w][(ch*32+j*4+0)*32 + row] = g[j].x;
      aT[w][(ch*32+j*4+1)*32 + row] = g[j].y;
      aT[w][(ch*32+j*4+2)*32 + row] = g[j].z;
      aT[w][(ch*32+j*4+3)*32 + row] = g[j].w;
    }
    if (it+1 < 20){
      int m = idxT[((size_t)b*KNN + (it+1)*2 + w)*N + n0 + row];
      const float* src = &inT[((size_t)b*N + m)*192 + inOff + ch*32];
#pragma unroll
      for (int j=0;j<8;j++) g[j] = ld4(src + j*4);
    }
    float acc[32];
#pragma unroll
    for (int i=0;i<32;i++) acc[i] = base[i];
    for (int c=0;c<64;c++){
      float4 w0 = ld4(&w1T[c*64+o0]), w1v = ld4(&w1T[c*64+o0+4]);
      float4 av = ld4(&aT[w][c*32+r0]);
      float wv[8] = {w0.x,w0.y,w0.z,w0.w,w1v.x,w1v.y,w1v.z,w1v.w};
      float rv[4] = {av.x,av.y,av.z,av.w};
#pragma unroll
      for (int oo=0;oo<8;oo++)
#pragma unroll
        for (int rr=0;rr<4;rr++) acc[oo*4+rr] = fmaf(wv[oo], rv[rr], acc[oo*4+rr]);
    }
#pragma unroll
    for (int i=0;i<32;i++) mx[i] = fmaxf(mx[i], lrelu(acc[i]));
  }
  __syncthreads();
#pragma unroll
  for (int rr=0;rr<4;rr++){
    float4 a = make_float4(mx[0*4+rr], mx[1*4+rr], mx[2*4+rr], mx[3*4+rr]);
    float4 bq = make_float4(mx[4*4+rr], mx[5*4+rr], mx[6*4+rr], mx[7*4+rr]);
    *(float4*)&wdT[w*2048 + (r0+rr)*64 + o0] = a;
    *(float4*)&wdT[w*2048 + (r0+rr)*64 + o0 + 4] = bq;
  }
  __syncthreads();
  for (int i=tid; i<2048; i+=128){
    float v = fmaxf(wdT[i], wdT[2048+i]);
    int r = i>>6, o = i&63;
    catT[((size_t)b*N + n0 + r)*192 + outOff + o] = v;
  }
}

// ---------------- conv1 (1024 outs) + lrelu + max -- dedup (R8 champion) ----------------
template<int CIN, int TAG>
__global__ __launch_bounds__(128) void convmax_kernel(
    const float* __restrict__ inT, const float* __restrict__ wT,
    float* __restrict__ partial, int N){
  __shared__ float wsh[CIN*64];
  __shared__ float ish[2][32*CIN];  // per-wave staging, XOR-swizzled 4-col groups
  const int tid = threadIdx.x, w = tid>>6, lane = tid&63;
  const int oq = lane&7, rg = lane>>3;
  const int o0 = oq*8;
  const int b = blockIdx.z, oc = blockIdx.x, nt = blockIdx.y;
  for (int i=tid; i<CIN*64; i+=128){
    int c = i>>6, o = i&63;
    wsh[i] = wT[(size_t)c*1024 + oc*64 + o];
  }
  __syncthreads();                  // wsh ready; ish is wave-private afterwards
  float mx[32];
#pragma unroll
  for (int i=0;i<32;i++) mx[i] = -__builtin_inff();
  const int nbase = nt*(N/8);
  float* mish = ish[w];
  for (int it=0; it<4; it++){
    const int st = it*2 + w;        // wave w handles tiles {w, w+2, w+4, w+6}
    const float* src = inT + ((size_t)b*N + nbase + st*32)*CIN;
    for (int i=lane; i<32*(CIN/4); i+=64){
      int p = i/(CIN/4), cq = i%(CIN/4);
      float4 v = ld4(src + p*CIN + 4*cq);
      int base = (((p>>2) ^ (cq&7))<<2) + (p&3);
      mish[(4*cq+0)*32 + base] = v.x;
      mish[(4*cq+1)*32 + base] = v.y;
      mish[(4*cq+2)*32 + base] = v.z;
      mish[(4*cq+3)*32 + base] = v.w;
    }
    float acc[32];
#pragma unroll
    for (int i=0;i<32;i++) acc[i]=0.f;
    for (int c=0;c<CIN;c++){
      float4 w0 = ld4(&wsh[c*64+o0]), w1v = ld4(&wsh[c*64+o0+4]);
      float4 av = ld4(&mish[c*32 + ((rg ^ ((c>>2)&7))<<2)]);
      float wv[8] = {w0.x,w0.y,w0.z,w0.w,w1v.x,w1v.y,w1v.z,w1v.w};
      float rv[4] = {av.x,av.y,av.z,av.w};
#pragma unroll
      for (int oo=0;oo<8;oo++)
#pragma unroll
        for (int rr=0;rr<4;rr++) acc[oo*4+rr] = fmaf(wv[oo], rv[rr], acc[oo*4+rr]);
    }
#pragma unroll
    for (int i=0;i<32;i++) mx[i] = fmaxf(mx[i], lrelu(acc[i]));
  }
  float m8[8];
#pragma unroll
  for (int oo=0;oo<8;oo++)
    m8[oo] = fmaxf(fmaxf(mx[oo*4+0], mx[oo*4+1]), fmaxf(mx[oo*4+2], mx[oo*4+3]));
  __syncthreads();                  // both waves done with their ish -> reuse ish[0] as merge buffer
  float* mb = ish[0];
  *(float4*)&mb[(w*8+rg)*64 + o0]     = make_float4(m8[0],m8[1],m8[2],m8[3]);
  *(float4*)&mb[(w*8+rg)*64 + o0 + 4] = make_float4(m8[4],m8[5],m8[6],m8[7]);
  __syncthreads();
  if (tid < 64){
    float v = -__builtin_inff();
#pragma unroll
    for (int g=0; g<16; g++) v = fmaxf(v, mb[g*64+tid]);
    partial[((size_t)b*8 + nt)*1024 + oc*64 + tid] = v;
  }
}

template<int TAG>
__global__ void reduce_max_kernel(const float* __restrict__ partial, float* __restrict__ out){
  int b = blockIdx.y; int o = blockIdx.x*256 + threadIdx.x;
  float v = -__builtin_inff();
  for (int s=0;s<8;s++) v = fmaxf(v, partial[((size_t)b*8 + s)*1024 + o]);
  out[(size_t)b*1024 + o] = v;
}

// ---------------- fused t-net MLP: 1024 ->512 ->256 ->9 (one launch) ----------------
// Same fmaf orders as the three fc_kernel calls -> bit-exact.
__global__ __launch_bounds__(512) void tnet_fc_kernel(
    const float* __restrict__ tg, const float* __restrict__ t_f1,
    const float* __restrict__ t_f2, const float* __restrict__ t_f3w,
    const float* __restrict__ t_f3b, float* __restrict__ T9){
  const int b = blockIdx.x, tid = threadIdx.x;
  __shared__ float in1[1024];
  __shared__ float h512[512];
  __shared__ float h256[256];
  for (int i=tid;i<1024;i+=512) in1[i] = tg[(size_t)b*1024+i];
  __syncthreads();
  {
    float s = 0.f;
    for (int c=0;c<1024;c++) s = fmaf(t_f1[(size_t)tid*1024+c], in1[c], s);
    h512[tid] = lrelu(s);
  }
  __syncthreads();
  if (tid < 256){
    float s = 0.f;
    for (int c=0;c<512;c++) s = fmaf(t_f2[(size_t)tid*512+c], h512[c], s);
    h256[tid] = lrelu(s);
  }
  __syncthreads();
  if (tid < 9){
    float s = t_f3b[tid];
    for (int c=0;c<256;c++) s = fmaf(t_f3w[(size_t)tid*256+c], h256[c], s);
    T9[(size_t)b*9+tid] = s;     // stride 9: transform_kernel reads T9 + b*9
  }
}

// ---------------- x' = T^T x per batch ----------------
__global__ void transform_kernel(const float* __restrict__ x, const float* __restrict__ T9,
                                 float* __restrict__ xp, int N){
  int b = blockIdx.y; int n = blockIdx.x*256 + threadIdx.x;
  const float* t = T9 + (size_t)b*9;
  float x0=x[((size_t)b*3+0)*N+n], x1=x[((size_t)b*3+1)*N+n], x2=x[((size_t)b*3+2)*N+n];
#pragma unroll
  for (int i=0;i<3;i++)
    xp[((size_t)b*3+i)*N+n] = t[i]*x0 + t[3+i]*x1 + t[6+i]*x2;
}

// ---------------- bias1: n-invariant part of h1 (lv = fc(l,m2) fused in) ----------------
__global__ void bias1_kernel(const float* __restrict__ g, const float* __restrict__ l,
                             const float* __restrict__ m2, const float* __restrict__ h1w,
                             float* __restrict__ bias1){
  int b = blockIdx.x;
  __shared__ float insh[1088];
  for (int i=threadIdx.x;i<1024;i+=256) insh[i] = g[(size_t)b*1024+i];
  if (threadIdx.x < 64){
    int o = threadIdx.x;
    float s = 0.f;
    for (int c=0;c<16;c++) s = fmaf(m2[(size_t)o*16+c], l[(size_t)b*16+c], s);
    insh[1024+o] = lrelu(s);
  }
  __syncthreads();
  int o = threadIdx.x;
  float s=0.f;
  for (int c=0;c<1088;c++) s = fmaf(h1w[(size_t)o*1280+c], insh[c], s);
  bias1[(size_t)b*256+o]=s;
}

// ---------------- head conv layers -- register-tiled (R8 champion) ----------------
template<int CI, int O, bool ACT>
__global__ __launch_bounds__(128) void conv1_kernel(
    const float* __restrict__ inT, const float* __restrict__ wT,
    const float* __restrict__ bias, float* __restrict__ outT, int N){
  constexpr int CCH = (CI % 128 == 0) ? 128 : 96;   // 256->128, 192->96
  constexpr int NCH = CI / CCH;
  __shared__ float wsh[CCH*64];
  __shared__ float ish[32*CCH];     // [c][32], XOR-swizzled 4-col groups
  const int tid = threadIdx.x, w = tid>>6, lane = tid&63;
  const int oq = lane&7, rg = lane>>3;
  const int o0 = oq*8, r0 = w*16 + rg*2;   // rows split across waves (dedup)
  const int b = blockIdx.y, n0 = blockIdx.x*32, oc = blockIdx.z;
  const float* src = inT + ((size_t)b*N + n0)*CI;
  float acc[16];
#pragma unroll
  for (int i=0;i<16;i++) acc[i]=0.f;
  for (int ch=0; ch<NCH; ch++){
    const int cc0 = ch*CCH;
    if (ch) __syncthreads();        // prev chunk's compute done before restage
    for (int i=tid; i<CCH*64; i+=128){
      int c = i>>6, od = i&63;
      wsh[i] = wT[(size_t)(cc0+c)*O + oc*64 + od];
    }
    for (int i=tid; i<32*(CCH/4); i+=128){
      int p = i/(CCH/4), cq = i%(CCH/4);
      float4 v = ld4(src + p*CI + cc0 + 4*cq);
      int base = (((p>>2) ^ (cq&7))<<2) + (p&3);
      ish[(4*cq+0)*32 + base] = v.x;
      ish[(4*cq+1)*32 + base] = v.y;
      ish[(4*cq+2)*32 + base] = v.z;
      ish[(4*cq+3)*32 + base] = v.w;
    }
    __syncthreads();
    for (int c=0;c<CCH;c++){
      float4 w0 = ld4(&wsh[c*64+o0]), w1v = ld4(&wsh[c*64+o0+4]);
      float2 av = *(const float2*)&ish[c*32 + ((((r0>>2) ^ ((c>>2)&7))<<2) + (r0&3))];
      float wv[8] = {w0.x,w0.y,w0.z,w0.w,w1v.x,w1v.y,w1v.z,w1v.w};
      float rv[2] = {av.x,av.y};
#pragma unroll
      for (int oo=0;oo<8;oo++)
#pragma unroll
        for (int rr=0;rr<2;rr++) acc[oo*2+rr] = fmaf(wv[oo], rv[rr], acc[oo*2+rr]);
    }
  }
  float bv[8];
  if (bias){
    float4 b0 = ld4(&bias[(size_t)b*O + oc*64 + o0]);
    float4 b1 = ld4(&bias[(size_t)b*O + oc*64 + o0 + 4]);
    bv[0]=b0.x; bv[1]=b0.y; bv[2]=b0.z; bv[3]=b0.w;
    bv[4]=b1.x; bv[5]=b1.y; bv[6]=b1.z; bv[7]=b1.w;
  } else {
#pragma unroll
    for (int i=0;i<8;i++) bv[i]=0.f;
  }
#pragma unroll
  for (int rr=0;rr<2;rr++){
    float oa[8];
#pragma unroll
    for (int oo=0;oo<8;oo++){
      float s = acc[oo*2+rr] + bv[oo];
      oa[oo] = ACT ? lrelu(s) : s;
    }
    float* dst = &outT[((size_t)b*N + n0 + r0 + rr)*O + oc*64 + o0];
    *(float4*)dst     = make_float4(oa[0],oa[1],oa[2],oa[3]);
    *(float4*)(dst+4) = make_float4(oa[4],oa[5],oa[6],oa[7]);
  }
}

// ---------------- final layer: 128 -> 50, rows-layout output (B,50,N) ----------------
__global__ __launch_bounds__(256) void conv_out_kernel(
    const float* __restrict__ inT, const float* __restrict__ wT,
    float* __restrict__ out, int N){
  const int b = blockIdx.y, n0 = blockIdx.x*32;
  __shared__ float insh[32*129];
  const float* src = inT + ((size_t)b*N + n0)*128;
  for (int i=threadIdx.x;i<32*128;i+=256){ int nn=i>>7, c=i&127; insh[nn*129+c]=src[i]; }
  __syncthreads();
  const int nl = threadIdx.x & 31, og = threadIdx.x >> 5;
  float acc[7];
#pragma unroll
  for (int t=0;t<7;t++) acc[t]=0.f;
  for (int c=0;c<128;c++){
    float iv = insh[nl*129+c];
#pragma unroll
    for (int t=0;t<7;t++){
      int o = og + 8*t;
      float wv = (o<50)? wT[c*50+o] : 0.f;
      acc[t] = fmaf(wv, iv, acc[t]);
    }
  }
#pragma unroll
  for (int t=0;t<7;t++){
    int o = og + 8*t;
    if (o < 50) out[((size_t)b*50+o)*N + n0 + nl] = acc[t];
  }
}

extern "C" void kernel_launch(void* const* d_in, const int* in_sizes, int n_in,
                              void* d_out, int out_size, void* d_ws, size_t ws_size,
                              hipStream_t stream){
  const float* x    = (const float*)d_in[0];
  const float* l    = (const float*)d_in[1];
  const float* t_c1 = (const float*)d_in[2];
  const float* t_c2 = (const float*)d_in[3];
  const float* t_c3 = (const float*)d_in[4];
  const float* t_f1 = (const float*)d_in[5];
  const float* t_f2 = (const float*)d_in[6];
  const float* t_f3w= (const float*)d_in[7];
  const float* t_f3b= (const float*)d_in[8];
  const float* b1a  = (const float*)d_in[9];
  const float* b1b  = (const float*)d_in[10];
  const float* b2a  = (const float*)d_in[11];
  const float* b2b  = (const float*)d_in[12];
  const float* b3a  = (const float*)d_in[13];
  const float* m1   = (const float*)d_in[14];
  const float* m2   = (const float*)d_in[15];
  const float* h1   = (const float*)d_in[16];
  const float* h2   = (const float*)d_in[17];
  const float* h3   = (const float*)d_in[18];
  const float* h4   = (const float*)d_in[19];
  float* out = (float*)d_out;
  float* ws = (float*)d_ws;
  const int N = NPTS, B = BATCH;

  size_t off = 0;
  auto alloc = [&](size_t nf){ float* p = ws + off; off += nf; return p; };
  float* WT_TC3 = alloc((size_t)128*1024);
  float* WT_M1  = alloc((size_t)192*1024);
  float* WT_H1B = alloc((size_t)192*256);
  float* WT_H2  = alloc((size_t)256*256);
  float* WT_H3  = alloc((size_t)256*128);
  float* WT_H4  = alloc((size_t)128*64);
  int*   IDXT   = (int*)alloc((size_t)B*N*KNN);
  float* XX     = alloc((size_t)B*N);
  float* TT     = alloc((size_t)B*N*128);
  float* PARTIAL= alloc((size_t)B*8*1024);
  float* TG     = alloc((size_t)B*1024);
  float* T9     = alloc((size_t)B*16);
  float* XP     = alloc((size_t)B*3*N);
  float* CATT   = alloc((size_t)B*N*192);
  float* G      = alloc((size_t)B*1024);
  float* BIAS1  = alloc((size_t)B*256);
  float* H1T    = alloc((size_t)B*N*256);
  float* H2T    = alloc((size_t)B*N*256);
  float* H3T    = alloc((size_t)B*N*128);
  (void)ws_size; (void)in_sizes; (void)n_in; (void)out_size;

  dim3 blk(256);
  dim3 eblk(128);
  // all 6 weight transposes in one launch
  transpose6_kernel<<<dim3(768,6), blk, 0, stream>>>(
      t_c3, WT_TC3, m1, WT_M1, h1, WT_H1B, h2, WT_H2, h3, WT_H3, h4, WT_H4);

  // t-path
  norms_rows_kernel<0><<<dim3(N/256,B), blk, 0, stream>>>(x, XX, N);
  knn3_kernel<0><<<dim3(N/4,B), blk, 0, stream>>>(x, XX, IDXT, N);
  edgeA_kernel<<<dim3(N/16,B), blk, 0, stream>>>(x, IDXT, t_c1, t_c2, TT, N);
  convmax_kernel<128,0><<<dim3(16,8,B), eblk, 0, stream>>>(TT, WT_TC3, PARTIAL, N);
  reduce_max_kernel<0><<<dim3(4,B), blk, 0, stream>>>(PARTIAL, TG);
  tnet_fc_kernel<<<dim3(B), dim3(512), 0, stream>>>(TG, t_f1, t_f2, t_f3w, t_f3b, T9);
  transform_kernel<<<dim3(N/256,B), blk, 0, stream>>>(x, T9, XP, N);

  // edge block 1 (transformed points, 3ch)
  norms_rows_kernel<1><<<dim3(N/256,B), blk, 0, stream>>>(XP, XX, N);
  knn3_kernel<1><<<dim3(N/4,B), blk, 0, stream>>>(XP, XX, IDXT, N);
  edgeB_kernel<<<dim3(N/32,B), eblk, 0, stream>>>(XP, IDXT, b1a, b1b, CATT, N);

  // edge block 2 (x1 = CATT[...,0:64])
  norms_cl_kernel<0><<<dim3(N/256,B), blk, 0, stream>>>(CATT, 0, XX, N);
  knn64_kernel<0><<<dim3(N/4,B), blk, 0, stream>>>(CATT, 0, XX, IDXT, N);
  edgeC_kernel<<<dim3(N/32,B), eblk, 0, stream>>>(CATT, 0, IDXT, b2a, b2b, CATT, 64, N);

  // edge block 3 (x2 = CATT[...,64:128])
  norms_cl_kernel<1><<<dim3(N/256,B), blk, 0, stream>>>(CATT, 64, XX, N);
  knn64_kernel<1><<<dim3(N/4,B), blk, 0, stream>>>(CATT, 64, XX, IDXT, N);
  edgeD_kernel<<<dim3(N/32,B), eblk, 0, stream>>>(CATT, 64, IDXT, b3a, CATT, 128, N);

  // global feature + head
  convmax_kernel<192,1><<<dim3(16,8,B), eblk, 0, stream>>>(CATT, WT_M1, PARTIAL, N);
  reduce_max_kernel<1><<<dim3(4,B), blk, 0, stream>>>(PARTIAL, G);
  bias1_kernel<<<dim3(B), blk, 0, stream>>>(G, l, m2, h1, BIAS1);
  conv1_kernel<192,256,true><<<dim3(N/32,B,4), eblk, 0, stream>>>(CATT, WT_H1B, BIAS1, H1T, N);
  conv1_kernel<256,256,true><<<dim3(N/32,B,4), eblk, 0, stream>>>(H1T, WT_H2, nullptr, H2T, N);
  conv1_kernel<256,128,true><<<dim3(N/32,B,2), eblk, 0, stream>>>(H2T, WT_H3, nullptr, H3T, N);
  conv_out_kernel<<<dim3(N/32,B), blk, 0, stream>>>(H3T, WT_H4, out, N);
}

// Round 12
// 2142.147 us; speedup vs baseline: 1.1796x; 1.0723x over previous
//
#include <hip/hip_runtime.h>
#include <cstdint>

#define NPTS 2048
#define BATCH 8
#define KNN 40

__device__ __forceinline__ float lrelu(float v){ return fmaxf(v, 0.2f*v); }
__device__ __forceinline__ bool better(float v1,int i1,float v2,int i2){
  return (v1>v2) || (v1==v2 && i1<i2);
}
__device__ __forceinline__ float4 ld4(const float* p){ return *(const float4*)p; }

// insert (d,m) into sorted-desc 8-list if it beats the tail; static CE chain.
#define INSERT8(v,id,d,m) \
  if (better(d, m, v[7], id[7])){ \
    v[7]=d; id[7]=m; \
    { if (better(v[7],id[7],v[6],id[6])){ float tv=v[6];int ti=id[6]; v[6]=v[7];id[6]=id[7]; v[7]=tv;id[7]=ti; } } \
    { if (better(v[6],id[6],v[5],id[5])){ float tv=v[5];int ti=id[5]; v[5]=v[6];id[5]=id[6]; v[6]=tv;id[6]=ti; } } \
    { if (better(v[5],id[5],v[4],id[4])){ float tv=v[4];int ti=id[4]; v[4]=v[5];id[4]=id[5]; v[5]=tv;id[5]=ti; } } \
    { if (better(v[4],id[4],v[3],id[3])){ float tv=v[3];int ti=id[3]; v[3]=v[4];id[3]=id[4]; v[4]=tv;id[4]=ti; } } \
    { if (better(v[3],id[3],v[2],id[2])){ float tv=v[2];int ti=id[2]; v[2]=v[3];id[2]=id[3]; v[3]=tv;id[3]=ti; } } \
    { if (better(v[2],id[2],v[1],id[1])){ float tv=v[1];int ti=id[1]; v[1]=v[2];id[1]=id[2]; v[2]=tv;id[2]=ti; } } \
    { if (better(v[1],id[1],v[0],id[0])){ float tv=v[0];int ti=id[0]; v[0]=v[1];id[0]=id[1]; v[1]=tv;id[1]=ti; } } \
  }

// ---------------- fused weight transposes (6 jobs, 1 launch) ----------------
__global__ void transpose6_kernel(
    const float* __restrict__ s0, float* __restrict__ d0,
    const float* __restrict__ s1, float* __restrict__ d1,
    const float* __restrict__ s2, float* __restrict__ d2,
    const float* __restrict__ s3, float* __restrict__ d3,
    const float* __restrict__ s4, float* __restrict__ d4,
    const float* __restrict__ s5, float* __restrict__ d5){
  int i = blockIdx.x*256 + threadIdx.x;
  const float* src; float* dst; int R,C,ld,off;
  switch (blockIdx.y){
    case 0:  src=s0; dst=d0; R=1024; C=128; ld=128;  off=0;    break;
    case 1:  src=s1; dst=d1; R=1024; C=192; ld=192;  off=0;    break;
    case 2:  src=s2; dst=d2; R=256;  C=192; ld=1280; off=1088; break;
    case 3:  src=s3; dst=d3; R=256;  C=256; ld=256;  off=0;    break;
    case 4:  src=s4; dst=d4; R=128;  C=256; ld=256;  off=0;    break;
    default: src=s5; dst=d5; R=50;   C=128; ld=128;  off=0;    break;
  }
  if (i < R*C){ int r = i / C, c = i % C; dst[c*R + r] = src[r*ld + off + c]; }
}

// ---------------- squared norms, rows layout (B,3,N) ----------------
template<int TAG>
__global__ void norms_rows_kernel(const float* __restrict__ x, float* __restrict__ xx, int N){
  int b = blockIdx.y; int n = blockIdx.x*256 + threadIdx.x;
  const float* xb = x + (size_t)b*3*N;
  float v0 = xb[n], v1 = xb[N+n], v2 = xb[2*N+n];
  xx[(size_t)b*N + n] = v0*v0 + v1*v1 + v2*v2;
}

// ---------------- squared norms, channel-last 64ch slice of (B,N,192) ----------------
template<int TAG>
__global__ void norms_cl_kernel(const float* __restrict__ f, int off, float* __restrict__ xx, int N){
  int b = blockIdx.y; int n = blockIdx.x*256 + threadIdx.x;
  const float4* p = (const float4*)(f + ((size_t)b*N + n)*192 + off);
  float s = 0.f;
#pragma unroll
  for (int q=0;q<16;q++){ float4 v = p[q]; s += v.x*v.x + v.y*v.y + v.z*v.z + v.w*v.w; }
  xx[(size_t)b*N + n] = s;
}

__device__ __forceinline__ void sort8(float (&v)[8], int (&id)[8]){
#define CE(a,bq) { if (better(v[bq],id[bq],v[a],id[a])){ float tv=v[a]; int ti=id[a]; v[a]=v[bq]; id[a]=id[bq]; v[bq]=tv; id[bq]=ti; } }
  CE(0,1) CE(2,3) CE(4,5) CE(6,7)
  CE(0,2) CE(1,3) CE(4,6) CE(5,7)
  CE(1,2) CE(5,6)
  CE(0,4) CE(1,5) CE(2,6) CE(3,7)
  CE(2,4) CE(3,5)
  CE(1,2) CE(3,4) CE(5,6)
#undef CE
}

// ---------------- knn 3-channel: 4 queries/block (1/wave), zero LDS, zero barriers ----------------
template<int TAG>
__global__ __launch_bounds__(256) void knn3_kernel(
    const float* __restrict__ xrows, const float* __restrict__ xx,
    int* __restrict__ idxT, int N){
  const int b = blockIdx.y, tid = threadIdx.x;
  const int w = tid>>6, lane = tid&63;
  const int nq = blockIdx.x*4 + w;
  const float* xb = xrows + (size_t)b*3*N;
  const float* xxb = xx + (size_t)b*N;
  float c0 = xb[nq], c1 = xb[N+nq], c2 = xb[2*N+nq];
  float xxn = xxb[nq];
  float v[8]; int id[8];
#pragma unroll
  for (int j=0;j<8;j++){ v[j]=-__builtin_inff(); id[j]=0x7FFFFFFF; }
  for (int j=0;j<32;j++){
    int m = j*64 + lane;
    float s = c0*xb[m] + c1*xb[N+m] + c2*xb[2*N+m];
    float d = 2.f*s - xxn - xxb[m];
    INSERT8(v, id, d, m)
  }
  float lastv = 0.f; int lasti = 0;
  int win = 0;
  for (int r=0;r<KNN;r++){
    float bv = v[0]; int bi = id[0];
#pragma unroll
    for (int off=32; off; off>>=1){
      float ov = __shfl_xor(bv, off);
      int   oi = __shfl_xor(bi, off);
      if (better(ov, oi, bv, bi)){ bv = ov; bi = oi; }
    }
    if (lane == r) win = bi;
    if (id[0] == bi){
      lastv = v[0]; lasti = id[0];
#pragma unroll
      for (int j=0;j<7;j++){ v[j]=v[j+1]; id[j]=id[j+1]; }
      v[7] = -__builtin_inff(); id[7] = 0x7FFFFFFF;
      if (id[0] == 0x7FFFFFFF){   // rare refill: best strictly worse than last pop
        float nv = -__builtin_inff(); int ni = 0x7FFFFFFF;
        for (int j=0;j<32;j++){
          int m = j*64 + lane;
          float s = c0*xb[m] + c1*xb[N+m] + c2*xb[2*N+m];
          float dd = 2.f*s - xxn - xxb[m];
          if (better(lastv, lasti, dd, m) && better(dd, m, nv, ni)){ nv=dd; ni=m; }
        }
        v[0] = nv; id[0] = ni;
      }
    }
  }
  if (lane < KNN) idxT[((size_t)b*KNN + lane)*N + nq] = win;
}

// ---------------- knn 64-channel (channel-last), 4 queries/block ----------------
// v6 (R5 champion): 32-cand tile (8 KiB) + 4x8K strips = 40960 B -> 16 waves/CU.
template<int TAG>
__global__ __launch_bounds__(256) void knn64_kernel(
    const float* __restrict__ featT, int featOff,
    const float* __restrict__ xx, int* __restrict__ idxT, int N){
  const int b = blockIdx.y, tid = threadIdx.x;
  const int w = tid>>6, lane = tid&63;
  __shared__ float cand[32*64];    // xor-swizzled [cand][ch] tile (8 KiB), block-shared
  __shared__ float dist[4*2048];   // wave-private strips (32 KiB)
  const float* fb = featT + featOff;
  const float* xxb = xx + (size_t)b*N;
  const int nq = blockIdx.x*4 + w;
  const int h = lane>>5;           // channel half this lane covers
  float4 ctr8[8];
  {
    const float4* cp = (const float4*)(fb + ((size_t)b*N + nq)*192);
#pragma unroll
    for (int q=0;q<8;q++) ctr8[q] = cp[h*8 + q];
  }
  float xxn = xxb[nq];
  float* dw = &dist[w*2048];
  float4 g[2];
#pragma unroll
  for (int r=0;r<2;r++){
    int k2 = tid + 256*r;
    int c = k2>>4, f = k2&15;
    g[r] = ld4(&fb[((size_t)b*N + c)*192 + 4*f]);
  }
  const int cc = lane&31, swz = cc&15, qb = h*8;
  for (int t=0;t<64;t++){
    __syncthreads();                 // prev compute done reading cand
#pragma unroll
    for (int r=0;r<2;r++){
      int k2 = tid + 256*r;
      int c = k2>>4, f = k2&15;
      *(float4*)&cand[(c<<6) + ((f ^ (c&15))<<2)] = g[r];
    }
    __syncthreads();
    if (t+1 < 64){                   // issue next tile's loads; latency overlaps compute
      int m0n = (t+1)*32;
#pragma unroll
      for (int r=0;r<2;r++){
        int k2 = tid + 256*r;
        int c = k2>>4, f = k2&15;
        g[r] = ld4(&fb[((size_t)b*N + m0n + c)*192 + 4*f]);
      }
    }
    float s0=0.f,s1=0.f,s2=0.f,s3=0.f;
#pragma unroll
    for (int j=0;j<8;j++){
      float4 mv = *(const float4*)&cand[(cc<<6) + (((qb + j) ^ swz)<<2)];
      s0 = fmaf(ctr8[j].x, mv.x, s0);
      s1 = fmaf(ctr8[j].y, mv.y, s1);
      s2 = fmaf(ctr8[j].z, mv.z, s2);
      s3 = fmaf(ctr8[j].w, mv.w, s3);
    }
    float p = (s0+s1)+(s2+s3);
    float tot = p + __shfl_xor(p, 32);    // combine channel halves (commutative -> both halves identical)
    if (h == (t&1)){                      // owner lane (m & 63 == lane) writes its strip slot
      int m = t*32 + cc;
      dw[(t>>1)*64 + lane] = 2.f*tot - xxn - xxb[m];
    }
  }
  // ---- per-lane exact top-8 of its 32 entries (sorted desc by (v desc, idx asc)) ----
  float v[8]; int id[8];
#pragma unroll
  for (int j=0;j<8;j++){ v[j]=dw[j*64+lane]; id[j]=j*64+lane; }
  sort8(v, id);
#pragma unroll
  for (int gq=1; gq<4; gq++){
    float a[8]; int ai[8];
#pragma unroll
    for (int j=0;j<8;j++){ a[j]=dw[(gq*8+j)*64+lane]; ai[j]=(gq*8+j)*64+lane; }
    sort8(a, ai);
    float m_[8]; int mi_[8];
#pragma unroll
    for (int k=0;k<8;k++){
      if (better(a[7-k], ai[7-k], v[k], id[k])){ m_[k]=a[7-k]; mi_[k]=ai[7-k]; }
      else                                     { m_[k]=v[k];   mi_[k]=id[k]; }
    }
#define CEB(x,y) { if (better(m_[y],mi_[y],m_[x],mi_[x])){ float tv=m_[x];int ti=mi_[x]; m_[x]=m_[y];mi_[x]=mi_[y]; m_[y]=tv;mi_[y]=ti; } }
    CEB(0,4) CEB(1,5) CEB(2,6) CEB(3,7)
    CEB(0,2) CEB(1,3) CEB(4,6) CEB(5,7)
    CEB(0,1) CEB(2,3) CEB(4,5) CEB(6,7)
#undef CEB
#pragma unroll
    for (int k=0;k<8;k++){ v[k]=m_[k]; id[k]=mi_[k]; }
  }
  // ---- 40 extraction rounds: butterfly + pop-shift; zero barriers, zero LDS steady state ----
  float lastv = 0.f; int lasti = 0;
  int win = 0;
  for (int r=0;r<KNN;r++){
    float bv = v[0]; int bi = id[0];
#pragma unroll
    for (int off=32; off; off>>=1){
      float ov = __shfl_xor(bv, off);
      int   oi = __shfl_xor(bi, off);
      if (better(ov, oi, bv, bi)){ bv = ov; bi = oi; }
    }
    if (lane == r) win = bi;
    if (id[0] == bi){                // unique owner (indices unique)
      lastv = v[0]; lasti = id[0];
#pragma unroll
      for (int j=0;j<7;j++){ v[j]=v[j+1]; id[j]=id[j+1]; }
      v[7] = -__builtin_inff(); id[7] = 0x7FFFFFFF;
      if (id[0] == 0x7FFFFFFF){      // rare: lane contributed >8 of top-40 -> refill head
        float nv = -__builtin_inff(); int ni = 0x7FFFFFFF;
        for (int j=0;j<32;j++){
          float vv = dw[j*64 + lane]; int m = j*64 + lane;
          if (better(lastv, lasti, vv, m) && better(vv, m, nv, ni)){ nv=vv; ni=m; }
        }
        v[0] = nv; id[0] = ni;
      }
    }
  }
  if (lane < KNN) idxT[((size_t)b*KNN + lane)*N + nq] = win;
}

// ==================== register-tiled edge kernels ====================

// ---- edgeA (t-path): 3ch -> 64 -> 128, max over k ----
__global__ __launch_bounds__(256) void edgeA_kernel(
    const float* __restrict__ x, const int* __restrict__ idxT,
    const float* __restrict__ w1, const float* __restrict__ w2,
    float* __restrict__ tT, int N){
  __shared__ float w1aT[3*64];
  __shared__ float wd3T[3*64];
  __shared__ float w2T[64*128];      // [c][o]; reused as merge buffer (4 x 16r x 128o)
  __shared__ float aT3[4][3*16];
  __shared__ float s1T[4][64*16];    // [c][r]
  const int tid = threadIdx.x, w = tid>>6, lane = tid&63;
  const int oq = lane&7, rg = lane>>3;
  const int o0 = oq*8, r0 = rg*2;
  const int b = blockIdx.y, n0 = blockIdx.x*16;
  for (int i=tid; i<192; i+=256){
    int o = i&63, c = i/64;
    float a = w1[o*6+c];
    w1aT[c*64+o] = a; wd3T[c*64+o] = w1[o*6+3+c] - a;
  }
  for (int i=tid; i<128*64; i+=256){
    int o = i>>6, c = i&63;
    w2T[c*128+o] = w2[o*64+c];
  }
  if (tid < 48){ int c = tid>>4, r = tid&15; aT3[0][c*16+r] = x[((size_t)b*3+c)*N + n0 + r]; }
  __syncthreads();
  float base[16];
#pragma unroll
  for (int i=0;i<16;i++) base[i]=0.f;
#pragma unroll
  for (int c=0;c<3;c++){
    float4 wA = ld4(&wd3T[c*64+o0]), wB = ld4(&wd3T[c*64+o0+4]);
    float2 av = *(const float2*)&aT3[0][c*16+r0];
    float wv[8] = {wA.x,wA.y,wA.z,wA.w,wB.x,wB.y,wB.z,wB.w};
    float rv[2] = {av.x,av.y};
#pragma unroll
    for (int oo=0;oo<8;oo++)
#pragma unroll
      for (int rr=0;rr<2;rr++) base[oo*2+rr] = fmaf(wv[oo], rv[rr], base[oo*2+rr]);
  }
  __syncthreads();   // all waves done reading aT3[0] before k-loop overwrites
  float mx[32];
#pragma unroll
  for (int i=0;i<32;i++) mx[i] = -__builtin_inff();
  for (int it=0; it<10; it++){
    int k = it*4 + w;
    int m = idxT[((size_t)b*KNN + k)*N + n0 + (lane&15)];
    if (lane < 48){ int c = lane>>4; aT3[w][c*16 + (lane&15)] = x[((size_t)b*3+c)*N + m]; }
    // stage1 (64 o x 16 r)
    float acc[16];
#pragma unroll
    for (int i=0;i<16;i++) acc[i] = base[i];
#pragma unroll
    for (int c=0;c<3;c++){
      float4 wA = ld4(&w1aT[c*64+o0]), wB = ld4(&w1aT[c*64+o0+4]);
      float2 av = *(const float2*)&aT3[w][c*16+r0];
      float wv[8] = {wA.x,wA.y,wA.z,wA.w,wB.x,wB.y,wB.z,wB.w};
      float rv[2] = {av.x,av.y};
#pragma unroll
      for (int oo=0;oo<8;oo++)
#pragma unroll
        for (int rr=0;rr<2;rr++) acc[oo*2+rr] = fmaf(wv[oo], rv[rr], acc[oo*2+rr]);
    }
#pragma unroll
    for (int oo=0;oo<8;oo++){
      float2 sv; sv.x = lrelu(acc[oo*2]); sv.y = lrelu(acc[oo*2+1]);
      *(float2*)&s1T[w][(o0+oo)*16 + r0] = sv;
    }
    // stage2 (128 o x 16 r): 4 panels, o = p*32 + oq*4 -> 32 banks, conflict-free
    float acc2[32];
#pragma unroll
    for (int i=0;i<32;i++) acc2[i]=0.f;
    for (int c=0;c<64;c++){
      float2 av = *(const float2*)&s1T[w][c*16 + r0];
#pragma unroll
      for (int p=0;p<4;p++){
        float4 wv = ld4(&w2T[c*128 + p*32 + oq*4]);
        acc2[p*8+0] = fmaf(wv.x, av.x, acc2[p*8+0]);
        acc2[p*8+1] = fmaf(wv.x, av.y, acc2[p*8+1]);
        acc2[p*8+2] = fmaf(wv.y, av.x, acc2[p*8+2]);
        acc2[p*8+3] = fmaf(wv.y, av.y, acc2[p*8+3]);
        acc2[p*8+4] = fmaf(wv.z, av.x, acc2[p*8+4]);
        acc2[p*8+5] = fmaf(wv.z, av.y, acc2[p*8+5]);
        acc2[p*8+6] = fmaf(wv.w, av.x, acc2[p*8+6]);
        acc2[p*8+7] = fmaf(wv.w, av.y, acc2[p*8+7]);
      }
    }
#pragma unroll
    for (int i=0;i<32;i++) mx[i] = fmaxf(mx[i], lrelu(acc2[i]));
  }
  __syncthreads();   // all waves done reading w2T -> reuse as merge buffer
#pragma unroll
  for (int rr=0;rr<2;rr++){
#pragma unroll
    for (int p=0;p<4;p++){
      float4 a = make_float4(mx[p*8+0+rr], mx[p*8+2+rr], mx[p*8+4+rr], mx[p*8+6+rr]);
      *(float4*)&w2T[w*2048 + (r0+rr)*128 + p*32 + oq*4] = a;
    }
  }
  __syncthreads();
  for (int i=tid; i<2048; i+=256){
    float vv = fmaxf(fmaxf(w2T[i], w2T[2048+i]), fmaxf(w2T[4096+i], w2T[6144+i]));
    int r = i>>7, o = i&127;
    tT[((size_t)b*N + n0 + r)*128 + o] = vv;
  }
}

// ---- edgeB: 3ch -> 64 -> 64, max over k ----
// v4: 4 waves/block, k = it*4 + w, it<10 -> all 40 neighbors (R11 bug: it<5 covered 20).
// Gather software-pipelined. 4-way max merge (max is exactly associative -> bit-exact).
__global__ __launch_bounds__(256) void edgeB_kernel(
    const float* __restrict__ xp, const int* __restrict__ idxT,
    const float* __restrict__ w1, const float* __restrict__ w2,
    float* __restrict__ catT, int N){
  __shared__ float w1aT[3*64];
  __shared__ float wd3T[3*64];
  __shared__ float w2T[64*64];
  __shared__ float aT3[4][3*32];
  __shared__ float s1T[4][64*32];
  const int tid = threadIdx.x, w = tid>>6, lane = tid&63;
  const int oq = lane&7, rg = lane>>3;
  const int o0 = oq*8, r0 = rg*4;
  const int b = blockIdx.y, n0 = blockIdx.x*32;
  for (int i=tid; i<192; i+=256){
    int o = i&63, c = i>>6;
    float a = w1[o*6+c], bb = w1[o*6+3+c];
    w1aT[c*64+o] = a; wd3T[c*64+o] = bb - a;
  }
  for (int i=tid; i<64*64; i+=256){
    int o = i>>6, c = i&63;
    w2T[c*64+o] = w2[o*64+c];
  }
  if (tid < 32){
#pragma unroll
    for (int c=0;c<3;c++) aT3[0][c*32+tid] = xp[((size_t)b*3+c)*N + n0 + tid];
  }
  __syncthreads();
  float base[32];
#pragma unroll
  for (int i=0;i<32;i++) base[i]=0.f;
#pragma unroll
  for (int c=0;c<3;c++){
    float4 w0 = ld4(&wd3T[c*64+o0]), w1v = ld4(&wd3T[c*64+o0+4]);
    float4 av = ld4(&aT3[0][c*32+r0]);
    float wv[8] = {w0.x,w0.y,w0.z,w0.w,w1v.x,w1v.y,w1v.z,w1v.w};
    float rv[4] = {av.x,av.y,av.z,av.w};
#pragma unroll
    for (int oo=0;oo<8;oo++)
#pragma unroll
      for (int rr=0;rr<4;rr++) base[oo*4+rr] = fmaf(wv[oo], rv[rr], base[oo*4+rr]);
  }
  __syncthreads();
  float mx[32];
#pragma unroll
  for (int i=0;i<32;i++) mx[i] = -__builtin_inff();
  const int row = lane&31;
  float g0=0.f, g1=0.f, g2=0.f;
  {
    int m = idxT[((size_t)b*KNN + w)*N + n0 + row];
    if (lane < 32){
      g0 = xp[((size_t)b*3+0)*N + m];
      g1 = xp[((size_t)b*3+1)*N + m];
      g2 = xp[((size_t)b*3+2)*N + m];
    }
  }
  for (int it=0; it<10; it++){
    if (lane < 32){
      aT3[w][0*32+row] = g0;
      aT3[w][1*32+row] = g1;
      aT3[w][2*32+row] = g2;
    }
    if (it+1 < 10){                  // prefetch next gather; latency hides under compute
      int m = idxT[((size_t)b*KNN + (it+1)*4 + w)*N + n0 + row];
      if (lane < 32){
        g0 = xp[((size_t)b*3+0)*N + m];
        g1 = xp[((size_t)b*3+1)*N + m];
        g2 = xp[((size_t)b*3+2)*N + m];
      }
    }
    float acc[32];
#pragma unroll
    for (int i=0;i<32;i++) acc[i] = base[i];
#pragma unroll
    for (int c=0;c<3;c++){
      float4 w0 = ld4(&w1aT[c*64+o0]), w1v = ld4(&w1aT[c*64+o0+4]);
      float4 av = ld4(&aT3[w][c*32+r0]);
      float wv[8] = {w0.x,w0.y,w0.z,w0.w,w1v.x,w1v.y,w1v.z,w1v.w};
      float rv[4] = {av.x,av.y,av.z,av.w};
#pragma unroll
      for (int oo=0;oo<8;oo++)
#pragma unroll
        for (int rr=0;rr<4;rr++) acc[oo*4+rr] = fmaf(wv[oo], rv[rr], acc[oo*4+rr]);
    }
#pragma unroll
    for (int oo=0;oo<8;oo++){
      float4 sv = make_float4(lrelu(acc[oo*4+0]), lrelu(acc[oo*4+1]), lrelu(acc[oo*4+2]), lrelu(acc[oo*4+3]));
      *(float4*)&s1T[w][(o0+oo)*32 + r0] = sv;
    }
    float acc2[32];
#pragma unroll
    for (int i=0;i<32;i++) acc2[i]=0.f;
    for (int c=0;c<64;c++){
      float4 w0 = ld4(&w2T[c*64+o0]), w1v = ld4(&w2T[c*64+o0+4]);
      float4 av = ld4(&s1T[w][c*32+r0]);
      float wv[8] = {w0.x,w0.y,w0.z,w0.w,w1v.x,w1v.y,w1v.z,w1v.w};
      float rv[4] = {av.x,av.y,av.z,av.w};
#pragma unroll
      for (int oo=0;oo<8;oo++)
#pragma unroll
        for (int rr=0;rr<4;rr++) acc2[oo*4+rr] = fmaf(wv[oo], rv[rr], acc2[oo*4+rr]);
    }
#pragma unroll
    for (int i=0;i<32;i++) mx[i] = fmaxf(mx[i], lrelu(acc2[i]));
  }
  __syncthreads();
#pragma unroll
  for (int rr=0;rr<4;rr++){
    float4 a = make_float4(mx[0*4+rr], mx[1*4+rr], mx[2*4+rr], mx[3*4+rr]);
    float4 bq = make_float4(mx[4*4+rr], mx[5*4+rr], mx[6*4+rr], mx[7*4+rr]);
    *(float4*)&s1T[w][(r0+rr)*64 + o0] = a;
    *(float4*)&s1T[w][(r0+rr)*64 + o0 + 4] = bq;
  }
  __syncthreads();
  for (int i=tid; i<2048; i+=256){
    float v = fmaxf(fmaxf(s1T[0][i], s1T[1][i]), fmaxf(s1T[2][i], s1T[3][i]));
    int r = i>>6, o = i&63;
    catT[((size_t)b*N + n0 + r)*192 + o] = v;
  }
}

// ---- edgeC: 64ch -> 64 -> 64, max over k ----
// v2 (R10): gather software-pipelined; 2 waves (LDS-capped; 4-wave variant needs 96KB).
__global__ __launch_bounds__(128) void edgeC_kernel(
    const float* __restrict__ inT, int inOff, const int* __restrict__ idxT,
    const float* __restrict__ w1, const float* __restrict__ w2,
    float* __restrict__ catT, int outOff, int N){
  __shared__ float w1T[64*64];
  __shared__ float w2T[64*64];
  __shared__ float aT[2][64*32];
  __shared__ float s1T[2][64*32];
  const int tid = threadIdx.x, w = tid>>6, lane = tid&63;
  const int oq = lane&7, rg = lane>>3;
  const int o0 = oq*8, r0 = rg*4;
  const int b = blockIdx.y, n0 = blockIdx.x*32;
  for (int i=tid; i<64*64; i+=128){
    int o = i>>6, c = i&63;
    float a = w1[o*128+c], bb = w1[o*128+64+c];
    w1T[c*64+o] = a; w2T[c*64+o] = bb - a;
  }
  for (int i=tid; i<512; i+=128){
    int p = i>>4, cq = i&15;
    float4 v = ld4(&inT[((size_t)b*N + n0 + p)*192 + inOff + cq*4]);
    aT[0][(cq*4+0)*32+p] = v.x; aT[0][(cq*4+1)*32+p] = v.y;
    aT[0][(cq*4+2)*32+p] = v.z; aT[0][(cq*4+3)*32+p] = v.w;
  }
  __syncthreads();
  float base[32];
#pragma unroll
  for (int i=0;i<32;i++) base[i]=0.f;
  for (int c=0;c<64;c++){
    float4 w0 = ld4(&w2T[c*64+o0]), w1v = ld4(&w2T[c*64+o0+4]);
    float4 av = ld4(&aT[0][c*32+r0]);
    float wv[8] = {w0.x,w0.y,w0.z,w0.w,w1v.x,w1v.y,w1v.z,w1v.w};
    float rv[4] = {av.x,av.y,av.z,av.w};
#pragma unroll
    for (int oo=0;oo<8;oo++)
#pragma unroll
      for (int rr=0;rr<4;rr++) base[oo*4+rr] = fmaf(wv[oo], rv[rr], base[oo*4+rr]);
  }
  __syncthreads();
  for (int i=tid; i<64*64; i+=128){
    int o = i>>6, c = i&63;
    w2T[c*64+o] = w2[o*64+c];
  }
  __syncthreads();
  float mx[32];
#pragma unroll
  for (int i=0;i<32;i++) mx[i] = -__builtin_inff();
  const int row = lane&31, ch = lane>>5;
  float4 g[8];
  {
    int m = idxT[((size_t)b*KNN + w)*N + n0 + row];
    const float* src = &inT[((size_t)b*N + m)*192 + inOff + ch*32];
#pragma unroll
    for (int j=0;j<8;j++) g[j] = ld4(src + j*4);
  }
  for (int it=0; it<20; it++){
#pragma unroll
    for (int j=0;j<8;j++){
      aT[w][(ch*32+j*4+0)*32 + row] = g[j].x;
      aT[w][(ch*32+j*4+1)*32 + row] = g[j].y;
      aT[w][(ch*32+j*4+2)*32 + row] = g[j].z;
      aT[w][(ch*32+j*4+3)*32 + row] = g[j].w;
    }
    if (it+1 < 20){                 // prefetch next gather; latency hides under compute
      int m = idxT[((size_t)b*KNN + (it+1)*2 + w)*N + n0 + row];
      const float* src = &inT[((size_t)b*N + m)*192 + inOff + ch*32];
#pragma unroll
      for (int j=0;j<8;j++) g[j] = ld4(src + j*4);
    }
    float acc[32];
#pragma unroll
    for (int i=0;i<32;i++) acc[i] = base[i];
    for (int c=0;c<64;c++){
      float4 w0 = ld4(&w1T[c*64+o0]), w1v = ld4(&w1T[c*64+o0+4]);
      float4 av = ld4(&aT[w][c*32+r0]);
      float wv[8] = {w0.x,w0.y,w0.z,w0.w,w1v.x,w1v.y,w1v.z,w1v.w};
      float rv[4] = {av.x,av.y,av.z,av.w};
#pragma unroll
      for (int oo=0;oo<8;oo++)
#pragma unroll
        for (int rr=0;rr<4;rr++) acc[oo*4+rr] = fmaf(wv[oo], rv[rr], acc[oo*4+rr]);
    }
#pragma unroll
    for (int oo=0;oo<8;oo++){
      float4 sv = make_float4(lrelu(acc[oo*4+0]), lrelu(acc[oo*4+1]), lrelu(acc[oo*4+2]), lrelu(acc[oo*4+3]));
      *(float4*)&s1T[w][(o0+oo)*32 + r0] = sv;
    }
    float acc2[32];
#pragma unroll
    for (int i=0;i<32;i++) acc2[i]=0.f;
    for (int c=0;c<64;c++){
      float4 w0 = ld4(&w2T[c*64+o0]), w1v = ld4(&w2T[c*64+o0+4]);
      float4 av = ld4(&s1T[w][c*32+r0]);
      float wv[8] = {w0.x,w0.y,w0.z,w0.w,w1v.x,w1v.y,w1v.z,w1v.w};
      float rv[4] = {av.x,av.y,av.z,av.w};
#pragma unroll
      for (int oo=0;oo<8;oo++)
#pragma unroll
        for (int rr=0;rr<4;rr++) acc2[oo*4+rr] = fmaf(wv[oo], rv[rr], acc2[oo*4+rr]);
    }
#pragma unroll
    for (int i=0;i<32;i++) mx[i] = fmaxf(mx[i], lrelu(acc2[i]));
  }
  __syncthreads();
#pragma unroll
  for (int rr=0;rr<4;rr++){
    float4 a = make_float4(mx[0*4+rr], mx[1*4+rr], mx[2*4+rr], mx[3*4+rr]);
    float4 bq = make_float4(mx[4*4+rr], mx[5*4+rr], mx[6*4+rr], mx[7*4+rr]);
    *(float4*)&s1T[w][(r0+rr)*64 + o0] = a;
    *(float4*)&s1T[w][(r0+rr)*64 + o0 + 4] = bq;
  }
  __syncthreads();
  for (int i=tid; i<2048; i+=128){
    float v = fmaxf(s1T[0][i], s1T[1][i]);
    int r = i>>6, o = i&63;
    catT[((size_t)b*N + n0 + r)*192 + outOff + o] = v;
  }
}

// ---- edgeD: 64ch -> 64 (single conv), max over k ----
// v4: 4 waves/block, k = it*4 + w, it<10 -> all 40 neighbors (R11 bug: it<5 covered 20).
// Merge stash uses wdT (waves 0-1) + w1T (waves 2-3), both dead post-barrier.
__global__ __launch_bounds__(256) void edgeD_kernel(
    const float* __restrict__ inT, int inOff, const int* __restrict__ idxT,
    const float* __restrict__ w1, float* __restrict__ catT, int outOff, int N){
  __shared__ float w1T[64*64];
  __shared__ float wdT[64*64];
  __shared__ float aT[4][64*32];
  const int tid = threadIdx.x, w = tid>>6, lane = tid&63;
  const int oq = lane&7, rg = lane>>3;
  const int o0 = oq*8, r0 = rg*4;
  const int b = blockIdx.y, n0 = blockIdx.x*32;
  for (int i=tid; i<64*64; i+=256){
    int o = i>>6, c = i&63;
    float a = w1[o*128+c], bb = w1[o*128+64+c];
    w1T[c*64+o] = a; wdT[c*64+o] = bb - a;
  }
  for (int i=tid; i<512; i+=256){
    int p = i>>4, cq = i&15;
    float4 v = ld4(&inT[((size_t)b*N + n0 + p)*192 + inOff + cq*4]);
    aT[0][(cq*4+0)*32+p] = v.x; aT[0][(cq*4+1)*32+p] = v.y;
    aT[0][(cq*4+2)*32+p] = v.z; aT[0][(cq*4+3)*32+p] = v.w;
  }
  __syncthreads();
  float base[32];
#pragma unroll
  for (int i=0;i<32;i++) base[i]=0.f;
  for (int c=0;c<64;c++){
    float4 w0 = ld4(&wdT[c*64+o0]), w1v = ld4(&wdT[c*64+o0+4]);
    float4 av = ld4(&aT[0][c*32+r0]);
    float wv[8] = {w0.x,w0.y,w0.z,w0.w,w1v.x,w1v.y,w1v.z,w1v.w};
    float rv[4] = {av.x,av.y,av.z,av.w};
#pragma unroll
    for (int oo=0;oo<8;oo++)
#pragma unroll
      for (int rr=0;rr<4;rr++) base[oo*4+rr] = fmaf(wv[oo], rv[rr], base[oo*4+rr]);
  }
  __syncthreads();
  float mx[32];
#pragma unroll
  for (int i=0;i<32;i++) mx[i] = -__builtin_inff();
  const int row = lane&31, ch = lane>>5;
  float4 g[8];
  {
    int m = idxT[((size_t)b*KNN + w)*N + n0 + row];
    const float* src = &inT[((size_t)b*N + m)*192 + inOff + ch*32];
#pragma unroll
    for (int j=0;j<8;j++) g[j] = ld4(src + j*4);
  }
  for (int it=0; it<10; it++){
#pragma unroll
    for (int j=0;j<8;j++){
      aT[w][(ch*32+j*4+0)*32 + row] = g[j].x;
      aT[w][(ch*32+j*4+1)*32 + row] = g[j].y;
      aT[w][(ch*32+j*4+2)*32 + row] = g[j].z;
      aT[w][(ch*32+j*4+3)*32 + row] = g[j].w;
    }
    if (it+1 < 10){
      int m = idxT[((size_t)b*KNN + (it+1)*4 + w)*N + n0 + row];
      const float* src = &inT[((size_t)b*N + m)*192 + inOff + ch*32];
#pragma unroll
      for (int j=0;j<8;j++) g[j] = ld4(src + j*4);
    }
    float acc[32];
#pragma unroll
    for (int i=0;i<32;i++) acc[i] = base[i];
    for (int c=0;c<64;c++){
      float4 w0 = ld4(&w1T[c*64+o0]), w1v = ld4(&w1T[c*64+o0+4]);
      float4 av = ld4(&aT[w][c*32+r0]);
      float wv[8] = {w0.x,w0.y,w0.z,w0.w,w1v.x,w1v.y,w1v.z,w1v.w};
      float rv[4] = {av.x,av.y,av.z,av.w};
#pragma unroll
      for (int oo=0;oo<8;oo++)
#pragma unroll
        for (int rr=0;rr<4;rr++) acc[oo*4+rr] = fmaf(wv[oo], rv[rr], acc[oo*4+rr]);
    }
#pragma unroll
    for (int i=0;i<32;i++) mx[i] = fmaxf(mx[i], lrelu(acc[i]));
  }
  __syncthreads();   // all waves done reading w1T/wdT -> reuse as merge stash
  {
    float* stash = (w < 2) ? &wdT[w*2048] : &w1T[(w-2)*2048];
#pragma unroll
    for (int rr=0;rr<4;rr++){
      float4 a = make_float4(mx[0*4+rr], mx[1*4+rr], mx[2*4+rr], mx[3*4+rr]);
      float4 bq = make_float4(mx[4*4+rr], mx[5*4+rr], mx[6*4+rr], mx[7*4+rr]);
      *(float4*)&stash[(r0+rr)*64 + o0] = a;
      *(float4*)&stash[(r0+rr)*64 + o0 + 4] = bq;
    }
  }
  __syncthreads();
  for (int i=tid; i<2048; i+=256){
    float v = fmaxf(fmaxf(wdT[i], wdT[2048+i]), fmaxf(w1T[i], w1T[2048+i]));
    int r = i>>6, o = i&63;
    catT[((size_t)b*N + n0 + r)*192 + outOff + o] = v;
  }
}

// ---------------- conv1 (1024 outs) + lrelu + max ----------------
// v4 (R11): oc split 64->32 outputs/block (grid.x=32). LDS 72KB (CIN=192) / 48KB
// (CIN=128). Per-thread 4o x 4r. Same c-order per output -> bit-exact.
template<int CIN, int TAG>
__global__ __launch_bounds__(128) void convmax_kernel(
    const float* __restrict__ inT, const float* __restrict__ wT,
    float* __restrict__ partial, int N){
  __shared__ float wsh[CIN*32];
  __shared__ float ish[2][32*CIN];  // per-wave staging, XOR-swizzled 4-col groups
  const int tid = threadIdx.x, w = tid>>6, lane = tid&63;
  const int oq = lane&7, rg = lane>>3;
  const int o0 = oq*4;
  const int b = blockIdx.z, oc = blockIdx.x, nt = blockIdx.y;
  for (int i=tid; i<CIN*32; i+=128){
    int c = i>>5, o = i&31;
    wsh[i] = wT[(size_t)c*1024 + oc*32 + o];
  }
  __syncthreads();                  // wsh ready; ish is wave-private afterwards
  float mx[16];
#pragma unroll
  for (int i=0;i<16;i++) mx[i] = -__builtin_inff();
  const int nbase = nt*(N/8);
  float* mish = ish[w];
  for (int it=0; it<4; it++){
    const int st = it*2 + w;        // wave w handles tiles {w, w+2, w+4, w+6}
    const float* src = inT + ((size_t)b*N + nbase + st*32)*CIN;
    for (int i=lane; i<32*(CIN/4); i+=64){
      int p = i/(CIN/4), cq = i%(CIN/4);
      float4 v = ld4(src + p*CIN + 4*cq);
      int base = (((p>>2) ^ (cq&7))<<2) + (p&3);
      mish[(4*cq+0)*32 + base] = v.x;
      mish[(4*cq+1)*32 + base] = v.y;
      mish[(4*cq+2)*32 + base] = v.z;
      mish[(4*cq+3)*32 + base] = v.w;
    }
    float acc[16];
#pragma unroll
    for (int i=0;i<16;i++) acc[i]=0.f;
    for (int c=0;c<CIN;c++){
      float4 w0 = ld4(&wsh[c*32+o0]);
      float4 av = ld4(&mish[c*32 + ((rg ^ ((c>>2)&7))<<2)]);
      float wv[4] = {w0.x,w0.y,w0.z,w0.w};
      float rv[4] = {av.x,av.y,av.z,av.w};
#pragma unroll
      for (int oo=0;oo<4;oo++)
#pragma unroll
        for (int rr=0;rr<4;rr++) acc[oo*4+rr] = fmaf(wv[oo], rv[rr], acc[oo*4+rr]);
    }
#pragma unroll
    for (int i=0;i<16;i++) mx[i] = fmaxf(mx[i], lrelu(acc[i]));
  }
  float m4[4];
#pragma unroll
  for (int oo=0;oo<4;oo++)
    m4[oo] = fmaxf(fmaxf(mx[oo*4+0], mx[oo*4+1]), fmaxf(mx[oo*4+2], mx[oo*4+3]));
  __syncthreads();                  // both waves done with their ish -> reuse ish[0] as merge buffer
  float* mb = ish[0];
  *(float4*)&mb[(w*8+rg)*32 + o0] = make_float4(m4[0],m4[1],m4[2],m4[3]);
  __syncthreads();
  if (tid < 32){
    float v = -__builtin_inff();
#pragma unroll
    for (int g=0; g<16; g++) v = fmaxf(v, mb[g*32+tid]);
    partial[((size_t)b*8 + nt)*1024 + oc*32 + tid] = v;
  }
}

template<int TAG>
__global__ void reduce_max_kernel(const float* __restrict__ partial, float* __restrict__ out){
  int b = blockIdx.y; int o = blockIdx.x*256 + threadIdx.x;
  float v = -__builtin_inff();
  for (int s=0;s<8;s++) v = fmaxf(v, partial[((size_t)b*8 + s)*1024 + o]);
  out[(size_t)b*1024 + o] = v;
}

// ---------------- fused t-net MLP: 1024 ->512 ->256 ->9 (one launch) ----------------
__global__ __launch_bounds__(512) void tnet_fc_kernel(
    const float* __restrict__ tg, const float* __restrict__ t_f1,
    const float* __restrict__ t_f2, const float* __restrict__ t_f3w,
    const float* __restrict__ t_f3b, float* __restrict__ T9){
  const int b = blockIdx.x, tid = threadIdx.x;
  __shared__ float in1[1024];
  __shared__ float h512[512];
  __shared__ float h256[256];
  for (int i=tid;i<1024;i+=512) in1[i] = tg[(size_t)b*1024+i];
  __syncthreads();
  {
    float s = 0.f;
    for (int c=0;c<1024;c++) s = fmaf(t_f1[(size_t)tid*1024+c], in1[c], s);
    h512[tid] = lrelu(s);
  }
  __syncthreads();
  if (tid < 256){
    float s = 0.f;
    for (int c=0;c<512;c++) s = fmaf(t_f2[(size_t)tid*512+c], h512[c], s);
    h256[tid] = lrelu(s);
  }
  __syncthreads();
  if (tid < 9){
    float s = t_f3b[tid];
    for (int c=0;c<256;c++) s = fmaf(t_f3w[(size_t)tid*256+c], h256[c], s);
    T9[(size_t)b*9+tid] = s;     // stride 9: transform_kernel reads T9 + b*9
  }
}

// ---------------- x' = T^T x per batch ----------------
__global__ void transform_kernel(const float* __restrict__ x, const float* __restrict__ T9,
                                 float* __restrict__ xp, int N){
  int b = blockIdx.y; int n = blockIdx.x*256 + threadIdx.x;
  const float* t = T9 + (size_t)b*9;
  float x0=x[((size_t)b*3+0)*N+n], x1=x[((size_t)b*3+1)*N+n], x2=x[((size_t)b*3+2)*N+n];
#pragma unroll
  for (int i=0;i<3;i++)
    xp[((size_t)b*3+i)*N+n] = t[i]*x0 + t[3+i]*x1 + t[6+i]*x2;
}

// ---------------- bias1: n-invariant part of h1 (lv = fc(l,m2) fused in) ----------------
__global__ void bias1_kernel(const float* __restrict__ g, const float* __restrict__ l,
                             const float* __restrict__ m2, const float* __restrict__ h1w,
                             float* __restrict__ bias1){
  int b = blockIdx.x;
  __shared__ float insh[1088];
  for (int i=threadIdx.x;i<1024;i+=256) insh[i] = g[(size_t)b*1024+i];
  if (threadIdx.x < 64){
    int o = threadIdx.x;
    float s = 0.f;
    for (int c=0;c<16;c++) s = fmaf(m2[(size_t)o*16+c], l[(size_t)b*16+c], s);
    insh[1024+o] = lrelu(s);
  }
  __syncthreads();
  int o = threadIdx.x;
  float s=0.f;
  for (int c=0;c<1088;c++) s = fmaf(h1w[(size_t)o*1280+c], insh[c], s);
  bias1[(size_t)b*256+o]=s;
}

// ---------------- head conv layers -- register-tiled (R8 champion) ----------------
template<int CI, int O, bool ACT>
__global__ __launch_bounds__(128) void conv1_kernel(
    const float* __restrict__ inT, const float* __restrict__ wT,
    const float* __restrict__ bias, float* __restrict__ outT, int N){
  constexpr int CCH = (CI % 128 == 0) ? 128 : 96;   // 256->128, 192->96
  constexpr int NCH = CI / CCH;
  __shared__ float wsh[CCH*64];
  __shared__ float ish[32*CCH];     // [c][32], XOR-swizzled 4-col groups
  const int tid = threadIdx.x, w = tid>>6, lane = tid&63;
  const int oq = lane&7, rg = lane>>3;
  const int o0 = oq*8, r0 = w*16 + rg*2;   // rows split across waves (dedup)
  const int b = blockIdx.y, n0 = blockIdx.x*32, oc = blockIdx.z;
  const float* src = inT + ((size_t)b*N + n0)*CI;
  float acc[16];
#pragma unroll
  for (int i=0;i<16;i++) acc[i]=0.f;
  for (int ch=0; ch<NCH; ch++){
    const int cc0 = ch*CCH;
    if (ch) __syncthreads();        // prev chunk's compute done before restage
    for (int i=tid; i<CCH*64; i+=128){
      int c = i>>6, od = i&63;
      wsh[i] = wT[(size_t)(cc0+c)*O + oc*64 + od];
    }
    for (int i=tid; i<32*(CCH/4); i+=128){
      int p = i/(CCH/4), cq = i%(CCH/4);
      float4 v = ld4(src + p*CI + cc0 + 4*cq);
      int base = (((p>>2) ^ (cq&7))<<2) + (p&3);
      ish[(4*cq+0)*32 + base] = v.x;
      ish[(4*cq+1)*32 + base] = v.y;
      ish[(4*cq+2)*32 + base] = v.z;
      ish[(4*cq+3)*32 + base] = v.w;
    }
    __syncthreads();
    for (int c=0;c<CCH;c++){
      float4 w0 = ld4(&wsh[c*64+o0]), w1v = ld4(&wsh[c*64+o0+4]);
      float2 av = *(const float2*)&ish[c*32 + ((((r0>>2) ^ ((c>>2)&7))<<2) + (r0&3))];
      float wv[8] = {w0.x,w0.y,w0.z,w0.w,w1v.x,w1v.y,w1v.z,w1v.w};
      float rv[2] = {av.x,av.y};
#pragma unroll
      for (int oo=0;oo<8;oo++)
#pragma unroll
        for (int rr=0;rr<2;rr++) acc[oo*2+rr] = fmaf(wv[oo], rv[rr], acc[oo*2+rr]);
    }
  }
  float bv[8];
  if (bias){
    float4 b0 = ld4(&bias[(size_t)b*O + oc*64 + o0]);
    float4 b1 = ld4(&bias[(size_t)b*O + oc*64 + o0 + 4]);
    bv[0]=b0.x; bv[1]=b0.y; bv[2]=b0.z; bv[3]=b0.w;
    bv[4]=b1.x; bv[5]=b1.y; bv[6]=b1.z; bv[7]=b1.w;
  } else {
#pragma unroll
    for (int i=0;i<8;i++) bv[i]=0.f;
  }
#pragma unroll
  for (int rr=0;rr<2;rr++){
    float oa[8];
#pragma unroll
    for (int oo=0;oo<8;oo++){
      float s = acc[oo*2+rr] + bv[oo];
      oa[oo] = ACT ? lrelu(s) : s;
    }
    float* dst = &outT[((size_t)b*N + n0 + r0 + rr)*O + oc*64 + o0];
    *(float4*)dst     = make_float4(oa[0],oa[1],oa[2],oa[3]);
    *(float4*)(dst+4) = make_float4(oa[4],oa[5],oa[6],oa[7]);
  }
}

// ---------------- final layer: 128 -> 50, rows-layout output (B,50,N) ----------------
__global__ __launch_bounds__(256) void conv_out_kernel(
    const float* __restrict__ inT, const float* __restrict__ wT,
    float* __restrict__ out, int N){
  const int b = blockIdx.y, n0 = blockIdx.x*32;
  __shared__ float insh[32*129];
  const float* src = inT + ((size_t)b*N + n0)*128;
  for (int i=threadIdx.x;i<32*128;i+=256){ int nn=i>>7, c=i&127; insh[nn*129+c]=src[i]; }
  __syncthreads();
  const int nl = threadIdx.x & 31, og = threadIdx.x >> 5;
  float acc[7];
#pragma unroll
  for (int t=0;t<7;t++) acc[t]=0.f;
  for (int c=0;c<128;c++){
    float iv = insh[nl*129+c];
#pragma unroll
    for (int t=0;t<7;t++){
      int o = og + 8*t;
      float wv = (o<50)? wT[c*50+o] : 0.f;
      acc[t] = fmaf(wv, iv, acc[t]);
    }
  }
#pragma unroll
  for (int t=0;t<7;t++){
    int o = og + 8*t;
    if (o < 50) out[((size_t)b*50+o)*N + n0 + nl] = acc[t];
  }
}

extern "C" void kernel_launch(void* const* d_in, const int* in_sizes, int n_in,
                              void* d_out, int out_size, void* d_ws, size_t ws_size,
                              hipStream_t stream){
  const float* x    = (const float*)d_in[0];
  const float* l    = (const float*)d_in[1];
  const float* t_c1 = (const float*)d_in[2];
  const float* t_c2 = (const float*)d_in[3];
  const float* t_c3 = (const float*)d_in[4];
  const float* t_f1 = (const float*)d_in[5];
  const float* t_f2 = (const float*)d_in[6];
  const float* t_f3w= (const float*)d_in[7];
  const float* t_f3b= (const float*)d_in[8];
  const float* b1a  = (const float*)d_in[9];
  const float* b1b  = (const float*)d_in[10];
  const float* b2a  = (const float*)d_in[11];
  const float* b2b  = (const float*)d_in[12];
  const float* b3a  = (const float*)d_in[13];
  const float* m1   = (const float*)d_in[14];
  const float* m2   = (const float*)d_in[15];
  const float* h1   = (const float*)d_in[16];
  const float* h2   = (const float*)d_in[17];
  const float* h3   = (const float*)d_in[18];
  const float* h4   = (const float*)d_in[19];
  float* out = (float*)d_out;
  float* ws = (float*)d_ws;
  const int N = NPTS, B = BATCH;

  size_t off = 0;
  auto alloc = [&](size_t nf){ float* p = ws + off; off += nf; return p; };
  float* WT_TC3 = alloc((size_t)128*1024);
  float* WT_M1  = alloc((size_t)192*1024);
  float* WT_H1B = alloc((size_t)192*256);
  float* WT_H2  = alloc((size_t)256*256);
  float* WT_H3  = alloc((size_t)256*128);
  float* WT_H4  = alloc((size_t)128*64);
  int*   IDXT   = (int*)alloc((size_t)B*N*KNN);
  float* XX     = alloc((size_t)B*N);
  float* TT     = alloc((size_t)B*N*128);
  float* PARTIAL= alloc((size_t)B*8*1024);
  float* TG     = alloc((size_t)B*1024);
  float* T9     = alloc((size_t)B*16);
  float* XP     = alloc((size_t)B*3*N);
  float* CATT   = alloc((size_t)B*N*192);
  float* G      = alloc((size_t)B*1024);
  float* BIAS1  = alloc((size_t)B*256);
  float* H1T    = alloc((size_t)B*N*256);
  float* H2T    = alloc((size_t)B*N*256);
  float* H3T    = alloc((size_t)B*N*128);
  (void)ws_size; (void)in_sizes; (void)n_in; (void)out_size;

  dim3 blk(256);
  dim3 eblk(128);
  // all 6 weight transposes in one launch
  transpose6_kernel<<<dim3(768,6), blk, 0, stream>>>(
      t_c3, WT_TC3, m1, WT_M1, h1, WT_H1B, h2, WT_H2, h3, WT_H3, h4, WT_H4);

  // t-path
  norms_rows_kernel<0><<<dim3(N/256,B), blk, 0, stream>>>(x, XX, N);
  knn3_kernel<0><<<dim3(N/4,B), blk, 0, stream>>>(x, XX, IDXT, N);
  edgeA_kernel<<<dim3(N/16,B), blk, 0, stream>>>(x, IDXT, t_c1, t_c2, TT, N);
  convmax_kernel<128,0><<<dim3(32,8,B), eblk, 0, stream>>>(TT, WT_TC3, PARTIAL, N);
  reduce_max_kernel<0><<<dim3(4,B), blk, 0, stream>>>(PARTIAL, TG);
  tnet_fc_kernel<<<dim3(B), dim3(512), 0, stream>>>(TG, t_f1, t_f2, t_f3w, t_f3b, T9);
  transform_kernel<<<dim3(N/256,B), blk, 0, stream>>>(x, T9, XP, N);

  // edge block 1 (transformed points, 3ch)
  norms_rows_kernel<1><<<dim3(N/256,B), blk, 0, stream>>>(XP, XX, N);
  knn3_kernel<1><<<dim3(N/4,B), blk, 0, stream>>>(XP, XX, IDXT, N);
  edgeB_kernel<<<dim3(N/32,B), dim3(256), 0, stream>>>(XP, IDXT, b1a, b1b, CATT, N);

  // edge block 2 (x1 = CATT[...,0:64])
  norms_cl_kernel<0><<<dim3(N/256,B), blk, 0, stream>>>(CATT, 0, XX, N);
  knn64_kernel<0><<<dim3(N/4,B), blk, 0, stream>>>(CATT, 0, XX, IDXT, N);
  edgeC_kernel<<<dim3(N/32,B), eblk, 0, stream>>>(CATT, 0, IDXT, b2a, b2b, CATT, 64, N);

  // edge block 3 (x2 = CATT[...,64:128])
  norms_cl_kernel<1><<<dim3(N/256,B), blk, 0, stream>>>(CATT, 64, XX, N);
  knn64_kernel<1><<<dim3(N/4,B), blk, 0, stream>>>(CATT, 64, XX, IDXT, N);
  edgeD_kernel<<<dim3(N/32,B), dim3(256), 0, stream>>>(CATT, 64, IDXT, b3a, CATT, 128, N);

  // global feature + head
  convmax_kernel<192,1><<<dim3(32,8,B), eblk, 0, stream>>>(CATT, WT_M1, PARTIAL, N);
  reduce_max_kernel<1><<<dim3(4,B), blk, 0, stream>>>(PARTIAL, G);
  bias1_kernel<<<dim3(B), blk, 0, stream>>>(G, l, m2, h1, BIAS1);
  conv1_kernel<192,256,true><<<dim3(N/32,B,4), eblk, 0, stream>>>(CATT, WT_H1B, BIAS1, H1T, N);
  conv1_kernel<256,256,true><<<dim3(N/32,B,4), eblk, 0, stream>>>(H1T, WT_H2, nullptr, H2T, N);
  conv1_kernel<256,128,true><<<dim3(N/32,B,2), eblk, 0, stream>>>(H2T, WT_H3, nullptr, H3T, N);
  conv_out_kernel<<<dim3(N/32,B), blk, 0, stream>>>(H3T, WT_H4, out, N);
}

// Round 13
// 2095.784 us; speedup vs baseline: 1.2057x; 1.0221x over previous
//
#include <hip/hip_runtime.h>
#include <cstdint>

#define NPTS 2048
#define BATCH 8
#define KNN 40

__device__ __forceinline__ float lrelu(float v){ return fmaxf(v, 0.2f*v); }
__device__ __forceinline__ bool better(float v1,int i1,float v2,int i2){
  return (v1>v2) || (v1==v2 && i1<i2);
}
__device__ __forceinline__ float4 ld4(const float* p){ return *(const float4*)p; }

// insert (d,m) into sorted-desc 8-list if it beats the tail; static CE chain.
#define INSERT8(v,id,d,m) \
  if (better(d, m, v[7], id[7])){ \
    v[7]=d; id[7]=m; \
    { if (better(v[7],id[7],v[6],id[6])){ float tv=v[6];int ti=id[6]; v[6]=v[7];id[6]=id[7]; v[7]=tv;id[7]=ti; } } \
    { if (better(v[6],id[6],v[5],id[5])){ float tv=v[5];int ti=id[5]; v[5]=v[6];id[5]=id[6]; v[6]=tv;id[6]=ti; } } \
    { if (better(v[5],id[5],v[4],id[4])){ float tv=v[4];int ti=id[4]; v[4]=v[5];id[4]=id[5]; v[5]=tv;id[5]=ti; } } \
    { if (better(v[4],id[4],v[3],id[3])){ float tv=v[3];int ti=id[3]; v[3]=v[4];id[3]=id[4]; v[4]=tv;id[4]=ti; } } \
    { if (better(v[3],id[3],v[2],id[2])){ float tv=v[2];int ti=id[2]; v[2]=v[3];id[2]=id[3]; v[3]=tv;id[3]=ti; } } \
    { if (better(v[2],id[2],v[1],id[1])){ float tv=v[1];int ti=id[1]; v[1]=v[2];id[1]=id[2]; v[2]=tv;id[2]=ti; } } \
    { if (better(v[1],id[1],v[0],id[0])){ float tv=v[0];int ti=id[0]; v[0]=v[1];id[0]=id[1]; v[1]=tv;id[1]=ti; } } \
  }

// ---------------- fused weight transposes (6 jobs, 1 launch) ----------------
__global__ void transpose6_kernel(
    const float* __restrict__ s0, float* __restrict__ d0,
    const float* __restrict__ s1, float* __restrict__ d1,
    const float* __restrict__ s2, float* __restrict__ d2,
    const float* __restrict__ s3, float* __restrict__ d3,
    const float* __restrict__ s4, float* __restrict__ d4,
    const float* __restrict__ s5, float* __restrict__ d5){
  int i = blockIdx.x*256 + threadIdx.x;
  const float* src; float* dst; int R,C,ld,off;
  switch (blockIdx.y){
    case 0:  src=s0; dst=d0; R=1024; C=128; ld=128;  off=0;    break;
    case 1:  src=s1; dst=d1; R=1024; C=192; ld=192;  off=0;    break;
    case 2:  src=s2; dst=d2; R=256;  C=192; ld=1280; off=1088; break;
    case 3:  src=s3; dst=d3; R=256;  C=256; ld=256;  off=0;    break;
    case 4:  src=s4; dst=d4; R=128;  C=256; ld=256;  off=0;    break;
    default: src=s5; dst=d5; R=50;   C=128; ld=128;  off=0;    break;
  }
  if (i < R*C){ int r = i / C, c = i % C; dst[c*R + r] = src[r*ld + off + c]; }
}

// ---------------- squared norms, rows layout (B,3,N) ----------------
template<int TAG>
__global__ void norms_rows_kernel(const float* __restrict__ x, float* __restrict__ xx, int N){
  int b = blockIdx.y; int n = blockIdx.x*256 + threadIdx.x;
  const float* xb = x + (size_t)b*3*N;
  float v0 = xb[n], v1 = xb[N+n], v2 = xb[2*N+n];
  xx[(size_t)b*N + n] = v0*v0 + v1*v1 + v2*v2;
}

// ---------------- squared norms, channel-last 64ch slice of (B,N,192) ----------------
template<int TAG>
__global__ void norms_cl_kernel(const float* __restrict__ f, int off, float* __restrict__ xx, int N){
  int b = blockIdx.y; int n = blockIdx.x*256 + threadIdx.x;
  const float4* p = (const float4*)(f + ((size_t)b*N + n)*192 + off);
  float s = 0.f;
#pragma unroll
  for (int q=0;q<16;q++){ float4 v = p[q]; s += v.x*v.x + v.y*v.y + v.z*v.z + v.w*v.w; }
  xx[(size_t)b*N + n] = s;
}

__device__ __forceinline__ void sort8(float (&v)[8], int (&id)[8]){
#define CE(a,bq) { if (better(v[bq],id[bq],v[a],id[a])){ float tv=v[a]; int ti=id[a]; v[a]=v[bq]; id[a]=id[bq]; v[bq]=tv; id[bq]=ti; } }
  CE(0,1) CE(2,3) CE(4,5) CE(6,7)
  CE(0,2) CE(1,3) CE(4,6) CE(5,7)
  CE(1,2) CE(5,6)
  CE(0,4) CE(1,5) CE(2,6) CE(3,7)
  CE(2,4) CE(3,5)
  CE(1,2) CE(3,4) CE(5,6)
#undef CE
}

// ---------------- knn 3-channel: 4 queries/block (1/wave), zero LDS, zero barriers ----------------
template<int TAG>
__global__ __launch_bounds__(256) void knn3_kernel(
    const float* __restrict__ xrows, const float* __restrict__ xx,
    int* __restrict__ idxT, int N){
  const int b = blockIdx.y, tid = threadIdx.x;
  const int w = tid>>6, lane = tid&63;
  const int nq = blockIdx.x*4 + w;
  const float* xb = xrows + (size_t)b*3*N;
  const float* xxb = xx + (size_t)b*N;
  float c0 = xb[nq], c1 = xb[N+nq], c2 = xb[2*N+nq];
  float xxn = xxb[nq];
  float v[8]; int id[8];
#pragma unroll
  for (int j=0;j<8;j++){ v[j]=-__builtin_inff(); id[j]=0x7FFFFFFF; }
  for (int j=0;j<32;j++){
    int m = j*64 + lane;
    float s = c0*xb[m] + c1*xb[N+m] + c2*xb[2*N+m];
    float d = 2.f*s - xxn - xxb[m];
    INSERT8(v, id, d, m)
  }
  float lastv = 0.f; int lasti = 0;
  int win = 0;
  for (int r=0;r<KNN;r++){
    float bv = v[0]; int bi = id[0];
#pragma unroll
    for (int off=32; off; off>>=1){
      float ov = __shfl_xor(bv, off);
      int   oi = __shfl_xor(bi, off);
      if (better(ov, oi, bv, bi)){ bv = ov; bi = oi; }
    }
    if (lane == r) win = bi;
    if (id[0] == bi){
      lastv = v[0]; lasti = id[0];
#pragma unroll
      for (int j=0;j<7;j++){ v[j]=v[j+1]; id[j]=id[j+1]; }
      v[7] = -__builtin_inff(); id[7] = 0x7FFFFFFF;
      if (id[0] == 0x7FFFFFFF){   // rare refill: best strictly worse than last pop
        float nv = -__builtin_inff(); int ni = 0x7FFFFFFF;
        for (int j=0;j<32;j++){
          int m = j*64 + lane;
          float s = c0*xb[m] + c1*xb[N+m] + c2*xb[2*N+m];
          float dd = 2.f*s - xxn - xxb[m];
          if (better(lastv, lasti, dd, m) && better(dd, m, nv, ni)){ nv=dd; ni=m; }
        }
        v[0] = nv; id[0] = ni;
      }
    }
  }
  if (lane < KNN) idxT[((size_t)b*KNN + lane)*N + nq] = win;
}

// ---------------- knn 64-channel (channel-last), 4 queries/block ----------------
// v6 (R5 champion): 32-cand tile (8 KiB) + 4x8K strips = 40960 B -> 16 waves/CU.
template<int TAG>
__global__ __launch_bounds__(256) void knn64_kernel(
    const float* __restrict__ featT, int featOff,
    const float* __restrict__ xx, int* __restrict__ idxT, int N){
  const int b = blockIdx.y, tid = threadIdx.x;
  const int w = tid>>6, lane = tid&63;
  __shared__ float cand[32*64];    // xor-swizzled [cand][ch] tile (8 KiB), block-shared
  __shared__ float dist[4*2048];   // wave-private strips (32 KiB)
  const float* fb = featT + featOff;
  const float* xxb = xx + (size_t)b*N;
  const int nq = blockIdx.x*4 + w;
  const int h = lane>>5;           // channel half this lane covers
  float4 ctr8[8];
  {
    const float4* cp = (const float4*)(fb + ((size_t)b*N + nq)*192);
#pragma unroll
    for (int q=0;q<8;q++) ctr8[q] = cp[h*8 + q];
  }
  float xxn = xxb[nq];
  float* dw = &dist[w*2048];
  float4 g[2];
#pragma unroll
  for (int r=0;r<2;r++){
    int k2 = tid + 256*r;
    int c = k2>>4, f = k2&15;
    g[r] = ld4(&fb[((size_t)b*N + c)*192 + 4*f]);
  }
  const int cc = lane&31, swz = cc&15, qb = h*8;
  for (int t=0;t<64;t++){
    __syncthreads();                 // prev compute done reading cand
#pragma unroll
    for (int r=0;r<2;r++){
      int k2 = tid + 256*r;
      int c = k2>>4, f = k2&15;
      *(float4*)&cand[(c<<6) + ((f ^ (c&15))<<2)] = g[r];
    }
    __syncthreads();
    if (t+1 < 64){                   // issue next tile's loads; latency overlaps compute
      int m0n = (t+1)*32;
#pragma unroll
      for (int r=0;r<2;r++){
        int k2 = tid + 256*r;
        int c = k2>>4, f = k2&15;
        g[r] = ld4(&fb[((size_t)b*N + m0n + c)*192 + 4*f]);
      }
    }
    float s0=0.f,s1=0.f,s2=0.f,s3=0.f;
#pragma unroll
    for (int j=0;j<8;j++){
      float4 mv = *(const float4*)&cand[(cc<<6) + (((qb + j) ^ swz)<<2)];
      s0 = fmaf(ctr8[j].x, mv.x, s0);
      s1 = fmaf(ctr8[j].y, mv.y, s1);
      s2 = fmaf(ctr8[j].z, mv.z, s2);
      s3 = fmaf(ctr8[j].w, mv.w, s3);
    }
    float p = (s0+s1)+(s2+s3);
    float tot = p + __shfl_xor(p, 32);    // combine channel halves (commutative -> both halves identical)
    if (h == (t&1)){                      // owner lane (m & 63 == lane) writes its strip slot
      int m = t*32 + cc;
      dw[(t>>1)*64 + lane] = 2.f*tot - xxn - xxb[m];
    }
  }
  // ---- per-lane exact top-8 of its 32 entries (sorted desc by (v desc, idx asc)) ----
  float v[8]; int id[8];
#pragma unroll
  for (int j=0;j<8;j++){ v[j]=dw[j*64+lane]; id[j]=j*64+lane; }
  sort8(v, id);
#pragma unroll
  for (int gq=1; gq<4; gq++){
    float a[8]; int ai[8];
#pragma unroll
    for (int j=0;j<8;j++){ a[j]=dw[(gq*8+j)*64+lane]; ai[j]=(gq*8+j)*64+lane; }
    sort8(a, ai);
    float m_[8]; int mi_[8];
#pragma unroll
    for (int k=0;k<8;k++){
      if (better(a[7-k], ai[7-k], v[k], id[k])){ m_[k]=a[7-k]; mi_[k]=ai[7-k]; }
      else                                     { m_[k]=v[k];   mi_[k]=id[k]; }
    }
#define CEB(x,y) { if (better(m_[y],mi_[y],m_[x],mi_[x])){ float tv=m_[x];int ti=mi_[x]; m_[x]=m_[y];mi_[x]=mi_[y]; m_[y]=tv;mi_[y]=ti; } }
    CEB(0,4) CEB(1,5) CEB(2,6) CEB(3,7)
    CEB(0,2) CEB(1,3) CEB(4,6) CEB(5,7)
    CEB(0,1) CEB(2,3) CEB(4,5) CEB(6,7)
#undef CEB
#pragma unroll
    for (int k=0;k<8;k++){ v[k]=m_[k]; id[k]=mi_[k]; }
  }
  // ---- 40 extraction rounds: butterfly + pop-shift; zero barriers, zero LDS steady state ----
  float lastv = 0.f; int lasti = 0;
  int win = 0;
  for (int r=0;r<KNN;r++){
    float bv = v[0]; int bi = id[0];
#pragma unroll
    for (int off=32; off; off>>=1){
      float ov = __shfl_xor(bv, off);
      int   oi = __shfl_xor(bi, off);
      if (better(ov, oi, bv, bi)){ bv = ov; bi = oi; }
    }
    if (lane == r) win = bi;
    if (id[0] == bi){                // unique owner (indices unique)
      lastv = v[0]; lasti = id[0];
#pragma unroll
      for (int j=0;j<7;j++){ v[j]=v[j+1]; id[j]=id[j+1]; }
      v[7] = -__builtin_inff(); id[7] = 0x7FFFFFFF;
      if (id[0] == 0x7FFFFFFF){      // rare: lane contributed >8 of top-40 -> refill head
        float nv = -__builtin_inff(); int ni = 0x7FFFFFFF;
        for (int j=0;j<32;j++){
          float vv = dw[j*64 + lane]; int m = j*64 + lane;
          if (better(lastv, lasti, vv, m) && better(vv, m, nv, ni)){ nv=vv; ni=m; }
        }
        v[0] = nv; id[0] = ni;
      }
    }
  }
  if (lane < KNN) idxT[((size_t)b*KNN + lane)*N + nq] = win;
}

// ==================== register-tiled edge kernels ====================

// ---- edgeA (t-path): 3ch -> 64 -> 128, max over k ----
__global__ __launch_bounds__(256) void edgeA_kernel(
    const float* __restrict__ x, const int* __restrict__ idxT,
    const float* __restrict__ w1, const float* __restrict__ w2,
    float* __restrict__ tT, int N){
  __shared__ float w1aT[3*64];
  __shared__ float wd3T[3*64];
  __shared__ float w2T[64*128];      // [c][o]; reused as merge buffer (4 x 16r x 128o)
  __shared__ float aT3[4][3*16];
  __shared__ float s1T[4][64*16];    // [c][r]
  const int tid = threadIdx.x, w = tid>>6, lane = tid&63;
  const int oq = lane&7, rg = lane>>3;
  const int o0 = oq*8, r0 = rg*2;
  const int b = blockIdx.y, n0 = blockIdx.x*16;
  for (int i=tid; i<192; i+=256){
    int o = i&63, c = i/64;
    float a = w1[o*6+c];
    w1aT[c*64+o] = a; wd3T[c*64+o] = w1[o*6+3+c] - a;
  }
  for (int i=tid; i<128*64; i+=256){
    int o = i>>6, c = i&63;
    w2T[c*128+o] = w2[o*64+c];
  }
  if (tid < 48){ int c = tid>>4, r = tid&15; aT3[0][c*16+r] = x[((size_t)b*3+c)*N + n0 + r]; }
  __syncthreads();
  float base[16];
#pragma unroll
  for (int i=0;i<16;i++) base[i]=0.f;
#pragma unroll
  for (int c=0;c<3;c++){
    float4 wA = ld4(&wd3T[c*64+o0]), wB = ld4(&wd3T[c*64+o0+4]);
    float2 av = *(const float2*)&aT3[0][c*16+r0];
    float wv[8] = {wA.x,wA.y,wA.z,wA.w,wB.x,wB.y,wB.z,wB.w};
    float rv[2] = {av.x,av.y};
#pragma unroll
    for (int oo=0;oo<8;oo++)
#pragma unroll
      for (int rr=0;rr<2;rr++) base[oo*2+rr] = fmaf(wv[oo], rv[rr], base[oo*2+rr]);
  }
  __syncthreads();   // all waves done reading aT3[0] before k-loop overwrites
  float mx[32];
#pragma unroll
  for (int i=0;i<32;i++) mx[i] = -__builtin_inff();
  for (int it=0; it<10; it++){
    int k = it*4 + w;
    int m = idxT[((size_t)b*KNN + k)*N + n0 + (lane&15)];
    if (lane < 48){ int c = lane>>4; aT3[w][c*16 + (lane&15)] = x[((size_t)b*3+c)*N + m]; }
    // stage1 (64 o x 16 r)
    float acc[16];
#pragma unroll
    for (int i=0;i<16;i++) acc[i] = base[i];
#pragma unroll
    for (int c=0;c<3;c++){
      float4 wA = ld4(&w1aT[c*64+o0]), wB = ld4(&w1aT[c*64+o0+4]);
      float2 av = *(const float2*)&aT3[w][c*16+r0];
      float wv[8] = {wA.x,wA.y,wA.z,wA.w,wB.x,wB.y,wB.z,wB.w};
      float rv[2] = {av.x,av.y};
#pragma unroll
      for (int oo=0;oo<8;oo++)
#pragma unroll
        for (int rr=0;rr<2;rr++) acc[oo*2+rr] = fmaf(wv[oo], rv[rr], acc[oo*2+rr]);
    }
#pragma unroll
    for (int oo=0;oo<8;oo++){
      float2 sv; sv.x = lrelu(acc[oo*2]); sv.y = lrelu(acc[oo*2+1]);
      *(float2*)&s1T[w][(o0+oo)*16 + r0] = sv;
    }
    // stage2 (128 o x 16 r): 4 panels, o = p*32 + oq*4 -> 32 banks, conflict-free
    float acc2[32];
#pragma unroll
    for (int i=0;i<32;i++) acc2[i]=0.f;
    for (int c=0;c<64;c++){
      float2 av = *(const float2*)&s1T[w][c*16 + r0];
#pragma unroll
      for (int p=0;p<4;p++){
        float4 wv = ld4(&w2T[c*128 + p*32 + oq*4]);
        acc2[p*8+0] = fmaf(wv.x, av.x, acc2[p*8+0]);
        acc2[p*8+1] = fmaf(wv.x, av.y, acc2[p*8+1]);
        acc2[p*8+2] = fmaf(wv.y, av.x, acc2[p*8+2]);
        acc2[p*8+3] = fmaf(wv.y, av.y, acc2[p*8+3]);
        acc2[p*8+4] = fmaf(wv.z, av.x, acc2[p*8+4]);
        acc2[p*8+5] = fmaf(wv.z, av.y, acc2[p*8+5]);
        acc2[p*8+6] = fmaf(wv.w, av.x, acc2[p*8+6]);
        acc2[p*8+7] = fmaf(wv.w, av.y, acc2[p*8+7]);
      }
    }
#pragma unroll
    for (int i=0;i<32;i++) mx[i] = fmaxf(mx[i], lrelu(acc2[i]));
  }
  __syncthreads();   // all waves done reading w2T -> reuse as merge buffer
#pragma unroll
  for (int rr=0;rr<2;rr++){
#pragma unroll
    for (int p=0;p<4;p++){
      float4 a = make_float4(mx[p*8+0+rr], mx[p*8+2+rr], mx[p*8+4+rr], mx[p*8+6+rr]);
      *(float4*)&w2T[w*2048 + (r0+rr)*128 + p*32 + oq*4] = a;
    }
  }
  __syncthreads();
  for (int i=tid; i<2048; i+=256){
    float vv = fmaxf(fmaxf(w2T[i], w2T[2048+i]), fmaxf(w2T[4096+i], w2T[6144+i]));
    int r = i>>7, o = i&127;
    tT[((size_t)b*N + n0 + r)*128 + o] = vv;
  }
}

// ---- edgeB: 3ch -> 64 -> 64, max over k ----
// v4 (R12 champion): 4 waves/block, k = it*4 + w, it<10 -> all 40 neighbors.
__global__ __launch_bounds__(256) void edgeB_kernel(
    const float* __restrict__ xp, const int* __restrict__ idxT,
    const float* __restrict__ w1, const float* __restrict__ w2,
    float* __restrict__ catT, int N){
  __shared__ float w1aT[3*64];
  __shared__ float wd3T[3*64];
  __shared__ float w2T[64*64];
  __shared__ float aT3[4][3*32];
  __shared__ float s1T[4][64*32];
  const int tid = threadIdx.x, w = tid>>6, lane = tid&63;
  const int oq = lane&7, rg = lane>>3;
  const int o0 = oq*8, r0 = rg*4;
  const int b = blockIdx.y, n0 = blockIdx.x*32;
  for (int i=tid; i<192; i+=256){
    int o = i&63, c = i>>6;
    float a = w1[o*6+c], bb = w1[o*6+3+c];
    w1aT[c*64+o] = a; wd3T[c*64+o] = bb - a;
  }
  for (int i=tid; i<64*64; i+=256){
    int o = i>>6, c = i&63;
    w2T[c*64+o] = w2[o*64+c];
  }
  if (tid < 32){
#pragma unroll
    for (int c=0;c<3;c++) aT3[0][c*32+tid] = xp[((size_t)b*3+c)*N + n0 + tid];
  }
  __syncthreads();
  float base[32];
#pragma unroll
  for (int i=0;i<32;i++) base[i]=0.f;
#pragma unroll
  for (int c=0;c<3;c++){
    float4 w0 = ld4(&wd3T[c*64+o0]), w1v = ld4(&wd3T[c*64+o0+4]);
    float4 av = ld4(&aT3[0][c*32+r0]);
    float wv[8] = {w0.x,w0.y,w0.z,w0.w,w1v.x,w1v.y,w1v.z,w1v.w};
    float rv[4] = {av.x,av.y,av.z,av.w};
#pragma unroll
    for (int oo=0;oo<8;oo++)
#pragma unroll
      for (int rr=0;rr<4;rr++) base[oo*4+rr] = fmaf(wv[oo], rv[rr], base[oo*4+rr]);
  }
  __syncthreads();
  float mx[32];
#pragma unroll
  for (int i=0;i<32;i++) mx[i] = -__builtin_inff();
  const int row = lane&31;
  float g0=0.f, g1=0.f, g2=0.f;
  {
    int m = idxT[((size_t)b*KNN + w)*N + n0 + row];
    if (lane < 32){
      g0 = xp[((size_t)b*3+0)*N + m];
      g1 = xp[((size_t)b*3+1)*N + m];
      g2 = xp[((size_t)b*3+2)*N + m];
    }
  }
  for (int it=0; it<10; it++){
    if (lane < 32){
      aT3[w][0*32+row] = g0;
      aT3[w][1*32+row] = g1;
      aT3[w][2*32+row] = g2;
    }
    if (it+1 < 10){                  // prefetch next gather; latency hides under compute
      int m = idxT[((size_t)b*KNN + (it+1)*4 + w)*N + n0 + row];
      if (lane < 32){
        g0 = xp[((size_t)b*3+0)*N + m];
        g1 = xp[((size_t)b*3+1)*N + m];
        g2 = xp[((size_t)b*3+2)*N + m];
      }
    }
    float acc[32];
#pragma unroll
    for (int i=0;i<32;i++) acc[i] = base[i];
#pragma unroll
    for (int c=0;c<3;c++){
      float4 w0 = ld4(&w1aT[c*64+o0]), w1v = ld4(&w1aT[c*64+o0+4]);
      float4 av = ld4(&aT3[w][c*32+r0]);
      float wv[8] = {w0.x,w0.y,w0.z,w0.w,w1v.x,w1v.y,w1v.z,w1v.w};
      float rv[4] = {av.x,av.y,av.z,av.w};
#pragma unroll
      for (int oo=0;oo<8;oo++)
#pragma unroll
        for (int rr=0;rr<4;rr++) acc[oo*4+rr] = fmaf(wv[oo], rv[rr], acc[oo*4+rr]);
    }
#pragma unroll
    for (int oo=0;oo<8;oo++){
      float4 sv = make_float4(lrelu(acc[oo*4+0]), lrelu(acc[oo*4+1]), lrelu(acc[oo*4+2]), lrelu(acc[oo*4+3]));
      *(float4*)&s1T[w][(o0+oo)*32 + r0] = sv;
    }
    float acc2[32];
#pragma unroll
    for (int i=0;i<32;i++) acc2[i]=0.f;
    for (int c=0;c<64;c++){
      float4 w0 = ld4(&w2T[c*64+o0]), w1v = ld4(&w2T[c*64+o0+4]);
      float4 av = ld4(&s1T[w][c*32+r0]);
      float wv[8] = {w0.x,w0.y,w0.z,w0.w,w1v.x,w1v.y,w1v.z,w1v.w};
      float rv[4] = {av.x,av.y,av.z,av.w};
#pragma unroll
      for (int oo=0;oo<8;oo++)
#pragma unroll
        for (int rr=0;rr<4;rr++) acc2[oo*4+rr] = fmaf(wv[oo], rv[rr], acc2[oo*4+rr]);
    }
#pragma unroll
    for (int i=0;i<32;i++) mx[i] = fmaxf(mx[i], lrelu(acc2[i]));
  }
  __syncthreads();
#pragma unroll
  for (int rr=0;rr<4;rr++){
    float4 a = make_float4(mx[0*4+rr], mx[1*4+rr], mx[2*4+rr], mx[3*4+rr]);
    float4 bq = make_float4(mx[4*4+rr], mx[5*4+rr], mx[6*4+rr], mx[7*4+rr]);
    *(float4*)&s1T[w][(r0+rr)*64 + o0] = a;
    *(float4*)&s1T[w][(r0+rr)*64 + o0 + 4] = bq;
  }
  __syncthreads();
  for (int i=tid; i<2048; i+=256){
    float v = fmaxf(fmaxf(s1T[0][i], s1T[1][i]), fmaxf(s1T[2][i], s1T[3][i]));
    int r = i>>6, o = i&63;
    catT[((size_t)b*N + n0 + r)*192 + o] = v;
  }
}

// ---- edgeC: 64ch -> 64 -> 64, max over k ----
// v2 (R10): gather software-pipelined; 2 waves (LDS-capped; 4-wave variant is neutral).
__global__ __launch_bounds__(128) void edgeC_kernel(
    const float* __restrict__ inT, int inOff, const int* __restrict__ idxT,
    const float* __restrict__ w1, const float* __restrict__ w2,
    float* __restrict__ catT, int outOff, int N){
  __shared__ float w1T[64*64];
  __shared__ float w2T[64*64];
  __shared__ float aT[2][64*32];
  __shared__ float s1T[2][64*32];
  const int tid = threadIdx.x, w = tid>>6, lane = tid&63;
  const int oq = lane&7, rg = lane>>3;
  const int o0 = oq*8, r0 = rg*4;
  const int b = blockIdx.y, n0 = blockIdx.x*32;
  for (int i=tid; i<64*64; i+=128){
    int o = i>>6, c = i&63;
    float a = w1[o*128+c], bb = w1[o*128+64+c];
    w1T[c*64+o] = a; w2T[c*64+o] = bb - a;
  }
  for (int i=tid; i<512; i+=128){
    int p = i>>4, cq = i&15;
    float4 v = ld4(&inT[((size_t)b*N + n0 + p)*192 + inOff + cq*4]);
    aT[0][(cq*4+0)*32+p] = v.x; aT[0][(cq*4+1)*32+p] = v.y;
    aT[0][(cq*4+2)*32+p] = v.z; aT[0][(cq*4+3)*32+p] = v.w;
  }
  __syncthreads();
  float base[32];
#pragma unroll
  for (int i=0;i<32;i++) base[i]=0.f;
  for (int c=0;c<64;c++){
    float4 w0 = ld4(&w2T[c*64+o0]), w1v = ld4(&w2T[c*64+o0+4]);
    float4 av = ld4(&aT[0][c*32+r0]);
    float wv[8] = {w0.x,w0.y,w0.z,w0.w,w1v.x,w1v.y,w1v.z,w1v.w};
    float rv[4] = {av.x,av.y,av.z,av.w};
#pragma unroll
    for (int oo=0;oo<8;oo++)
#pragma unroll
      for (int rr=0;rr<4;rr++) base[oo*4+rr] = fmaf(wv[oo], rv[rr], base[oo*4+rr]);
  }
  __syncthreads();
  for (int i=tid; i<64*64; i+=128){
    int o = i>>6, c = i&63;
    w2T[c*64+o] = w2[o*64+c];
  }
  __syncthreads();
  float mx[32];
#pragma unroll
  for (int i=0;i<32;i++) mx[i] = -__builtin_inff();
  const int row = lane&31, ch = lane>>5;
  float4 g[8];
  {
    int m = idxT[((size_t)b*KNN + w)*N + n0 + row];
    const float* src = &inT[((size_t)b*N + m)*192 + inOff + ch*32];
#pragma unroll
    for (int j=0;j<8;j++) g[j] = ld4(src + j*4);
  }
  for (int it=0; it<20; it++){
#pragma unroll
    for (int j=0;j<8;j++){
      aT[w][(ch*32+j*4+0)*32 + row] = g[j].x;
      aT[w][(ch*32+j*4+1)*32 + row] = g[j].y;
      aT[w][(ch*32+j*4+2)*32 + row] = g[j].z;
      aT[w][(ch*32+j*4+3)*32 + row] = g[j].w;
    }
    if (it+1 < 20){                 // prefetch next gather; latency hides under compute
      int m = idxT[((size_t)b*KNN + (it+1)*2 + w)*N + n0 + row];
      const float* src = &inT[((size_t)b*N + m)*192 + inOff + ch*32];
#pragma unroll
      for (int j=0;j<8;j++) g[j] = ld4(src + j*4);
    }
    float acc[32];
#pragma unroll
    for (int i=0;i<32;i++) acc[i] = base[i];
    for (int c=0;c<64;c++){
      float4 w0 = ld4(&w1T[c*64+o0]), w1v = ld4(&w1T[c*64+o0+4]);
      float4 av = ld4(&aT[w][c*32+r0]);
      float wv[8] = {w0.x,w0.y,w0.z,w0.w,w1v.x,w1v.y,w1v.z,w1v.w};
      float rv[4] = {av.x,av.y,av.z,av.w};
#pragma unroll
      for (int oo=0;oo<8;oo++)
#pragma unroll
        for (int rr=0;rr<4;rr++) acc[oo*4+rr] = fmaf(wv[oo], rv[rr], acc[oo*4+rr]);
    }
#pragma unroll
    for (int oo=0;oo<8;oo++){
      float4 sv = make_float4(lrelu(acc[oo*4+0]), lrelu(acc[oo*4+1]), lrelu(acc[oo*4+2]), lrelu(acc[oo*4+3]));
      *(float4*)&s1T[w][(o0+oo)*32 + r0] = sv;
    }
    float acc2[32];
#pragma unroll
    for (int i=0;i<32;i++) acc2[i]=0.f;
    for (int c=0;c<64;c++){
      float4 w0 = ld4(&w2T[c*64+o0]), w1v = ld4(&w2T[c*64+o0+4]);
      float4 av = ld4(&s1T[w][c*32+r0]);
      float wv[8] = {w0.x,w0.y,w0.z,w0.w,w1v.x,w1v.y,w1v.z,w1v.w};
      float rv[4] = {av.x,av.y,av.z,av.w};
#pragma unroll
      for (int oo=0;oo<8;oo++)
#pragma unroll
        for (int rr=0;rr<4;rr++) acc2[oo*4+rr] = fmaf(wv[oo], rv[rr], acc2[oo*4+rr]);
    }
#pragma unroll
    for (int i=0;i<32;i++) mx[i] = fmaxf(mx[i], lrelu(acc2[i]));
  }
  __syncthreads();
#pragma unroll
  for (int rr=0;rr<4;rr++){
    float4 a = make_float4(mx[0*4+rr], mx[1*4+rr], mx[2*4+rr], mx[3*4+rr]);
    float4 bq = make_float4(mx[4*4+rr], mx[5*4+rr], mx[6*4+rr], mx[7*4+rr]);
    *(float4*)&s1T[w][(r0+rr)*64 + o0] = a;
    *(float4*)&s1T[w][(r0+rr)*64 + o0 + 4] = bq;
  }
  __syncthreads();
  for (int i=tid; i<2048; i+=128){
    float v = fmaxf(s1T[0][i], s1T[1][i]);
    int r = i>>6, o = i&63;
    catT[((size_t)b*N + n0 + r)*192 + outOff + o] = v;
  }
}

// ---- edgeD: 64ch -> 64 (single conv), max over k ----
// v4 (R12 champion): 4 waves/block, it<10 -> all 40 neighbors; merge via wdT/w1T stash.
__global__ __launch_bounds__(256) void edgeD_kernel(
    const float* __restrict__ inT, int inOff, const int* __restrict__ idxT,
    const float* __restrict__ w1, float* __restrict__ catT, int outOff, int N){
  __shared__ float w1T[64*64];
  __shared__ float wdT[64*64];
  __shared__ float aT[4][64*32];
  const int tid = threadIdx.x, w = tid>>6, lane = tid&63;
  const int oq = lane&7, rg = lane>>3;
  const int o0 = oq*8, r0 = rg*4;
  const int b = blockIdx.y, n0 = blockIdx.x*32;
  for (int i=tid; i<64*64; i+=256){
    int o = i>>6, c = i&63;
    float a = w1[o*128+c], bb = w1[o*128+64+c];
    w1T[c*64+o] = a; wdT[c*64+o] = bb - a;
  }
  for (int i=tid; i<512; i+=256){
    int p = i>>4, cq = i&15;
    float4 v = ld4(&inT[((size_t)b*N + n0 + p)*192 + inOff + cq*4]);
    aT[0][(cq*4+0)*32+p] = v.x; aT[0][(cq*4+1)*32+p] = v.y;
    aT[0][(cq*4+2)*32+p] = v.z; aT[0][(cq*4+3)*32+p] = v.w;
  }
  __syncthreads();
  float base[32];
#pragma unroll
  for (int i=0;i<32;i++) base[i]=0.f;
  for (int c=0;c<64;c++){
    float4 w0 = ld4(&wdT[c*64+o0]), w1v = ld4(&wdT[c*64+o0+4]);
    float4 av = ld4(&aT[0][c*32+r0]);
    float wv[8] = {w0.x,w0.y,w0.z,w0.w,w1v.x,w1v.y,w1v.z,w1v.w};
    float rv[4] = {av.x,av.y,av.z,av.w};
#pragma unroll
    for (int oo=0;oo<8;oo++)
#pragma unroll
      for (int rr=0;rr<4;rr++) base[oo*4+rr] = fmaf(wv[oo], rv[rr], base[oo*4+rr]);
  }
  __syncthreads();
  float mx[32];
#pragma unroll
  for (int i=0;i<32;i++) mx[i] = -__builtin_inff();
  const int row = lane&31, ch = lane>>5;
  float4 g[8];
  {
    int m = idxT[((size_t)b*KNN + w)*N + n0 + row];
    const float* src = &inT[((size_t)b*N + m)*192 + inOff + ch*32];
#pragma unroll
    for (int j=0;j<8;j++) g[j] = ld4(src + j*4);
  }
  for (int it=0; it<10; it++){
#pragma unroll
    for (int j=0;j<8;j++){
      aT[w][(ch*32+j*4+0)*32 + row] = g[j].x;
      aT[w][(ch*32+j*4+1)*32 + row] = g[j].y;
      aT[w][(ch*32+j*4+2)*32 + row] = g[j].z;
      aT[w][(ch*32+j*4+3)*32 + row] = g[j].w;
    }
    if (it+1 < 10){
      int m = idxT[((size_t)b*KNN + (it+1)*4 + w)*N + n0 + row];
      const float* src = &inT[((size_t)b*N + m)*192 + inOff + ch*32];
#pragma unroll
      for (int j=0;j<8;j++) g[j] = ld4(src + j*4);
    }
    float acc[32];
#pragma unroll
    for (int i=0;i<32;i++) acc[i] = base[i];
    for (int c=0;c<64;c++){
      float4 w0 = ld4(&w1T[c*64+o0]), w1v = ld4(&w1T[c*64+o0+4]);
      float4 av = ld4(&aT[w][c*32+r0]);
      float wv[8] = {w0.x,w0.y,w0.z,w0.w,w1v.x,w1v.y,w1v.z,w1v.w};
      float rv[4] = {av.x,av.y,av.z,av.w};
#pragma unroll
      for (int oo=0;oo<8;oo++)
#pragma unroll
        for (int rr=0;rr<4;rr++) acc[oo*4+rr] = fmaf(wv[oo], rv[rr], acc[oo*4+rr]);
    }
#pragma unroll
    for (int i=0;i<32;i++) mx[i] = fmaxf(mx[i], lrelu(acc[i]));
  }
  __syncthreads();   // all waves done reading w1T/wdT -> reuse as merge stash
  {
    float* stash = (w < 2) ? &wdT[w*2048] : &w1T[(w-2)*2048];
#pragma unroll
    for (int rr=0;rr<4;rr++){
      float4 a = make_float4(mx[0*4+rr], mx[1*4+rr], mx[2*4+rr], mx[3*4+rr]);
      float4 bq = make_float4(mx[4*4+rr], mx[5*4+rr], mx[6*4+rr], mx[7*4+rr]);
      *(float4*)&stash[(r0+rr)*64 + o0] = a;
      *(float4*)&stash[(r0+rr)*64 + o0 + 4] = bq;
    }
  }
  __syncthreads();
  for (int i=tid; i<2048; i+=256){
    float v = fmaxf(fmaxf(wdT[i], wdT[2048+i]), fmaxf(w1T[i], w1T[2048+i]));
    int r = i>>6, o = i&63;
    catT[((size_t)b*N + n0 + r)*192 + outOff + o] = v;
  }
}

// ---------------- conv1 (1024 outs) + lrelu + max ----------------
// v4 (R12 champion): oc split 32 outputs/block, LDS 72/48KB, 4o x 4r per thread.
template<int CIN, int TAG>
__global__ __launch_bounds__(128) void convmax_kernel(
    const float* __restrict__ inT, const float* __restrict__ wT,
    float* __restrict__ partial, int N){
  __shared__ float wsh[CIN*32];
  __shared__ float ish[2][32*CIN];  // per-wave staging, XOR-swizzled 4-col groups
  const int tid = threadIdx.x, w = tid>>6, lane = tid&63;
  const int oq = lane&7, rg = lane>>3;
  const int o0 = oq*4;
  const int b = blockIdx.z, oc = blockIdx.x, nt = blockIdx.y;
  for (int i=tid; i<CIN*32; i+=128){
    int c = i>>5, o = i&31;
    wsh[i] = wT[(size_t)c*1024 + oc*32 + o];
  }
  __syncthreads();                  // wsh ready; ish is wave-private afterwards
  float mx[16];
#pragma unroll
  for (int i=0;i<16;i++) mx[i] = -__builtin_inff();
  const int nbase = nt*(N/8);
  float* mish = ish[w];
  for (int it=0; it<4; it++){
    const int st = it*2 + w;        // wave w handles tiles {w, w+2, w+4, w+6}
    const float* src = inT + ((size_t)b*N + nbase + st*32)*CIN;
    for (int i=lane; i<32*(CIN/4); i+=64){
      int p = i/(CIN/4), cq = i%(CIN/4);
      float4 v = ld4(src + p*CIN + 4*cq);
      int base = (((p>>2) ^ (cq&7))<<2) + (p&3);
      mish[(4*cq+0)*32 + base] = v.x;
      mish[(4*cq+1)*32 + base] = v.y;
      mish[(4*cq+2)*32 + base] = v.z;
      mish[(4*cq+3)*32 + base] = v.w;
    }
    float acc[16];
#pragma unroll
    for (int i=0;i<16;i++) acc[i]=0.f;
    for (int c=0;c<CIN;c++){
      float4 w0 = ld4(&wsh[c*32+o0]);
      float4 av = ld4(&mish[c*32 + ((rg ^ ((c>>2)&7))<<2)]);
      float wv[4] = {w0.x,w0.y,w0.z,w0.w};
      float rv[4] = {av.x,av.y,av.z,av.w};
#pragma unroll
      for (int oo=0;oo<4;oo++)
#pragma unroll
        for (int rr=0;rr<4;rr++) acc[oo*4+rr] = fmaf(wv[oo], rv[rr], acc[oo*4+rr]);
    }
#pragma unroll
    for (int i=0;i<16;i++) mx[i] = fmaxf(mx[i], lrelu(acc[i]));
  }
  float m4[4];
#pragma unroll
  for (int oo=0;oo<4;oo++)
    m4[oo] = fmaxf(fmaxf(mx[oo*4+0], mx[oo*4+1]), fmaxf(mx[oo*4+2], mx[oo*4+3]));
  __syncthreads();                  // both waves done with their ish -> reuse ish[0] as merge buffer
  float* mb = ish[0];
  *(float4*)&mb[(w*8+rg)*32 + o0] = make_float4(m4[0],m4[1],m4[2],m4[3]);
  __syncthreads();
  if (tid < 32){
    float v = -__builtin_inff();
#pragma unroll
    for (int g=0; g<16; g++) v = fmaxf(v, mb[g*32+tid]);
    partial[((size_t)b*8 + nt)*1024 + oc*32 + tid] = v;
  }
}

template<int TAG>
__global__ void reduce_max_kernel(const float* __restrict__ partial, float* __restrict__ out){
  int b = blockIdx.y; int o = blockIdx.x*256 + threadIdx.x;
  float v = -__builtin_inff();
  for (int s=0;s<8;s++) v = fmaxf(v, partial[((size_t)b*8 + s)*1024 + o]);
  out[(size_t)b*1024 + o] = v;
}

// ---------------- fused t-net MLP: 1024 ->512 ->256 ->9 (one launch) ----------------
__global__ __launch_bounds__(512) void tnet_fc_kernel(
    const float* __restrict__ tg, const float* __restrict__ t_f1,
    const float* __restrict__ t_f2, const float* __restrict__ t_f3w,
    const float* __restrict__ t_f3b, float* __restrict__ T9){
  const int b = blockIdx.x, tid = threadIdx.x;
  __shared__ float in1[1024];
  __shared__ float h512[512];
  __shared__ float h256[256];
  for (int i=tid;i<1024;i+=512) in1[i] = tg[(size_t)b*1024+i];
  __syncthreads();
  {
    float s = 0.f;
    for (int c=0;c<1024;c++) s = fmaf(t_f1[(size_t)tid*1024+c], in1[c], s);
    h512[tid] = lrelu(s);
  }
  __syncthreads();
  if (tid < 256){
    float s = 0.f;
    for (int c=0;c<512;c++) s = fmaf(t_f2[(size_t)tid*512+c], h512[c], s);
    h256[tid] = lrelu(s);
  }
  __syncthreads();
  if (tid < 9){
    float s = t_f3b[tid];
    for (int c=0;c<256;c++) s = fmaf(t_f3w[(size_t)tid*256+c], h256[c], s);
    T9[(size_t)b*9+tid] = s;     // stride 9: transform_kernel reads T9 + b*9
  }
}

// ---------------- x' = T^T x per batch ----------------
__global__ void transform_kernel(const float* __restrict__ x, const float* __restrict__ T9,
                                 float* __restrict__ xp, int N){
  int b = blockIdx.y; int n = blockIdx.x*256 + threadIdx.x;
  const float* t = T9 + (size_t)b*9;
  float x0=x[((size_t)b*3+0)*N+n], x1=x[((size_t)b*3+1)*N+n], x2=x[((size_t)b*3+2)*N+n];
#pragma unroll
  for (int i=0;i<3;i++)
    xp[((size_t)b*3+i)*N+n] = t[i]*x0 + t[3+i]*x1 + t[6+i]*x2;
}

// ---------------- bias1: n-invariant part of h1 (lv = fc(l,m2) fused in) ----------------
__global__ void bias1_kernel(const float* __restrict__ g, const float* __restrict__ l,
                             const float* __restrict__ m2, const float* __restrict__ h1w,
                             float* __restrict__ bias1){
  int b = blockIdx.x;
  __shared__ float insh[1088];
  for (int i=threadIdx.x;i<1024;i+=256) insh[i] = g[(size_t)b*1024+i];
  if (threadIdx.x < 64){
    int o = threadIdx.x;
    float s = 0.f;
    for (int c=0;c<16;c++) s = fmaf(m2[(size_t)o*16+c], l[(size_t)b*16+c], s);
    insh[1024+o] = lrelu(s);
  }
  __syncthreads();
  int o = threadIdx.x;
  float s=0.f;
  for (int c=0;c<1088;c++) s = fmaf(h1w[(size_t)o*1280+c], insh[c], s);
  bias1[(size_t)b*256+o]=s;
}

// ---------------- head conv layers -- register-tiled ----------------
// v3: 128 outputs/block (oc chunks of 128), c-chunks of 64 (wsh 32KB + ish 8KB =
// 40KB -> 4 blocks/CU = 8 waves/CU, was 6). Each thread 8o x 4r (32 acc): per c,
// 2 b128 weight + 1 b128 input reads for 32 FMA (was 30cyc DS per 16 FMA).
// acc persists across ascending c-chunks -> same per-output sum order -> bit-exact.
template<int CI, int O, bool ACT>
__global__ __launch_bounds__(128) void conv1_kernel(
    const float* __restrict__ inT, const float* __restrict__ wT,
    const float* __restrict__ bias, float* __restrict__ outT, int N){
  constexpr int CCH = 64;
  constexpr int NCH = CI / CCH;     // 192->3, 256->4
  __shared__ float wsh[CCH*128];    // [c][128 outputs]
  __shared__ float ish[32*CCH];     // [c][32], XOR-swizzled 4-col groups
  const int tid = threadIdx.x, w = tid>>6, lane = tid&63;
  const int o0 = (lane&15)*8;                 // 16 o-groups x 8 = 128 outputs
  const int r0 = w*16 + (lane>>4)*4;          // 4 row-groups x 4 = 16 rows per wave
  const int b = blockIdx.y, n0 = blockIdx.x*32, oc = blockIdx.z;
  const float* src = inT + ((size_t)b*N + n0)*CI;
  float acc[32];
#pragma unroll
  for (int i=0;i<32;i++) acc[i]=0.f;
  for (int ch=0; ch<NCH; ch++){
    const int cc0 = ch*CCH;
    if (ch) __syncthreads();        // prev chunk's compute done before restage
    for (int i=tid; i<CCH*128; i+=128){
      int c = i>>7, od = i&127;
      wsh[i] = wT[(size_t)(cc0+c)*O + oc*128 + od];
    }
    for (int i=tid; i<32*(CCH/4); i+=128){
      int p = i/(CCH/4), cq = i%(CCH/4);
      float4 v = ld4(src + p*CI + cc0 + 4*cq);
      int base = (((p>>2) ^ (cq&7))<<2) + (p&3);
      ish[(4*cq+0)*32 + base] = v.x;
      ish[(4*cq+1)*32 + base] = v.y;
      ish[(4*cq+2)*32 + base] = v.z;
      ish[(4*cq+3)*32 + base] = v.w;
    }
    __syncthreads();
    for (int c=0;c<CCH;c++){
      float4 w0 = ld4(&wsh[c*128+o0]), w1v = ld4(&wsh[c*128+o0+4]);
      float4 av = ld4(&ish[c*32 + (((r0>>2) ^ ((c>>2)&7))<<2)]);   // r0 multiple of 4
      float wv[8] = {w0.x,w0.y,w0.z,w0.w,w1v.x,w1v.y,w1v.z,w1v.w};
      float rv[4] = {av.x,av.y,av.z,av.w};
#pragma unroll
      for (int oo=0;oo<8;oo++)
#pragma unroll
        for (int rr=0;rr<4;rr++) acc[oo*4+rr] = fmaf(wv[oo], rv[rr], acc[oo*4+rr]);
    }
  }
  float bv[8];
  if (bias){
    float4 b0 = ld4(&bias[(size_t)b*O + oc*128 + o0]);
    float4 b1 = ld4(&bias[(size_t)b*O + oc*128 + o0 + 4]);
    bv[0]=b0.x; bv[1]=b0.y; bv[2]=b0.z; bv[3]=b0.w;
    bv[4]=b1.x; bv[5]=b1.y; bv[6]=b1.z; bv[7]=b1.w;
  } else {
#pragma unroll
    for (int i=0;i<8;i++) bv[i]=0.f;
  }
#pragma unroll
  for (int rr=0;rr<4;rr++){
    float oa[8];
#pragma unroll
    for (int oo=0;oo<8;oo++){
      float s = acc[oo*4+rr] + bv[oo];
      oa[oo] = ACT ? lrelu(s) : s;
    }
    float* dst = &outT[((size_t)b*N + n0 + r0 + rr)*O + oc*128 + o0];
    *(float4*)dst     = make_float4(oa[0],oa[1],oa[2],oa[3]);
    *(float4*)(dst+4) = make_float4(oa[4],oa[5],oa[6],oa[7]);
  }
}

// ---------------- final layer: 128 -> 50, rows-layout output (B,50,N) ----------------
__global__ __launch_bounds__(256) void conv_out_kernel(
    const float* __restrict__ inT, const float* __restrict__ wT,
    float* __restrict__ out, int N){
  const int b = blockIdx.y, n0 = blockIdx.x*32;
  __shared__ float insh[32*129];
  const float* src = inT + ((size_t)b*N + n0)*128;
  for (int i=threadIdx.x;i<32*128;i+=256){ int nn=i>>7, c=i&127; insh[nn*129+c]=src[i]; }
  __syncthreads();
  const int nl = threadIdx.x & 31, og = threadIdx.x >> 5;
  float acc[7];
#pragma unroll
  for (int t=0;t<7;t++) acc[t]=0.f;
  for (int c=0;c<128;c++){
    float iv = insh[nl*129+c];
#pragma unroll
    for (int t=0;t<7;t++){
      int o = og + 8*t;
      float wv = (o<50)? wT[c*50+o] : 0.f;
      acc[t] = fmaf(wv, iv, acc[t]);
    }
  }
#pragma unroll
  for (int t=0;t<7;t++){
    int o = og + 8*t;
    if (o < 50) out[((size_t)b*50+o)*N + n0 + nl] = acc[t];
  }
}

extern "C" void kernel_launch(void* const* d_in, const int* in_sizes, int n_in,
                              void* d_out, int out_size, void* d_ws, size_t ws_size,
                              hipStream_t stream){
  const float* x    = (const float*)d_in[0];
  const float* l    = (const float*)d_in[1];
  const float* t_c1 = (const float*)d_in[2];
  const float* t_c2 = (const float*)d_in[3];
  const float* t_c3 = (const float*)d_in[4];
  const float* t_f1 = (const float*)d_in[5];
  const float* t_f2 = (const float*)d_in[6];
  const float* t_f3w= (const float*)d_in[7];
  const float* t_f3b= (const float*)d_in[8];
  const float* b1a  = (const float*)d_in[9];
  const float* b1b  = (const float*)d_in[10];
  const float* b2a  = (const float*)d_in[11];
  const float* b2b  = (const float*)d_in[12];
  const float* b3a  = (const float*)d_in[13];
  const float* m1   = (const float*)d_in[14];
  const float* m2   = (const float*)d_in[15];
  const float* h1   = (const float*)d_in[16];
  const float* h2   = (const float*)d_in[17];
  const float* h3   = (const float*)d_in[18];
  const float* h4   = (const float*)d_in[19];
  float* out = (float*)d_out;
  float* ws = (float*)d_ws;
  const int N = NPTS, B = BATCH;

  size_t off = 0;
  auto alloc = [&](size_t nf){ float* p = ws + off; off += nf; return p; };
  float* WT_TC3 = alloc((size_t)128*1024);
  float* WT_M1  = alloc((size_t)192*1024);
  float* WT_H1B = alloc((size_t)192*256);
  float* WT_H2  = alloc((size_t)256*256);
  float* WT_H3  = alloc((size_t)256*128);
  float* WT_H4  = alloc((size_t)128*64);
  int*   IDXT   = (int*)alloc((size_t)B*N*KNN);
  float* XX     = alloc((size_t)B*N);
  float* TT     = alloc((size_t)B*N*128);
  float* PARTIAL= alloc((size_t)B*8*1024);
  float* TG     = alloc((size_t)B*1024);
  float* T9     = alloc((size_t)B*16);
  float* XP     = alloc((size_t)B*3*N);
  float* CATT   = alloc((size_t)B*N*192);
  float* G      = alloc((size_t)B*1024);
  float* BIAS1  = alloc((size_t)B*256);
  float* H1T    = alloc((size_t)B*N*256);
  float* H2T    = alloc((size_t)B*N*256);
  float* H3T    = alloc((size_t)B*N*128);
  (void)ws_size; (void)in_sizes; (void)n_in; (void)out_size;

  dim3 blk(256);
  dim3 eblk(128);
  // all 6 weight transposes in one launch
  transpose6_kernel<<<dim3(768,6), blk, 0, stream>>>(
      t_c3, WT_TC3, m1, WT_M1, h1, WT_H1B, h2, WT_H2, h3, WT_H3, h4, WT_H4);

  // t-path
  norms_rows_kernel<0><<<dim3(N/256,B), blk, 0, stream>>>(x, XX, N);
  knn3_kernel<0><<<dim3(N/4,B), blk, 0, stream>>>(x, XX, IDXT, N);
  edgeA_kernel<<<dim3(N/16,B), blk, 0, stream>>>(x, IDXT, t_c1, t_c2, TT, N);
  convmax_kernel<128,0><<<dim3(32,8,B), eblk, 0, stream>>>(TT, WT_TC3, PARTIAL, N);
  reduce_max_kernel<0><<<dim3(4,B), blk, 0, stream>>>(PARTIAL, TG);
  tnet_fc_kernel<<<dim3(B), dim3(512), 0, stream>>>(TG, t_f1, t_f2, t_f3w, t_f3b, T9);
  transform_kernel<<<dim3(N/256,B), blk, 0, stream>>>(x, T9, XP, N);

  // edge block 1 (transformed points, 3ch)
  norms_rows_kernel<1><<<dim3(N/256,B), blk, 0, stream>>>(XP, XX, N);
  knn3_kernel<1><<<dim3(N/4,B), blk, 0, stream>>>(XP, XX, IDXT, N);
  edgeB_kernel<<<dim3(N/32,B), dim3(256), 0, stream>>>(XP, IDXT, b1a, b1b, CATT, N);

  // edge block 2 (x1 = CATT[...,0:64])
  norms_cl_kernel<0><<<dim3(N/256,B), blk, 0, stream>>>(CATT, 0, XX, N);
  knn64_kernel<0><<<dim3(N/4,B), blk, 0, stream>>>(CATT, 0, XX, IDXT, N);
  edgeC_kernel<<<dim3(N/32,B), eblk, 0, stream>>>(CATT, 0, IDXT, b2a, b2b, CATT, 64, N);

  // edge block 3 (x2 = CATT[...,64:128])
  norms_cl_kernel<1><<<dim3(N/256,B), blk, 0, stream>>>(CATT, 64, XX, N);
  knn64_kernel<1><<<dim3(N/4,B), blk, 0, stream>>>(CATT, 64, XX, IDXT, N);
  edgeD_kernel<<<dim3(N/32,B), dim3(256), 0, stream>>>(CATT, 64, IDXT, b3a, CATT, 128, N);

  // global feature + head
  convmax_kernel<192,1><<<dim3(32,8,B), eblk, 0, stream>>>(CATT, WT_M1, PARTIAL, N);
  reduce_max_kernel<1><<<dim3(4,B), blk, 0, stream>>>(PARTIAL, G);
  bias1_kernel<<<dim3(B), blk, 0, stream>>>(G, l, m2, h1, BIAS1);
  conv1_kernel<192,256,true><<<dim3(N/32,B,2), eblk, 0, stream>>>(CATT, WT_H1B, BIAS1, H1T, N);
  conv1_kernel<256,256,true><<<dim3(N/32,B,2), eblk, 0, stream>>>(H1T, WT_H2, nullptr, H2T, N);
  conv1_kernel<256,128,true><<<dim3(N/32,B,1), eblk, 0, stream>>>(H2T, WT_H3, nullptr, H3T, N);
  conv_out_kernel<<<dim3(N/32,B), blk, 0, stream>>>(H3T, WT_H4, out, N);
}

// Round 14
// 2066.720 us; speedup vs baseline: 1.2226x; 1.0141x over previous
//
#include <hip/hip_runtime.h>
#include <cstdint>

#define NPTS 2048
#define BATCH 8
#define KNN 40

__device__ __forceinline__ float lrelu(float v){ return fmaxf(v, 0.2f*v); }
__device__ __forceinline__ bool better(float v1,int i1,float v2,int i2){
  return (v1>v2) || (v1==v2 && i1<i2);
}
__device__ __forceinline__ float4 ld4(const float* p){ return *(const float4*)p; }

// insert (d,m) into sorted-desc 8-list if it beats the tail; static CE chain.
#define INSERT8(v,id,d,m) \
  if (better(d, m, v[7], id[7])){ \
    v[7]=d; id[7]=m; \
    { if (better(v[7],id[7],v[6],id[6])){ float tv=v[6];int ti=id[6]; v[6]=v[7];id[6]=id[7]; v[7]=tv;id[7]=ti; } } \
    { if (better(v[6],id[6],v[5],id[5])){ float tv=v[5];int ti=id[5]; v[5]=v[6];id[5]=id[6]; v[6]=tv;id[6]=ti; } } \
    { if (better(v[5],id[5],v[4],id[4])){ float tv=v[4];int ti=id[4]; v[4]=v[5];id[4]=id[5]; v[5]=tv;id[5]=ti; } } \
    { if (better(v[4],id[4],v[3],id[3])){ float tv=v[3];int ti=id[3]; v[3]=v[4];id[3]=id[4]; v[4]=tv;id[4]=ti; } } \
    { if (better(v[3],id[3],v[2],id[2])){ float tv=v[2];int ti=id[2]; v[2]=v[3];id[2]=id[3]; v[3]=tv;id[3]=ti; } } \
    { if (better(v[2],id[2],v[1],id[1])){ float tv=v[1];int ti=id[1]; v[1]=v[2];id[1]=id[2]; v[2]=tv;id[2]=ti; } } \
    { if (better(v[1],id[1],v[0],id[0])){ float tv=v[0];int ti=id[0]; v[0]=v[1];id[0]=id[1]; v[1]=tv;id[1]=ti; } } \
  }

// ---------------- fused weight transposes (6 jobs, 1 launch) ----------------
__global__ void transpose6_kernel(
    const float* __restrict__ s0, float* __restrict__ d0,
    const float* __restrict__ s1, float* __restrict__ d1,
    const float* __restrict__ s2, float* __restrict__ d2,
    const float* __restrict__ s3, float* __restrict__ d3,
    const float* __restrict__ s4, float* __restrict__ d4,
    const float* __restrict__ s5, float* __restrict__ d5){
  int i = blockIdx.x*256 + threadIdx.x;
  const float* src; float* dst; int R,C,ld,off;
  switch (blockIdx.y){
    case 0:  src=s0; dst=d0; R=1024; C=128; ld=128;  off=0;    break;
    case 1:  src=s1; dst=d1; R=1024; C=192; ld=192;  off=0;    break;
    case 2:  src=s2; dst=d2; R=256;  C=192; ld=1280; off=1088; break;
    case 3:  src=s3; dst=d3; R=256;  C=256; ld=256;  off=0;    break;
    case 4:  src=s4; dst=d4; R=128;  C=256; ld=256;  off=0;    break;
    default: src=s5; dst=d5; R=50;   C=128; ld=128;  off=0;    break;
  }
  if (i < R*C){ int r = i / C, c = i % C; dst[c*R + r] = src[r*ld + off + c]; }
}

// ---------------- squared norms, rows layout (B,3,N) ----------------
template<int TAG>
__global__ void norms_rows_kernel(const float* __restrict__ x, float* __restrict__ xx, int N){
  int b = blockIdx.y; int n = blockIdx.x*256 + threadIdx.x;
  const float* xb = x + (size_t)b*3*N;
  float v0 = xb[n], v1 = xb[N+n], v2 = xb[2*N+n];
  xx[(size_t)b*N + n] = v0*v0 + v1*v1 + v2*v2;
}

// ---------------- squared norms, channel-last 64ch slice of (B,N,192) ----------------
template<int TAG>
__global__ void norms_cl_kernel(const float* __restrict__ f, int off, float* __restrict__ xx, int N){
  int b = blockIdx.y; int n = blockIdx.x*256 + threadIdx.x;
  const float4* p = (const float4*)(f + ((size_t)b*N + n)*192 + off);
  float s = 0.f;
#pragma unroll
  for (int q=0;q<16;q++){ float4 v = p[q]; s += v.x*v.x + v.y*v.y + v.z*v.z + v.w*v.w; }
  xx[(size_t)b*N + n] = s;
}

__device__ __forceinline__ void sort8(float (&v)[8], int (&id)[8]){
#define CE(a,bq) { if (better(v[bq],id[bq],v[a],id[a])){ float tv=v[a]; int ti=id[a]; v[a]=v[bq]; id[a]=id[bq]; v[bq]=tv; id[bq]=ti; } }
  CE(0,1) CE(2,3) CE(4,5) CE(6,7)
  CE(0,2) CE(1,3) CE(4,6) CE(5,7)
  CE(1,2) CE(5,6)
  CE(0,4) CE(1,5) CE(2,6) CE(3,7)
  CE(2,4) CE(3,5)
  CE(1,2) CE(3,4) CE(5,6)
#undef CE
}

// ---------------- knn 3-channel: 4 queries/block (1/wave), zero LDS, zero barriers ----------------
template<int TAG>
__global__ __launch_bounds__(256) void knn3_kernel(
    const float* __restrict__ xrows, const float* __restrict__ xx,
    int* __restrict__ idxT, int N){
  const int b = blockIdx.y, tid = threadIdx.x;
  const int w = tid>>6, lane = tid&63;
  const int nq = blockIdx.x*4 + w;
  const float* xb = xrows + (size_t)b*3*N;
  const float* xxb = xx + (size_t)b*N;
  float c0 = xb[nq], c1 = xb[N+nq], c2 = xb[2*N+nq];
  float xxn = xxb[nq];
  float v[8]; int id[8];
#pragma unroll
  for (int j=0;j<8;j++){ v[j]=-__builtin_inff(); id[j]=0x7FFFFFFF; }
  for (int j=0;j<32;j++){
    int m = j*64 + lane;
    float s = c0*xb[m] + c1*xb[N+m] + c2*xb[2*N+m];
    float d = 2.f*s - xxn - xxb[m];
    INSERT8(v, id, d, m)
  }
  float lastv = 0.f; int lasti = 0;
  int win = 0;
  for (int r=0;r<KNN;r++){
    float bv = v[0]; int bi = id[0];
#pragma unroll
    for (int off=32; off; off>>=1){
      float ov = __shfl_xor(bv, off);
      int   oi = __shfl_xor(bi, off);
      if (better(ov, oi, bv, bi)){ bv = ov; bi = oi; }
    }
    if (lane == r) win = bi;
    if (id[0] == bi){
      lastv = v[0]; lasti = id[0];
#pragma unroll
      for (int j=0;j<7;j++){ v[j]=v[j+1]; id[j]=id[j+1]; }
      v[7] = -__builtin_inff(); id[7] = 0x7FFFFFFF;
      if (id[0] == 0x7FFFFFFF){   // rare refill: best strictly worse than last pop
        float nv = -__builtin_inff(); int ni = 0x7FFFFFFF;
        for (int j=0;j<32;j++){
          int m = j*64 + lane;
          float s = c0*xb[m] + c1*xb[N+m] + c2*xb[2*N+m];
          float dd = 2.f*s - xxn - xxb[m];
          if (better(lastv, lasti, dd, m) && better(dd, m, nv, ni)){ nv=dd; ni=m; }
        }
        v[0] = nv; id[0] = ni;
      }
    }
  }
  if (lane < KNN) idxT[((size_t)b*KNN + lane)*N + nq] = win;
}

// ---------------- knn 64-channel (channel-last), 4 queries/block ----------------
// v6 (R5 champion): 32-cand tile (8 KiB) + 4x8K strips = 40960 B -> 16 waves/CU.
template<int TAG>
__global__ __launch_bounds__(256) void knn64_kernel(
    const float* __restrict__ featT, int featOff,
    const float* __restrict__ xx, int* __restrict__ idxT, int N){
  const int b = blockIdx.y, tid = threadIdx.x;
  const int w = tid>>6, lane = tid&63;
  __shared__ float cand[32*64];    // xor-swizzled [cand][ch] tile (8 KiB), block-shared
  __shared__ float dist[4*2048];   // wave-private strips (32 KiB)
  const float* fb = featT + featOff;
  const float* xxb = xx + (size_t)b*N;
  const int nq = blockIdx.x*4 + w;
  const int h = lane>>5;           // channel half this lane covers
  float4 ctr8[8];
  {
    const float4* cp = (const float4*)(fb + ((size_t)b*N + nq)*192);
#pragma unroll
    for (int q=0;q<8;q++) ctr8[q] = cp[h*8 + q];
  }
  float xxn = xxb[nq];
  float* dw = &dist[w*2048];
  float4 g[2];
#pragma unroll
  for (int r=0;r<2;r++){
    int k2 = tid + 256*r;
    int c = k2>>4, f = k2&15;
    g[r] = ld4(&fb[((size_t)b*N + c)*192 + 4*f]);
  }
  const int cc = lane&31, swz = cc&15, qb = h*8;
  for (int t=0;t<64;t++){
    __syncthreads();                 // prev compute done reading cand
#pragma unroll
    for (int r=0;r<2;r++){
      int k2 = tid + 256*r;
      int c = k2>>4, f = k2&15;
      *(float4*)&cand[(c<<6) + ((f ^ (c&15))<<2)] = g[r];
    }
    __syncthreads();
    if (t+1 < 64){                   // issue next tile's loads; latency overlaps compute
      int m0n = (t+1)*32;
#pragma unroll
      for (int r=0;r<2;r++){
        int k2 = tid + 256*r;
        int c = k2>>4, f = k2&15;
        g[r] = ld4(&fb[((size_t)b*N + m0n + c)*192 + 4*f]);
      }
    }
    float s0=0.f,s1=0.f,s2=0.f,s3=0.f;
#pragma unroll
    for (int j=0;j<8;j++){
      float4 mv = *(const float4*)&cand[(cc<<6) + (((qb + j) ^ swz)<<2)];
      s0 = fmaf(ctr8[j].x, mv.x, s0);
      s1 = fmaf(ctr8[j].y, mv.y, s1);
      s2 = fmaf(ctr8[j].z, mv.z, s2);
      s3 = fmaf(ctr8[j].w, mv.w, s3);
    }
    float p = (s0+s1)+(s2+s3);
    float tot = p + __shfl_xor(p, 32);    // combine channel halves (commutative -> both halves identical)
    if (h == (t&1)){                      // owner lane (m & 63 == lane) writes its strip slot
      int m = t*32 + cc;
      dw[(t>>1)*64 + lane] = 2.f*tot - xxn - xxb[m];
    }
  }
  // ---- per-lane exact top-8 of its 32 entries (sorted desc by (v desc, idx asc)) ----
  float v[8]; int id[8];
#pragma unroll
  for (int j=0;j<8;j++){ v[j]=dw[j*64+lane]; id[j]=j*64+lane; }
  sort8(v, id);
#pragma unroll
  for (int gq=1; gq<4; gq++){
    float a[8]; int ai[8];
#pragma unroll
    for (int j=0;j<8;j++){ a[j]=dw[(gq*8+j)*64+lane]; ai[j]=(gq*8+j)*64+lane; }
    sort8(a, ai);
    float m_[8]; int mi_[8];
#pragma unroll
    for (int k=0;k<8;k++){
      if (better(a[7-k], ai[7-k], v[k], id[k])){ m_[k]=a[7-k]; mi_[k]=ai[7-k]; }
      else                                     { m_[k]=v[k];   mi_[k]=id[k]; }
    }
#define CEB(x,y) { if (better(m_[y],mi_[y],m_[x],mi_[x])){ float tv=m_[x];int ti=mi_[x]; m_[x]=m_[y];mi_[x]=mi_[y]; m_[y]=tv;mi_[y]=ti; } }
    CEB(0,4) CEB(1,5) CEB(2,6) CEB(3,7)
    CEB(0,2) CEB(1,3) CEB(4,6) CEB(5,7)
    CEB(0,1) CEB(2,3) CEB(4,5) CEB(6,7)
#undef CEB
#pragma unroll
    for (int k=0;k<8;k++){ v[k]=m_[k]; id[k]=mi_[k]; }
  }
  // ---- 40 extraction rounds: butterfly + pop-shift; zero barriers, zero LDS steady state ----
  float lastv = 0.f; int lasti = 0;
  int win = 0;
  for (int r=0;r<KNN;r++){
    float bv = v[0]; int bi = id[0];
#pragma unroll
    for (int off=32; off; off>>=1){
      float ov = __shfl_xor(bv, off);
      int   oi = __shfl_xor(bi, off);
      if (better(ov, oi, bv, bi)){ bv = ov; bi = oi; }
    }
    if (lane == r) win = bi;
    if (id[0] == bi){                // unique owner (indices unique)
      lastv = v[0]; lasti = id[0];
#pragma unroll
      for (int j=0;j<7;j++){ v[j]=v[j+1]; id[j]=id[j+1]; }
      v[7] = -__builtin_inff(); id[7] = 0x7FFFFFFF;
      if (id[0] == 0x7FFFFFFF){      // rare: lane contributed >8 of top-40 -> refill head
        float nv = -__builtin_inff(); int ni = 0x7FFFFFFF;
        for (int j=0;j<32;j++){
          float vv = dw[j*64 + lane]; int m = j*64 + lane;
          if (better(lastv, lasti, vv, m) && better(vv, m, nv, ni)){ nv=vv; ni=m; }
        }
        v[0] = nv; id[0] = ni;
      }
    }
  }
  if (lane < KNN) idxT[((size_t)b*KNN + lane)*N + nq] = win;
}

// ==================== register-tiled edge kernels ====================

// ---- edgeA (t-path): 3ch -> 64 -> 128, max over k ----
__global__ __launch_bounds__(256) void edgeA_kernel(
    const float* __restrict__ x, const int* __restrict__ idxT,
    const float* __restrict__ w1, const float* __restrict__ w2,
    float* __restrict__ tT, int N){
  __shared__ float w1aT[3*64];
  __shared__ float wd3T[3*64];
  __shared__ float w2T[64*128];      // [c][o]; reused as merge buffer (4 x 16r x 128o)
  __shared__ float aT3[4][3*16];
  __shared__ float s1T[4][64*16];    // [c][r]
  const int tid = threadIdx.x, w = tid>>6, lane = tid&63;
  const int oq = lane&7, rg = lane>>3;
  const int o0 = oq*8, r0 = rg*2;
  const int b = blockIdx.y, n0 = blockIdx.x*16;
  for (int i=tid; i<192; i+=256){
    int o = i&63, c = i/64;
    float a = w1[o*6+c];
    w1aT[c*64+o] = a; wd3T[c*64+o] = w1[o*6+3+c] - a;
  }
  for (int i=tid; i<128*64; i+=256){
    int o = i>>6, c = i&63;
    w2T[c*128+o] = w2[o*64+c];
  }
  if (tid < 48){ int c = tid>>4, r = tid&15; aT3[0][c*16+r] = x[((size_t)b*3+c)*N + n0 + r]; }
  __syncthreads();
  float base[16];
#pragma unroll
  for (int i=0;i<16;i++) base[i]=0.f;
#pragma unroll
  for (int c=0;c<3;c++){
    float4 wA = ld4(&wd3T[c*64+o0]), wB = ld4(&wd3T[c*64+o0+4]);
    float2 av = *(const float2*)&aT3[0][c*16+r0];
    float wv[8] = {wA.x,wA.y,wA.z,wA.w,wB.x,wB.y,wB.z,wB.w};
    float rv[2] = {av.x,av.y};
#pragma unroll
    for (int oo=0;oo<8;oo++)
#pragma unroll
      for (int rr=0;rr<2;rr++) base[oo*2+rr] = fmaf(wv[oo], rv[rr], base[oo*2+rr]);
  }
  __syncthreads();   // all waves done reading aT3[0] before k-loop overwrites
  float mx[32];
#pragma unroll
  for (int i=0;i<32;i++) mx[i] = -__builtin_inff();
  for (int it=0; it<10; it++){
    int k = it*4 + w;
    int m = idxT[((size_t)b*KNN + k)*N + n0 + (lane&15)];
    if (lane < 48){ int c = lane>>4; aT3[w][c*16 + (lane&15)] = x[((size_t)b*3+c)*N + m]; }
    // stage1 (64 o x 16 r)
    float acc[16];
#pragma unroll
    for (int i=0;i<16;i++) acc[i] = base[i];
#pragma unroll
    for (int c=0;c<3;c++){
      float4 wA = ld4(&w1aT[c*64+o0]), wB = ld4(&w1aT[c*64+o0+4]);
      float2 av = *(const float2*)&aT3[w][c*16+r0];
      float wv[8] = {wA.x,wA.y,wA.z,wA.w,wB.x,wB.y,wB.z,wB.w};
      float rv[2] = {av.x,av.y};
#pragma unroll
      for (int oo=0;oo<8;oo++)
#pragma unroll
        for (int rr=0;rr<2;rr++) acc[oo*2+rr] = fmaf(wv[oo], rv[rr], acc[oo*2+rr]);
    }
#pragma unroll
    for (int oo=0;oo<8;oo++){
      float2 sv; sv.x = lrelu(acc[oo*2]); sv.y = lrelu(acc[oo*2+1]);
      *(float2*)&s1T[w][(o0+oo)*16 + r0] = sv;
    }
    // stage2 (128 o x 16 r): 4 panels, o = p*32 + oq*4 -> 32 banks, conflict-free
    float acc2[32];
#pragma unroll
    for (int i=0;i<32;i++) acc2[i]=0.f;
    for (int c=0;c<64;c++){
      float2 av = *(const float2*)&s1T[w][c*16 + r0];
#pragma unroll
      for (int p=0;p<4;p++){
        float4 wv = ld4(&w2T[c*128 + p*32 + oq*4]);
        acc2[p*8+0] = fmaf(wv.x, av.x, acc2[p*8+0]);
        acc2[p*8+1] = fmaf(wv.x, av.y, acc2[p*8+1]);
        acc2[p*8+2] = fmaf(wv.y, av.x, acc2[p*8+2]);
        acc2[p*8+3] = fmaf(wv.y, av.y, acc2[p*8+3]);
        acc2[p*8+4] = fmaf(wv.z, av.x, acc2[p*8+4]);
        acc2[p*8+5] = fmaf(wv.z, av.y, acc2[p*8+5]);
        acc2[p*8+6] = fmaf(wv.w, av.x, acc2[p*8+6]);
        acc2[p*8+7] = fmaf(wv.w, av.y, acc2[p*8+7]);
      }
    }
#pragma unroll
    for (int i=0;i<32;i++) mx[i] = fmaxf(mx[i], lrelu(acc2[i]));
  }
  __syncthreads();   // all waves done reading w2T -> reuse as merge buffer
#pragma unroll
  for (int rr=0;rr<2;rr++){
#pragma unroll
    for (int p=0;p<4;p++){
      float4 a = make_float4(mx[p*8+0+rr], mx[p*8+2+rr], mx[p*8+4+rr], mx[p*8+6+rr]);
      *(float4*)&w2T[w*2048 + (r0+rr)*128 + p*32 + oq*4] = a;
    }
  }
  __syncthreads();
  for (int i=tid; i<2048; i+=256){
    float vv = fmaxf(fmaxf(w2T[i], w2T[2048+i]), fmaxf(w2T[4096+i], w2T[6144+i]));
    int r = i>>7, o = i&127;
    tT[((size_t)b*N + n0 + r)*128 + o] = vv;
  }
}

// ---- edgeB: 3ch -> 64 -> 64, max over k ----
// v4 (R12 champion): 4 waves/block, k = it*4 + w, it<10 -> all 40 neighbors.
__global__ __launch_bounds__(256) void edgeB_kernel(
    const float* __restrict__ xp, const int* __restrict__ idxT,
    const float* __restrict__ w1, const float* __restrict__ w2,
    float* __restrict__ catT, int N){
  __shared__ float w1aT[3*64];
  __shared__ float wd3T[3*64];
  __shared__ float w2T[64*64];
  __shared__ float aT3[4][3*32];
  __shared__ float s1T[4][64*32];
  const int tid = threadIdx.x, w = tid>>6, lane = tid&63;
  const int oq = lane&7, rg = lane>>3;
  const int o0 = oq*8, r0 = rg*4;
  const int b = blockIdx.y, n0 = blockIdx.x*32;
  for (int i=tid; i<192; i+=256){
    int o = i&63, c = i>>6;
    float a = w1[o*6+c], bb = w1[o*6+3+c];
    w1aT[c*64+o] = a; wd3T[c*64+o] = bb - a;
  }
  for (int i=tid; i<64*64; i+=256){
    int o = i>>6, c = i&63;
    w2T[c*64+o] = w2[o*64+c];
  }
  if (tid < 32){
#pragma unroll
    for (int c=0;c<3;c++) aT3[0][c*32+tid] = xp[((size_t)b*3+c)*N + n0 + tid];
  }
  __syncthreads();
  float base[32];
#pragma unroll
  for (int i=0;i<32;i++) base[i]=0.f;
#pragma unroll
  for (int c=0;c<3;c++){
    float4 w0 = ld4(&wd3T[c*64+o0]), w1v = ld4(&wd3T[c*64+o0+4]);
    float4 av = ld4(&aT3[0][c*32+r0]);
    float wv[8] = {w0.x,w0.y,w0.z,w0.w,w1v.x,w1v.y,w1v.z,w1v.w};
    float rv[4] = {av.x,av.y,av.z,av.w};
#pragma unroll
    for (int oo=0;oo<8;oo++)
#pragma unroll
      for (int rr=0;rr<4;rr++) base[oo*4+rr] = fmaf(wv[oo], rv[rr], base[oo*4+rr]);
  }
  __syncthreads();
  float mx[32];
#pragma unroll
  for (int i=0;i<32;i++) mx[i] = -__builtin_inff();
  const int row = lane&31;
  float g0=0.f, g1=0.f, g2=0.f;
  {
    int m = idxT[((size_t)b*KNN + w)*N + n0 + row];
    if (lane < 32){
      g0 = xp[((size_t)b*3+0)*N + m];
      g1 = xp[((size_t)b*3+1)*N + m];
      g2 = xp[((size_t)b*3+2)*N + m];
    }
  }
  for (int it=0; it<10; it++){
    if (lane < 32){
      aT3[w][0*32+row] = g0;
      aT3[w][1*32+row] = g1;
      aT3[w][2*32+row] = g2;
    }
    if (it+1 < 10){                  // prefetch next gather; latency hides under compute
      int m = idxT[((size_t)b*KNN + (it+1)*4 + w)*N + n0 + row];
      if (lane < 32){
        g0 = xp[((size_t)b*3+0)*N + m];
        g1 = xp[((size_t)b*3+1)*N + m];
        g2 = xp[((size_t)b*3+2)*N + m];
      }
    }
    float acc[32];
#pragma unroll
    for (int i=0;i<32;i++) acc[i] = base[i];
#pragma unroll
    for (int c=0;c<3;c++){
      float4 w0 = ld4(&w1aT[c*64+o0]), w1v = ld4(&w1aT[c*64+o0+4]);
      float4 av = ld4(&aT3[w][c*32+r0]);
      float wv[8] = {w0.x,w0.y,w0.z,w0.w,w1v.x,w1v.y,w1v.z,w1v.w};
      float rv[4] = {av.x,av.y,av.z,av.w};
#pragma unroll
      for (int oo=0;oo<8;oo++)
#pragma unroll
      for (int rr=0;rr<4;rr++) acc[oo*4+rr] = fmaf(wv[oo], rv[rr], acc[oo*4+rr]);
    }
#pragma unroll
    for (int oo=0;oo<8;oo++){
      float4 sv = make_float4(lrelu(acc[oo*4+0]), lrelu(acc[oo*4+1]), lrelu(acc[oo*4+2]), lrelu(acc[oo*4+3]));
      *(float4*)&s1T[w][(o0+oo)*32 + r0] = sv;
    }
    float acc2[32];
#pragma unroll
    for (int i=0;i<32;i++) acc2[i]=0.f;
    for (int c=0;c<64;c++){
      float4 w0 = ld4(&w2T[c*64+o0]), w1v = ld4(&w2T[c*64+o0+4]);
      float4 av = ld4(&s1T[w][c*32+r0]);
      float wv[8] = {w0.x,w0.y,w0.z,w0.w,w1v.x,w1v.y,w1v.z,w1v.w};
      float rv[4] = {av.x,av.y,av.z,av.w};
#pragma unroll
      for (int oo=0;oo<8;oo++)
#pragma unroll
        for (int rr=0;rr<4;rr++) acc2[oo*4+rr] = fmaf(wv[oo], rv[rr], acc2[oo*4+rr]);
    }
#pragma unroll
    for (int i=0;i<32;i++) mx[i] = fmaxf(mx[i], lrelu(acc2[i]));
  }
  __syncthreads();
#pragma unroll
  for (int rr=0;rr<4;rr++){
    float4 a = make_float4(mx[0*4+rr], mx[1*4+rr], mx[2*4+rr], mx[3*4+rr]);
    float4 bq = make_float4(mx[4*4+rr], mx[5*4+rr], mx[6*4+rr], mx[7*4+rr]);
    *(float4*)&s1T[w][(r0+rr)*64 + o0] = a;
    *(float4*)&s1T[w][(r0+rr)*64 + o0 + 4] = bq;
  }
  __syncthreads();
  for (int i=tid; i<2048; i+=256){
    float v = fmaxf(fmaxf(s1T[0][i], s1T[1][i]), fmaxf(s1T[2][i], s1T[3][i]));
    int r = i>>6, o = i&63;
    catT[((size_t)b*N + n0 + r)*192 + o] = v;
  }
}

// ---- edgeC: 64ch -> 64 -> 64, max over k ----
// v3: 4 waves/block (k = it*4 + w, it<10), s1 OVERWRITES aT[w] after stage1
// (aT dead once acc computed; s1 born then) -> LDS 16+16+32 = 64KB -> 2 blocks/CU
// = 8 waves/CU (was 4). Program order keeps stage1 reads before s1 writes (same
// buffer, compiler can't prove non-alias). Max merge 4-way -> bit-exact.
__global__ __launch_bounds__(256) void edgeC_kernel(
    const float* __restrict__ inT, int inOff, const int* __restrict__ idxT,
    const float* __restrict__ w1, const float* __restrict__ w2,
    float* __restrict__ catT, int outOff, int N){
  __shared__ float w1T[64*64];
  __shared__ float w2T[64*64];
  __shared__ float aT[4][64*32];   // gather tile; reused as s1 and as merge stash
  const int tid = threadIdx.x, w = tid>>6, lane = tid&63;
  const int oq = lane&7, rg = lane>>3;
  const int o0 = oq*8, r0 = rg*4;
  const int b = blockIdx.y, n0 = blockIdx.x*32;
  for (int i=tid; i<64*64; i+=256){
    int o = i>>6, c = i&63;
    float a = w1[o*128+c], bb = w1[o*128+64+c];
    w1T[c*64+o] = a; w2T[c*64+o] = bb - a;
  }
  for (int i=tid; i<512; i+=256){
    int p = i>>4, cq = i&15;
    float4 v = ld4(&inT[((size_t)b*N + n0 + p)*192 + inOff + cq*4]);
    aT[0][(cq*4+0)*32+p] = v.x; aT[0][(cq*4+1)*32+p] = v.y;
    aT[0][(cq*4+2)*32+p] = v.z; aT[0][(cq*4+3)*32+p] = v.w;
  }
  __syncthreads();
  float base[32];
#pragma unroll
  for (int i=0;i<32;i++) base[i]=0.f;
  for (int c=0;c<64;c++){
    float4 w0 = ld4(&w2T[c*64+o0]), w1v = ld4(&w2T[c*64+o0+4]);
    float4 av = ld4(&aT[0][c*32+r0]);
    float wv[8] = {w0.x,w0.y,w0.z,w0.w,w1v.x,w1v.y,w1v.z,w1v.w};
    float rv[4] = {av.x,av.y,av.z,av.w};
#pragma unroll
    for (int oo=0;oo<8;oo++)
#pragma unroll
      for (int rr=0;rr<4;rr++) base[oo*4+rr] = fmaf(wv[oo], rv[rr], base[oo*4+rr]);
  }
  __syncthreads();
  for (int i=tid; i<64*64; i+=256){
    int o = i>>6, c = i&63;
    w2T[c*64+o] = w2[o*64+c];
  }
  __syncthreads();                  // also: all waves done reading aT[0] for base
  float mx[32];
#pragma unroll
  for (int i=0;i<32;i++) mx[i] = -__builtin_inff();
  const int row = lane&31, ch = lane>>5;
  float4 g[8];
  {
    int m = idxT[((size_t)b*KNN + w)*N + n0 + row];
    const float* src = &inT[((size_t)b*N + m)*192 + inOff + ch*32];
#pragma unroll
    for (int j=0;j<8;j++) g[j] = ld4(src + j*4);
  }
  for (int it=0; it<10; it++){
#pragma unroll
    for (int j=0;j<8;j++){
      aT[w][(ch*32+j*4+0)*32 + row] = g[j].x;
      aT[w][(ch*32+j*4+1)*32 + row] = g[j].y;
      aT[w][(ch*32+j*4+2)*32 + row] = g[j].z;
      aT[w][(ch*32+j*4+3)*32 + row] = g[j].w;
    }
    if (it+1 < 10){                 // prefetch next gather; latency hides under compute
      int m = idxT[((size_t)b*KNN + (it+1)*4 + w)*N + n0 + row];
      const float* src = &inT[((size_t)b*N + m)*192 + inOff + ch*32];
#pragma unroll
      for (int j=0;j<8;j++) g[j] = ld4(src + j*4);
    }
    float acc[32];
#pragma unroll
    for (int i=0;i<32;i++) acc[i] = base[i];
    for (int c=0;c<64;c++){
      float4 w0 = ld4(&w1T[c*64+o0]), w1v = ld4(&w1T[c*64+o0+4]);
      float4 av = ld4(&aT[w][c*32+r0]);
      float wv[8] = {w0.x,w0.y,w0.z,w0.w,w1v.x,w1v.y,w1v.z,w1v.w};
      float rv[4] = {av.x,av.y,av.z,av.w};
#pragma unroll
      for (int oo=0;oo<8;oo++)
#pragma unroll
        for (int rr=0;rr<4;rr++) acc[oo*4+rr] = fmaf(wv[oo], rv[rr], acc[oo*4+rr]);
    }
    // s1 overwrites aT[w] (gather data dead; wave-local in-order DS keeps ordering)
#pragma unroll
    for (int oo=0;oo<8;oo++){
      float4 sv = make_float4(lrelu(acc[oo*4+0]), lrelu(acc[oo*4+1]), lrelu(acc[oo*4+2]), lrelu(acc[oo*4+3]));
      *(float4*)&aT[w][(o0+oo)*32 + r0] = sv;
    }
    float acc2[32];
#pragma unroll
    for (int i=0;i<32;i++) acc2[i]=0.f;
    for (int c=0;c<64;c++){
      float4 w0 = ld4(&w2T[c*64+o0]), w1v = ld4(&w2T[c*64+o0+4]);
      float4 av = ld4(&aT[w][c*32+r0]);
      float wv[8] = {w0.x,w0.y,w0.z,w0.w,w1v.x,w1v.y,w1v.z,w1v.w};
      float rv[4] = {av.x,av.y,av.z,av.w};
#pragma unroll
      for (int oo=0;oo<8;oo++)
#pragma unroll
        for (int rr=0;rr<4;rr++) acc2[oo*4+rr] = fmaf(wv[oo], rv[rr], acc2[oo*4+rr]);
    }
#pragma unroll
    for (int i=0;i<32;i++) mx[i] = fmaxf(mx[i], lrelu(acc2[i]));
  }
  __syncthreads();                  // all waves done with aT -> reuse as merge stash
#pragma unroll
  for (int rr=0;rr<4;rr++){
    float4 a = make_float4(mx[0*4+rr], mx[1*4+rr], mx[2*4+rr], mx[3*4+rr]);
    float4 bq = make_float4(mx[4*4+rr], mx[5*4+rr], mx[6*4+rr], mx[7*4+rr]);
    *(float4*)&aT[w][(r0+rr)*64 + o0] = a;
    *(float4*)&aT[w][(r0+rr)*64 + o0 + 4] = bq;
  }
  __syncthreads();
  for (int i=tid; i<2048; i+=256){
    float v = fmaxf(fmaxf(aT[0][i], aT[1][i]), fmaxf(aT[2][i], aT[3][i]));
    int r = i>>6, o = i&63;
    catT[((size_t)b*N + n0 + r)*192 + outOff + o] = v;
  }
}

// ---- edgeD: 64ch -> 64 (single conv), max over k ----
// v4 (R12 champion): 4 waves/block, it<10 -> all 40 neighbors; merge via wdT/w1T stash.
__global__ __launch_bounds__(256) void edgeD_kernel(
    const float* __restrict__ inT, int inOff, const int* __restrict__ idxT,
    const float* __restrict__ w1, float* __restrict__ catT, int outOff, int N){
  __shared__ float w1T[64*64];
  __shared__ float wdT[64*64];
  __shared__ float aT[4][64*32];
  const int tid = threadIdx.x, w = tid>>6, lane = tid&63;
  const int oq = lane&7, rg = lane>>3;
  const int o0 = oq*8, r0 = rg*4;
  const int b = blockIdx.y, n0 = blockIdx.x*32;
  for (int i=tid; i<64*64; i+=256){
    int o = i>>6, c = i&63;
    float a = w1[o*128+c], bb = w1[o*128+64+c];
    w1T[c*64+o] = a; wdT[c*64+o] = bb - a;
  }
  for (int i=tid; i<512; i+=256){
    int p = i>>4, cq = i&15;
    float4 v = ld4(&inT[((size_t)b*N + n0 + p)*192 + inOff + cq*4]);
    aT[0][(cq*4+0)*32+p] = v.x; aT[0][(cq*4+1)*32+p] = v.y;
    aT[0][(cq*4+2)*32+p] = v.z; aT[0][(cq*4+3)*32+p] = v.w;
  }
  __syncthreads();
  float base[32];
#pragma unroll
  for (int i=0;i<32;i++) base[i]=0.f;
  for (int c=0;c<64;c++){
    float4 w0 = ld4(&wdT[c*64+o0]), w1v = ld4(&wdT[c*64+o0+4]);
    float4 av = ld4(&aT[0][c*32+r0]);
    float wv[8] = {w0.x,w0.y,w0.z,w0.w,w1v.x,w1v.y,w1v.z,w1v.w};
    float rv[4] = {av.x,av.y,av.z,av.w};
#pragma unroll
    for (int oo=0;oo<8;oo++)
#pragma unroll
      for (int rr=0;rr<4;rr++) base[oo*4+rr] = fmaf(wv[oo], rv[rr], base[oo*4+rr]);
  }
  __syncthreads();
  float mx[32];
#pragma unroll
  for (int i=0;i<32;i++) mx[i] = -__builtin_inff();
  const int row = lane&31, ch = lane>>5;
  float4 g[8];
  {
    int m = idxT[((size_t)b*KNN + w)*N + n0 + row];
    const float* src = &inT[((size_t)b*N + m)*192 + inOff + ch*32];
#pragma unroll
    for (int j=0;j<8;j++) g[j] = ld4(src + j*4);
  }
  for (int it=0; it<10; it++){
#pragma unroll
    for (int j=0;j<8;j++){
      aT[w][(ch*32+j*4+0)*32 + row] = g[j].x;
      aT[w][(ch*32+j*4+1)*32 + row] = g[j].y;
      aT[w][(ch*32+j*4+2)*32 + row] = g[j].z;
      aT[w][(ch*32+j*4+3)*32 + row] = g[j].w;
    }
    if (it+1 < 10){
      int m = idxT[((size_t)b*KNN + (it+1)*4 + w)*N + n0 + row];
      const float* src = &inT[((size_t)b*N + m)*192 + inOff + ch*32];
#pragma unroll
      for (int j=0;j<8;j++) g[j] = ld4(src + j*4);
    }
    float acc[32];
#pragma unroll
    for (int i=0;i<32;i++) acc[i] = base[i];
    for (int c=0;c<64;c++){
      float4 w0 = ld4(&w1T[c*64+o0]), w1v = ld4(&w1T[c*64+o0+4]);
      float4 av = ld4(&aT[w][c*32+r0]);
      float wv[8] = {w0.x,w0.y,w0.z,w0.w,w1v.x,w1v.y,w1v.z,w1v.w};
      float rv[4] = {av.x,av.y,av.z,av.w};
#pragma unroll
      for (int oo=0;oo<8;oo++)
#pragma unroll
        for (int rr=0;rr<4;rr++) acc[oo*4+rr] = fmaf(wv[oo], rv[rr], acc[oo*4+rr]);
    }
#pragma unroll
    for (int i=0;i<32;i++) mx[i] = fmaxf(mx[i], lrelu(acc[i]));
  }
  __syncthreads();   // all waves done reading w1T/wdT -> reuse as merge stash
  {
    float* stash = (w < 2) ? &wdT[w*2048] : &w1T[(w-2)*2048];
#pragma unroll
    for (int rr=0;rr<4;rr++){
      float4 a = make_float4(mx[0*4+rr], mx[1*4+rr], mx[2*4+rr], mx[3*4+rr]);
      float4 bq = make_float4(mx[4*4+rr], mx[5*4+rr], mx[6*4+rr], mx[7*4+rr]);
      *(float4*)&stash[(r0+rr)*64 + o0] = a;
      *(float4*)&stash[(r0+rr)*64 + o0 + 4] = bq;
    }
  }
  __syncthreads();
  for (int i=tid; i<2048; i+=256){
    float v = fmaxf(fmaxf(wdT[i], wdT[2048+i]), fmaxf(w1T[i], w1T[2048+i]));
    int r = i>>6, o = i&63;
    catT[((size_t)b*N + n0 + r)*192 + outOff + o] = v;
  }
}

// ---------------- conv1 (1024 outs) + lrelu + max ----------------
// v4 (R12 champion): oc split 32 outputs/block, LDS 72/48KB, 4o x 4r per thread.
template<int CIN, int TAG>
__global__ __launch_bounds__(128) void convmax_kernel(
    const float* __restrict__ inT, const float* __restrict__ wT,
    float* __restrict__ partial, int N){
  __shared__ float wsh[CIN*32];
  __shared__ float ish[2][32*CIN];  // per-wave staging, XOR-swizzled 4-col groups
  const int tid = threadIdx.x, w = tid>>6, lane = tid&63;
  const int oq = lane&7, rg = lane>>3;
  const int o0 = oq*4;
  const int b = blockIdx.z, oc = blockIdx.x, nt = blockIdx.y;
  for (int i=tid; i<CIN*32; i+=128){
    int c = i>>5, o = i&31;
    wsh[i] = wT[(size_t)c*1024 + oc*32 + o];
  }
  __syncthreads();                  // wsh ready; ish is wave-private afterwards
  float mx[16];
#pragma unroll
  for (int i=0;i<16;i++) mx[i] = -__builtin_inff();
  const int nbase = nt*(N/8);
  float* mish = ish[w];
  for (int it=0; it<4; it++){
    const int st = it*2 + w;        // wave w handles tiles {w, w+2, w+4, w+6}
    const float* src = inT + ((size_t)b*N + nbase + st*32)*CIN;
    for (int i=lane; i<32*(CIN/4); i+=64){
      int p = i/(CIN/4), cq = i%(CIN/4);
      float4 v = ld4(src + p*CIN + 4*cq);
      int base = (((p>>2) ^ (cq&7))<<2) + (p&3);
      mish[(4*cq+0)*32 + base] = v.x;
      mish[(4*cq+1)*32 + base] = v.y;
      mish[(4*cq+2)*32 + base] = v.z;
      mish[(4*cq+3)*32 + base] = v.w;
    }
    float acc[16];
#pragma unroll
    for (int i=0;i<16;i++) acc[i]=0.f;
    for (int c=0;c<CIN;c++){
      float4 w0 = ld4(&wsh[c*32+o0]);
      float4 av = ld4(&mish[c*32 + ((rg ^ ((c>>2)&7))<<2)]);
      float wv[4] = {w0.x,w0.y,w0.z,w0.w};
      float rv[4] = {av.x,av.y,av.z,av.w};
#pragma unroll
      for (int oo=0;oo<4;oo++)
#pragma unroll
        for (int rr=0;rr<4;rr++) acc[oo*4+rr] = fmaf(wv[oo], rv[rr], acc[oo*4+rr]);
    }
#pragma unroll
    for (int i=0;i<16;i++) mx[i] = fmaxf(mx[i], lrelu(acc[i]));
  }
  float m4[4];
#pragma unroll
  for (int oo=0;oo<4;oo++)
    m4[oo] = fmaxf(fmaxf(mx[oo*4+0], mx[oo*4+1]), fmaxf(mx[oo*4+2], mx[oo*4+3]));
  __syncthreads();                  // both waves done with their ish -> reuse ish[0] as merge buffer
  float* mb = ish[0];
  *(float4*)&mb[(w*8+rg)*32 + o0] = make_float4(m4[0],m4[1],m4[2],m4[3]);
  __syncthreads();
  if (tid < 32){
    float v = -__builtin_inff();
#pragma unroll
    for (int g=0; g<16; g++) v = fmaxf(v, mb[g*32+tid]);
    partial[((size_t)b*8 + nt)*1024 + oc*32 + tid] = v;
  }
}

template<int TAG>
__global__ void reduce_max_kernel(const float* __restrict__ partial, float* __restrict__ out){
  int b = blockIdx.y; int o = blockIdx.x*256 + threadIdx.x;
  float v = -__builtin_inff();
  for (int s=0;s<8;s++) v = fmaxf(v, partial[((size_t)b*8 + s)*1024 + o]);
  out[(size_t)b*1024 + o] = v;
}

// ---------------- fused t-net MLP: 1024 ->512 ->256 ->9 (one launch) ----------------
__global__ __launch_bounds__(512) void tnet_fc_kernel(
    const float* __restrict__ tg, const float* __restrict__ t_f1,
    const float* __restrict__ t_f2, const float* __restrict__ t_f3w,
    const float* __restrict__ t_f3b, float* __restrict__ T9){
  const int b = blockIdx.x, tid = threadIdx.x;
  __shared__ float in1[1024];
  __shared__ float h512[512];
  __shared__ float h256[256];
  for (int i=tid;i<1024;i+=512) in1[i] = tg[(size_t)b*1024+i];
  __syncthreads();
  {
    float s = 0.f;
    for (int c=0;c<1024;c++) s = fmaf(t_f1[(size_t)tid*1024+c], in1[c], s);
    h512[tid] = lrelu(s);
  }
  __syncthreads();
  if (tid < 256){
    float s = 0.f;
    for (int c=0;c<512;c++) s = fmaf(t_f2[(size_t)tid*512+c], h512[c], s);
    h256[tid] = lrelu(s);
  }
  __syncthreads();
  if (tid < 9){
    float s = t_f3b[tid];
    for (int c=0;c<256;c++) s = fmaf(t_f3w[(size_t)tid*256+c], h256[c], s);
    T9[(size_t)b*9+tid] = s;     // stride 9: transform_kernel reads T9 + b*9
  }
}

// ---------------- x' = T^T x per batch ----------------
__global__ void transform_kernel(const float* __restrict__ x, const float* __restrict__ T9,
                                 float* __restrict__ xp, int N){
  int b = blockIdx.y; int n = blockIdx.x*256 + threadIdx.x;
  const float* t = T9 + (size_t)b*9;
  float x0=x[((size_t)b*3+0)*N+n], x1=x[((size_t)b*3+1)*N+n], x2=x[((size_t)b*3+2)*N+n];
#pragma unroll
  for (int i=0;i<3;i++)
    xp[((size_t)b*3+i)*N+n] = t[i]*x0 + t[3+i]*x1 + t[6+i]*x2;
}

// ---------------- bias1: n-invariant part of h1 (lv = fc(l,m2) fused in) ----------------
__global__ void bias1_kernel(const float* __restrict__ g, const float* __restrict__ l,
                             const float* __restrict__ m2, const float* __restrict__ h1w,
                             float* __restrict__ bias1){
  int b = blockIdx.x;
  __shared__ float insh[1088];
  for (int i=threadIdx.x;i<1024;i+=256) insh[i] = g[(size_t)b*1024+i];
  if (threadIdx.x < 64){
    int o = threadIdx.x;
    float s = 0.f;
    for (int c=0;c<16;c++) s = fmaf(m2[(size_t)o*16+c], l[(size_t)b*16+c], s);
    insh[1024+o] = lrelu(s);
  }
  __syncthreads();
  int o = threadIdx.x;
  float s=0.f;
  for (int c=0;c<1088;c++) s = fmaf(h1w[(size_t)o*1280+c], insh[c], s);
  bias1[(size_t)b*256+o]=s;
}

// ---------------- head conv layers -- register-tiled (R13 champion) ----------------
template<int CI, int O, bool ACT>
__global__ __launch_bounds__(128) void conv1_kernel(
    const float* __restrict__ inT, const float* __restrict__ wT,
    const float* __restrict__ bias, float* __restrict__ outT, int N){
  constexpr int CCH = 64;
  constexpr int NCH = CI / CCH;     // 192->3, 256->4
  __shared__ float wsh[CCH*128];    // [c][128 outputs]
  __shared__ float ish[32*CCH];     // [c][32], XOR-swizzled 4-col groups
  const int tid = threadIdx.x, w = tid>>6, lane = tid&63;
  const int o0 = (lane&15)*8;                 // 16 o-groups x 8 = 128 outputs
  const int r0 = w*16 + (lane>>4)*4;          // 4 row-groups x 4 = 16 rows per wave
  const int b = blockIdx.y, n0 = blockIdx.x*32, oc = blockIdx.z;
  const float* src = inT + ((size_t)b*N + n0)*CI;
  float acc[32];
#pragma unroll
  for (int i=0;i<32;i++) acc[i]=0.f;
  for (int ch=0; ch<NCH; ch++){
    const int cc0 = ch*CCH;
    if (ch) __syncthreads();        // prev chunk's compute done before restage
    for (int i=tid; i<CCH*128; i+=128){
      int c = i>>7, od = i&127;
      wsh[i] = wT[(size_t)(cc0+c)*O + oc*128 + od];
    }
    for (int i=tid; i<32*(CCH/4); i+=128){
      int p = i/(CCH/4), cq = i%(CCH/4);
      float4 v = ld4(src + p*CI + cc0 + 4*cq);
      int base = (((p>>2) ^ (cq&7))<<2) + (p&3);
      ish[(4*cq+0)*32 + base] = v.x;
      ish[(4*cq+1)*32 + base] = v.y;
      ish[(4*cq+2)*32 + base] = v.z;
      ish[(4*cq+3)*32 + base] = v.w;
    }
    __syncthreads();
    for (int c=0;c<CCH;c++){
      float4 w0 = ld4(&wsh[c*128+o0]), w1v = ld4(&wsh[c*128+o0+4]);
      float4 av = ld4(&ish[c*32 + (((r0>>2) ^ ((c>>2)&7))<<2)]);   // r0 multiple of 4
      float wv[8] = {w0.x,w0.y,w0.z,w0.w,w1v.x,w1v.y,w1v.z,w1v.w};
      float rv[4] = {av.x,av.y,av.z,av.w};
#pragma unroll
      for (int oo=0;oo<8;oo++)
#pragma unroll
        for (int rr=0;rr<4;rr++) acc[oo*4+rr] = fmaf(wv[oo], rv[rr], acc[oo*4+rr]);
    }
  }
  float bv[8];
  if (bias){
    float4 b0 = ld4(&bias[(size_t)b*O + oc*128 + o0]);
    float4 b1 = ld4(&bias[(size_t)b*O + oc*128 + o0 + 4]);
    bv[0]=b0.x; bv[1]=b0.y; bv[2]=b0.z; bv[3]=b0.w;
    bv[4]=b1.x; bv[5]=b1.y; bv[6]=b1.z; bv[7]=b1.w;
  } else {
#pragma unroll
    for (int i=0;i<8;i++) bv[i]=0.f;
  }
#pragma unroll
  for (int rr=0;rr<4;rr++){
    float oa[8];
#pragma unroll
    for (int oo=0;oo<8;oo++){
      float s = acc[oo*4+rr] + bv[oo];
      oa[oo] = ACT ? lrelu(s) : s;
    }
    float* dst = &outT[((size_t)b*N + n0 + r0 + rr)*O + oc*128 + o0];
    *(float4*)dst     = make_float4(oa[0],oa[1],oa[2],oa[3]);
    *(float4*)(dst+4) = make_float4(oa[4],oa[5],oa[6],oa[7]);
  }
}

// ---------------- final layer: 128 -> 50, rows-layout output (B,50,N) ----------------
__global__ __launch_bounds__(256) void conv_out_kernel(
    const float* __restrict__ inT, const float* __restrict__ wT,
    float* __restrict__ out, int N){
  const int b = blockIdx.y, n0 = blockIdx.x*32;
  __shared__ float insh[32*129];
  const float* src = inT + ((size_t)b*N + n0)*128;
  for (int i=threadIdx.x;i<32*128;i+=256){ int nn=i>>7, c=i&127; insh[nn*129+c]=src[i]; }
  __syncthreads();
  const int nl = threadIdx.x & 31, og = threadIdx.x >> 5;
  float acc[7];
#pragma unroll
  for (int t=0;t<7;t++) acc[t]=0.f;
  for (int c=0;c<128;c++){
    float iv = insh[nl*129+c];
#pragma unroll
    for (int t=0;t<7;t++){
      int o = og + 8*t;
      float wv = (o<50)? wT[c*50+o] : 0.f;
      acc[t] = fmaf(wv, iv, acc[t]);
    }
  }
#pragma unroll
  for (int t=0;t<7;t++){
    int o = og + 8*t;
    if (o < 50) out[((size_t)b*50+o)*N + n0 + nl] = acc[t];
  }
}

extern "C" void kernel_launch(void* const* d_in, const int* in_sizes, int n_in,
                              void* d_out, int out_size, void* d_ws, size_t ws_size,
                              hipStream_t stream){
  const float* x    = (const float*)d_in[0];
  const float* l    = (const float*)d_in[1];
  const float* t_c1 = (const float*)d_in[2];
  const float* t_c2 = (const float*)d_in[3];
  const float* t_c3 = (const float*)d_in[4];
  const float* t_f1 = (const float*)d_in[5];
  const float* t_f2 = (const float*)d_in[6];
  const float* t_f3w= (const float*)d_in[7];
  const float* t_f3b= (const float*)d_in[8];
  const float* b1a  = (const float*)d_in[9];
  const float* b1b  = (const float*)d_in[10];
  const float* b2a  = (const float*)d_in[11];
  const float* b2b  = (const float*)d_in[12];
  const float* b3a  = (const float*)d_in[13];
  const float* m1   = (const float*)d_in[14];
  const float* m2   = (const float*)d_in[15];
  const float* h1   = (const float*)d_in[16];
  const float* h2   = (const float*)d_in[17];
  const float* h3   = (const float*)d_in[18];
  const float* h4   = (const float*)d_in[19];
  float* out = (float*)d_out;
  float* ws = (float*)d_ws;
  const int N = NPTS, B = BATCH;

  size_t off = 0;
  auto alloc = [&](size_t nf){ float* p = ws + off; off += nf; return p; };
  float* WT_TC3 = alloc((size_t)128*1024);
  float* WT_M1  = alloc((size_t)192*1024);
  float* WT_H1B = alloc((size_t)192*256);
  float* WT_H2  = alloc((size_t)256*256);
  float* WT_H3  = alloc((size_t)256*128);
  float* WT_H4  = alloc((size_t)128*64);
  int*   IDXT   = (int*)alloc((size_t)B*N*KNN);
  float* XX     = alloc((size_t)B*N);
  float* TT     = alloc((size_t)B*N*128);
  float* PARTIAL= alloc((size_t)B*8*1024);
  float* TG     = alloc((size_t)B*1024);
  float* T9     = alloc((size_t)B*16);
  float* XP     = alloc((size_t)B*3*N);
  float* CATT   = alloc((size_t)B*N*192);
  float* G      = alloc((size_t)B*1024);
  float* BIAS1  = alloc((size_t)B*256);
  float* H1T    = alloc((size_t)B*N*256);
  float* H2T    = alloc((size_t)B*N*256);
  float* H3T    = alloc((size_t)B*N*128);
  (void)ws_size; (void)in_sizes; (void)n_in; (void)out_size;

  dim3 blk(256);
  dim3 eblk(128);
  // all 6 weight transposes in one launch
  transpose6_kernel<<<dim3(768,6), blk, 0, stream>>>(
      t_c3, WT_TC3, m1, WT_M1, h1, WT_H1B, h2, WT_H2, h3, WT_H3, h4, WT_H4);

  // t-path
  norms_rows_kernel<0><<<dim3(N/256,B), blk, 0, stream>>>(x, XX, N);
  knn3_kernel<0><<<dim3(N/4,B), blk, 0, stream>>>(x, XX, IDXT, N);
  edgeA_kernel<<<dim3(N/16,B), blk, 0, stream>>>(x, IDXT, t_c1, t_c2, TT, N);
  convmax_kernel<128,0><<<dim3(32,8,B), eblk, 0, stream>>>(TT, WT_TC3, PARTIAL, N);
  reduce_max_kernel<0><<<dim3(4,B), blk, 0, stream>>>(PARTIAL, TG);
  tnet_fc_kernel<<<dim3(B), dim3(512), 0, stream>>>(TG, t_f1, t_f2, t_f3w, t_f3b, T9);
  transform_kernel<<<dim3(N/256,B), blk, 0, stream>>>(x, T9, XP, N);

  // edge block 1 (transformed points, 3ch)
  norms_rows_kernel<1><<<dim3(N/256,B), blk, 0, stream>>>(XP, XX, N);
  knn3_kernel<1><<<dim3(N/4,B), blk, 0, stream>>>(XP, XX, IDXT, N);
  edgeB_kernel<<<dim3(N/32,B), dim3(256), 0, stream>>>(XP, IDXT, b1a, b1b, CATT, N);

  // edge block 2 (x1 = CATT[...,0:64])
  norms_cl_kernel<0><<<dim3(N/256,B), blk, 0, stream>>>(CATT, 0, XX, N);
  knn64_kernel<0><<<dim3(N/4,B), blk, 0, stream>>>(CATT, 0, XX, IDXT, N);
  edgeC_kernel<<<dim3(N/32,B), dim3(256), 0, stream>>>(CATT, 0, IDXT, b2a, b2b, CATT, 64, N);

  // edge block 3 (x2 = CATT[...,64:128])
  norms_cl_kernel<1><<<dim3(N/256,B), blk, 0, stream>>>(CATT, 64, XX, N);
  knn64_kernel<1><<<dim3(N/4,B), blk, 0, stream>>>(CATT, 64, XX, IDXT, N);
  edgeD_kernel<<<dim3(N/32,B), dim3(256), 0, stream>>>(CATT, 64, IDXT, b3a, CATT, 128, N);

  // global feature + head
  convmax_kernel<192,1><<<dim3(32,8,B), eblk, 0, stream>>>(CATT, WT_M1, PARTIAL, N);
  reduce_max_kernel<1><<<dim3(4,B), blk, 0, stream>>>(PARTIAL, G);
  bias1_kernel<<<dim3(B), blk, 0, stream>>>(G, l, m2, h1, BIAS1);
  conv1_kernel<192,256,true><<<dim3(N/32,B,2), eblk, 0, stream>>>(CATT, WT_H1B, BIAS1, H1T, N);
  conv1_kernel<256,256,true><<<dim3(N/32,B,2), eblk, 0, stream>>>(H1T, WT_H2, nullptr, H2T, N);
  conv1_kernel<256,128,true><<<dim3(N/32,B,1), eblk, 0, stream>>>(H2T, WT_H3, nullptr, H3T, N);
  conv_out_kernel<<<dim3(N/32,B), blk, 0, stream>>>(H3T, WT_H4, out, N);
}

// Round 15
// 1977.277 us; speedup vs baseline: 1.2780x; 1.0452x over previous
//
#include <hip/hip_runtime.h>
#include <cstdint>

#define NPTS 2048
#define BATCH 8
#define KNN 40

__device__ __forceinline__ float lrelu(float v){ return fmaxf(v, 0.2f*v); }
__device__ __forceinline__ bool better(float v1,int i1,float v2,int i2){
  return (v1>v2) || (v1==v2 && i1<i2);
}
__device__ __forceinline__ float4 ld4(const float* p){ return *(const float4*)p; }

// insert (d,m) into sorted-desc 8-list if it beats the tail; static CE chain.
#define INSERT8(v,id,d,m) \
  if (better(d, m, v[7], id[7])){ \
    v[7]=d; id[7]=m; \
    { if (better(v[7],id[7],v[6],id[6])){ float tv=v[6];int ti=id[6]; v[6]=v[7];id[6]=id[7]; v[7]=tv;id[7]=ti; } } \
    { if (better(v[6],id[6],v[5],id[5])){ float tv=v[5];int ti=id[5]; v[5]=v[6];id[5]=id[6]; v[6]=tv;id[6]=ti; } } \
    { if (better(v[5],id[5],v[4],id[4])){ float tv=v[4];int ti=id[4]; v[4]=v[5];id[4]=id[5]; v[5]=tv;id[5]=ti; } } \
    { if (better(v[4],id[4],v[3],id[3])){ float tv=v[3];int ti=id[3]; v[3]=v[4];id[3]=id[4]; v[4]=tv;id[4]=ti; } } \
    { if (better(v[3],id[3],v[2],id[2])){ float tv=v[2];int ti=id[2]; v[2]=v[3];id[2]=id[3]; v[3]=tv;id[3]=ti; } } \
    { if (better(v[2],id[2],v[1],id[1])){ float tv=v[1];int ti=id[1]; v[1]=v[2];id[1]=id[2]; v[2]=tv;id[2]=ti; } } \
    { if (better(v[1],id[1],v[0],id[0])){ float tv=v[0];int ti=id[0]; v[0]=v[1];id[0]=id[1]; v[1]=tv;id[1]=ti; } } \
  }

// ---------------- fused weight transposes (6 jobs, 1 launch) ----------------
__global__ void transpose6_kernel(
    const float* __restrict__ s0, float* __restrict__ d0,
    const float* __restrict__ s1, float* __restrict__ d1,
    const float* __restrict__ s2, float* __restrict__ d2,
    const float* __restrict__ s3, float* __restrict__ d3,
    const float* __restrict__ s4, float* __restrict__ d4,
    const float* __restrict__ s5, float* __restrict__ d5){
  int i = blockIdx.x*256 + threadIdx.x;
  const float* src; float* dst; int R,C,ld,off;
  switch (blockIdx.y){
    case 0:  src=s0; dst=d0; R=1024; C=128; ld=128;  off=0;    break;
    case 1:  src=s1; dst=d1; R=1024; C=192; ld=192;  off=0;    break;
    case 2:  src=s2; dst=d2; R=256;  C=192; ld=1280; off=1088; break;
    case 3:  src=s3; dst=d3; R=256;  C=256; ld=256;  off=0;    break;
    case 4:  src=s4; dst=d4; R=128;  C=256; ld=256;  off=0;    break;
    default: src=s5; dst=d5; R=50;   C=128; ld=128;  off=0;    break;
  }
  if (i < R*C){ int r = i / C, c = i % C; dst[c*R + r] = src[r*ld + off + c]; }
}

// ---------------- squared norms, rows layout (B,3,N) ----------------
template<int TAG>
__global__ void norms_rows_kernel(const float* __restrict__ x, float* __restrict__ xx, int N){
  int b = blockIdx.y; int n = blockIdx.x*256 + threadIdx.x;
  const float* xb = x + (size_t)b*3*N;
  float v0 = xb[n], v1 = xb[N+n], v2 = xb[2*N+n];
  xx[(size_t)b*N + n] = v0*v0 + v1*v1 + v2*v2;
}

// ---------------- squared norms, channel-last 64ch slice of (B,N,192) ----------------
template<int TAG>
__global__ void norms_cl_kernel(const float* __restrict__ f, int off, float* __restrict__ xx, int N){
  int b = blockIdx.y; int n = blockIdx.x*256 + threadIdx.x;
  const float4* p = (const float4*)(f + ((size_t)b*N + n)*192 + off);
  float s = 0.f;
#pragma unroll
  for (int q=0;q<16;q++){ float4 v = p[q]; s += v.x*v.x + v.y*v.y + v.z*v.z + v.w*v.w; }
  xx[(size_t)b*N + n] = s;
}

__device__ __forceinline__ void sort8(float (&v)[8], int (&id)[8]){
#define CE(a,bq) { if (better(v[bq],id[bq],v[a],id[a])){ float tv=v[a]; int ti=id[a]; v[a]=v[bq]; id[a]=id[bq]; v[bq]=tv; id[bq]=ti; } }
  CE(0,1) CE(2,3) CE(4,5) CE(6,7)
  CE(0,2) CE(1,3) CE(4,6) CE(5,7)
  CE(1,2) CE(5,6)
  CE(0,4) CE(1,5) CE(2,6) CE(3,7)
  CE(2,4) CE(3,5)
  CE(1,2) CE(3,4) CE(5,6)
#undef CE
}

// ---------------- knn 3-channel: 4 queries/block (1/wave), zero LDS, zero barriers ----------------
template<int TAG>
__global__ __launch_bounds__(256) void knn3_kernel(
    const float* __restrict__ xrows, const float* __restrict__ xx,
    int* __restrict__ idxT, int N){
  const int b = blockIdx.y, tid = threadIdx.x;
  const int w = tid>>6, lane = tid&63;
  const int nq = blockIdx.x*4 + w;
  const float* xb = xrows + (size_t)b*3*N;
  const float* xxb = xx + (size_t)b*N;
  float c0 = xb[nq], c1 = xb[N+nq], c2 = xb[2*N+nq];
  float xxn = xxb[nq];
  float v[8]; int id[8];
#pragma unroll
  for (int j=0;j<8;j++){ v[j]=-__builtin_inff(); id[j]=0x7FFFFFFF; }
  for (int j=0;j<32;j++){
    int m = j*64 + lane;
    float s = c0*xb[m] + c1*xb[N+m] + c2*xb[2*N+m];
    float d = 2.f*s - xxn - xxb[m];
    INSERT8(v, id, d, m)
  }
  float lastv = 0.f; int lasti = 0;
  int win = 0;
  for (int r=0;r<KNN;r++){
    float bv = v[0]; int bi = id[0];
#pragma unroll
    for (int off=32; off; off>>=1){
      float ov = __shfl_xor(bv, off);
      int   oi = __shfl_xor(bi, off);
      if (better(ov, oi, bv, bi)){ bv = ov; bi = oi; }
    }
    if (lane == r) win = bi;
    if (id[0] == bi){
      lastv = v[0]; lasti = id[0];
#pragma unroll
      for (int j=0;j<7;j++){ v[j]=v[j+1]; id[j]=id[j+1]; }
      v[7] = -__builtin_inff(); id[7] = 0x7FFFFFFF;
      if (id[0] == 0x7FFFFFFF){   // rare refill: best strictly worse than last pop
        float nv = -__builtin_inff(); int ni = 0x7FFFFFFF;
        for (int j=0;j<32;j++){
          int m = j*64 + lane;
          float s = c0*xb[m] + c1*xb[N+m] + c2*xb[2*N+m];
          float dd = 2.f*s - xxn - xxb[m];
          if (better(lastv, lasti, dd, m) && better(dd, m, nv, ni)){ nv=dd; ni=m; }
        }
        v[0] = nv; id[0] = ni;
      }
    }
  }
  if (lane < KNN) idxT[((size_t)b*KNN + lane)*N + nq] = win;
}

// ---------------- knn 64-channel (channel-last), 4 queries/block ----------------
// v6 (R5 champion): 32-cand tile (8 KiB) + 4x8K strips = 40960 B -> 16 waves/CU.
template<int TAG>
__global__ __launch_bounds__(256) void knn64_kernel(
    const float* __restrict__ featT, int featOff,
    const float* __restrict__ xx, int* __restrict__ idxT, int N){
  const int b = blockIdx.y, tid = threadIdx.x;
  const int w = tid>>6, lane = tid&63;
  __shared__ float cand[32*64];    // xor-swizzled [cand][ch] tile (8 KiB), block-shared
  __shared__ float dist[4*2048];   // wave-private strips (32 KiB)
  const float* fb = featT + featOff;
  const float* xxb = xx + (size_t)b*N;
  const int nq = blockIdx.x*4 + w;
  const int h = lane>>5;           // channel half this lane covers
  float4 ctr8[8];
  {
    const float4* cp = (const float4*)(fb + ((size_t)b*N + nq)*192);
#pragma unroll
    for (int q=0;q<8;q++) ctr8[q] = cp[h*8 + q];
  }
  float xxn = xxb[nq];
  float* dw = &dist[w*2048];
  float4 g[2];
#pragma unroll
  for (int r=0;r<2;r++){
    int k2 = tid + 256*r;
    int c = k2>>4, f = k2&15;
    g[r] = ld4(&fb[((size_t)b*N + c)*192 + 4*f]);
  }
  const int cc = lane&31, swz = cc&15, qb = h*8;
  for (int t=0;t<64;t++){
    __syncthreads();                 // prev compute done reading cand
#pragma unroll
    for (int r=0;r<2;r++){
      int k2 = tid + 256*r;
      int c = k2>>4, f = k2&15;
      *(float4*)&cand[(c<<6) + ((f ^ (c&15))<<2)] = g[r];
    }
    __syncthreads();
    if (t+1 < 64){                   // issue next tile's loads; latency overlaps compute
      int m0n = (t+1)*32;
#pragma unroll
      for (int r=0;r<2;r++){
        int k2 = tid + 256*r;
        int c = k2>>4, f = k2&15;
        g[r] = ld4(&fb[((size_t)b*N + m0n + c)*192 + 4*f]);
      }
    }
    float s0=0.f,s1=0.f,s2=0.f,s3=0.f;
#pragma unroll
    for (int j=0;j<8;j++){
      float4 mv = *(const float4*)&cand[(cc<<6) + (((qb + j) ^ swz)<<2)];
      s0 = fmaf(ctr8[j].x, mv.x, s0);
      s1 = fmaf(ctr8[j].y, mv.y, s1);
      s2 = fmaf(ctr8[j].z, mv.z, s2);
      s3 = fmaf(ctr8[j].w, mv.w, s3);
    }
    float p = (s0+s1)+(s2+s3);
    float tot = p + __shfl_xor(p, 32);    // combine channel halves (commutative -> both halves identical)
    if (h == (t&1)){                      // owner lane (m & 63 == lane) writes its strip slot
      int m = t*32 + cc;
      dw[(t>>1)*64 + lane] = 2.f*tot - xxn - xxb[m];
    }
  }
  // ---- per-lane exact top-8 of its 32 entries (sorted desc by (v desc, idx asc)) ----
  float v[8]; int id[8];
#pragma unroll
  for (int j=0;j<8;j++){ v[j]=dw[j*64+lane]; id[j]=j*64+lane; }
  sort8(v, id);
#pragma unroll
  for (int gq=1; gq<4; gq++){
    float a[8]; int ai[8];
#pragma unroll
    for (int j=0;j<8;j++){ a[j]=dw[(gq*8+j)*64+lane]; ai[j]=(gq*8+j)*64+lane; }
    sort8(a, ai);
    float m_[8]; int mi_[8];
#pragma unroll
    for (int k=0;k<8;k++){
      if (better(a[7-k], ai[7-k], v[k], id[k])){ m_[k]=a[7-k]; mi_[k]=ai[7-k]; }
      else                                     { m_[k]=v[k];   mi_[k]=id[k]; }
    }
#define CEB(x,y) { if (better(m_[y],mi_[y],m_[x],mi_[x])){ float tv=m_[x];int ti=mi_[x]; m_[x]=m_[y];mi_[x]=mi_[y]; m_[y]=tv;mi_[y]=ti; } }
    CEB(0,4) CEB(1,5) CEB(2,6) CEB(3,7)
    CEB(0,2) CEB(1,3) CEB(4,6) CEB(5,7)
    CEB(0,1) CEB(2,3) CEB(4,5) CEB(6,7)
#undef CEB
#pragma unroll
    for (int k=0;k<8;k++){ v[k]=m_[k]; id[k]=mi_[k]; }
  }
  // ---- 40 extraction rounds: butterfly + pop-shift; zero barriers, zero LDS steady state ----
  float lastv = 0.f; int lasti = 0;
  int win = 0;
  for (int r=0;r<KNN;r++){
    float bv = v[0]; int bi = id[0];
#pragma unroll
    for (int off=32; off; off>>=1){
      float ov = __shfl_xor(bv, off);
      int   oi = __shfl_xor(bi, off);
      if (better(ov, oi, bv, bi)){ bv = ov; bi = oi; }
    }
    if (lane == r) win = bi;
    if (id[0] == bi){                // unique owner (indices unique)
      lastv = v[0]; lasti = id[0];
#pragma unroll
      for (int j=0;j<7;j++){ v[j]=v[j+1]; id[j]=id[j+1]; }
      v[7] = -__builtin_inff(); id[7] = 0x7FFFFFFF;
      if (id[0] == 0x7FFFFFFF){      // rare: lane contributed >8 of top-40 -> refill head
        float nv = -__builtin_inff(); int ni = 0x7FFFFFFF;
        for (int j=0;j<32;j++){
          float vv = dw[j*64 + lane]; int m = j*64 + lane;
          if (better(lastv, lasti, vv, m) && better(vv, m, nv, ni)){ nv=vv; ni=m; }
        }
        v[0] = nv; id[0] = ni;
      }
    }
  }
  if (lane < KNN) idxT[((size_t)b*KNN + lane)*N + nq] = win;
}

// ==================== register-tiled edge kernels ====================

// ---- edgeA (t-path): 3ch -> 64 -> 128, max over k ----
__global__ __launch_bounds__(256) void edgeA_kernel(
    const float* __restrict__ x, const int* __restrict__ idxT,
    const float* __restrict__ w1, const float* __restrict__ w2,
    float* __restrict__ tT, int N){
  __shared__ float w1aT[3*64];
  __shared__ float wd3T[3*64];
  __shared__ float w2T[64*128];      // [c][o]; reused as merge buffer (4 x 16r x 128o)
  __shared__ float aT3[4][3*16];
  __shared__ float s1T[4][64*16];    // [c][r]
  const int tid = threadIdx.x, w = tid>>6, lane = tid&63;
  const int oq = lane&7, rg = lane>>3;
  const int o0 = oq*8, r0 = rg*2;
  const int b = blockIdx.y, n0 = blockIdx.x*16;
  for (int i=tid; i<192; i+=256){
    int o = i&63, c = i/64;
    float a = w1[o*6+c];
    w1aT[c*64+o] = a; wd3T[c*64+o] = w1[o*6+3+c] - a;
  }
  for (int i=tid; i<128*64; i+=256){
    int o = i>>6, c = i&63;
    w2T[c*128+o] = w2[o*64+c];
  }
  if (tid < 48){ int c = tid>>4, r = tid&15; aT3[0][c*16+r] = x[((size_t)b*3+c)*N + n0 + r]; }
  __syncthreads();
  float base[16];
#pragma unroll
  for (int i=0;i<16;i++) base[i]=0.f;
#pragma unroll
  for (int c=0;c<3;c++){
    float4 wA = ld4(&wd3T[c*64+o0]), wB = ld4(&wd3T[c*64+o0+4]);
    float2 av = *(const float2*)&aT3[0][c*16+r0];
    float wv[8] = {wA.x,wA.y,wA.z,wA.w,wB.x,wB.y,wB.z,wB.w};
    float rv[2] = {av.x,av.y};
#pragma unroll
    for (int oo=0;oo<8;oo++)
#pragma unroll
      for (int rr=0;rr<2;rr++) base[oo*2+rr] = fmaf(wv[oo], rv[rr], base[oo*2+rr]);
  }
  __syncthreads();   // all waves done reading aT3[0] before k-loop overwrites
  float mx[32];
#pragma unroll
  for (int i=0;i<32;i++) mx[i] = -__builtin_inff();
  for (int it=0; it<10; it++){
    int k = it*4 + w;
    int m = idxT[((size_t)b*KNN + k)*N + n0 + (lane&15)];
    if (lane < 48){ int c = lane>>4; aT3[w][c*16 + (lane&15)] = x[((size_t)b*3+c)*N + m]; }
    // stage1 (64 o x 16 r)
    float acc[16];
#pragma unroll
    for (int i=0;i<16;i++) acc[i] = base[i];
#pragma unroll
    for (int c=0;c<3;c++){
      float4 wA = ld4(&w1aT[c*64+o0]), wB = ld4(&w1aT[c*64+o0+4]);
      float2 av = *(const float2*)&aT3[w][c*16+r0];
      float wv[8] = {wA.x,wA.y,wA.z,wA.w,wB.x,wB.y,wB.z,wB.w};
      float rv[2] = {av.x,av.y};
#pragma unroll
      for (int oo=0;oo<8;oo++)
#pragma unroll
        for (int rr=0;rr<2;rr++) acc[oo*2+rr] = fmaf(wv[oo], rv[rr], acc[oo*2+rr]);
    }
#pragma unroll
    for (int oo=0;oo<8;oo++){
      float2 sv; sv.x = lrelu(acc[oo*2]); sv.y = lrelu(acc[oo*2+1]);
      *(float2*)&s1T[w][(o0+oo)*16 + r0] = sv;
    }
    // stage2 (128 o x 16 r): 4 panels, o = p*32 + oq*4 -> 32 banks, conflict-free
    float acc2[32];
#pragma unroll
    for (int i=0;i<32;i++) acc2[i]=0.f;
    for (int c=0;c<64;c++){
      float2 av = *(const float2*)&s1T[w][c*16 + r0];
#pragma unroll
      for (int p=0;p<4;p++){
        float4 wv = ld4(&w2T[c*128 + p*32 + oq*4]);
        acc2[p*8+0] = fmaf(wv.x, av.x, acc2[p*8+0]);
        acc2[p*8+1] = fmaf(wv.x, av.y, acc2[p*8+1]);
        acc2[p*8+2] = fmaf(wv.y, av.x, acc2[p*8+2]);
        acc2[p*8+3] = fmaf(wv.y, av.y, acc2[p*8+3]);
        acc2[p*8+4] = fmaf(wv.z, av.x, acc2[p*8+4]);
        acc2[p*8+5] = fmaf(wv.z, av.y, acc2[p*8+5]);
        acc2[p*8+6] = fmaf(wv.w, av.x, acc2[p*8+6]);
        acc2[p*8+7] = fmaf(wv.w, av.y, acc2[p*8+7]);
      }
    }
#pragma unroll
    for (int i=0;i<32;i++) mx[i] = fmaxf(mx[i], lrelu(acc2[i]));
  }
  __syncthreads();   // all waves done reading w2T -> reuse as merge buffer
#pragma unroll
  for (int rr=0;rr<2;rr++){
#pragma unroll
    for (int p=0;p<4;p++){
      float4 a = make_float4(mx[p*8+0+rr], mx[p*8+2+rr], mx[p*8+4+rr], mx[p*8+6+rr]);
      *(float4*)&w2T[w*2048 + (r0+rr)*128 + p*32 + oq*4] = a;
    }
  }
  __syncthreads();
  for (int i=tid; i<2048; i+=256){
    float vv = fmaxf(fmaxf(w2T[i], w2T[2048+i]), fmaxf(w2T[4096+i], w2T[6144+i]));
    int r = i>>7, o = i&127;
    tT[((size_t)b*N + n0 + r)*128 + o] = vv;
  }
}

// ---- edgeB: 3ch -> 64 -> 64, max over k ----
// v4 (R12 champion): 4 waves/block, k = it*4 + w, it<10 -> all 40 neighbors.
__global__ __launch_bounds__(256) void edgeB_kernel(
    const float* __restrict__ xp, const int* __restrict__ idxT,
    const float* __restrict__ w1, const float* __restrict__ w2,
    float* __restrict__ catT, int N){
  __shared__ float w1aT[3*64];
  __shared__ float wd3T[3*64];
  __shared__ float w2T[64*64];
  __shared__ float aT3[4][3*32];
  __shared__ float s1T[4][64*32];
  const int tid = threadIdx.x, w = tid>>6, lane = tid&63;
  const int oq = lane&7, rg = lane>>3;
  const int o0 = oq*8, r0 = rg*4;
  const int b = blockIdx.y, n0 = blockIdx.x*32;
  for (int i=tid; i<192; i+=256){
    int o = i&63, c = i>>6;
    float a = w1[o*6+c], bb = w1[o*6+3+c];
    w1aT[c*64+o] = a; wd3T[c*64+o] = bb - a;
  }
  for (int i=tid; i<64*64; i+=256){
    int o = i>>6, c = i&63;
    w2T[c*64+o] = w2[o*64+c];
  }
  if (tid < 32){
#pragma unroll
    for (int c=0;c<3;c++) aT3[0][c*32+tid] = xp[((size_t)b*3+c)*N + n0 + tid];
  }
  __syncthreads();
  float base[32];
#pragma unroll
  for (int i=0;i<32;i++) base[i]=0.f;
#pragma unroll
  for (int c=0;c<3;c++){
    float4 w0 = ld4(&wd3T[c*64+o0]), w1v = ld4(&wd3T[c*64+o0+4]);
    float4 av = ld4(&aT3[0][c*32+r0]);
    float wv[8] = {w0.x,w0.y,w0.z,w0.w,w1v.x,w1v.y,w1v.z,w1v.w};
    float rv[4] = {av.x,av.y,av.z,av.w};
#pragma unroll
    for (int oo=0;oo<8;oo++)
#pragma unroll
      for (int rr=0;rr<4;rr++) base[oo*4+rr] = fmaf(wv[oo], rv[rr], base[oo*4+rr]);
  }
  __syncthreads();
  float mx[32];
#pragma unroll
  for (int i=0;i<32;i++) mx[i] = -__builtin_inff();
  const int row = lane&31;
  float g0=0.f, g1=0.f, g2=0.f;
  {
    int m = idxT[((size_t)b*KNN + w)*N + n0 + row];
    if (lane < 32){
      g0 = xp[((size_t)b*3+0)*N + m];
      g1 = xp[((size_t)b*3+1)*N + m];
      g2 = xp[((size_t)b*3+2)*N + m];
    }
  }
  for (int it=0; it<10; it++){
    if (lane < 32){
      aT3[w][0*32+row] = g0;
      aT3[w][1*32+row] = g1;
      aT3[w][2*32+row] = g2;
    }
    if (it+1 < 10){                  // prefetch next gather; latency hides under compute
      int m = idxT[((size_t)b*KNN + (it+1)*4 + w)*N + n0 + row];
      if (lane < 32){
        g0 = xp[((size_t)b*3+0)*N + m];
        g1 = xp[((size_t)b*3+1)*N + m];
        g2 = xp[((size_t)b*3+2)*N + m];
      }
    }
    float acc[32];
#pragma unroll
    for (int i=0;i<32;i++) acc[i] = base[i];
#pragma unroll
    for (int c=0;c<3;c++){
      float4 w0 = ld4(&w1aT[c*64+o0]), w1v = ld4(&w1aT[c*64+o0+4]);
      float4 av = ld4(&aT3[w][c*32+r0]);
      float wv[8] = {w0.x,w0.y,w0.z,w0.w,w1v.x,w1v.y,w1v.z,w1v.w};
      float rv[4] = {av.x,av.y,av.z,av.w};
#pragma unroll
      for (int oo=0;oo<8;oo++)
#pragma unroll
      for (int rr=0;rr<4;rr++) acc[oo*4+rr] = fmaf(wv[oo], rv[rr], acc[oo*4+rr]);
    }
#pragma unroll
    for (int oo=0;oo<8;oo++){
      float4 sv = make_float4(lrelu(acc[oo*4+0]), lrelu(acc[oo*4+1]), lrelu(acc[oo*4+2]), lrelu(acc[oo*4+3]));
      *(float4*)&s1T[w][(o0+oo)*32 + r0] = sv;
    }
    float acc2[32];
#pragma unroll
    for (int i=0;i<32;i++) acc2[i]=0.f;
    for (int c=0;c<64;c++){
      float4 w0 = ld4(&w2T[c*64+o0]), w1v = ld4(&w2T[c*64+o0+4]);
      float4 av = ld4(&s1T[w][c*32+r0]);
      float wv[8] = {w0.x,w0.y,w0.z,w0.w,w1v.x,w1v.y,w1v.z,w1v.w};
      float rv[4] = {av.x,av.y,av.z,av.w};
#pragma unroll
      for (int oo=0;oo<8;oo++)
#pragma unroll
        for (int rr=0;rr<4;rr++) acc2[oo*4+rr] = fmaf(wv[oo], rv[rr], acc2[oo*4+rr]);
    }
#pragma unroll
    for (int i=0;i<32;i++) mx[i] = fmaxf(mx[i], lrelu(acc2[i]));
  }
  __syncthreads();
#pragma unroll
  for (int rr=0;rr<4;rr++){
    float4 a = make_float4(mx[0*4+rr], mx[1*4+rr], mx[2*4+rr], mx[3*4+rr]);
    float4 bq = make_float4(mx[4*4+rr], mx[5*4+rr], mx[6*4+rr], mx[7*4+rr]);
    *(float4*)&s1T[w][(r0+rr)*64 + o0] = a;
    *(float4*)&s1T[w][(r0+rr)*64 + o0 + 4] = bq;
  }
  __syncthreads();
  for (int i=tid; i<2048; i+=256){
    float v = fmaxf(fmaxf(s1T[0][i], s1T[1][i]), fmaxf(s1T[2][i], s1T[3][i]));
    int r = i>>6, o = i&63;
    catT[((size_t)b*N + n0 + r)*192 + o] = v;
  }
}

// ---- edgeC: 64ch -> 64 -> 64, max over k ----
// v3 (R14 champion): 4 waves/block, s1 overwrites aT[w]; 64KB -> 8 waves/CU.
__global__ __launch_bounds__(256) void edgeC_kernel(
    const float* __restrict__ inT, int inOff, const int* __restrict__ idxT,
    const float* __restrict__ w1, const float* __restrict__ w2,
    float* __restrict__ catT, int outOff, int N){
  __shared__ float w1T[64*64];
  __shared__ float w2T[64*64];
  __shared__ float aT[4][64*32];   // gather tile; reused as s1 and as merge stash
  const int tid = threadIdx.x, w = tid>>6, lane = tid&63;
  const int oq = lane&7, rg = lane>>3;
  const int o0 = oq*8, r0 = rg*4;
  const int b = blockIdx.y, n0 = blockIdx.x*32;
  for (int i=tid; i<64*64; i+=256){
    int o = i>>6, c = i&63;
    float a = w1[o*128+c], bb = w1[o*128+64+c];
    w1T[c*64+o] = a; w2T[c*64+o] = bb - a;
  }
  for (int i=tid; i<512; i+=256){
    int p = i>>4, cq = i&15;
    float4 v = ld4(&inT[((size_t)b*N + n0 + p)*192 + inOff + cq*4]);
    aT[0][(cq*4+0)*32+p] = v.x; aT[0][(cq*4+1)*32+p] = v.y;
    aT[0][(cq*4+2)*32+p] = v.z; aT[0][(cq*4+3)*32+p] = v.w;
  }
  __syncthreads();
  float base[32];
#pragma unroll
  for (int i=0;i<32;i++) base[i]=0.f;
  for (int c=0;c<64;c++){
    float4 w0 = ld4(&w2T[c*64+o0]), w1v = ld4(&w2T[c*64+o0+4]);
    float4 av = ld4(&aT[0][c*32+r0]);
    float wv[8] = {w0.x,w0.y,w0.z,w0.w,w1v.x,w1v.y,w1v.z,w1v.w};
    float rv[4] = {av.x,av.y,av.z,av.w};
#pragma unroll
    for (int oo=0;oo<8;oo++)
#pragma unroll
      for (int rr=0;rr<4;rr++) base[oo*4+rr] = fmaf(wv[oo], rv[rr], base[oo*4+rr]);
  }
  __syncthreads();
  for (int i=tid; i<64*64; i+=256){
    int o = i>>6, c = i&63;
    w2T[c*64+o] = w2[o*64+c];
  }
  __syncthreads();                  // also: all waves done reading aT[0] for base
  float mx[32];
#pragma unroll
  for (int i=0;i<32;i++) mx[i] = -__builtin_inff();
  const int row = lane&31, ch = lane>>5;
  float4 g[8];
  {
    int m = idxT[((size_t)b*KNN + w)*N + n0 + row];
    const float* src = &inT[((size_t)b*N + m)*192 + inOff + ch*32];
#pragma unroll
    for (int j=0;j<8;j++) g[j] = ld4(src + j*4);
  }
  for (int it=0; it<10; it++){
#pragma unroll
    for (int j=0;j<8;j++){
      aT[w][(ch*32+j*4+0)*32 + row] = g[j].x;
      aT[w][(ch*32+j*4+1)*32 + row] = g[j].y;
      aT[w][(ch*32+j*4+2)*32 + row] = g[j].z;
      aT[w][(ch*32+j*4+3)*32 + row] = g[j].w;
    }
    if (it+1 < 10){                 // prefetch next gather; latency hides under compute
      int m = idxT[((size_t)b*KNN + (it+1)*4 + w)*N + n0 + row];
      const float* src = &inT[((size_t)b*N + m)*192 + inOff + ch*32];
#pragma unroll
      for (int j=0;j<8;j++) g[j] = ld4(src + j*4);
    }
    float acc[32];
#pragma unroll
    for (int i=0;i<32;i++) acc[i] = base[i];
    for (int c=0;c<64;c++){
      float4 w0 = ld4(&w1T[c*64+o0]), w1v = ld4(&w1T[c*64+o0+4]);
      float4 av = ld4(&aT[w][c*32+r0]);
      float wv[8] = {w0.x,w0.y,w0.z,w0.w,w1v.x,w1v.y,w1v.z,w1v.w};
      float rv[4] = {av.x,av.y,av.z,av.w};
#pragma unroll
      for (int oo=0;oo<8;oo++)
#pragma unroll
        for (int rr=0;rr<4;rr++) acc[oo*4+rr] = fmaf(wv[oo], rv[rr], acc[oo*4+rr]);
    }
    // s1 overwrites aT[w] (gather data dead; wave-local in-order DS keeps ordering)
#pragma unroll
    for (int oo=0;oo<8;oo++){
      float4 sv = make_float4(lrelu(acc[oo*4+0]), lrelu(acc[oo*4+1]), lrelu(acc[oo*4+2]), lrelu(acc[oo*4+3]));
      *(float4*)&aT[w][(o0+oo)*32 + r0] = sv;
    }
    float acc2[32];
#pragma unroll
    for (int i=0;i<32;i++) acc2[i]=0.f;
    for (int c=0;c<64;c++){
      float4 w0 = ld4(&w2T[c*64+o0]), w1v = ld4(&w2T[c*64+o0+4]);
      float4 av = ld4(&aT[w][c*32+r0]);
      float wv[8] = {w0.x,w0.y,w0.z,w0.w,w1v.x,w1v.y,w1v.z,w1v.w};
      float rv[4] = {av.x,av.y,av.z,av.w};
#pragma unroll
      for (int oo=0;oo<8;oo++)
#pragma unroll
        for (int rr=0;rr<4;rr++) acc2[oo*4+rr] = fmaf(wv[oo], rv[rr], acc2[oo*4+rr]);
    }
#pragma unroll
    for (int i=0;i<32;i++) mx[i] = fmaxf(mx[i], lrelu(acc2[i]));
  }
  __syncthreads();                  // all waves done with aT -> reuse as merge stash
#pragma unroll
  for (int rr=0;rr<4;rr++){
    float4 a = make_float4(mx[0*4+rr], mx[1*4+rr], mx[2*4+rr], mx[3*4+rr]);
    float4 bq = make_float4(mx[4*4+rr], mx[5*4+rr], mx[6*4+rr], mx[7*4+rr]);
    *(float4*)&aT[w][(r0+rr)*64 + o0] = a;
    *(float4*)&aT[w][(r0+rr)*64 + o0 + 4] = bq;
  }
  __syncthreads();
  for (int i=tid; i<2048; i+=256){
    float v = fmaxf(fmaxf(aT[0][i], aT[1][i]), fmaxf(aT[2][i], aT[3][i]));
    int r = i>>6, o = i&63;
    catT[((size_t)b*N + n0 + r)*192 + outOff + o] = v;
  }
}

// ---- edgeD: 64ch -> 64 (single conv), max over k ----
// v4 (R12 champion): 4 waves/block, it<10 -> all 40 neighbors; merge via wdT/w1T stash.
__global__ __launch_bounds__(256) void edgeD_kernel(
    const float* __restrict__ inT, int inOff, const int* __restrict__ idxT,
    const float* __restrict__ w1, float* __restrict__ catT, int outOff, int N){
  __shared__ float w1T[64*64];
  __shared__ float wdT[64*64];
  __shared__ float aT[4][64*32];
  const int tid = threadIdx.x, w = tid>>6, lane = tid&63;
  const int oq = lane&7, rg = lane>>3;
  const int o0 = oq*8, r0 = rg*4;
  const int b = blockIdx.y, n0 = blockIdx.x*32;
  for (int i=tid; i<64*64; i+=256){
    int o = i>>6, c = i&63;
    float a = w1[o*128+c], bb = w1[o*128+64+c];
    w1T[c*64+o] = a; wdT[c*64+o] = bb - a;
  }
  for (int i=tid; i<512; i+=256){
    int p = i>>4, cq = i&15;
    float4 v = ld4(&inT[((size_t)b*N + n0 + p)*192 + inOff + cq*4]);
    aT[0][(cq*4+0)*32+p] = v.x; aT[0][(cq*4+1)*32+p] = v.y;
    aT[0][(cq*4+2)*32+p] = v.z; aT[0][(cq*4+3)*32+p] = v.w;
  }
  __syncthreads();
  float base[32];
#pragma unroll
  for (int i=0;i<32;i++) base[i]=0.f;
  for (int c=0;c<64;c++){
    float4 w0 = ld4(&wdT[c*64+o0]), w1v = ld4(&wdT[c*64+o0+4]);
    float4 av = ld4(&aT[0][c*32+r0]);
    float wv[8] = {w0.x,w0.y,w0.z,w0.w,w1v.x,w1v.y,w1v.z,w1v.w};
    float rv[4] = {av.x,av.y,av.z,av.w};
#pragma unroll
    for (int oo=0;oo<8;oo++)
#pragma unroll
      for (int rr=0;rr<4;rr++) base[oo*4+rr] = fmaf(wv[oo], rv[rr], base[oo*4+rr]);
  }
  __syncthreads();
  float mx[32];
#pragma unroll
  for (int i=0;i<32;i++) mx[i] = -__builtin_inff();
  const int row = lane&31, ch = lane>>5;
  float4 g[8];
  {
    int m = idxT[((size_t)b*KNN + w)*N + n0 + row];
    const float* src = &inT[((size_t)b*N + m)*192 + inOff + ch*32];
#pragma unroll
    for (int j=0;j<8;j++) g[j] = ld4(src + j*4);
  }
  for (int it=0; it<10; it++){
#pragma unroll
    for (int j=0;j<8;j++){
      aT[w][(ch*32+j*4+0)*32 + row] = g[j].x;
      aT[w][(ch*32+j*4+1)*32 + row] = g[j].y;
      aT[w][(ch*32+j*4+2)*32 + row] = g[j].z;
      aT[w][(ch*32+j*4+3)*32 + row] = g[j].w;
    }
    if (it+1 < 10){
      int m = idxT[((size_t)b*KNN + (it+1)*4 + w)*N + n0 + row];
      const float* src = &inT[((size_t)b*N + m)*192 + inOff + ch*32];
#pragma unroll
      for (int j=0;j<8;j++) g[j] = ld4(src + j*4);
    }
    float acc[32];
#pragma unroll
    for (int i=0;i<32;i++) acc[i] = base[i];
    for (int c=0;c<64;c++){
      float4 w0 = ld4(&w1T[c*64+o0]), w1v = ld4(&w1T[c*64+o0+4]);
      float4 av = ld4(&aT[w][c*32+r0]);
      float wv[8] = {w0.x,w0.y,w0.z,w0.w,w1v.x,w1v.y,w1v.z,w1v.w};
      float rv[4] = {av.x,av.y,av.z,av.w};
#pragma unroll
      for (int oo=0;oo<8;oo++)
#pragma unroll
        for (int rr=0;rr<4;rr++) acc[oo*4+rr] = fmaf(wv[oo], rv[rr], acc[oo*4+rr]);
    }
#pragma unroll
    for (int i=0;i<32;i++) mx[i] = fmaxf(mx[i], lrelu(acc[i]));
  }
  __syncthreads();   // all waves done reading w1T/wdT -> reuse as merge stash
  {
    float* stash = (w < 2) ? &wdT[w*2048] : &w1T[(w-2)*2048];
#pragma unroll
    for (int rr=0;rr<4;rr++){
      float4 a = make_float4(mx[0*4+rr], mx[1*4+rr], mx[2*4+rr], mx[3*4+rr]);
      float4 bq = make_float4(mx[4*4+rr], mx[5*4+rr], mx[6*4+rr], mx[7*4+rr]);
      *(float4*)&stash[(r0+rr)*64 + o0] = a;
      *(float4*)&stash[(r0+rr)*64 + o0 + 4] = bq;
    }
  }
  __syncthreads();
  for (int i=tid; i<2048; i+=256){
    float v = fmaxf(fmaxf(wdT[i], wdT[2048+i]), fmaxf(w1T[i], w1T[2048+i]));
    int r = i>>6, o = i&63;
    catT[((size_t)b*N + n0 + r)*192 + outOff + o] = v;
  }
}

// ---------------- conv1 (1024 outs) + lrelu + max ----------------
// v5: ish c-chunked to 64 (wave-private; no extra barriers). LDS: CIN=128 ->
// 16K wsh + 16K ish = 32KB -> 5 blocks/CU (10 waves, was 6); CIN=192 -> 24K+16K
// = 40KB -> 4 blocks/CU (8 waves, was 4). acc accumulates across ascending
// chunks -> same per-output c-order -> bit-exact.
template<int CIN, int TAG>
__global__ __launch_bounds__(128) void convmax_kernel(
    const float* __restrict__ inT, const float* __restrict__ wT,
    float* __restrict__ partial, int N){
  __shared__ float wsh[CIN*32];
  __shared__ float ish[2][32*64];   // per-wave staging, one 64-ch chunk
  const int tid = threadIdx.x, w = tid>>6, lane = tid&63;
  const int oq = lane&7, rg = lane>>3;
  const int o0 = oq*4;
  const int b = blockIdx.z, oc = blockIdx.x, nt = blockIdx.y;
  for (int i=tid; i<CIN*32; i+=128){
    int c = i>>5, o = i&31;
    wsh[i] = wT[(size_t)c*1024 + oc*32 + o];
  }
  __syncthreads();                  // wsh ready; ish is wave-private afterwards
  float mx[16];
#pragma unroll
  for (int i=0;i<16;i++) mx[i] = -__builtin_inff();
  const int nbase = nt*(N/8);
  float* mish = ish[w];
  for (int it=0; it<4; it++){
    const int st = it*2 + w;        // wave w handles tiles {w, w+2, w+4, w+6}
    const float* src = inT + ((size_t)b*N + nbase + st*32)*CIN;
    float acc[16];
#pragma unroll
    for (int i=0;i<16;i++) acc[i]=0.f;
    for (int chn=0; chn<CIN/64; chn++){
      const int cc0 = chn*64;
      for (int i=lane; i<32*16; i+=64){
        int p = i/16, cq = i%16;
        float4 v = ld4(src + p*CIN + cc0 + 4*cq);
        int base = (((p>>2) ^ (cq&7))<<2) + (p&3);
        mish[(4*cq+0)*32 + base] = v.x;
        mish[(4*cq+1)*32 + base] = v.y;
        mish[(4*cq+2)*32 + base] = v.z;
        mish[(4*cq+3)*32 + base] = v.w;
      }
      for (int c=0;c<64;c++){
        float4 w0 = ld4(&wsh[(cc0+c)*32+o0]);
        float4 av = ld4(&mish[c*32 + ((rg ^ ((c>>2)&7))<<2)]);
        float wv[4] = {w0.x,w0.y,w0.z,w0.w};
        float rv[4] = {av.x,av.y,av.z,av.w};
#pragma unroll
        for (int oo=0;oo<4;oo++)
#pragma unroll
          for (int rr=0;rr<4;rr++) acc[oo*4+rr] = fmaf(wv[oo], rv[rr], acc[oo*4+rr]);
      }
    }
#pragma unroll
    for (int i=0;i<16;i++) mx[i] = fmaxf(mx[i], lrelu(acc[i]));
  }
  float m4[4];
#pragma unroll
  for (int oo=0;oo<4;oo++)
    m4[oo] = fmaxf(fmaxf(mx[oo*4+0], mx[oo*4+1]), fmaxf(mx[oo*4+2], mx[oo*4+3]));
  __syncthreads();                  // both waves done with their ish -> reuse ish[0] as merge buffer
  float* mb = ish[0];
  *(float4*)&mb[(w*8+rg)*32 + o0] = make_float4(m4[0],m4[1],m4[2],m4[3]);
  __syncthreads();
  if (tid < 32){
    float v = -__builtin_inff();
#pragma unroll
    for (int g=0; g<16; g++) v = fmaxf(v, mb[g*32+tid]);
    partial[((size_t)b*8 + nt)*1024 + oc*32 + tid] = v;
  }
}

template<int TAG>
__global__ void reduce_max_kernel(const float* __restrict__ partial, float* __restrict__ out){
  int b = blockIdx.y; int o = blockIdx.x*256 + threadIdx.x;
  float v = -__builtin_inff();
  for (int s=0;s<8;s++) v = fmaxf(v, partial[((size_t)b*8 + s)*1024 + o]);
  out[(size_t)b*1024 + o] = v;
}

// ---------------- fused t-net MLP: 1024 ->512 ->256 ->9 (one launch) ----------------
__global__ __launch_bounds__(512) void tnet_fc_kernel(
    const float* __restrict__ tg, const float* __restrict__ t_f1,
    const float* __restrict__ t_f2, const float* __restrict__ t_f3w,
    const float* __restrict__ t_f3b, float* __restrict__ T9){
  const int b = blockIdx.x, tid = threadIdx.x;
  __shared__ float in1[1024];
  __shared__ float h512[512];
  __shared__ float h256[256];
  for (int i=tid;i<1024;i+=512) in1[i] = tg[(size_t)b*1024+i];
  __syncthreads();
  {
    float s = 0.f;
    for (int c=0;c<1024;c++) s = fmaf(t_f1[(size_t)tid*1024+c], in1[c], s);
    h512[tid] = lrelu(s);
  }
  __syncthreads();
  if (tid < 256){
    float s = 0.f;
    for (int c=0;c<512;c++) s = fmaf(t_f2[(size_t)tid*512+c], h512[c], s);
    h256[tid] = lrelu(s);
  }
  __syncthreads();
  if (tid < 9){
    float s = t_f3b[tid];
    for (int c=0;c<256;c++) s = fmaf(t_f3w[(size_t)tid*256+c], h256[c], s);
    T9[(size_t)b*9+tid] = s;     // stride 9: transform_kernel reads T9 + b*9
  }
}

// ---------------- x' = T^T x per batch ----------------
__global__ void transform_kernel(const float* __restrict__ x, const float* __restrict__ T9,
                                 float* __restrict__ xp, int N){
  int b = blockIdx.y; int n = blockIdx.x*256 + threadIdx.x;
  const float* t = T9 + (size_t)b*9;
  float x0=x[((size_t)b*3+0)*N+n], x1=x[((size_t)b*3+1)*N+n], x2=x[((size_t)b*3+2)*N+n];
#pragma unroll
  for (int i=0;i<3;i++)
    xp[((size_t)b*3+i)*N+n] = t[i]*x0 + t[3+i]*x1 + t[6+i]*x2;
}

// ---------------- bias1: n-invariant part of h1 (lv = fc(l,m2) fused in) ----------------
__global__ void bias1_kernel(const float* __restrict__ g, const float* __restrict__ l,
                             const float* __restrict__ m2, const float* __restrict__ h1w,
                             float* __restrict__ bias1){
  int b = blockIdx.x;
  __shared__ float insh[1088];
  for (int i=threadIdx.x;i<1024;i+=256) insh[i] = g[(size_t)b*1024+i];
  if (threadIdx.x < 64){
    int o = threadIdx.x;
    float s = 0.f;
    for (int c=0;c<16;c++) s = fmaf(m2[(size_t)o*16+c], l[(size_t)b*16+c], s);
    insh[1024+o] = lrelu(s);
  }
  __syncthreads();
  int o = threadIdx.x;
  float s=0.f;
  for (int c=0;c<1088;c++) s = fmaf(h1w[(size_t)o*1280+c], insh[c], s);
  bias1[(size_t)b*256+o]=s;
}

// ---------------- head conv layers -- register-tiled (R13 champion) ----------------
template<int CI, int O, bool ACT>
__global__ __launch_bounds__(128) void conv1_kernel(
    const float* __restrict__ inT, const float* __restrict__ wT,
    const float* __restrict__ bias, float* __restrict__ outT, int N){
  constexpr int CCH = 64;
  constexpr int NCH = CI / CCH;     // 192->3, 256->4
  __shared__ float wsh[CCH*128];    // [c][128 outputs]
  __shared__ float ish[32*CCH];     // [c][32], XOR-swizzled 4-col groups
  const int tid = threadIdx.x, w = tid>>6, lane = tid&63;
  const int o0 = (lane&15)*8;                 // 16 o-groups x 8 = 128 outputs
  const int r0 = w*16 + (lane>>4)*4;          // 4 row-groups x 4 = 16 rows per wave
  const int b = blockIdx.y, n0 = blockIdx.x*32, oc = blockIdx.z;
  const float* src = inT + ((size_t)b*N + n0)*CI;
  float acc[32];
#pragma unroll
  for (int i=0;i<32;i++) acc[i]=0.f;
  for (int ch=0; ch<NCH; ch++){
    const int cc0 = ch*CCH;
    if (ch) __syncthreads();        // prev chunk's compute done before restage
    for (int i=tid; i<CCH*128; i+=128){
      int c = i>>7, od = i&127;
      wsh[i] = wT[(size_t)(cc0+c)*O + oc*128 + od];
    }
    for (int i=tid; i<32*(CCH/4); i+=128){
      int p = i/(CCH/4), cq = i%(CCH/4);
      float4 v = ld4(src + p*CI + cc0 + 4*cq);
      int base = (((p>>2) ^ (cq&7))<<2) + (p&3);
      ish[(4*cq+0)*32 + base] = v.x;
      ish[(4*cq+1)*32 + base] = v.y;
      ish[(4*cq+2)*32 + base] = v.z;
      ish[(4*cq+3)*32 + base] = v.w;
    }
    __syncthreads();
    for (int c=0;c<CCH;c++){
      float4 w0 = ld4(&wsh[c*128+o0]), w1v = ld4(&wsh[c*128+o0+4]);
      float4 av = ld4(&ish[c*32 + (((r0>>2) ^ ((c>>2)&7))<<2)]);   // r0 multiple of 4
      float wv[8] = {w0.x,w0.y,w0.z,w0.w,w1v.x,w1v.y,w1v.z,w1v.w};
      float rv[4] = {av.x,av.y,av.z,av.w};
#pragma unroll
      for (int oo=0;oo<8;oo++)
#pragma unroll
        for (int rr=0;rr<4;rr++) acc[oo*4+rr] = fmaf(wv[oo], rv[rr], acc[oo*4+rr]);
    }
  }
  float bv[8];
  if (bias){
    float4 b0 = ld4(&bias[(size_t)b*O + oc*128 + o0]);
    float4 b1 = ld4(&bias[(size_t)b*O + oc*128 + o0 + 4]);
    bv[0]=b0.x; bv[1]=b0.y; bv[2]=b0.z; bv[3]=b0.w;
    bv[4]=b1.x; bv[5]=b1.y; bv[6]=b1.z; bv[7]=b1.w;
  } else {
#pragma unroll
    for (int i=0;i<8;i++) bv[i]=0.f;
  }
#pragma unroll
  for (int rr=0;rr<4;rr++){
    float oa[8];
#pragma unroll
    for (int oo=0;oo<8;oo++){
      float s = acc[oo*4+rr] + bv[oo];
      oa[oo] = ACT ? lrelu(s) : s;
    }
    float* dst = &outT[((size_t)b*N + n0 + r0 + rr)*O + oc*128 + o0];
    *(float4*)dst     = make_float4(oa[0],oa[1],oa[2],oa[3]);
    *(float4*)(dst+4) = make_float4(oa[4],oa[5],oa[6],oa[7]);
  }
}

// ---------------- final layer: 128 -> 50, rows-layout output (B,50,N) ----------------
__global__ __launch_bounds__(256) void conv_out_kernel(
    const float* __restrict__ inT, const float* __restrict__ wT,
    float* __restrict__ out, int N){
  const int b = blockIdx.y, n0 = blockIdx.x*32;
  __shared__ float insh[32*129];
  const float* src = inT + ((size_t)b*N + n0)*128;
  for (int i=threadIdx.x;i<32*128;i+=256){ int nn=i>>7, c=i&127; insh[nn*129+c]=src[i]; }
  __syncthreads();
  const int nl = threadIdx.x & 31, og = threadIdx.x >> 5;
  float acc[7];
#pragma unroll
  for (int t=0;t<7;t++) acc[t]=0.f;
  for (int c=0;c<128;c++){
    float iv = insh[nl*129+c];
#pragma unroll
    for (int t=0;t<7;t++){
      int o = og + 8*t;
      float wv = (o<50)? wT[c*50+o] : 0.f;
      acc[t] = fmaf(wv, iv, acc[t]);
    }
  }
#pragma unroll
  for (int t=0;t<7;t++){
    int o = og + 8*t;
    if (o < 50) out[((size_t)b*50+o)*N + n0 + nl] = acc[t];
  }
}

extern "C" void kernel_launch(void* const* d_in, const int* in_sizes, int n_in,
                              void* d_out, int out_size, void* d_ws, size_t ws_size,
                              hipStream_t stream){
  const float* x    = (const float*)d_in[0];
  const float* l    = (const float*)d_in[1];
  const float* t_c1 = (const float*)d_in[2];
  const float* t_c2 = (const float*)d_in[3];
  const float* t_c3 = (const float*)d_in[4];
  const float* t_f1 = (const float*)d_in[5];
  const float* t_f2 = (const float*)d_in[6];
  const float* t_f3w= (const float*)d_in[7];
  const float* t_f3b= (const float*)d_in[8];
  const float* b1a  = (const float*)d_in[9];
  const float* b1b  = (const float*)d_in[10];
  const float* b2a  = (const float*)d_in[11];
  const float* b2b  = (const float*)d_in[12];
  const float* b3a  = (const float*)d_in[13];
  const float* m1   = (const float*)d_in[14];
  const float* m2   = (const float*)d_in[15];
  const float* h1   = (const float*)d_in[16];
  const float* h2   = (const float*)d_in[17];
  const float* h3   = (const float*)d_in[18];
  const float* h4   = (const float*)d_in[19];
  float* out = (float*)d_out;
  float* ws = (float*)d_ws;
  const int N = NPTS, B = BATCH;

  size_t off = 0;
  auto alloc = [&](size_t nf){ float* p = ws + off; off += nf; return p; };
  float* WT_TC3 = alloc((size_t)128*1024);
  float* WT_M1  = alloc((size_t)192*1024);
  float* WT_H1B = alloc((size_t)192*256);
  float* WT_H2  = alloc((size_t)256*256);
  float* WT_H3  = alloc((size_t)256*128);
  float* WT_H4  = alloc((size_t)128*64);
  int*   IDXT   = (int*)alloc((size_t)B*N*KNN);
  float* XX     = alloc((size_t)B*N);
  float* TT     = alloc((size_t)B*N*128);
  float* PARTIAL= alloc((size_t)B*8*1024);
  float* TG     = alloc((size_t)B*1024);
  float* T9     = alloc((size_t)B*16);
  float* XP     = alloc((size_t)B*3*N);
  float* CATT   = alloc((size_t)B*N*192);
  float* G      = alloc((size_t)B*1024);
  float* BIAS1  = alloc((size_t)B*256);
  float* H1T    = alloc((size_t)B*N*256);
  float* H2T    = alloc((size_t)B*N*256);
  float* H3T    = alloc((size_t)B*N*128);
  (void)ws_size; (void)in_sizes; (void)n_in; (void)out_size;

  dim3 blk(256);
  dim3 eblk(128);
  // all 6 weight transposes in one launch
  transpose6_kernel<<<dim3(768,6), blk, 0, stream>>>(
      t_c3, WT_TC3, m1, WT_M1, h1, WT_H1B, h2, WT_H2, h3, WT_H3, h4, WT_H4);

  // t-path
  norms_rows_kernel<0><<<dim3(N/256,B), blk, 0, stream>>>(x, XX, N);
  knn3_kernel<0><<<dim3(N/4,B), blk, 0, stream>>>(x, XX, IDXT, N);
  edgeA_kernel<<<dim3(N/16,B), blk, 0, stream>>>(x, IDXT, t_c1, t_c2, TT, N);
  convmax_kernel<128,0><<<dim3(32,8,B), eblk, 0, stream>>>(TT, WT_TC3, PARTIAL, N);
  reduce_max_kernel<0><<<dim3(4,B), blk, 0, stream>>>(PARTIAL, TG);
  tnet_fc_kernel<<<dim3(B), dim3(512), 0, stream>>>(TG, t_f1, t_f2, t_f3w, t_f3b, T9);
  transform_kernel<<<dim3(N/256,B), blk, 0, stream>>>(x, T9, XP, N);

  // edge block 1 (transformed points, 3ch)
  norms_rows_kernel<1><<<dim3(N/256,B), blk, 0, stream>>>(XP, XX, N);
  knn3_kernel<1><<<dim3(N/4,B), blk, 0, stream>>>(XP, XX, IDXT, N);
  edgeB_kernel<<<dim3(N/32,B), dim3(256), 0, stream>>>(XP, IDXT, b1a, b1b, CATT, N);

  // edge block 2 (x1 = CATT[...,0:64])
  norms_cl_kernel<0><<<dim3(N/256,B), blk, 0, stream>>>(CATT, 0, XX, N);
  knn64_kernel<0><<<dim3(N/4,B), blk, 0, stream>>>(CATT, 0, XX, IDXT, N);
  edgeC_kernel<<<dim3(N/32,B), dim3(256), 0, stream>>>(CATT, 0, IDXT, b2a, b2b, CATT, 64, N);

  // edge block 3 (x2 = CATT[...,64:128])
  norms_cl_kernel<1><<<dim3(N/256,B), blk, 0, stream>>>(CATT, 64, XX, N);
  knn64_kernel<1><<<dim3(N/4,B), blk, 0, stream>>>(CATT, 64, XX, IDXT, N);
  edgeD_kernel<<<dim3(N/32,B), dim3(256), 0, stream>>>(CATT, 64, IDXT, b3a, CATT, 128, N);

  // global feature + head
  convmax_kernel<192,1><<<dim3(32,8,B), eblk, 0, stream>>>(CATT, WT_M1, PARTIAL, N);
  reduce_max_kernel<1><<<dim3(4,B), blk, 0, stream>>>(PARTIAL, G);
  bias1_kernel<<<dim3(B), blk, 0, stream>>>(G, l, m2, h1, BIAS1);
  conv1_kernel<192,256,true><<<dim3(N/32,B,2), eblk, 0, stream>>>(CATT, WT_H1B, BIAS1, H1T, N);
  conv1_kernel<256,256,true><<<dim3(N/32,B,2), eblk, 0, stream>>>(H1T, WT_H2, nullptr, H2T, N);
  conv1_kernel<256,128,true><<<dim3(N/32,B,1), eblk, 0, stream>>>(H2T, WT_H3, nullptr, H3T, N);
  conv_out_kernel<<<dim3(N/32,B), blk, 0, stream>>>(H3T, WT_H4, out, N);
}

// Round 16
// 1970.194 us; speedup vs baseline: 1.2825x; 1.0036x over previous
//
#include <hip/hip_runtime.h>
#include <cstdint>

#define NPTS 2048
#define BATCH 8
#define KNN 40

__device__ __forceinline__ float lrelu(float v){ return fmaxf(v, 0.2f*v); }
__device__ __forceinline__ bool better(float v1,int i1,float v2,int i2){
  return (v1>v2) || (v1==v2 && i1<i2);
}
__device__ __forceinline__ float4 ld4(const float* p){ return *(const float4*)p; }

// order-preserving bijection float<->uint: max over encodings == encoding of max (exact)
#define ENC_NEGINF 0x007FFFFFu
__device__ __forceinline__ unsigned encf(float f){
  unsigned u = __float_as_uint(f);
  return (u & 0x80000000u) ? ~u : (u | 0x80000000u);
}
__device__ __forceinline__ float decf(unsigned u){
  return __uint_as_float((u & 0x80000000u) ? (u & 0x7FFFFFFFu) : ~u);
}

// insert (d,m) into sorted-desc 8-list if it beats the tail; static CE chain.
#define INSERT8(v,id,d,m) \
  if (better(d, m, v[7], id[7])){ \
    v[7]=d; id[7]=m; \
    { if (better(v[7],id[7],v[6],id[6])){ float tv=v[6];int ti=id[6]; v[6]=v[7];id[6]=id[7]; v[7]=tv;id[7]=ti; } } \
    { if (better(v[6],id[6],v[5],id[5])){ float tv=v[5];int ti=id[5]; v[5]=v[6];id[5]=id[6]; v[6]=tv;id[6]=ti; } } \
    { if (better(v[5],id[5],v[4],id[4])){ float tv=v[4];int ti=id[4]; v[4]=v[5];id[4]=id[5]; v[5]=tv;id[5]=ti; } } \
    { if (better(v[4],id[4],v[3],id[3])){ float tv=v[3];int ti=id[3]; v[3]=v[4];id[3]=id[4]; v[4]=tv;id[4]=ti; } } \
    { if (better(v[3],id[3],v[2],id[2])){ float tv=v[2];int ti=id[2]; v[2]=v[3];id[2]=id[3]; v[3]=tv;id[3]=ti; } } \
    { if (better(v[2],id[2],v[1],id[1])){ float tv=v[1];int ti=id[1]; v[1]=v[2];id[1]=id[2]; v[2]=tv;id[2]=ti; } } \
    { if (better(v[1],id[1],v[0],id[0])){ float tv=v[0];int ti=id[0]; v[0]=v[1];id[0]=id[1]; v[1]=tv;id[1]=ti; } } \
  }

// ---------------- fused weight transposes + encoded-max buffer init (7 jobs, 1 launch) ----------------
__global__ void transpose6_kernel(
    const float* __restrict__ s0, float* __restrict__ d0,
    const float* __restrict__ s1, float* __restrict__ d1,
    const float* __restrict__ s2, float* __restrict__ d2,
    const float* __restrict__ s3, float* __restrict__ d3,
    const float* __restrict__ s4, float* __restrict__ d4,
    const float* __restrict__ s5, float* __restrict__ d5,
    unsigned* __restrict__ tgE, unsigned* __restrict__ gE){
  int i = blockIdx.x*256 + threadIdx.x;
  if (blockIdx.y == 6){
    if (i < 8192) tgE[i] = ENC_NEGINF;
    else if (i < 16384) gE[i-8192] = ENC_NEGINF;
    return;
  }
  const float* src; float* dst; int R,C,ld,off;
  switch (blockIdx.y){
    case 0:  src=s0; dst=d0; R=1024; C=128; ld=128;  off=0;    break;
    case 1:  src=s1; dst=d1; R=1024; C=192; ld=192;  off=0;    break;
    case 2:  src=s2; dst=d2; R=256;  C=192; ld=1280; off=1088; break;
    case 3:  src=s3; dst=d3; R=256;  C=256; ld=256;  off=0;    break;
    case 4:  src=s4; dst=d4; R=128;  C=256; ld=256;  off=0;    break;
    default: src=s5; dst=d5; R=50;   C=128; ld=128;  off=0;    break;
  }
  if (i < R*C){ int r = i / C, c = i % C; dst[c*R + r] = src[r*ld + off + c]; }
}

// ---------------- squared norms, rows layout (B,3,N) ----------------
template<int TAG>
__global__ void norms_rows_kernel(const float* __restrict__ x, float* __restrict__ xx, int N){
  int b = blockIdx.y; int n = blockIdx.x*256 + threadIdx.x;
  const float* xb = x + (size_t)b*3*N;
  float v0 = xb[n], v1 = xb[N+n], v2 = xb[2*N+n];
  xx[(size_t)b*N + n] = v0*v0 + v1*v1 + v2*v2;
}

// ---------------- squared norms, channel-last 64ch slice of (B,N,192) ----------------
template<int TAG>
__global__ void norms_cl_kernel(const float* __restrict__ f, int off, float* __restrict__ xx, int N){
  int b = blockIdx.y; int n = blockIdx.x*256 + threadIdx.x;
  const float4* p = (const float4*)(f + ((size_t)b*N + n)*192 + off);
  float s = 0.f;
#pragma unroll
  for (int q=0;q<16;q++){ float4 v = p[q]; s += v.x*v.x + v.y*v.y + v.z*v.z + v.w*v.w; }
  xx[(size_t)b*N + n] = s;
}

__device__ __forceinline__ void sort8(float (&v)[8], int (&id)[8]){
#define CE(a,bq) { if (better(v[bq],id[bq],v[a],id[a])){ float tv=v[a]; int ti=id[a]; v[a]=v[bq]; id[a]=id[bq]; v[bq]=tv; id[bq]=ti; } }
  CE(0,1) CE(2,3) CE(4,5) CE(6,7)
  CE(0,2) CE(1,3) CE(4,6) CE(5,7)
  CE(1,2) CE(5,6)
  CE(0,4) CE(1,5) CE(2,6) CE(3,7)
  CE(2,4) CE(3,5)
  CE(1,2) CE(3,4) CE(5,6)
#undef CE
}

// ---------------- knn 3-channel: 4 queries/block (1/wave), zero LDS, zero barriers ----------------
template<int TAG>
__global__ __launch_bounds__(256) void knn3_kernel(
    const float* __restrict__ xrows, const float* __restrict__ xx,
    int* __restrict__ idxT, int N){
  const int b = blockIdx.y, tid = threadIdx.x;
  const int w = tid>>6, lane = tid&63;
  const int nq = blockIdx.x*4 + w;
  const float* xb = xrows + (size_t)b*3*N;
  const float* xxb = xx + (size_t)b*N;
  float c0 = xb[nq], c1 = xb[N+nq], c2 = xb[2*N+nq];
  float xxn = xxb[nq];
  float v[8]; int id[8];
#pragma unroll
  for (int j=0;j<8;j++){ v[j]=-__builtin_inff(); id[j]=0x7FFFFFFF; }
  for (int j=0;j<32;j++){
    int m = j*64 + lane;
    float s = c0*xb[m] + c1*xb[N+m] + c2*xb[2*N+m];
    float d = 2.f*s - xxn - xxb[m];
    INSERT8(v, id, d, m)
  }
  float lastv = 0.f; int lasti = 0;
  int win = 0;
  for (int r=0;r<KNN;r++){
    float bv = v[0]; int bi = id[0];
#pragma unroll
    for (int off=32; off; off>>=1){
      float ov = __shfl_xor(bv, off);
      int   oi = __shfl_xor(bi, off);
      if (better(ov, oi, bv, bi)){ bv = ov; bi = oi; }
    }
    if (lane == r) win = bi;
    if (id[0] == bi){
      lastv = v[0]; lasti = id[0];
#pragma unroll
      for (int j=0;j<7;j++){ v[j]=v[j+1]; id[j]=id[j+1]; }
      v[7] = -__builtin_inff(); id[7] = 0x7FFFFFFF;
      if (id[0] == 0x7FFFFFFF){   // rare refill: best strictly worse than last pop
        float nv = -__builtin_inff(); int ni = 0x7FFFFFFF;
        for (int j=0;j<32;j++){
          int m = j*64 + lane;
          float s = c0*xb[m] + c1*xb[N+m] + c2*xb[2*N+m];
          float dd = 2.f*s - xxn - xxb[m];
          if (better(lastv, lasti, dd, m) && better(dd, m, nv, ni)){ nv=dd; ni=m; }
        }
        v[0] = nv; id[0] = ni;
      }
    }
  }
  if (lane < KNN) idxT[((size_t)b*KNN + lane)*N + nq] = win;
}

// ---------------- knn 64-channel (channel-last), 4 queries/block ----------------
// v6 (R5 champion): 32-cand tile (8 KiB) + 4x8K strips = 40960 B -> 16 waves/CU.
template<int TAG>
__global__ __launch_bounds__(256) void knn64_kernel(
    const float* __restrict__ featT, int featOff,
    const float* __restrict__ xx, int* __restrict__ idxT, int N){
  const int b = blockIdx.y, tid = threadIdx.x;
  const int w = tid>>6, lane = tid&63;
  __shared__ float cand[32*64];    // xor-swizzled [cand][ch] tile (8 KiB), block-shared
  __shared__ float dist[4*2048];   // wave-private strips (32 KiB)
  const float* fb = featT + featOff;
  const float* xxb = xx + (size_t)b*N;
  const int nq = blockIdx.x*4 + w;
  const int h = lane>>5;           // channel half this lane covers
  float4 ctr8[8];
  {
    const float4* cp = (const float4*)(fb + ((size_t)b*N + nq)*192);
#pragma unroll
    for (int q=0;q<8;q++) ctr8[q] = cp[h*8 + q];
  }
  float xxn = xxb[nq];
  float* dw = &dist[w*2048];
  float4 g[2];
#pragma unroll
  for (int r=0;r<2;r++){
    int k2 = tid + 256*r;
    int c = k2>>4, f = k2&15;
    g[r] = ld4(&fb[((size_t)b*N + c)*192 + 4*f]);
  }
  const int cc = lane&31, swz = cc&15, qb = h*8;
  for (int t=0;t<64;t++){
    __syncthreads();                 // prev compute done reading cand
#pragma unroll
    for (int r=0;r<2;r++){
      int k2 = tid + 256*r;
      int c = k2>>4, f = k2&15;
      *(float4*)&cand[(c<<6) + ((f ^ (c&15))<<2)] = g[r];
    }
    __syncthreads();
    if (t+1 < 64){                   // issue next tile's loads; latency overlaps compute
      int m0n = (t+1)*32;
#pragma unroll
      for (int r=0;r<2;r++){
        int k2 = tid + 256*r;
        int c = k2>>4, f = k2&15;
        g[r] = ld4(&fb[((size_t)b*N + m0n + c)*192 + 4*f]);
      }
    }
    float s0=0.f,s1=0.f,s2=0.f,s3=0.f;
#pragma unroll
    for (int j=0;j<8;j++){
      float4 mv = *(const float4*)&cand[(cc<<6) + (((qb + j) ^ swz)<<2)];
      s0 = fmaf(ctr8[j].x, mv.x, s0);
      s1 = fmaf(ctr8[j].y, mv.y, s1);
      s2 = fmaf(ctr8[j].z, mv.z, s2);
      s3 = fmaf(ctr8[j].w, mv.w, s3);
    }
    float p = (s0+s1)+(s2+s3);
    float tot = p + __shfl_xor(p, 32);    // combine channel halves (commutative -> both halves identical)
    if (h == (t&1)){                      // owner lane (m & 63 == lane) writes its strip slot
      int m = t*32 + cc;
      dw[(t>>1)*64 + lane] = 2.f*tot - xxn - xxb[m];
    }
  }
  // ---- per-lane exact top-8 of its 32 entries (sorted desc by (v desc, idx asc)) ----
  float v[8]; int id[8];
#pragma unroll
  for (int j=0;j<8;j++){ v[j]=dw[j*64+lane]; id[j]=j*64+lane; }
  sort8(v, id);
#pragma unroll
  for (int gq=1; gq<4; gq++){
    float a[8]; int ai[8];
#pragma unroll
    for (int j=0;j<8;j++){ a[j]=dw[(gq*8+j)*64+lane]; ai[j]=(gq*8+j)*64+lane; }
    sort8(a, ai);
    float m_[8]; int mi_[8];
#pragma unroll
    for (int k=0;k<8;k++){
      if (better(a[7-k], ai[7-k], v[k], id[k])){ m_[k]=a[7-k]; mi_[k]=ai[7-k]; }
      else                                     { m_[k]=v[k];   mi_[k]=id[k]; }
    }
#define CEB(x,y) { if (better(m_[y],mi_[y],m_[x],mi_[x])){ float tv=m_[x];int ti=mi_[x]; m_[x]=m_[y];mi_[x]=mi_[y]; m_[y]=tv;mi_[y]=ti; } }
    CEB(0,4) CEB(1,5) CEB(2,6) CEB(3,7)
    CEB(0,2) CEB(1,3) CEB(4,6) CEB(5,7)
    CEB(0,1) CEB(2,3) CEB(4,5) CEB(6,7)
#undef CEB
#pragma unroll
    for (int k=0;k<8;k++){ v[k]=m_[k]; id[k]=mi_[k]; }
  }
  // ---- 40 extraction rounds: butterfly + pop-shift; zero barriers, zero LDS steady state ----
  float lastv = 0.f; int lasti = 0;
  int win = 0;
  for (int r=0;r<KNN;r++){
    float bv = v[0]; int bi = id[0];
#pragma unroll
    for (int off=32; off; off>>=1){
      float ov = __shfl_xor(bv, off);
      int   oi = __shfl_xor(bi, off);
      if (better(ov, oi, bv, bi)){ bv = ov; bi = oi; }
    }
    if (lane == r) win = bi;
    if (id[0] == bi){                // unique owner (indices unique)
      lastv = v[0]; lasti = id[0];
#pragma unroll
      for (int j=0;j<7;j++){ v[j]=v[j+1]; id[j]=id[j+1]; }
      v[7] = -__builtin_inff(); id[7] = 0x7FFFFFFF;
      if (id[0] == 0x7FFFFFFF){      // rare: lane contributed >8 of top-40 -> refill head
        float nv = -__builtin_inff(); int ni = 0x7FFFFFFF;
        for (int j=0;j<32;j++){
          float vv = dw[j*64 + lane]; int m = j*64 + lane;
          if (better(lastv, lasti, vv, m) && better(vv, m, nv, ni)){ nv=vv; ni=m; }
        }
        v[0] = nv; id[0] = ni;
      }
    }
  }
  if (lane < KNN) idxT[((size_t)b*KNN + lane)*N + nq] = win;
}

// ==================== register-tiled edge kernels ====================

// ---- edgeA (t-path): 3ch -> 64 -> 128, max over k ----
__global__ __launch_bounds__(256) void edgeA_kernel(
    const float* __restrict__ x, const int* __restrict__ idxT,
    const float* __restrict__ w1, const float* __restrict__ w2,
    float* __restrict__ tT, int N){
  __shared__ float w1aT[3*64];
  __shared__ float wd3T[3*64];
  __shared__ float w2T[64*128];      // [c][o]; reused as merge buffer (4 x 16r x 128o)
  __shared__ float aT3[4][3*16];
  __shared__ float s1T[4][64*16];    // [c][r]
  const int tid = threadIdx.x, w = tid>>6, lane = tid&63;
  const int oq = lane&7, rg = lane>>3;
  const int o0 = oq*8, r0 = rg*2;
  const int b = blockIdx.y, n0 = blockIdx.x*16;
  for (int i=tid; i<192; i+=256){
    int o = i&63, c = i/64;
    float a = w1[o*6+c];
    w1aT[c*64+o] = a; wd3T[c*64+o] = w1[o*6+3+c] - a;
  }
  for (int i=tid; i<128*64; i+=256){
    int o = i>>6, c = i&63;
    w2T[c*128+o] = w2[o*64+c];
  }
  if (tid < 48){ int c = tid>>4, r = tid&15; aT3[0][c*16+r] = x[((size_t)b*3+c)*N + n0 + r]; }
  __syncthreads();
  float base[16];
#pragma unroll
  for (int i=0;i<16;i++) base[i]=0.f;
#pragma unroll
  for (int c=0;c<3;c++){
    float4 wA = ld4(&wd3T[c*64+o0]), wB = ld4(&wd3T[c*64+o0+4]);
    float2 av = *(const float2*)&aT3[0][c*16+r0];
    float wv[8] = {wA.x,wA.y,wA.z,wA.w,wB.x,wB.y,wB.z,wB.w};
    float rv[2] = {av.x,av.y};
#pragma unroll
    for (int oo=0;oo<8;oo++)
#pragma unroll
      for (int rr=0;rr<2;rr++) base[oo*2+rr] = fmaf(wv[oo], rv[rr], base[oo*2+rr]);
  }
  __syncthreads();   // all waves done reading aT3[0] before k-loop overwrites
  float mx[32];
#pragma unroll
  for (int i=0;i<32;i++) mx[i] = -__builtin_inff();
  for (int it=0; it<10; it++){
    int k = it*4 + w;
    int m = idxT[((size_t)b*KNN + k)*N + n0 + (lane&15)];
    if (lane < 48){ int c = lane>>4; aT3[w][c*16 + (lane&15)] = x[((size_t)b*3+c)*N + m]; }
    // stage1 (64 o x 16 r)
    float acc[16];
#pragma unroll
    for (int i=0;i<16;i++) acc[i] = base[i];
#pragma unroll
    for (int c=0;c<3;c++){
      float4 wA = ld4(&w1aT[c*64+o0]), wB = ld4(&w1aT[c*64+o0+4]);
      float2 av = *(const float2*)&aT3[w][c*16+r0];
      float wv[8] = {wA.x,wA.y,wA.z,wA.w,wB.x,wB.y,wB.z,wB.w};
      float rv[2] = {av.x,av.y};
#pragma unroll
      for (int oo=0;oo<8;oo++)
#pragma unroll
        for (int rr=0;rr<2;rr++) acc[oo*2+rr] = fmaf(wv[oo], rv[rr], acc[oo*2+rr]);
    }
#pragma unroll
    for (int oo=0;oo<8;oo++){
      float2 sv; sv.x = lrelu(acc[oo*2]); sv.y = lrelu(acc[oo*2+1]);
      *(float2*)&s1T[w][(o0+oo)*16 + r0] = sv;
    }
    // stage2 (128 o x 16 r): 4 panels, o = p*32 + oq*4 -> 32 banks, conflict-free
    float acc2[32];
#pragma unroll
    for (int i=0;i<32;i++) acc2[i]=0.f;
    for (int c=0;c<64;c++){
      float2 av = *(const float2*)&s1T[w][c*16 + r0];
#pragma unroll
      for (int p=0;p<4;p++){
        float4 wv = ld4(&w2T[c*128 + p*32 + oq*4]);
        acc2[p*8+0] = fmaf(wv.x, av.x, acc2[p*8+0]);
        acc2[p*8+1] = fmaf(wv.x, av.y, acc2[p*8+1]);
        acc2[p*8+2] = fmaf(wv.y, av.x, acc2[p*8+2]);
        acc2[p*8+3] = fmaf(wv.y, av.y, acc2[p*8+3]);
        acc2[p*8+4] = fmaf(wv.z, av.x, acc2[p*8+4]);
        acc2[p*8+5] = fmaf(wv.z, av.y, acc2[p*8+5]);
        acc2[p*8+6] = fmaf(wv.w, av.x, acc2[p*8+6]);
        acc2[p*8+7] = fmaf(wv.w, av.y, acc2[p*8+7]);
      }
    }
#pragma unroll
    for (int i=0;i<32;i++) mx[i] = fmaxf(mx[i], lrelu(acc2[i]));
  }
  __syncthreads();   // all waves done reading w2T -> reuse as merge buffer
#pragma unroll
  for (int rr=0;rr<2;rr++){
#pragma unroll
    for (int p=0;p<4;p++){
      float4 a = make_float4(mx[p*8+0+rr], mx[p*8+2+rr], mx[p*8+4+rr], mx[p*8+6+rr]);
      *(float4*)&w2T[w*2048 + (r0+rr)*128 + p*32 + oq*4] = a;
    }
  }
  __syncthreads();
  for (int i=tid; i<2048; i+=256){
    float vv = fmaxf(fmaxf(w2T[i], w2T[2048+i]), fmaxf(w2T[4096+i], w2T[6144+i]));
    int r = i>>7, o = i&127;
    tT[((size_t)b*N + n0 + r)*128 + o] = vv;
  }
}

// ---- edgeB: 3ch -> 64 -> 64, max over k ----
// v4 (R12 champion): 4 waves/block, k = it*4 + w, it<10 -> all 40 neighbors.
__global__ __launch_bounds__(256) void edgeB_kernel(
    const float* __restrict__ xp, const int* __restrict__ idxT,
    const float* __restrict__ w1, const float* __restrict__ w2,
    float* __restrict__ catT, int N){
  __shared__ float w1aT[3*64];
  __shared__ float wd3T[3*64];
  __shared__ float w2T[64*64];
  __shared__ float aT3[4][3*32];
  __shared__ float s1T[4][64*32];
  const int tid = threadIdx.x, w = tid>>6, lane = tid&63;
  const int oq = lane&7, rg = lane>>3;
  const int o0 = oq*8, r0 = rg*4;
  const int b = blockIdx.y, n0 = blockIdx.x*32;
  for (int i=tid; i<192; i+=256){
    int o = i&63, c = i>>6;
    float a = w1[o*6+c], bb = w1[o*6+3+c];
    w1aT[c*64+o] = a; wd3T[c*64+o] = bb - a;
  }
  for (int i=tid; i<64*64; i+=256){
    int o = i>>6, c = i&63;
    w2T[c*64+o] = w2[o*64+c];
  }
  if (tid < 32){
#pragma unroll
    for (int c=0;c<3;c++) aT3[0][c*32+tid] = xp[((size_t)b*3+c)*N + n0 + tid];
  }
  __syncthreads();
  float base[32];
#pragma unroll
  for (int i=0;i<32;i++) base[i]=0.f;
#pragma unroll
  for (int c=0;c<3;c++){
    float4 w0 = ld4(&wd3T[c*64+o0]), w1v = ld4(&wd3T[c*64+o0+4]);
    float4 av = ld4(&aT3[0][c*32+r0]);
    float wv[8] = {w0.x,w0.y,w0.z,w0.w,w1v.x,w1v.y,w1v.z,w1v.w};
    float rv[4] = {av.x,av.y,av.z,av.w};
#pragma unroll
    for (int oo=0;oo<8;oo++)
#pragma unroll
      for (int rr=0;rr<4;rr++) base[oo*4+rr] = fmaf(wv[oo], rv[rr], base[oo*4+rr]);
  }
  __syncthreads();
  float mx[32];
#pragma unroll
  for (int i=0;i<32;i++) mx[i] = -__builtin_inff();
  const int row = lane&31;
  float g0=0.f, g1=0.f, g2=0.f;
  {
    int m = idxT[((size_t)b*KNN + w)*N + n0 + row];
    if (lane < 32){
      g0 = xp[((size_t)b*3+0)*N + m];
      g1 = xp[((size_t)b*3+1)*N + m];
      g2 = xp[((size_t)b*3+2)*N + m];
    }
  }
  for (int it=0; it<10; it++){
    if (lane < 32){
      aT3[w][0*32+row] = g0;
      aT3[w][1*32+row] = g1;
      aT3[w][2*32+row] = g2;
    }
    if (it+1 < 10){                  // prefetch next gather; latency hides under compute
      int m = idxT[((size_t)b*KNN + (it+1)*4 + w)*N + n0 + row];
      if (lane < 32){
        g0 = xp[((size_t)b*3+0)*N + m];
        g1 = xp[((size_t)b*3+1)*N + m];
        g2 = xp[((size_t)b*3+2)*N + m];
      }
    }
    float acc[32];
#pragma unroll
    for (int i=0;i<32;i++) acc[i] = base[i];
#pragma unroll
    for (int c=0;c<3;c++){
      float4 w0 = ld4(&w1aT[c*64+o0]), w1v = ld4(&w1aT[c*64+o0+4]);
      float4 av = ld4(&aT3[w][c*32+r0]);
      float wv[8] = {w0.x,w0.y,w0.z,w0.w,w1v.x,w1v.y,w1v.z,w1v.w};
      float rv[4] = {av.x,av.y,av.z,av.w};
#pragma unroll
      for (int oo=0;oo<8;oo++)
#pragma unroll
      for (int rr=0;rr<4;rr++) acc[oo*4+rr] = fmaf(wv[oo], rv[rr], acc[oo*4+rr]);
    }
#pragma unroll
    for (int oo=0;oo<8;oo++){
      float4 sv = make_float4(lrelu(acc[oo*4+0]), lrelu(acc[oo*4+1]), lrelu(acc[oo*4+2]), lrelu(acc[oo*4+3]));
      *(float4*)&s1T[w][(o0+oo)*32 + r0] = sv;
    }
    float acc2[32];
#pragma unroll
    for (int i=0;i<32;i++) acc2[i]=0.f;
    for (int c=0;c<64;c++){
      float4 w0 = ld4(&w2T[c*64+o0]), w1v = ld4(&w2T[c*64+o0+4]);
      float4 av = ld4(&s1T[w][c*32+r0]);
      float wv[8] = {w0.x,w0.y,w0.z,w0.w,w1v.x,w1v.y,w1v.z,w1v.w};
      float rv[4] = {av.x,av.y,av.z,av.w};
#pragma unroll
      for (int oo=0;oo<8;oo++)
#pragma unroll
        for (int rr=0;rr<4;rr++) acc2[oo*4+rr] = fmaf(wv[oo], rv[rr], acc2[oo*4+rr]);
    }
#pragma unroll
    for (int i=0;i<32;i++) mx[i] = fmaxf(mx[i], lrelu(acc2[i]));
  }
  __syncthreads();
#pragma unroll
  for (int rr=0;rr<4;rr++){
    float4 a = make_float4(mx[0*4+rr], mx[1*4+rr], mx[2*4+rr], mx[3*4+rr]);
    float4 bq = make_float4(mx[4*4+rr], mx[5*4+rr], mx[6*4+rr], mx[7*4+rr]);
    *(float4*)&s1T[w][(r0+rr)*64 + o0] = a;
    *(float4*)&s1T[w][(r0+rr)*64 + o0 + 4] = bq;
  }
  __syncthreads();
  for (int i=tid; i<2048; i+=256){
    float v = fmaxf(fmaxf(s1T[0][i], s1T[1][i]), fmaxf(s1T[2][i], s1T[3][i]));
    int r = i>>6, o = i&63;
    catT[((size_t)b*N + n0 + r)*192 + o] = v;
  }
}

// ---- edgeC: 64ch -> 64 -> 64, max over k ----
// v3 (R14 champion): 4 waves/block, s1 overwrites aT[w]; 64KB -> 8 waves/CU.
__global__ __launch_bounds__(256) void edgeC_kernel(
    const float* __restrict__ inT, int inOff, const int* __restrict__ idxT,
    const float* __restrict__ w1, const float* __restrict__ w2,
    float* __restrict__ catT, int outOff, int N){
  __shared__ float w1T[64*64];
  __shared__ float w2T[64*64];
  __shared__ float aT[4][64*32];   // gather tile; reused as s1 and as merge stash
  const int tid = threadIdx.x, w = tid>>6, lane = tid&63;
  const int oq = lane&7, rg = lane>>3;
  const int o0 = oq*8, r0 = rg*4;
  const int b = blockIdx.y, n0 = blockIdx.x*32;
  for (int i=tid; i<64*64; i+=256){
    int o = i>>6, c = i&63;
    float a = w1[o*128+c], bb = w1[o*128+64+c];
    w1T[c*64+o] = a; w2T[c*64+o] = bb - a;
  }
  for (int i=tid; i<512; i+=256){
    int p = i>>4, cq = i&15;
    float4 v = ld4(&inT[((size_t)b*N + n0 + p)*192 + inOff + cq*4]);
    aT[0][(cq*4+0)*32+p] = v.x; aT[0][(cq*4+1)*32+p] = v.y;
    aT[0][(cq*4+2)*32+p] = v.z; aT[0][(cq*4+3)*32+p] = v.w;
  }
  __syncthreads();
  float base[32];
#pragma unroll
  for (int i=0;i<32;i++) base[i]=0.f;
  for (int c=0;c<64;c++){
    float4 w0 = ld4(&w2T[c*64+o0]), w1v = ld4(&w2T[c*64+o0+4]);
    float4 av = ld4(&aT[0][c*32+r0]);
    float wv[8] = {w0.x,w0.y,w0.z,w0.w,w1v.x,w1v.y,w1v.z,w1v.w};
    float rv[4] = {av.x,av.y,av.z,av.w};
#pragma unroll
    for (int oo=0;oo<8;oo++)
#pragma unroll
      for (int rr=0;rr<4;rr++) base[oo*4+rr] = fmaf(wv[oo], rv[rr], base[oo*4+rr]);
  }
  __syncthreads();
  for (int i=tid; i<64*64; i+=256){
    int o = i>>6, c = i&63;
    w2T[c*64+o] = w2[o*64+c];
  }
  __syncthreads();                  // also: all waves done reading aT[0] for base
  float mx[32];
#pragma unroll
  for (int i=0;i<32;i++) mx[i] = -__builtin_inff();
  const int row = lane&31, ch = lane>>5;
  float4 g[8];
  {
    int m = idxT[((size_t)b*KNN + w)*N + n0 + row];
    const float* src = &inT[((size_t)b*N + m)*192 + inOff + ch*32];
#pragma unroll
    for (int j=0;j<8;j++) g[j] = ld4(src + j*4);
  }
  for (int it=0; it<10; it++){
#pragma unroll
    for (int j=0;j<8;j++){
      aT[w][(ch*32+j*4+0)*32 + row] = g[j].x;
      aT[w][(ch*32+j*4+1)*32 + row] = g[j].y;
      aT[w][(ch*32+j*4+2)*32 + row] = g[j].z;
      aT[w][(ch*32+j*4+3)*32 + row] = g[j].w;
    }
    if (it+1 < 10){                 // prefetch next gather; latency hides under compute
      int m = idxT[((size_t)b*KNN + (it+1)*4 + w)*N + n0 + row];
      const float* src = &inT[((size_t)b*N + m)*192 + inOff + ch*32];
#pragma unroll
      for (int j=0;j<8;j++) g[j] = ld4(src + j*4);
    }
    float acc[32];
#pragma unroll
    for (int i=0;i<32;i++) acc[i] = base[i];
    for (int c=0;c<64;c++){
      float4 w0 = ld4(&w1T[c*64+o0]), w1v = ld4(&w1T[c*64+o0+4]);
      float4 av = ld4(&aT[w][c*32+r0]);
      float wv[8] = {w0.x,w0.y,w0.z,w0.w,w1v.x,w1v.y,w1v.z,w1v.w};
      float rv[4] = {av.x,av.y,av.z,av.w};
#pragma unroll
      for (int oo=0;oo<8;oo++)
#pragma unroll
        for (int rr=0;rr<4;rr++) acc[oo*4+rr] = fmaf(wv[oo], rv[rr], acc[oo*4+rr]);
    }
    // s1 overwrites aT[w] (gather data dead; wave-local in-order DS keeps ordering)
#pragma unroll
    for (int oo=0;oo<8;oo++){
      float4 sv = make_float4(lrelu(acc[oo*4+0]), lrelu(acc[oo*4+1]), lrelu(acc[oo*4+2]), lrelu(acc[oo*4+3]));
      *(float4*)&aT[w][(o0+oo)*32 + r0] = sv;
    }
    float acc2[32];
#pragma unroll
    for (int i=0;i<32;i++) acc2[i]=0.f;
    for (int c=0;c<64;c++){
      float4 w0 = ld4(&w2T[c*64+o0]), w1v = ld4(&w2T[c*64+o0+4]);
      float4 av = ld4(&aT[w][c*32+r0]);
      float wv[8] = {w0.x,w0.y,w0.z,w0.w,w1v.x,w1v.y,w1v.z,w1v.w};
      float rv[4] = {av.x,av.y,av.z,av.w};
#pragma unroll
      for (int oo=0;oo<8;oo++)
#pragma unroll
        for (int rr=0;rr<4;rr++) acc2[oo*4+rr] = fmaf(wv[oo], rv[rr], acc2[oo*4+rr]);
    }
#pragma unroll
    for (int i=0;i<32;i++) mx[i] = fmaxf(mx[i], lrelu(acc2[i]));
  }
  __syncthreads();                  // all waves done with aT -> reuse as merge stash
#pragma unroll
  for (int rr=0;rr<4;rr++){
    float4 a = make_float4(mx[0*4+rr], mx[1*4+rr], mx[2*4+rr], mx[3*4+rr]);
    float4 bq = make_float4(mx[4*4+rr], mx[5*4+rr], mx[6*4+rr], mx[7*4+rr]);
    *(float4*)&aT[w][(r0+rr)*64 + o0] = a;
    *(float4*)&aT[w][(r0+rr)*64 + o0 + 4] = bq;
  }
  __syncthreads();
  for (int i=tid; i<2048; i+=256){
    float v = fmaxf(fmaxf(aT[0][i], aT[1][i]), fmaxf(aT[2][i], aT[3][i]));
    int r = i>>6, o = i&63;
    catT[((size_t)b*N + n0 + r)*192 + outOff + o] = v;
  }
}

// ---- edgeD: 64ch -> 64 (single conv), max over k ----
// v4 (R12 champion): 4 waves/block, it<10 -> all 40 neighbors; merge via wdT/w1T stash.
__global__ __launch_bounds__(256) void edgeD_kernel(
    const float* __restrict__ inT, int inOff, const int* __restrict__ idxT,
    const float* __restrict__ w1, float* __restrict__ catT, int outOff, int N){
  __shared__ float w1T[64*64];
  __shared__ float wdT[64*64];
  __shared__ float aT[4][64*32];
  const int tid = threadIdx.x, w = tid>>6, lane = tid&63;
  const int oq = lane&7, rg = lane>>3;
  const int o0 = oq*8, r0 = rg*4;
  const int b = blockIdx.y, n0 = blockIdx.x*32;
  for (int i=tid; i<64*64; i+=256){
    int o = i>>6, c = i&63;
    float a = w1[o*128+c], bb = w1[o*128+64+c];
    w1T[c*64+o] = a; wdT[c*64+o] = bb - a;
  }
  for (int i=tid; i<512; i+=256){
    int p = i>>4, cq = i&15;
    float4 v = ld4(&inT[((size_t)b*N + n0 + p)*192 + inOff + cq*4]);
    aT[0][(cq*4+0)*32+p] = v.x; aT[0][(cq*4+1)*32+p] = v.y;
    aT[0][(cq*4+2)*32+p] = v.z; aT[0][(cq*4+3)*32+p] = v.w;
  }
  __syncthreads();
  float base[32];
#pragma unroll
  for (int i=0;i<32;i++) base[i]=0.f;
  for (int c=0;c<64;c++){
    float4 w0 = ld4(&wdT[c*64+o0]), w1v = ld4(&wdT[c*64+o0+4]);
    float4 av = ld4(&aT[0][c*32+r0]);
    float wv[8] = {w0.x,w0.y,w0.z,w0.w,w1v.x,w1v.y,w1v.z,w1v.w};
    float rv[4] = {av.x,av.y,av.z,av.w};
#pragma unroll
    for (int oo=0;oo<8;oo++)
#pragma unroll
      for (int rr=0;rr<4;rr++) base[oo*4+rr] = fmaf(wv[oo], rv[rr], base[oo*4+rr]);
  }
  __syncthreads();
  float mx[32];
#pragma unroll
  for (int i=0;i<32;i++) mx[i] = -__builtin_inff();
  const int row = lane&31, ch = lane>>5;
  float4 g[8];
  {
    int m = idxT[((size_t)b*KNN + w)*N + n0 + row];
    const float* src = &inT[((size_t)b*N + m)*192 + inOff + ch*32];
#pragma unroll
    for (int j=0;j<8;j++) g[j] = ld4(src + j*4);
  }
  for (int it=0; it<10; it++){
#pragma unroll
    for (int j=0;j<8;j++){
      aT[w][(ch*32+j*4+0)*32 + row] = g[j].x;
      aT[w][(ch*32+j*4+1)*32 + row] = g[j].y;
      aT[w][(ch*32+j*4+2)*32 + row] = g[j].z;
      aT[w][(ch*32+j*4+3)*32 + row] = g[j].w;
    }
    if (it+1 < 10){
      int m = idxT[((size_t)b*KNN + (it+1)*4 + w)*N + n0 + row];
      const float* src = &inT[((size_t)b*N + m)*192 + inOff + ch*32];
#pragma unroll
      for (int j=0;j<8;j++) g[j] = ld4(src + j*4);
    }
    float acc[32];
#pragma unroll
    for (int i=0;i<32;i++) acc[i] = base[i];
    for (int c=0;c<64;c++){
      float4 w0 = ld4(&w1T[c*64+o0]), w1v = ld4(&w1T[c*64+o0+4]);
      float4 av = ld4(&aT[w][c*32+r0]);
      float wv[8] = {w0.x,w0.y,w0.z,w0.w,w1v.x,w1v.y,w1v.z,w1v.w};
      float rv[4] = {av.x,av.y,av.z,av.w};
#pragma unroll
      for (int oo=0;oo<8;oo++)
#pragma unroll
        for (int rr=0;rr<4;rr++) acc[oo*4+rr] = fmaf(wv[oo], rv[rr], acc[oo*4+rr]);
    }
#pragma unroll
    for (int i=0;i<32;i++) mx[i] = fmaxf(mx[i], lrelu(acc[i]));
  }
  __syncthreads();   // all waves done reading w1T/wdT -> reuse as merge stash
  {
    float* stash = (w < 2) ? &wdT[w*2048] : &w1T[(w-2)*2048];
#pragma unroll
    for (int rr=0;rr<4;rr++){
      float4 a = make_float4(mx[0*4+rr], mx[1*4+rr], mx[2*4+rr], mx[3*4+rr]);
      float4 bq = make_float4(mx[4*4+rr], mx[5*4+rr], mx[6*4+rr], mx[7*4+rr]);
      *(float4*)&stash[(r0+rr)*64 + o0] = a;
      *(float4*)&stash[(r0+rr)*64 + o0 + 4] = bq;
    }
  }
  __syncthreads();
  for (int i=tid; i<2048; i+=256){
    float v = fmaxf(fmaxf(wdT[i], wdT[2048+i]), fmaxf(w1T[i], w1T[2048+i]));
    int r = i>>6, o = i&63;
    catT[((size_t)b*N + n0 + r)*192 + outOff + o] = v;
  }
}

// ---------------- conv1 (1024 outs) + lrelu + max ----------------
// v6: R15 c-chunked staging + fused global reduction: block result goes to the
// per-batch 1024-wide encoded buffer via atomicMax on an order-preserving uint
// encoding (bijective monotone -> max is EXACT). reduce_max kernels eliminated.
template<int CIN, int TAG>
__global__ __launch_bounds__(128) void convmax_kernel(
    const float* __restrict__ inT, const float* __restrict__ wT,
    unsigned* __restrict__ outE, int N){
  __shared__ float wsh[CIN*32];
  __shared__ float ish[2][32*64];   // per-wave staging, one 64-ch chunk
  const int tid = threadIdx.x, w = tid>>6, lane = tid&63;
  const int oq = lane&7, rg = lane>>3;
  const int o0 = oq*4;
  const int b = blockIdx.z, oc = blockIdx.x, nt = blockIdx.y;
  for (int i=tid; i<CIN*32; i+=128){
    int c = i>>5, o = i&31;
    wsh[i] = wT[(size_t)c*1024 + oc*32 + o];
  }
  __syncthreads();                  // wsh ready; ish is wave-private afterwards
  float mx[16];
#pragma unroll
  for (int i=0;i<16;i++) mx[i] = -__builtin_inff();
  const int nbase = nt*(N/8);
  float* mish = ish[w];
  for (int it=0; it<4; it++){
    const int st = it*2 + w;        // wave w handles tiles {w, w+2, w+4, w+6}
    const float* src = inT + ((size_t)b*N + nbase + st*32)*CIN;
    float acc[16];
#pragma unroll
    for (int i=0;i<16;i++) acc[i]=0.f;
    for (int chn=0; chn<CIN/64; chn++){
      const int cc0 = chn*64;
      for (int i=lane; i<32*16; i+=64){
        int p = i/16, cq = i%16;
        float4 v = ld4(src + p*CIN + cc0 + 4*cq);
        int base = (((p>>2) ^ (cq&7))<<2) + (p&3);
        mish[(4*cq+0)*32 + base] = v.x;
        mish[(4*cq+1)*32 + base] = v.y;
        mish[(4*cq+2)*32 + base] = v.z;
        mish[(4*cq+3)*32 + base] = v.w;
      }
      for (int c=0;c<64;c++){
        float4 w0 = ld4(&wsh[(cc0+c)*32+o0]);
        float4 av = ld4(&mish[c*32 + ((rg ^ ((c>>2)&7))<<2)]);
        float wv[4] = {w0.x,w0.y,w0.z,w0.w};
        float rv[4] = {av.x,av.y,av.z,av.w};
#pragma unroll
        for (int oo=0;oo<4;oo++)
#pragma unroll
          for (int rr=0;rr<4;rr++) acc[oo*4+rr] = fmaf(wv[oo], rv[rr], acc[oo*4+rr]);
      }
    }
#pragma unroll
    for (int i=0;i<16;i++) mx[i] = fmaxf(mx[i], lrelu(acc[i]));
  }
  float m4[4];
#pragma unroll
  for (int oo=0;oo<4;oo++)
    m4[oo] = fmaxf(fmaxf(mx[oo*4+0], mx[oo*4+1]), fmaxf(mx[oo*4+2], mx[oo*4+3]));
  __syncthreads();                  // both waves done with their ish -> reuse ish[0] as merge buffer
  float* mb = ish[0];
  *(float4*)&mb[(w*8+rg)*32 + o0] = make_float4(m4[0],m4[1],m4[2],m4[3]);
  __syncthreads();
  if (tid < 32){
    float v = -__builtin_inff();
#pragma unroll
    for (int g=0; g<16; g++) v = fmaxf(v, mb[g*32+tid]);
    atomicMax(&outE[(size_t)b*1024 + oc*32 + tid], encf(v));
  }
}

// ---------------- fused t-net MLP: 1024 ->512 ->256 ->9 (one launch) ----------------
__global__ __launch_bounds__(512) void tnet_fc_kernel(
    const unsigned* __restrict__ tgE, const float* __restrict__ t_f1,
    const float* __restrict__ t_f2, const float* __restrict__ t_f3w,
    const float* __restrict__ t_f3b, float* __restrict__ T9){
  const int b = blockIdx.x, tid = threadIdx.x;
  __shared__ float in1[1024];
  __shared__ float h512[512];
  __shared__ float h256[256];
  for (int i=tid;i<1024;i+=512) in1[i] = decf(tgE[(size_t)b*1024+i]);
  __syncthreads();
  {
    float s = 0.f;
    for (int c=0;c<1024;c++) s = fmaf(t_f1[(size_t)tid*1024+c], in1[c], s);
    h512[tid] = lrelu(s);
  }
  __syncthreads();
  if (tid < 256){
    float s = 0.f;
    for (int c=0;c<512;c++) s = fmaf(t_f2[(size_t)tid*512+c], h512[c], s);
    h256[tid] = lrelu(s);
  }
  __syncthreads();
  if (tid < 9){
    float s = t_f3b[tid];
    for (int c=0;c<256;c++) s = fmaf(t_f3w[(size_t)tid*256+c], h256[c], s);
    T9[(size_t)b*9+tid] = s;     // stride 9: transform_kernel reads T9 + b*9
  }
}

// ---------------- x' = T^T x per batch ----------------
__global__ void transform_kernel(const float* __restrict__ x, const float* __restrict__ T9,
                                 float* __restrict__ xp, int N){
  int b = blockIdx.y; int n = blockIdx.x*256 + threadIdx.x;
  const float* t = T9 + (size_t)b*9;
  float x0=x[((size_t)b*3+0)*N+n], x1=x[((size_t)b*3+1)*N+n], x2=x[((size_t)b*3+2)*N+n];
#pragma unroll
  for (int i=0;i<3;i++)
    xp[((size_t)b*3+i)*N+n] = t[i]*x0 + t[3+i]*x1 + t[6+i]*x2;
}

// ---------------- bias1: n-invariant part of h1 (lv = fc(l,m2) fused in) ----------------
__global__ void bias1_kernel(const unsigned* __restrict__ gE, const float* __restrict__ l,
                             const float* __restrict__ m2, const float* __restrict__ h1w,
                             float* __restrict__ bias1){
  int b = blockIdx.x;
  __shared__ float insh[1088];
  for (int i=threadIdx.x;i<1024;i+=256) insh[i] = decf(gE[(size_t)b*1024+i]);
  if (threadIdx.x < 64){
    int o = threadIdx.x;
    float s = 0.f;
    for (int c=0;c<16;c++) s = fmaf(m2[(size_t)o*16+c], l[(size_t)b*16+c], s);
    insh[1024+o] = lrelu(s);
  }
  __syncthreads();
  int o = threadIdx.x;
  float s=0.f;
  for (int c=0;c<1088;c++) s = fmaf(h1w[(size_t)o*1280+c], insh[c], s);
  bias1[(size_t)b*256+o]=s;
}

// ---------------- head conv layers -- register-tiled (R13 champion) ----------------
template<int CI, int O, bool ACT>
__global__ __launch_bounds__(128) void conv1_kernel(
    const float* __restrict__ inT, const float* __restrict__ wT,
    const float* __restrict__ bias, float* __restrict__ outT, int N){
  constexpr int CCH = 64;
  constexpr int NCH = CI / CCH;     // 192->3, 256->4
  __shared__ float wsh[CCH*128];    // [c][128 outputs]
  __shared__ float ish[32*CCH];     // [c][32], XOR-swizzled 4-col groups
  const int tid = threadIdx.x, w = tid>>6, lane = tid&63;
  const int o0 = (lane&15)*8;                 // 16 o-groups x 8 = 128 outputs
  const int r0 = w*16 + (lane>>4)*4;          // 4 row-groups x 4 = 16 rows per wave
  const int b = blockIdx.y, n0 = blockIdx.x*32, oc = blockIdx.z;
  const float* src = inT + ((size_t)b*N + n0)*CI;
  float acc[32];
#pragma unroll
  for (int i=0;i<32;i++) acc[i]=0.f;
  for (int ch=0; ch<NCH; ch++){
    const int cc0 = ch*CCH;
    if (ch) __syncthreads();        // prev chunk's compute done before restage
    for (int i=tid; i<CCH*128; i+=128){
      int c = i>>7, od = i&127;
      wsh[i] = wT[(size_t)(cc0+c)*O + oc*128 + od];
    }
    for (int i=tid; i<32*(CCH/4); i+=128){
      int p = i/(CCH/4), cq = i%(CCH/4);
      float4 v = ld4(src + p*CI + cc0 + 4*cq);
      int base = (((p>>2) ^ (cq&7))<<2) + (p&3);
      ish[(4*cq+0)*32 + base] = v.x;
      ish[(4*cq+1)*32 + base] = v.y;
      ish[(4*cq+2)*32 + base] = v.z;
      ish[(4*cq+3)*32 + base] = v.w;
    }
    __syncthreads();
    for (int c=0;c<CCH;c++){
      float4 w0 = ld4(&wsh[c*128+o0]), w1v = ld4(&wsh[c*128+o0+4]);
      float4 av = ld4(&ish[c*32 + (((r0>>2) ^ ((c>>2)&7))<<2)]);   // r0 multiple of 4
      float wv[8] = {w0.x,w0.y,w0.z,w0.w,w1v.x,w1v.y,w1v.z,w1v.w};
      float rv[4] = {av.x,av.y,av.z,av.w};
#pragma unroll
      for (int oo=0;oo<8;oo++)
#pragma unroll
        for (int rr=0;rr<4;rr++) acc[oo*4+rr] = fmaf(wv[oo], rv[rr], acc[oo*4+rr]);
    }
  }
  float bv[8];
  if (bias){
    float4 b0 = ld4(&bias[(size_t)b*O + oc*128 + o0]);
    float4 b1 = ld4(&bias[(size_t)b*O + oc*128 + o0 + 4]);
    bv[0]=b0.x; bv[1]=b0.y; bv[2]=b0.z; bv[3]=b0.w;
    bv[4]=b1.x; bv[5]=b1.y; bv[6]=b1.z; bv[7]=b1.w;
  } else {
#pragma unroll
    for (int i=0;i<8;i++) bv[i]=0.f;
  }
#pragma unroll
  for (int rr=0;rr<4;rr++){
    float oa[8];
#pragma unroll
    for (int oo=0;oo<8;oo++){
      float s = acc[oo*4+rr] + bv[oo];
      oa[oo] = ACT ? lrelu(s) : s;
    }
    float* dst = &outT[((size_t)b*N + n0 + r0 + rr)*O + oc*128 + o0];
    *(float4*)dst     = make_float4(oa[0],oa[1],oa[2],oa[3]);
    *(float4*)(dst+4) = make_float4(oa[4],oa[5],oa[6],oa[7]);
  }
}

// ---------------- final layer: 128 -> 50, rows-layout output (B,50,N) ----------------
__global__ __launch_bounds__(256) void conv_out_kernel(
    const float* __restrict__ inT, const float* __restrict__ wT,
    float* __restrict__ out, int N){
  const int b = blockIdx.y, n0 = blockIdx.x*32;
  __shared__ float insh[32*129];
  const float* src = inT + ((size_t)b*N + n0)*128;
  for (int i=threadIdx.x;i<32*128;i+=256){ int nn=i>>7, c=i&127; insh[nn*129+c]=src[i]; }
  __syncthreads();
  const int nl = threadIdx.x & 31, og = threadIdx.x >> 5;
  float acc[7];
#pragma unroll
  for (int t=0;t<7;t++) acc[t]=0.f;
  for (int c=0;c<128;c++){
    float iv = insh[nl*129+c];
#pragma unroll
    for (int t=0;t<7;t++){
      int o = og + 8*t;
      float wv = (o<50)? wT[c*50+o] : 0.f;
      acc[t] = fmaf(wv, iv, acc[t]);
    }
  }
#pragma unroll
  for (int t=0;t<7;t++){
    int o = og + 8*t;
    if (o < 50) out[((size_t)b*50+o)*N + n0 + nl] = acc[t];
  }
}

extern "C" void kernel_launch(void* const* d_in, const int* in_sizes, int n_in,
                              void* d_out, int out_size, void* d_ws, size_t ws_size,
                              hipStream_t stream){
  const float* x    = (const float*)d_in[0];
  const float* l    = (const float*)d_in[1];
  const float* t_c1 = (const float*)d_in[2];
  const float* t_c2 = (const float*)d_in[3];
  const float* t_c3 = (const float*)d_in[4];
  const float* t_f1 = (const float*)d_in[5];
  const float* t_f2 = (const float*)d_in[6];
  const float* t_f3w= (const float*)d_in[7];
  const float* t_f3b= (const float*)d_in[8];
  const float* b1a  = (const float*)d_in[9];
  const float* b1b  = (const float*)d_in[10];
  const float* b2a  = (const float*)d_in[11];
  const float* b2b  = (const float*)d_in[12];
  const float* b3a  = (const float*)d_in[13];
  const float* m1   = (const float*)d_in[14];
  const float* m2   = (const float*)d_in[15];
  const float* h1   = (const float*)d_in[16];
  const float* h2   = (const float*)d_in[17];
  const float* h3   = (const float*)d_in[18];
  const float* h4   = (const float*)d_in[19];
  float* out = (float*)d_out;
  float* ws = (float*)d_ws;
  const int N = NPTS, B = BATCH;

  size_t off = 0;
  auto alloc = [&](size_t nf){ float* p = ws + off; off += nf; return p; };
  float* WT_TC3 = alloc((size_t)128*1024);
  float* WT_M1  = alloc((size_t)192*1024);
  float* WT_H1B = alloc((size_t)192*256);
  float* WT_H2  = alloc((size_t)256*256);
  float* WT_H3  = alloc((size_t)256*128);
  float* WT_H4  = alloc((size_t)128*64);
  int*   IDXT   = (int*)alloc((size_t)B*N*KNN);
  float* XX     = alloc((size_t)B*N);
  float* TT     = alloc((size_t)B*N*128);
  unsigned* TGE = (unsigned*)alloc((size_t)B*1024);
  unsigned* GE  = (unsigned*)alloc((size_t)B*1024);
  float* T9     = alloc((size_t)B*16);
  float* XP     = alloc((size_t)B*3*N);
  float* CATT   = alloc((size_t)B*N*192);
  float* BIAS1  = alloc((size_t)B*256);
  float* H1T    = alloc((size_t)B*N*256);
  float* H2T    = alloc((size_t)B*N*256);
  float* H3T    = alloc((size_t)B*N*128);
  (void)ws_size; (void)in_sizes; (void)n_in; (void)out_size;

  dim3 blk(256);
  dim3 eblk(128);
  // 6 weight transposes + TGE/GE init (enc(-inf)) in one launch
  transpose6_kernel<<<dim3(768,7), blk, 0, stream>>>(
      t_c3, WT_TC3, m1, WT_M1, h1, WT_H1B, h2, WT_H2, h3, WT_H3, h4, WT_H4, TGE, GE);

  // t-path
  norms_rows_kernel<0><<<dim3(N/256,B), blk, 0, stream>>>(x, XX, N);
  knn3_kernel<0><<<dim3(N/4,B), blk, 0, stream>>>(x, XX, IDXT, N);
  edgeA_kernel<<<dim3(N/16,B), blk, 0, stream>>>(x, IDXT, t_c1, t_c2, TT, N);
  convmax_kernel<128,0><<<dim3(32,8,B), eblk, 0, stream>>>(TT, WT_TC3, TGE, N);
  tnet_fc_kernel<<<dim3(B), dim3(512), 0, stream>>>(TGE, t_f1, t_f2, t_f3w, t_f3b, T9);
  transform_kernel<<<dim3(N/256,B), blk, 0, stream>>>(x, T9, XP, N);

  // edge block 1 (transformed points, 3ch)
  norms_rows_kernel<1><<<dim3(N/256,B), blk, 0, stream>>>(XP, XX, N);
  knn3_kernel<1><<<dim3(N/4,B), blk, 0, stream>>>(XP, XX, IDXT, N);
  edgeB_kernel<<<dim3(N/32,B), dim3(256), 0, stream>>>(XP, IDXT, b1a, b1b, CATT, N);

  // edge block 2 (x1 = CATT[...,0:64])
  norms_cl_kernel<0><<<dim3(N/256,B), blk, 0, stream>>>(CATT, 0, XX, N);
  knn64_kernel<0><<<dim3(N/4,B), blk, 0, stream>>>(CATT, 0, XX, IDXT, N);
  edgeC_kernel<<<dim3(N/32,B), dim3(256), 0, stream>>>(CATT, 0, IDXT, b2a, b2b, CATT, 64, N);

  // edge block 3 (x2 = CATT[...,64:128])
  norms_cl_kernel<1><<<dim3(N/256,B), blk, 0, stream>>>(CATT, 64, XX, N);
  knn64_kernel<1><<<dim3(N/4,B), blk, 0, stream>>>(CATT, 64, XX, IDXT, N);
  edgeD_kernel<<<dim3(N/32,B), dim3(256), 0, stream>>>(CATT, 64, IDXT, b3a, CATT, 128, N);

  // global feature + head
  convmax_kernel<192,1><<<dim3(32,8,B), eblk, 0, stream>>>(CATT, WT_M1, GE, N);
  bias1_kernel<<<dim3(B), blk, 0, stream>>>(GE, l, m2, h1, BIAS1);
  conv1_kernel<192,256,true><<<dim3(N/32,B,2), eblk, 0, stream>>>(CATT, WT_H1B, BIAS1, H1T, N);
  conv1_kernel<256,256,true><<<dim3(N/32,B,2), eblk, 0, stream>>>(H1T, WT_H2, nullptr, H2T, N);
  conv1_kernel<256,128,true><<<dim3(N/32,B,1), eblk, 0, stream>>>(H2T, WT_H3, nullptr, H3T, N);
  conv_out_kernel<<<dim3(N/32,B), blk, 0, stream>>>(H3T, WT_H4, out, N);
}